// Round 4
// baseline (2771.352 us; speedup 1.0000x reference)
//
#include <hip/hip_runtime.h>

// ACGI_32195074850822 — round 3: double-bf16 (hi+lo) split GEMM everywhere the
// error budget demands it. Harness compares on the bf16 grid with threshold
// 2% of ref absmax; single-bf16 operand roundings accumulated to 2.23%.
// gemm_nt<AS,BS,EPI>: A/B given as 1 or 2 bf16 components; <2,2> computes
// AhBh + AhBl + AlBh (~16-bit mantissa). Workspace ~211 MB (<= proven 217).

#define B_ 8
#define N_ 1024
#define D_ 512
#define L_ 4

typedef short s8v __attribute__((ext_vector_type(8)));
typedef short s4v __attribute__((ext_vector_type(4)));
typedef float f4v __attribute__((ext_vector_type(4)));

__device__ __forceinline__ unsigned short f2b(float f) {
  unsigned u = __builtin_bit_cast(unsigned, f);
  u += 0x7FFFu + ((u >> 16) & 1u);          // round-to-nearest-even
  return (unsigned short)(u >> 16);
}
__device__ __forceinline__ float b2f(short s) {
  unsigned u = ((unsigned)(unsigned short)s) << 16;
  return __builtin_bit_cast(float, u);
}

enum {
  EPI_B16_BIAS = 0,        // bf16 out = acc + bias
  EPI_SPLIT_BIAS,          // hi bf16 -> C, lo bf16 -> C2, of (acc + bias)
  EPI_SPLIT_SCALE,         // hi/lo of acc * alpha
  EPI_F32_SCALE,           // f32  out = acc * alpha
  EPI_F32_ACC,             // f32  out += acc
  EPI_F32_BIAS_RF32,       // f32  out = acc + bias + R(f32)
  EPI_F32_LEAKY_BIAS_RF32, // f32  out = leaky(acc + bias) + R(f32)
  EPI_BOTH_LEAKY_BIAS      // bf16 out AND f32 out2 = leaky(acc + bias)
};

// C[M,Nn] = (ΣA_c)(ΣB_c)^T with components in bf16; skips Al*Bl when both
// split. NT layout: B stored Nn x K row-major. M,Nn mult of 128, K mult of 32.
template<int AS, int BS, int EPI>
__global__ __launch_bounds__(256) void gemm_nt(
    const short* __restrict__ A0, const short* __restrict__ A1, long sA,
    const short* __restrict__ B0, const short* __restrict__ B1, long sB,
    void* __restrict__ Cv, long sC, void* __restrict__ C2v,
    const float* __restrict__ bias, const void* __restrict__ Rv,
    float alpha, int M, int Nn, int K)
{
  __shared__ short lA[AS][128][40];   // +8 pad
  __shared__ short lB[BS][128][40];
  const int z = blockIdx.z;
  const int tm = blockIdx.x * 128;
  const int tn = blockIdx.y * 128;
  const int tid = threadIdx.x;
  const int lane = tid & 63;
  const int w = tid >> 6;
  const int wr = (w >> 1) * 64, wc = (w & 1) * 64;
  const int r16 = lane & 15, kg = lane >> 4;
  const int srow = tid >> 1, scol = (tid & 1) * 16;

  const short* ga[AS];
  const short* gb[BS];
  ga[0] = A0 + (size_t)z * sA + (size_t)(tm + srow) * K + scol;
  if constexpr (AS == 2) ga[1] = A1 + (size_t)z * sA + (size_t)(tm + srow) * K + scol;
  gb[0] = B0 + (size_t)z * sB + (size_t)(tn + srow) * K + scol;
  if constexpr (BS == 2) gb[1] = B1 + (size_t)z * sB + (size_t)(tn + srow) * K + scol;

  f4v acc[4][4];
  #pragma unroll
  for (int i = 0; i < 4; i++)
    #pragma unroll
    for (int j = 0; j < 4; j++) acc[i][j] = (f4v)0.f;

  s8v pa[AS][2], pb[BS][2];
  #pragma unroll
  for (int c = 0; c < AS; c++) { pa[c][0] = *(const s8v*)ga[c]; pa[c][1] = *(const s8v*)(ga[c] + 8); }
  #pragma unroll
  for (int c = 0; c < BS; c++) { pb[c][0] = *(const s8v*)gb[c]; pb[c][1] = *(const s8v*)(gb[c] + 8); }

  for (int k0 = 0; k0 < K; k0 += 32) {
    __syncthreads();
    #pragma unroll
    for (int c = 0; c < AS; c++) {
      *(s8v*)&lA[c][srow][scol]     = pa[c][0];
      *(s8v*)&lA[c][srow][scol + 8] = pa[c][1];
    }
    #pragma unroll
    for (int c = 0; c < BS; c++) {
      *(s8v*)&lB[c][srow][scol]     = pb[c][0];
      *(s8v*)&lB[c][srow][scol + 8] = pb[c][1];
    }
    __syncthreads();
    if (k0 + 32 < K) {
      #pragma unroll
      for (int c = 0; c < AS; c++) {
        ga[c] += 32;
        pa[c][0] = *(const s8v*)ga[c]; pa[c][1] = *(const s8v*)(ga[c] + 8);
      }
      #pragma unroll
      for (int c = 0; c < BS; c++) {
        gb[c] += 32;
        pb[c][0] = *(const s8v*)gb[c]; pb[c][1] = *(const s8v*)(gb[c] + 8);
      }
    }
    s8v va[AS][4], vb[BS][4];
    #pragma unroll
    for (int c = 0; c < AS; c++)
      #pragma unroll
      for (int i = 0; i < 4; i++) va[c][i] = *(const s8v*)&lA[c][wr + i * 16 + r16][kg * 8];
    #pragma unroll
    for (int c = 0; c < BS; c++)
      #pragma unroll
      for (int i = 0; i < 4; i++) vb[c][i] = *(const s8v*)&lB[c][wc + i * 16 + r16][kg * 8];
    #pragma unroll
    for (int ca = 0; ca < AS; ca++)
      #pragma unroll
      for (int cb = 0; cb < BS; cb++) {
        if (ca == 1 && cb == 1) continue;   // drop lo*lo (compile-time folded)
        #pragma unroll
        for (int mi = 0; mi < 4; mi++)
          #pragma unroll
          for (int ni = 0; ni < 4; ni++)
            acc[mi][ni] = __builtin_amdgcn_mfma_f32_16x16x32_bf16(va[ca][mi], vb[cb][ni], acc[mi][ni], 0, 0, 0);
      }
  }

  short* Cs = (short*)Cv;
  float* Cf = (float*)Cv;
  float* C2f = (float*)C2v;
  short* C2s = (short*)C2v;
  const float* Rf = (const float*)Rv;
  #pragma unroll
  for (int mi = 0; mi < 4; mi++) {
    #pragma unroll
    for (int ni = 0; ni < 4; ni++) {
      const int col = tn + wc + ni * 16 + r16;
      float bv = 0.f;
      if constexpr (EPI == EPI_B16_BIAS || EPI == EPI_SPLIT_BIAS ||
                    EPI == EPI_F32_BIAS_RF32 || EPI == EPI_F32_LEAKY_BIAS_RF32 ||
                    EPI == EPI_BOTH_LEAKY_BIAS)
        bv = bias[col];
      #pragma unroll
      for (int r = 0; r < 4; r++) {
        const int row = tm + wr + mi * 16 + kg * 4 + r;   // verified C/D layout
        const size_t idx = (size_t)z * sC + (size_t)row * Nn + col;
        const float v = acc[mi][ni][r];
        if constexpr (EPI == EPI_B16_BIAS)  Cs[idx] = (short)f2b(v + bv);
        else if constexpr (EPI == EPI_SPLIT_BIAS) {
          float t = v + bv;
          short h = (short)f2b(t);
          Cs[idx] = h;
          C2s[idx] = (short)f2b(t - b2f(h));
        }
        else if constexpr (EPI == EPI_SPLIT_SCALE) {
          float t = v * alpha;
          short h = (short)f2b(t);
          Cs[idx] = h;
          C2s[idx] = (short)f2b(t - b2f(h));
        }
        else if constexpr (EPI == EPI_F32_SCALE) Cf[idx] = v * alpha;
        else if constexpr (EPI == EPI_F32_ACC)   Cf[idx] += v;
        else if constexpr (EPI == EPI_F32_BIAS_RF32) Cf[idx] = v + bv + Rf[idx];
        else if constexpr (EPI == EPI_F32_LEAKY_BIAS_RF32) {
          float t = v + bv; t = (t >= 0.f) ? t : 0.01f * t;
          Cf[idx] = t + Rf[idx];
        } else { // EPI_BOTH_LEAKY_BIAS
          float t = v + bv; t = (t >= 0.f) ? t : 0.01f * t;
          Cs[idx] = (short)f2b(t);
          C2f[idx] = t;
        }
      }
    }
  }
}

// f32 (z,D,D) -> bf16 transposed, single: dst[z][j][i] = bf16(src[z][i][j])
__global__ __launch_bounds__(256) void wt_cvt_t(const float* __restrict__ src,
                                                short* __restrict__ dst) {
  __shared__ float t[32][33];
  const int bx = blockIdx.x * 32, by = blockIdx.y * 32;
  const size_t zo = (size_t)blockIdx.z * D_ * D_;
  const int tx = threadIdx.x, ty = threadIdx.y;
  #pragma unroll
  for (int k = 0; k < 4; k++)
    t[ty + 8 * k][tx] = src[zo + (size_t)(by + ty + 8 * k) * D_ + bx + tx];
  __syncthreads();
  #pragma unroll
  for (int k = 0; k < 4; k++)
    dst[zo + (size_t)(bx + ty + 8 * k) * D_ + by + tx] = (short)f2b(t[tx][ty + 8 * k]);
}

// f32 (z,D,D) -> bf16 transposed hi+lo
__global__ __launch_bounds__(256) void wt_cvt_t2(const float* __restrict__ src,
                                                 short* __restrict__ hi,
                                                 short* __restrict__ lo) {
  __shared__ float t[32][33];
  const int bx = blockIdx.x * 32, by = blockIdx.y * 32;
  const size_t zo = (size_t)blockIdx.z * D_ * D_;
  const int tx = threadIdx.x, ty = threadIdx.y;
  #pragma unroll
  for (int k = 0; k < 4; k++)
    t[ty + 8 * k][tx] = src[zo + (size_t)(by + ty + 8 * k) * D_ + bx + tx];
  __syncthreads();
  #pragma unroll
  for (int k = 0; k < 4; k++) {
    const size_t o = zo + (size_t)(bx + ty + 8 * k) * D_ + by + tx;
    float v = t[tx][ty + 8 * k];
    short h = (short)f2b(v);
    hi[o] = h;
    lo[o] = (short)f2b(v - b2f(h));
  }
}

// bf16 (B,N,D) -> (B,D,N)
__global__ __launch_bounds__(256) void tr_b16(const short* __restrict__ src,
                                              short* __restrict__ dst) {
  __shared__ short t[32][33];
  const int bx = blockIdx.x * 32;   // d tile
  const int by = blockIdx.y * 32;   // n tile
  const size_t zo = (size_t)blockIdx.z * N_ * D_;
  const int tx = threadIdx.x, ty = threadIdx.y;
  #pragma unroll
  for (int k = 0; k < 4; k++)
    t[ty + 8 * k][tx] = src[zo + (size_t)(by + ty + 8 * k) * D_ + bx + tx];
  __syncthreads();
  #pragma unroll
  for (int k = 0; k < 4; k++)
    dst[zo + (size_t)(bx + ty + 8 * k) * N_ + by + tx] = t[tx][ty + 8 * k];
}

// f32 * scale -> hi bf16 + lo bf16
__global__ __launch_bounds__(256) void split_f32(const float* __restrict__ src,
                                                 short* __restrict__ hi,
                                                 short* __restrict__ lo, float scale) {
  const size_t i = ((size_t)blockIdx.x * 256 + threadIdx.x) * 4;
  f4v v = *(const f4v*)(src + i);
  s4v h, l;
  #pragma unroll
  for (int j = 0; j < 4; j++) {
    float t = v[j] * scale;
    h[j] = (short)f2b(t);
    l[j] = (short)f2b(t - b2f(h[j]));
  }
  *(s4v*)(hi + i) = h;
  *(s4v*)(lo + i) = l;
}

// sum = a + b (f32): write bf16 + f32
__global__ __launch_bounds__(256) void add_both(const float* __restrict__ a,
                                                const float* __restrict__ b,
                                                short* __restrict__ outb,
                                                float* __restrict__ outf) {
  const size_t i = ((size_t)blockIdx.x * 256 + threadIdx.x) * 4;
  f4v av = *(const f4v*)(a + i);
  f4v bv = *(const f4v*)(b + i);
  f4v s; s4v o;
  #pragma unroll
  for (int j = 0; j < 4; j++) { s[j] = av[j] + bv[j]; o[j] = (short)f2b(s[j]); }
  *(f4v*)(outf + i) = s;
  *(s4v*)(outb + i) = o;
}

// softmax over rows of 1024 f32 -> bf16
__global__ __launch_bounds__(256) void softmax_rows(const float* __restrict__ src,
                                                    short* __restrict__ dst) {
  __shared__ float red[256];
  const size_t base = (size_t)blockIdx.x * 1024;
  const int tid = threadIdx.x;
  f4v v = *(const f4v*)(src + base + tid * 4);
  float m = fmaxf(fmaxf(v[0], v[1]), fmaxf(v[2], v[3]));
  red[tid] = m; __syncthreads();
  for (int s = 128; s > 0; s >>= 1) {
    if (tid < s) red[tid] = fmaxf(red[tid], red[tid + s]);
    __syncthreads();
  }
  const float mx = red[0]; __syncthreads();
  float e0 = __expf(v[0] - mx), e1 = __expf(v[1] - mx);
  float e2 = __expf(v[2] - mx), e3 = __expf(v[3] - mx);
  red[tid] = e0 + e1 + e2 + e3; __syncthreads();
  for (int s = 128; s > 0; s >>= 1) {
    if (tid < s) red[tid] += red[tid + s];
    __syncthreads();
  }
  const float inv = 1.f / red[0];
  s4v o;
  o[0] = (short)f2b(e0 * inv); o[1] = (short)f2b(e1 * inv);
  o[2] = (short)f2b(e2 * inv); o[3] = (short)f2b(e3 * inv);
  *(s4v*)(dst + base + tid * 4) = o;
}

// L2-normalize over axis=1 (N axis) of (B,N,D) f32, deterministic 3-phase.
#define NCHUNK 16
__global__ __launch_bounds__(256) void norm_part(const float* __restrict__ t,
                                                 float* __restrict__ part) {
  const int d = blockIdx.x * 256 + threadIdx.x;
  const int b = blockIdx.y;
  const int c = blockIdx.z;
  const int n0 = c * (N_ / NCHUNK);
  const float* p = t + ((size_t)b * N_ + n0) * D_ + d;
  float ss = 0.f;
  for (int n = 0; n < N_ / NCHUNK; n++) { float v = p[(size_t)n * D_]; ss += v * v; }
  part[((size_t)c * B_ + b) * D_ + d] = ss;
}
__global__ __launch_bounds__(256) void norm_inv(const float* __restrict__ part,
                                                float* __restrict__ inv) {
  const int i = blockIdx.x * 256 + threadIdx.x;
  float ss = 0.f;
  for (int c = 0; c < NCHUNK; c++) ss += part[(size_t)c * (B_ * D_) + i];
  inv[i] = 1.f / fmaxf(sqrtf(ss), 1e-12f);
}
// writes hi bf16, lo bf16, f32
__global__ __launch_bounds__(256) void norm_scale(const float* __restrict__ t,
                                                  const float* __restrict__ inv,
                                                  short* __restrict__ outh,
                                                  short* __restrict__ outl,
                                                  float* __restrict__ outf) {
  const size_t i = ((size_t)blockIdx.x * 256 + threadIdx.x) * 4;
  const int b = (int)(i >> 19);        // N_*D_ = 2^19
  const int d = (int)(i & (D_ - 1));
  f4v v = *(const f4v*)(t + i);
  f4v w = *(const f4v*)(inv + (size_t)b * D_ + d);
  f4v o; s4v oh, ol;
  #pragma unroll
  for (int j = 0; j < 4; j++) {
    o[j] = v[j] * w[j];
    oh[j] = (short)f2b(o[j]);
    ol[j] = (short)f2b(o[j] - b2f(oh[j]));
  }
  *(f4v*)(outf + i) = o;
  *(s4v*)(outh + i) = oh;
  *(s4v*)(outl + i) = ol;
}

extern "C" void kernel_launch(void* const* d_in, const int* in_sizes, int n_in,
                              void* d_out, int out_size, void* d_ws, size_t ws_size,
                              hipStream_t stream) {
  (void)in_sizes; (void)n_in; (void)out_size; (void)ws_size;
  const float* in1f = (const float*)d_in[0];
  const float* in2f = (const float*)d_in[1];

  const size_t SB = (size_t)B_ * N_ * D_ * 2;      // 8 MB bf16 act
  const size_t SF = (size_t)B_ * N_ * D_ * 4;      // 16 MB f32 act
  const size_t WL = (size_t)L_ * D_ * D_ * 2;      // 2 MB
  const size_t W1 = (size_t)D_ * D_ * 2;           // 0.5 MB
  const size_t SAF32 = (size_t)B_ * N_ * N_ * 4;   // 32 MB
  const size_t SAB16 = (size_t)B_ * N_ * N_ * 2;   // 16 MB

  char* ws = (char*)d_ws;
  size_t off = 0;
  auto alloc = [&](size_t bytes) -> char* {
    char* p = ws + off;
    off += (bytes + 255) & ~(size_t)255;
    return p;
  };

  // ---- weight region: stage-1 splits (19 MB), later overlaid by a1/a2 ----
  char* wreg = alloc(8 * WL + 6 * W1);
  short* c_thT_h = (short*)(wreg);
  short* c_thT_l = (short*)(wreg + WL);
  short* c_phT_h = (short*)(wreg + 2 * WL);
  short* c_phT_l = (short*)(wreg + 3 * WL);
  short* c_rhT_h = (short*)(wreg + 4 * WL);
  short* c_rhT_l = (short*)(wreg + 5 * WL);
  short* c_psT_h = (short*)(wreg + 6 * WL);
  short* c_psT_l = (short*)(wreg + 7 * WL);
  short* c_intT_h = (short*)(wreg + 8 * WL);
  short* c_intT_l = (short*)(wreg + 8 * WL + W1);
  short* c_f1T_h  = (short*)(wreg + 8 * WL + 2 * W1);
  short* c_f1T_l  = (short*)(wreg + 8 * WL + 3 * W1);
  short* c_f2T_h  = (short*)(wreg + 8 * WL + 4 * W1);
  short* c_f2T_l  = (short*)(wreg + 8 * WL + 5 * W1);
  // overlay (converted AFTER stage 1; stage-1 weights dead by then)
  short* a1_thT = (short*)(wreg);
  short* a1_phT = (short*)(wreg + WL);
  short* a1_rhT = (short*)(wreg + 2 * WL);
  short* a2_thT = (short*)(wreg + 3 * WL);
  short* a2_phT = (short*)(wreg + 4 * WL);
  short* a2_rhT = (short*)(wreg + 5 * WL);
  char*  aw = wreg + 6 * WL;
  short* a1_intT_h = (short*)(aw);
  short* a1_intT_l = (short*)(aw + W1);
  short* a1_f1T_h  = (short*)(aw + 2 * W1);
  short* a1_f1T_l  = (short*)(aw + 3 * W1);
  short* a1_f2T_h  = (short*)(aw + 4 * W1);
  short* a1_f2T_l  = (short*)(aw + 5 * W1);
  short* a2_intT_h = (short*)(aw + 6 * W1);
  short* a2_intT_l = (short*)(aw + 7 * W1);
  short* a2_f1T_h  = (short*)(aw + 8 * W1);
  short* a2_f1T_l  = (short*)(aw + 9 * W1);
  short* a2_f2T_h  = (short*)(aw + 10 * W1);
  short* a2_f2T_l  = (short*)(aw + 11 * W1);

  // ---- activations ----
  short* in1h = (short*)alloc(SB);
  short* in1l = (short*)alloc(SB);
  short* in2h = (short*)alloc(SB);
  short* in2l = (short*)alloc(SB);
  short* thh  = (short*)alloc(SB);
  short* thl  = (short*)alloc(SB);
  short* phh  = (short*)alloc(SB);
  short* phl  = (short*)alloc(SB);
  short* tmpb = (short*)alloc(SB);
  short* rhTb = (short*)alloc(SB);
  // aliases (liveness-checked against launch order):
  short* feed1 = in1h;   // in1 split dead after stage-1 layer loop
  short* feed2 = in2h;
  short* resh  = in1l;
  short* resl  = in2l;
  short* hidh  = thh;    // th dead after last aff GEMM
  short* hidl  = thl;
  short* self1 = phl;    // phl dead after stage 1 (agi uses single ph in phh)
  short* inth  = rhTb;   // dead after last apply of the phase
  short* intl  = tmpb;

  // affinity union (48 MB)
  char* affU = alloc(SAF32 + SAB16);
  float* aff32 = (float*)affU;               // [0,32) agi logits
  float* resf  = (float*)affU;               // [0,16) after affs dead
  short* affl  = (short*)(affU + SAB16);     // [16,32) stage-1 lo
  short* affh  = (short*)(affU + SAF32);     // [32,48) stage-1 hi / agi P

  float* acc1   = (float*)alloc(SF);
  float* acc2   = (float*)alloc(SF);
  float* feed1f = (float*)alloc(SF);
  float* feed2f = (float*)alloc(SF);
  float* tmpf   = acc1;            // acc1 raw dead after its split_f32
  float* self1f = acc2;            // acc2 dead after stream-2 epilogue
  float* self2f = feed1f;          // feed1f dead after agi1 residual read
  float* sumf   = feed2f;          // feed2f dead after agi2 residual read
  short* psTb   = (short*)feed1f;  // stage-1 loop only; feed1f written later

  float* npart = (float*)alloc((size_t)NCHUNK * B_ * D_ * 4);
  float* ninv  = (float*)alloc((size_t)B_ * D_ * 4);
  // total ≈ 19 + 80 + 48 + 64 + 0.3 ≈ 211 MB

  const float scl = 0.04419417382415922f;   // 512^-0.5
  const long sAct = (long)N_ * D_;
  const long sAff = (long)N_ * N_;
  dim3 tb(32, 8);
  const int GE = (B_ * N_ * D_) / (4 * 256);

  const float* bia = nullptr;
  #define F32P(i) ((const float*)d_in[i])

  // ---- stage-1 weight conversion (split) + input split ----
  wt_cvt_t2<<<dim3(16,16,L_), tb, 0, stream>>>(F32P(2),  c_thT_h, c_thT_l);
  wt_cvt_t2<<<dim3(16,16,L_), tb, 0, stream>>>(F32P(4),  c_phT_h, c_phT_l);
  wt_cvt_t2<<<dim3(16,16,L_), tb, 0, stream>>>(F32P(6),  c_rhT_h, c_rhT_l);
  wt_cvt_t2<<<dim3(16,16,L_), tb, 0, stream>>>(F32P(8),  c_psT_h, c_psT_l);
  wt_cvt_t2<<<dim3(16,16,1),  tb, 0, stream>>>(F32P(10), c_intT_h, c_intT_l);
  wt_cvt_t2<<<dim3(16,16,1),  tb, 0, stream>>>(F32P(12), c_f1T_h, c_f1T_l);
  wt_cvt_t2<<<dim3(16,16,1),  tb, 0, stream>>>(F32P(14), c_f2T_h, c_f2T_l);
  split_f32<<<GE, 256, 0, stream>>>(in1f, in1h, in1l, 1.0f);
  split_f32<<<GE, 256, 0, stream>>>(in2f, in2h, in2l, 1.0f);

  hipMemsetAsync(acc1, 0, SF, stream);
  hipMemsetAsync(acc2, 0, SF, stream);

  auto normalize = [&](const float* src, short* outh, short* outl, float* outf) {
    norm_part<<<dim3(D_/256, B_, NCHUNK), 256, 0, stream>>>(src, npart);
    norm_inv<<<(B_*D_)/256, 256, 0, stream>>>(npart, ninv);
    norm_scale<<<GE, 256, 0, stream>>>(src, ninv, outh, outl, outf);
  };

  // ---- stage 1: cross-attention (no softmax), full split precision ----
  for (int i = 0; i < L_; i++) {
    const size_t wo = (size_t)i * D_ * D_;
    const size_t bo = (size_t)i * D_;
    gemm_nt<2,2,EPI_SPLIT_BIAS><<<dim3(64,4,1),256,0,stream>>>(in1h,in1l,0, c_thT_h+wo,c_thT_l+wo,0, thh,0, thl, F32P(3)+bo, nullptr, 0.f, 8192,512,512);
    gemm_nt<2,2,EPI_SPLIT_BIAS><<<dim3(64,4,1),256,0,stream>>>(in2h,in2l,0, c_phT_h+wo,c_phT_l+wo,0, phh,0, phl, F32P(5)+bo, nullptr, 0.f, 8192,512,512);
    gemm_nt<2,2,EPI_B16_BIAS><<<dim3(64,4,1),256,0,stream>>>(in1h,in1l,0, c_rhT_h+wo,c_rhT_l+wo,0, tmpb,0, nullptr, F32P(7)+bo, nullptr, 0.f, 8192,512,512);
    tr_b16<<<dim3(16,32,B_), tb, 0, stream>>>(tmpb, rhTb);
    gemm_nt<2,2,EPI_B16_BIAS><<<dim3(64,4,1),256,0,stream>>>(in2h,in2l,0, c_psT_h+wo,c_psT_l+wo,0, tmpb,0, nullptr, F32P(9)+bo, nullptr, 0.f, 8192,512,512);
    tr_b16<<<dim3(16,32,B_), tb, 0, stream>>>(tmpb, psTb);
    gemm_nt<2,2,EPI_SPLIT_SCALE><<<dim3(8,8,B_),256,0,stream>>>(thh,thl,sAct, phh,phl,sAct, affh,sAff, affl, bia, nullptr, scl, 1024,1024,512);
    gemm_nt<2,1,EPI_F32_ACC><<<dim3(8,4,B_),256,0,stream>>>(affh,affl,sAff, rhTb,nullptr,sAct, acc1,sAct, nullptr, bia, nullptr, 0.f, 1024,512,1024);
    gemm_nt<2,1,EPI_F32_ACC><<<dim3(8,4,B_),256,0,stream>>>(affh,affl,sAff, psTb,nullptr,sAct, acc2,sAct, nullptr, bia, nullptr, 0.f, 1024,512,1024);
  }

  // stream-1 epilogue
  split_f32<<<GE, 256, 0, stream>>>(acc1, inth, intl, 0.25f);
  gemm_nt<2,2,EPI_F32_BIAS_RF32><<<dim3(64,4,1),256,0,stream>>>(inth,intl,0, c_intT_h,c_intT_l,0, tmpf,0, nullptr, F32P(11), in1f, 0.f, 8192,512,512);
  normalize(tmpf, resh, resl, resf);
  gemm_nt<2,2,EPI_SPLIT_BIAS><<<dim3(64,4,1),256,0,stream>>>(resh,resl,0, c_f1T_h,c_f1T_l,0, hidh,0, hidl, F32P(13), nullptr, 0.f, 8192,512,512);
  gemm_nt<2,2,EPI_BOTH_LEAKY_BIAS><<<dim3(64,4,1),256,0,stream>>>(hidh,hidl,0, c_f2T_h,c_f2T_l,0, feed1,0, feed1f, F32P(15), nullptr, 0.f, 8192,512,512);
  // stream-2 epilogue
  split_f32<<<GE, 256, 0, stream>>>(acc2, inth, intl, 0.25f);
  gemm_nt<2,2,EPI_F32_BIAS_RF32><<<dim3(64,4,1),256,0,stream>>>(inth,intl,0, c_intT_h,c_intT_l,0, tmpf,0, nullptr, F32P(11), in2f, 0.f, 8192,512,512);
  normalize(tmpf, resh, resl, resf);
  gemm_nt<2,2,EPI_SPLIT_BIAS><<<dim3(64,4,1),256,0,stream>>>(resh,resl,0, c_f1T_h,c_f1T_l,0, hidh,0, hidl, F32P(13), nullptr, 0.f, 8192,512,512);
  gemm_nt<2,2,EPI_BOTH_LEAKY_BIAS><<<dim3(64,4,1),256,0,stream>>>(hidh,hidl,0, c_f2T_h,c_f2T_l,0, feed2,0, feed2f, F32P(15), nullptr, 0.f, 8192,512,512);

  // ---- a1/a2 weight conversion (overlays dead stage-1 weights) ----
  wt_cvt_t<<<dim3(16,16,L_), tb, 0, stream>>>(F32P(16), a1_thT);
  wt_cvt_t<<<dim3(16,16,L_), tb, 0, stream>>>(F32P(18), a1_phT);
  wt_cvt_t<<<dim3(16,16,L_), tb, 0, stream>>>(F32P(20), a1_rhT);
  wt_cvt_t2<<<dim3(16,16,1), tb, 0, stream>>>(F32P(22), a1_intT_h, a1_intT_l);
  wt_cvt_t2<<<dim3(16,16,1), tb, 0, stream>>>(F32P(24), a1_f1T_h, a1_f1T_l);
  wt_cvt_t2<<<dim3(16,16,1), tb, 0, stream>>>(F32P(26), a1_f2T_h, a1_f2T_l);
  wt_cvt_t<<<dim3(16,16,L_), tb, 0, stream>>>(F32P(28), a2_thT);
  wt_cvt_t<<<dim3(16,16,L_), tb, 0, stream>>>(F32P(30), a2_phT);
  wt_cvt_t<<<dim3(16,16,L_), tb, 0, stream>>>(F32P(32), a2_rhT);
  wt_cvt_t2<<<dim3(16,16,1), tb, 0, stream>>>(F32P(34), a2_intT_h, a2_intT_l);
  wt_cvt_t2<<<dim3(16,16,1), tb, 0, stream>>>(F32P(36), a2_f1T_h, a2_f1T_l);
  wt_cvt_t2<<<dim3(16,16,1), tb, 0, stream>>>(F32P(38), a2_f2T_h, a2_f2T_l);

  // ---- _agi block: proj/softmax single-bf16; int & FFN paths split ----
  auto agi = [&](const short* xb, const float* xf,
                 const short* thT, const float* thB,
                 const short* phT, const float* phB,
                 const short* rhT, const float* rhB,
                 const short* inTh, const short* inTl, const float* inB,
                 const short* f1Th, const short* f1Tl, const float* f1B,
                 const short* f2Th, const short* f2Tl, const float* f2B,
                 short* outb, short* outlo, float* outf) {
    hipMemsetAsync(acc1, 0, SF, stream);
    for (int i = 0; i < L_; i++) {
      const size_t wo = (size_t)i * D_ * D_;
      const size_t bo = (size_t)i * D_;
      gemm_nt<1,1,EPI_B16_BIAS><<<dim3(64,4,1),256,0,stream>>>(xb,nullptr,0, thT+wo,nullptr,0, thh,0, nullptr, thB+bo, nullptr, 0.f, 8192,512,512);
      gemm_nt<1,1,EPI_B16_BIAS><<<dim3(64,4,1),256,0,stream>>>(xb,nullptr,0, phT+wo,nullptr,0, phh,0, nullptr, phB+bo, nullptr, 0.f, 8192,512,512);
      gemm_nt<1,1,EPI_B16_BIAS><<<dim3(64,4,1),256,0,stream>>>(xb,nullptr,0, rhT+wo,nullptr,0, tmpb,0, nullptr, rhB+bo, nullptr, 0.f, 8192,512,512);
      tr_b16<<<dim3(16,32,B_), tb, 0, stream>>>(tmpb, rhTb);
      gemm_nt<1,1,EPI_F32_SCALE><<<dim3(8,8,B_),256,0,stream>>>(thh,nullptr,sAct, phh,nullptr,sAct, aff32,sAff, nullptr, bia, nullptr, scl, 1024,1024,512);
      softmax_rows<<<B_*N_, 256, 0, stream>>>(aff32, affh);
      gemm_nt<1,1,EPI_F32_ACC><<<dim3(8,4,B_),256,0,stream>>>(affh,nullptr,sAff, rhTb,nullptr,sAct, acc1,sAct, nullptr, bia, nullptr, 0.f, 1024,512,1024);
    }
    split_f32<<<GE, 256, 0, stream>>>(acc1, inth, intl, 0.25f);
    gemm_nt<2,2,EPI_F32_BIAS_RF32><<<dim3(64,4,1),256,0,stream>>>(inth,intl,0, inTh,inTl,0, tmpf,0, nullptr, inB, xf, 0.f, 8192,512,512);
    normalize(tmpf, resh, resl, resf);
    gemm_nt<2,2,EPI_SPLIT_BIAS><<<dim3(64,4,1),256,0,stream>>>(resh,resl,0, f1Th,f1Tl,0, hidh,0, hidl, f1B, nullptr, 0.f, 8192,512,512);
    gemm_nt<2,2,EPI_F32_LEAKY_BIAS_RF32><<<dim3(64,4,1),256,0,stream>>>(hidh,hidl,0, f2Th,f2Tl,0, tmpf,0, nullptr, f2B, resf, 0.f, 8192,512,512);
    normalize(tmpf, outb, outlo, outf);
  };

  // self1/self2 both use AGI_1 weights (faithful to reference)
  agi(feed1, feed1f, a1_thT,F32P(17), a1_phT,F32P(19), a1_rhT,F32P(21),
      a1_intT_h,a1_intT_l,F32P(23), a1_f1T_h,a1_f1T_l,F32P(25),
      a1_f2T_h,a1_f2T_l,F32P(27), thh, thl, self1f);
  agi(feed2, feed2f, a1_thT,F32P(17), a1_phT,F32P(19), a1_rhT,F32P(21),
      a1_intT_h,a1_intT_l,F32P(23), a1_f1T_h,a1_f1T_l,F32P(25),
      a1_f2T_h,a1_f2T_l,F32P(27), thh, thl, self2f);
  add_both<<<GE, 256, 0, stream>>>(self1f, self2f, self1, sumf);
  agi(self1, sumf, a2_thT,F32P(29), a2_phT,F32P(31), a2_rhT,F32P(33),
      a2_intT_h,a2_intT_l,F32P(35), a2_f1T_h,a2_f1T_l,F32P(37),
      a2_f2T_h,a2_f2T_l,F32P(39), thh, thl, (float*)d_out);
}

// Round 5
// 2537.606 us; speedup vs baseline: 1.0921x; 1.0921x over previous
//
#include <hip/hip_runtime.h>

// ACGI_32195074850822 — round 4: schedule/memory optimization, numerics frozen.
//  * global_load_lds (16B) staging, linear LDS + both-sides XOR swizzle
//  * fused GEMMs (th|rh, ph|ps, agi th|ph|rh, apply acc1|acc2) for >=2 blocks/CU
//  * transposed-write epilogue kills all tr_b16 dispatches
// Precision config identical to round 3 (passed at absmax 2.44e-3).

#define B_ 8
#define N_ 1024
#define D_ 512
#define L_ 4

typedef short s8v __attribute__((ext_vector_type(8)));
typedef short s4v __attribute__((ext_vector_type(4)));
typedef float f4v __attribute__((ext_vector_type(4)));

__device__ __forceinline__ unsigned short f2b(float f) {
  unsigned u = __builtin_bit_cast(unsigned, f);
  u += 0x7FFFu + ((u >> 16) & 1u);          // round-to-nearest-even
  return (unsigned short)(u >> 16);
}
__device__ __forceinline__ float b2f(short s) {
  unsigned u = ((unsigned)(unsigned short)s) << 16;
  return __builtin_bit_cast(float, u);
}

__device__ __forceinline__ void glds16(const short* g, short* l) {
  __builtin_amdgcn_global_load_lds(
      (const __attribute__((address_space(1))) void*)g,
      (__attribute__((address_space(3))) void*)l, 16, 0, 0);
}

enum {
  EPI_SPLIT_BIAS = 0,      // hi bf16 -> C0, lo bf16 -> C0b of (acc + bias)
  EPI_SPLIT_SCALE,         // hi/lo of acc * alpha
  EPI_F32_SCALE,           // f32 C0 = acc * alpha
  EPI_F32_ACC,             // f32 C0 += acc
  EPI_F32_BIAS_RF32,       // f32 C0 = acc + bias + R
  EPI_F32_LEAKY_BIAS_RF32, // f32 C0 = leaky(acc + bias) + R
  EPI_BOTH_LEAKY_BIAS,     // bf16 C0 AND f32 C0b = leaky(acc + bias)
  EPI_SEG2_SPLIT_TR,       // seg0: split->C0/C0b; seg1: bf16 transposed->C1
  EPI_SEG3_B16_TR,         // seg0->C0, seg1->C1 (bf16); seg2: bf16 transposed->C2
  EPI_SEG2_ACC             // seg0: C0 +=; seg1: C1 +=
};

struct GArgs {
  const short* A0; const short* A1; long sA;
  const short* B0h; const short* B0l;
  const short* B1h; const short* B1l;
  const short* B2h; const short* B2l; long sB;
  void* C0; void* C0b; void* C1; void* C2; long sC;
  const float* bias0; const float* bias1; const float* bias2;
  const void* Rv;
  float alpha;
  int Nn, K;               // Nn = C row stride for non-seg EPIs (seg uses 512)
};

// C = (ΣA_c)(ΣB_c)^T, bf16 comps, f32 accum; <2,2> drops Al*Bl.
// NT: B stored rows x K. Tiles 128x128, 4 waves. Staging: global_load_lds 16B,
// linear LDS [128][32] with XOR-swizzled source + reads (2-way, free).
template<int AS, int BS, int EPI>
__global__ __launch_bounds__(256) void gemm_k(GArgs g) {
  __shared__ short lA[AS][128][32];
  __shared__ short lB[BS][128][32];
  constexpr bool SEG = (EPI == EPI_SEG2_SPLIT_TR || EPI == EPI_SEG3_B16_TR ||
                        EPI == EPI_SEG2_ACC);
  const int z = blockIdx.z;
  const int tm = blockIdx.x * 128;
  const int tn = blockIdx.y * 128;
  const int tid = threadIdx.x;
  const int lane = tid & 63;
  const int w = tid >> 6;
  const int wr = (w >> 1) * 64, wc = (w & 1) * 64;
  const int r16 = lane & 15, kg = lane >> 4;
  const int K = g.K;

  int seg = 0, tnl = tn;
  if constexpr (SEG) { seg = tn >> 9; tnl = tn & 511; }
  const short* Bh;
  const short* Blo = nullptr;
  if constexpr (SEG) {
    Bh = seg == 0 ? g.B0h : (seg == 1 ? g.B1h : g.B2h);
    if constexpr (BS == 2) Blo = seg == 0 ? g.B0l : (seg == 1 ? g.B1l : g.B2l);
  } else {
    Bh = g.B0h;
    if constexpr (BS == 2) Blo = g.B0l;
  }

  // staging: wave w stages rows [w*16,w*16+16) and [64+w*16, ...).
  // lane l -> LDS row base+(l>>2), slot l&3; source slot pre-swizzled.
  const int srow = lane >> 2;
  const int scol = ((lane & 3) ^ ((lane >> 3) & 3)) * 8;
  const short* gA[2]; const short* gB[2];
  gA[0] = g.A0 + (size_t)z * g.sA + (size_t)(tm + w * 16 + srow) * K + scol;
  if constexpr (AS == 2)
    gA[1] = g.A1 + (size_t)z * g.sA + (size_t)(tm + w * 16 + srow) * K + scol;
  gB[0] = Bh + (size_t)z * g.sB + (size_t)(tnl + w * 16 + srow) * K + scol;
  if constexpr (BS == 2)
    gB[1] = Blo + (size_t)z * g.sB + (size_t)(tnl + w * 16 + srow) * K + scol;
  const size_t hoff = (size_t)64 * K;

  short* la[2][2]; short* lb[2][2];
  #pragma unroll
  for (int c = 0; c < AS; c++) {
    la[c][0] = &lA[c][w * 16][0];
    la[c][1] = &lA[c][64 + w * 16][0];
  }
  #pragma unroll
  for (int c = 0; c < BS; c++) {
    lb[c][0] = &lB[c][w * 16][0];
    lb[c][1] = &lB[c][64 + w * 16][0];
  }

  f4v acc[4][4];
  #pragma unroll
  for (int i = 0; i < 4; i++)
    #pragma unroll
    for (int j = 0; j < 4; j++) acc[i][j] = (f4v)0.f;

  const int rc = (kg ^ ((r16 >> 1) & 3)) * 8;   // swizzled read col (elements)

  for (int k0 = 0; k0 < K; k0 += 32) {
    #pragma unroll
    for (int c = 0; c < AS; c++) {
      glds16(gA[c] + k0, la[c][0]);
      glds16(gA[c] + hoff + k0, la[c][1]);
    }
    #pragma unroll
    for (int c = 0; c < BS; c++) {
      glds16(gB[c] + k0, lb[c][0]);
      glds16(gB[c] + hoff + k0, lb[c][1]);
    }
    __syncthreads();          // drains vmcnt: staged tile visible
    s8v va[2][4], vb[2][4];
    #pragma unroll
    for (int c = 0; c < AS; c++)
      #pragma unroll
      for (int i = 0; i < 4; i++)
        va[c][i] = *(const s8v*)&lA[c][wr + i * 16 + r16][rc];
    #pragma unroll
    for (int c = 0; c < BS; c++)
      #pragma unroll
      for (int i = 0; i < 4; i++)
        vb[c][i] = *(const s8v*)&lB[c][wc + i * 16 + r16][rc];
    #pragma unroll
    for (int ca = 0; ca < AS; ca++)
      #pragma unroll
      for (int cb = 0; cb < BS; cb++) {
        if (ca == 1 && cb == 1) continue;   // drop lo*lo
        #pragma unroll
        for (int mi = 0; mi < 4; mi++)
          #pragma unroll
          for (int ni = 0; ni < 4; ni++)
            acc[mi][ni] = __builtin_amdgcn_mfma_f32_16x16x32_bf16(
                va[ca][mi], vb[cb][ni], acc[mi][ni], 0, 0, 0);
      }
    __syncthreads();          // LDS reads done before next overwrite
  }

  short* C0s = (short*)g.C0;  float* C0f = (float*)g.C0;
  short* C0bs = (short*)g.C0b; float* C0bf = (float*)g.C0b;
  short* C1s = (short*)g.C1;  float* C1f = (float*)g.C1;
  short* C2s = (short*)g.C2;
  const float* Rf = (const float*)g.Rv;

  #pragma unroll
  for (int mi = 0; mi < 4; mi++) {
    #pragma unroll
    for (int ni = 0; ni < 4; ni++) {
      const int colL = tnl + wc + ni * 16 + r16;
      const int grow0 = tm + wr + mi * 16 + kg * 4;   // +r, verified C/D layout
      if constexpr (EPI == EPI_SEG2_SPLIT_TR) {
        if (seg == 0) {
          const float bv = g.bias0[colL];
          #pragma unroll
          for (int r = 0; r < 4; r++) {
            const size_t idx = (size_t)(grow0 + r) * 512 + colL;
            float t = acc[mi][ni][r] + bv;
            short h = (short)f2b(t);
            C0s[idx] = h;
            C0bs[idx] = (short)f2b(t - b2f(h));
          }
        } else {
          const float bv = g.bias1[colL];
          s4v o;
          #pragma unroll
          for (int r = 0; r < 4; r++) o[r] = (short)f2b(acc[mi][ni][r] + bv);
          const int b = grow0 >> 10, n = grow0 & 1023;
          *(s4v*)&C1s[(size_t)b * (D_ * N_) + (size_t)colL * N_ + n] = o;
        }
      } else if constexpr (EPI == EPI_SEG3_B16_TR) {
        if (seg == 2) {
          const float bv = g.bias2[colL];
          s4v o;
          #pragma unroll
          for (int r = 0; r < 4; r++) o[r] = (short)f2b(acc[mi][ni][r] + bv);
          const int b = grow0 >> 10, n = grow0 & 1023;
          *(s4v*)&C2s[(size_t)b * (D_ * N_) + (size_t)colL * N_ + n] = o;
        } else {
          const float bv = (seg == 0 ? g.bias0 : g.bias1)[colL];
          short* Cp = seg == 0 ? C0s : C1s;
          #pragma unroll
          for (int r = 0; r < 4; r++)
            Cp[(size_t)(grow0 + r) * 512 + colL] = (short)f2b(acc[mi][ni][r] + bv);
        }
      } else if constexpr (EPI == EPI_SEG2_ACC) {
        float* Cp = seg == 0 ? C0f : C1f;
        #pragma unroll
        for (int r = 0; r < 4; r++)
          Cp[(size_t)z * g.sC + (size_t)(grow0 + r) * 512 + colL] += acc[mi][ni][r];
      } else {
        float bv = 0.f;
        if constexpr (EPI == EPI_SPLIT_BIAS || EPI == EPI_F32_BIAS_RF32 ||
                      EPI == EPI_F32_LEAKY_BIAS_RF32 || EPI == EPI_BOTH_LEAKY_BIAS)
          bv = g.bias0[colL];
        #pragma unroll
        for (int r = 0; r < 4; r++) {
          const size_t idx = (size_t)z * g.sC + (size_t)(grow0 + r) * g.Nn + colL;
          const float v = acc[mi][ni][r];
          if constexpr (EPI == EPI_SPLIT_BIAS) {
            float t = v + bv;
            short h = (short)f2b(t);
            C0s[idx] = h;
            C0bs[idx] = (short)f2b(t - b2f(h));
          } else if constexpr (EPI == EPI_SPLIT_SCALE) {
            float t = v * g.alpha;
            short h = (short)f2b(t);
            C0s[idx] = h;
            C0bs[idx] = (short)f2b(t - b2f(h));
          } else if constexpr (EPI == EPI_F32_SCALE) C0f[idx] = v * g.alpha;
          else if constexpr (EPI == EPI_F32_ACC)     C0f[idx] += v;
          else if constexpr (EPI == EPI_F32_BIAS_RF32) C0f[idx] = v + bv + Rf[idx];
          else if constexpr (EPI == EPI_F32_LEAKY_BIAS_RF32) {
            float t = v + bv; t = (t >= 0.f) ? t : 0.01f * t;
            C0f[idx] = t + Rf[idx];
          } else { // EPI_BOTH_LEAKY_BIAS
            float t = v + bv; t = (t >= 0.f) ? t : 0.01f * t;
            C0s[idx] = (short)f2b(t);
            C0bf[idx] = t;
          }
        }
      }
    }
  }
}

// f32 (z,D,D) -> bf16 transposed, single
__global__ __launch_bounds__(256) void wt_cvt_t(const float* __restrict__ src,
                                                short* __restrict__ dst) {
  __shared__ float t[32][33];
  const int bx = blockIdx.x * 32, by = blockIdx.y * 32;
  const size_t zo = (size_t)blockIdx.z * D_ * D_;
  const int tx = threadIdx.x, ty = threadIdx.y;
  #pragma unroll
  for (int k = 0; k < 4; k++)
    t[ty + 8 * k][tx] = src[zo + (size_t)(by + ty + 8 * k) * D_ + bx + tx];
  __syncthreads();
  #pragma unroll
  for (int k = 0; k < 4; k++)
    dst[zo + (size_t)(bx + ty + 8 * k) * D_ + by + tx] = (short)f2b(t[tx][ty + 8 * k]);
}

// f32 (z,D,D) -> bf16 transposed hi+lo
__global__ __launch_bounds__(256) void wt_cvt_t2(const float* __restrict__ src,
                                                 short* __restrict__ hi,
                                                 short* __restrict__ lo) {
  __shared__ float t[32][33];
  const int bx = blockIdx.x * 32, by = blockIdx.y * 32;
  const size_t zo = (size_t)blockIdx.z * D_ * D_;
  const int tx = threadIdx.x, ty = threadIdx.y;
  #pragma unroll
  for (int k = 0; k < 4; k++)
    t[ty + 8 * k][tx] = src[zo + (size_t)(by + ty + 8 * k) * D_ + bx + tx];
  __syncthreads();
  #pragma unroll
  for (int k = 0; k < 4; k++) {
    const size_t o = zo + (size_t)(bx + ty + 8 * k) * D_ + by + tx;
    float v = t[tx][ty + 8 * k];
    short h = (short)f2b(v);
    hi[o] = h;
    lo[o] = (short)f2b(v - b2f(h));
  }
}

// f32 * scale -> hi bf16 + lo bf16
__global__ __launch_bounds__(256) void split_f32(const float* __restrict__ src,
                                                 short* __restrict__ hi,
                                                 short* __restrict__ lo, float scale) {
  const size_t i = ((size_t)blockIdx.x * 256 + threadIdx.x) * 4;
  f4v v = *(const f4v*)(src + i);
  s4v h, l;
  #pragma unroll
  for (int j = 0; j < 4; j++) {
    float t = v[j] * scale;
    h[j] = (short)f2b(t);
    l[j] = (short)f2b(t - b2f(h[j]));
  }
  *(s4v*)(hi + i) = h;
  *(s4v*)(lo + i) = l;
}

// sum = a + b (f32): write bf16 + f32
__global__ __launch_bounds__(256) void add_both(const float* __restrict__ a,
                                                const float* __restrict__ b,
                                                short* __restrict__ outb,
                                                float* __restrict__ outf) {
  const size_t i = ((size_t)blockIdx.x * 256 + threadIdx.x) * 4;
  f4v av = *(const f4v*)(a + i);
  f4v bv = *(const f4v*)(b + i);
  f4v s; s4v o;
  #pragma unroll
  for (int j = 0; j < 4; j++) { s[j] = av[j] + bv[j]; o[j] = (short)f2b(s[j]); }
  *(f4v*)(outf + i) = s;
  *(s4v*)(outb + i) = o;
}

// softmax over rows of 1024 f32 -> bf16
__global__ __launch_bounds__(256) void softmax_rows(const float* __restrict__ src,
                                                    short* __restrict__ dst) {
  __shared__ float red[256];
  const size_t base = (size_t)blockIdx.x * 1024;
  const int tid = threadIdx.x;
  f4v v = *(const f4v*)(src + base + tid * 4);
  float m = fmaxf(fmaxf(v[0], v[1]), fmaxf(v[2], v[3]));
  red[tid] = m; __syncthreads();
  for (int s = 128; s > 0; s >>= 1) {
    if (tid < s) red[tid] = fmaxf(red[tid], red[tid + s]);
    __syncthreads();
  }
  const float mx = red[0]; __syncthreads();
  float e0 = __expf(v[0] - mx), e1 = __expf(v[1] - mx);
  float e2 = __expf(v[2] - mx), e3 = __expf(v[3] - mx);
  red[tid] = e0 + e1 + e2 + e3; __syncthreads();
  for (int s = 128; s > 0; s >>= 1) {
    if (tid < s) red[tid] += red[tid + s];
    __syncthreads();
  }
  const float inv = 1.f / red[0];
  s4v o;
  o[0] = (short)f2b(e0 * inv); o[1] = (short)f2b(e1 * inv);
  o[2] = (short)f2b(e2 * inv); o[3] = (short)f2b(e3 * inv);
  *(s4v*)(dst + base + tid * 4) = o;
}

// L2-normalize over axis=1 (N axis) of (B,N,D) f32, deterministic 3-phase.
#define NCHUNK 16
__global__ __launch_bounds__(256) void norm_part(const float* __restrict__ t,
                                                 float* __restrict__ part) {
  const int d = blockIdx.x * 256 + threadIdx.x;
  const int b = blockIdx.y;
  const int c = blockIdx.z;
  const int n0 = c * (N_ / NCHUNK);
  const float* p = t + ((size_t)b * N_ + n0) * D_ + d;
  float ss = 0.f;
  for (int n = 0; n < N_ / NCHUNK; n++) { float v = p[(size_t)n * D_]; ss += v * v; }
  part[((size_t)c * B_ + b) * D_ + d] = ss;
}
__global__ __launch_bounds__(256) void norm_inv(const float* __restrict__ part,
                                                float* __restrict__ inv) {
  const int i = blockIdx.x * 256 + threadIdx.x;
  float ss = 0.f;
  for (int c = 0; c < NCHUNK; c++) ss += part[(size_t)c * (B_ * D_) + i];
  inv[i] = 1.f / fmaxf(sqrtf(ss), 1e-12f);
}
__global__ __launch_bounds__(256) void norm_scale(const float* __restrict__ t,
                                                  const float* __restrict__ inv,
                                                  short* __restrict__ outh,
                                                  short* __restrict__ outl,
                                                  float* __restrict__ outf) {
  const size_t i = ((size_t)blockIdx.x * 256 + threadIdx.x) * 4;
  const int b = (int)(i >> 19);        // N_*D_ = 2^19
  const int d = (int)(i & (D_ - 1));
  f4v v = *(const f4v*)(t + i);
  f4v w = *(const f4v*)(inv + (size_t)b * D_ + d);
  f4v o; s4v oh, ol;
  #pragma unroll
  for (int j = 0; j < 4; j++) {
    o[j] = v[j] * w[j];
    oh[j] = (short)f2b(o[j]);
    ol[j] = (short)f2b(o[j] - b2f(oh[j]));
  }
  *(f4v*)(outf + i) = o;
  *(s4v*)(outh + i) = oh;
  *(s4v*)(outl + i) = ol;
}

extern "C" void kernel_launch(void* const* d_in, const int* in_sizes, int n_in,
                              void* d_out, int out_size, void* d_ws, size_t ws_size,
                              hipStream_t stream) {
  (void)in_sizes; (void)n_in; (void)out_size; (void)ws_size;
  const float* in1f = (const float*)d_in[0];
  const float* in2f = (const float*)d_in[1];

  const size_t SB = (size_t)B_ * N_ * D_ * 2;      // 8 MB
  const size_t SF = (size_t)B_ * N_ * D_ * 4;      // 16 MB
  const size_t WL = (size_t)L_ * D_ * D_ * 2;      // 2 MB
  const size_t W1 = (size_t)D_ * D_ * 2;           // 0.5 MB
  const size_t SAF32 = (size_t)B_ * N_ * N_ * 4;   // 32 MB
  const size_t SAB16 = (size_t)B_ * N_ * N_ * 2;   // 16 MB

  char* ws = (char*)d_ws;
  size_t off = 0;
  auto alloc = [&](size_t bytes) -> char* {
    char* p = ws + off;
    off += (bytes + 255) & ~(size_t)255;
    return p;
  };

  // ---- weight region (19 MB), a1/a2 overlay after stage 1 ----
  char* wreg = alloc(8 * WL + 6 * W1);
  short* c_thT_h = (short*)(wreg);
  short* c_thT_l = (short*)(wreg + WL);
  short* c_phT_h = (short*)(wreg + 2 * WL);
  short* c_phT_l = (short*)(wreg + 3 * WL);
  short* c_rhT_h = (short*)(wreg + 4 * WL);
  short* c_rhT_l = (short*)(wreg + 5 * WL);
  short* c_psT_h = (short*)(wreg + 6 * WL);
  short* c_psT_l = (short*)(wreg + 7 * WL);
  short* c_intT_h = (short*)(wreg + 8 * WL);
  short* c_intT_l = (short*)(wreg + 8 * WL + W1);
  short* c_f1T_h  = (short*)(wreg + 8 * WL + 2 * W1);
  short* c_f1T_l  = (short*)(wreg + 8 * WL + 3 * W1);
  short* c_f2T_h  = (short*)(wreg + 8 * WL + 4 * W1);
  short* c_f2T_l  = (short*)(wreg + 8 * WL + 5 * W1);
  short* a1_thT = (short*)(wreg);
  short* a1_phT = (short*)(wreg + WL);
  short* a1_rhT = (short*)(wreg + 2 * WL);
  short* a2_thT = (short*)(wreg + 3 * WL);
  short* a2_phT = (short*)(wreg + 4 * WL);
  short* a2_rhT = (short*)(wreg + 5 * WL);
  char*  aw = wreg + 6 * WL;
  short* a1_intT_h = (short*)(aw);
  short* a1_intT_l = (short*)(aw + W1);
  short* a1_f1T_h  = (short*)(aw + 2 * W1);
  short* a1_f1T_l  = (short*)(aw + 3 * W1);
  short* a1_f2T_h  = (short*)(aw + 4 * W1);
  short* a1_f2T_l  = (short*)(aw + 5 * W1);
  short* a2_intT_h = (short*)(aw + 6 * W1);
  short* a2_intT_l = (short*)(aw + 7 * W1);
  short* a2_f1T_h  = (short*)(aw + 8 * W1);
  short* a2_f1T_l  = (short*)(aw + 9 * W1);
  short* a2_f2T_h  = (short*)(aw + 10 * W1);
  short* a2_f2T_l  = (short*)(aw + 11 * W1);

  // ---- activations (identical to round 3 layout) ----
  short* in1h = (short*)alloc(SB);
  short* in1l = (short*)alloc(SB);
  short* in2h = (short*)alloc(SB);
  short* in2l = (short*)alloc(SB);
  short* thh  = (short*)alloc(SB);
  short* thl  = (short*)alloc(SB);
  short* phh  = (short*)alloc(SB);
  short* phl  = (short*)alloc(SB);
  short* tmpb = (short*)alloc(SB);
  short* rhTb = (short*)alloc(SB);
  short* feed1 = in1h;
  short* feed2 = in2h;
  short* resh  = in1l;
  short* resl  = in2l;
  short* hidh  = thh;
  short* hidl  = thl;
  short* self1 = phl;
  short* inth  = rhTb;
  short* intl  = tmpb;

  char* affU = alloc(SAF32 + SAB16);
  float* aff32 = (float*)affU;
  float* resf  = (float*)affU;
  short* affl  = (short*)(affU + SAB16);
  short* affh  = (short*)(affU + SAF32);

  float* acc1   = (float*)alloc(SF);
  float* acc2   = (float*)alloc(SF);
  float* feed1f = (float*)alloc(SF);
  float* feed2f = (float*)alloc(SF);
  float* tmpf   = acc1;
  float* self1f = acc2;
  float* self2f = feed1f;
  float* sumf   = feed2f;
  short* psTb   = (short*)feed1f;   // stage-1 loop only

  float* npart = (float*)alloc((size_t)NCHUNK * B_ * D_ * 4);
  float* ninv  = (float*)alloc((size_t)B_ * D_ * 4);

  const float scl = 0.04419417382415922f;   // 512^-0.5
  const long sAct = (long)N_ * D_;
  const long sAff = (long)N_ * N_;
  dim3 tb(32, 8);
  const int GE = (B_ * N_ * D_) / (4 * 256);
  #define F32P(i) ((const float*)d_in[i])

  // ---- stage-1 weight conversion + input split ----
  wt_cvt_t2<<<dim3(16,16,L_), tb, 0, stream>>>(F32P(2),  c_thT_h, c_thT_l);
  wt_cvt_t2<<<dim3(16,16,L_), tb, 0, stream>>>(F32P(4),  c_phT_h, c_phT_l);
  wt_cvt_t2<<<dim3(16,16,L_), tb, 0, stream>>>(F32P(6),  c_rhT_h, c_rhT_l);
  wt_cvt_t2<<<dim3(16,16,L_), tb, 0, stream>>>(F32P(8),  c_psT_h, c_psT_l);
  wt_cvt_t2<<<dim3(16,16,1),  tb, 0, stream>>>(F32P(10), c_intT_h, c_intT_l);
  wt_cvt_t2<<<dim3(16,16,1),  tb, 0, stream>>>(F32P(12), c_f1T_h, c_f1T_l);
  wt_cvt_t2<<<dim3(16,16,1),  tb, 0, stream>>>(F32P(14), c_f2T_h, c_f2T_l);
  split_f32<<<GE, 256, 0, stream>>>(in1f, in1h, in1l, 1.0f);
  split_f32<<<GE, 256, 0, stream>>>(in2f, in2h, in2l, 1.0f);

  hipMemsetAsync(acc1, 0, SF, stream);
  hipMemsetAsync(acc2, 0, SF, stream);

  auto normalize = [&](const float* src, short* outh, short* outl, float* outf) {
    norm_part<<<dim3(D_/256, B_, NCHUNK), 256, 0, stream>>>(src, npart);
    norm_inv<<<(B_*D_)/256, 256, 0, stream>>>(npart, ninv);
    norm_scale<<<GE, 256, 0, stream>>>(src, ninv, outh, outl, outf);
  };

  auto GA = [&]() { GArgs a; __builtin_memset(&a, 0, sizeof(a)); return a; };

  // ---- stage 1 ----
  for (int i = 0; i < L_; i++) {
    const size_t wo = (size_t)i * D_ * D_;
    const size_t bo = (size_t)i * D_;
    { // th | rh fused (stream 1): seg0 split -> thh/thl, seg1 TR -> rhTb
      GArgs a = GA();
      a.A0 = in1h; a.A1 = in1l;
      a.B0h = c_thT_h + wo; a.B0l = c_thT_l + wo;
      a.B1h = c_rhT_h + wo; a.B1l = c_rhT_l + wo;
      a.C0 = thh; a.C0b = thl; a.C1 = rhTb;
      a.bias0 = F32P(3) + bo; a.bias1 = F32P(7) + bo;
      a.Nn = 512; a.K = 512;
      gemm_k<2,2,EPI_SEG2_SPLIT_TR><<<dim3(64,8,1),256,0,stream>>>(a);
    }
    { // ph | ps fused (stream 2): seg0 split -> phh/phl, seg1 TR -> psTb
      GArgs a = GA();
      a.A0 = in2h; a.A1 = in2l;
      a.B0h = c_phT_h + wo; a.B0l = c_phT_l + wo;
      a.B1h = c_psT_h + wo; a.B1l = c_psT_l + wo;
      a.C0 = phh; a.C0b = phl; a.C1 = psTb;
      a.bias0 = F32P(5) + bo; a.bias1 = F32P(9) + bo;
      a.Nn = 512; a.K = 512;
      gemm_k<2,2,EPI_SEG2_SPLIT_TR><<<dim3(64,8,1),256,0,stream>>>(a);
    }
    { // affinity, split hi/lo output
      GArgs a = GA();
      a.A0 = thh; a.A1 = thl; a.sA = sAct;
      a.B0h = phh; a.B0l = phl; a.sB = sAct;
      a.C0 = affh; a.C0b = affl; a.sC = sAff;
      a.alpha = scl; a.Nn = 1024; a.K = 512;
      gemm_k<2,2,EPI_SPLIT_SCALE><<<dim3(8,8,B_),256,0,stream>>>(a);
    }
    { // fused applies: seg0 -> acc1, seg1 -> acc2
      GArgs a = GA();
      a.A0 = affh; a.A1 = affl; a.sA = sAff;
      a.B0h = rhTb; a.B1h = psTb; a.sB = sAct;
      a.C0 = acc1; a.C1 = acc2; a.sC = sAct;
      a.Nn = 512; a.K = 1024;
      gemm_k<2,1,EPI_SEG2_ACC><<<dim3(8,8,B_),256,0,stream>>>(a);
    }
  }

  auto epilogue1 = [&](float* accN, const float* inN, short* feedb, float* feedf) {
    split_f32<<<GE, 256, 0, stream>>>(accN, inth, intl, 0.25f);
    { GArgs a = GA();
      a.A0 = inth; a.A1 = intl;
      a.B0h = c_intT_h; a.B0l = c_intT_l;
      a.C0 = tmpf; a.bias0 = F32P(11); a.Rv = inN;
      a.Nn = 512; a.K = 512;
      gemm_k<2,2,EPI_F32_BIAS_RF32><<<dim3(64,4,1),256,0,stream>>>(a); }
    normalize(tmpf, resh, resl, resf);
    { GArgs a = GA();
      a.A0 = resh; a.A1 = resl;
      a.B0h = c_f1T_h; a.B0l = c_f1T_l;
      a.C0 = hidh; a.C0b = hidl; a.bias0 = F32P(13);
      a.Nn = 512; a.K = 512;
      gemm_k<2,2,EPI_SPLIT_BIAS><<<dim3(64,4,1),256,0,stream>>>(a); }
    { GArgs a = GA();
      a.A0 = hidh; a.A1 = hidl;
      a.B0h = c_f2T_h; a.B0l = c_f2T_l;
      a.C0 = feedb; a.C0b = feedf; a.bias0 = F32P(15);
      a.Nn = 512; a.K = 512;
      gemm_k<2,2,EPI_BOTH_LEAKY_BIAS><<<dim3(64,4,1),256,0,stream>>>(a); }
  };
  epilogue1(acc1, in1f, feed1, feed1f);
  epilogue1(acc2, in2f, feed2, feed2f);

  // ---- a1/a2 weight conversion (overlays dead stage-1 weights) ----
  wt_cvt_t<<<dim3(16,16,L_), tb, 0, stream>>>(F32P(16), a1_thT);
  wt_cvt_t<<<dim3(16,16,L_), tb, 0, stream>>>(F32P(18), a1_phT);
  wt_cvt_t<<<dim3(16,16,L_), tb, 0, stream>>>(F32P(20), a1_rhT);
  wt_cvt_t2<<<dim3(16,16,1), tb, 0, stream>>>(F32P(22), a1_intT_h, a1_intT_l);
  wt_cvt_t2<<<dim3(16,16,1), tb, 0, stream>>>(F32P(24), a1_f1T_h, a1_f1T_l);
  wt_cvt_t2<<<dim3(16,16,1), tb, 0, stream>>>(F32P(26), a1_f2T_h, a1_f2T_l);
  wt_cvt_t<<<dim3(16,16,L_), tb, 0, stream>>>(F32P(28), a2_thT);
  wt_cvt_t<<<dim3(16,16,L_), tb, 0, stream>>>(F32P(30), a2_phT);
  wt_cvt_t<<<dim3(16,16,L_), tb, 0, stream>>>(F32P(32), a2_rhT);
  wt_cvt_t2<<<dim3(16,16,1), tb, 0, stream>>>(F32P(34), a2_intT_h, a2_intT_l);
  wt_cvt_t2<<<dim3(16,16,1), tb, 0, stream>>>(F32P(36), a2_f1T_h, a2_f1T_l);
  wt_cvt_t2<<<dim3(16,16,1), tb, 0, stream>>>(F32P(38), a2_f2T_h, a2_f2T_l);

  // ---- _agi ----
  auto agi = [&](const short* xb, const float* xf,
                 const short* thT, const float* thB,
                 const short* phT, const float* phB,
                 const short* rhT, const float* rhB,
                 const short* inTh, const short* inTl, const float* inB,
                 const short* f1Th, const short* f1Tl, const float* f1B,
                 const short* f2Th, const short* f2Tl, const float* f2B,
                 short* outb, short* outlo, float* outf) {
    hipMemsetAsync(acc1, 0, SF, stream);
    for (int i = 0; i < L_; i++) {
      const size_t wo = (size_t)i * D_ * D_;
      const size_t bo = (size_t)i * D_;
      { // th | ph | rh fused: seg0->thh, seg1->phh, seg2 TR->rhTb
        GArgs a = GA();
        a.A0 = xb;
        a.B0h = thT + wo; a.B1h = phT + wo; a.B2h = rhT + wo;
        a.C0 = thh; a.C1 = phh; a.C2 = rhTb;
        a.bias0 = thB + bo; a.bias1 = phB + bo; a.bias2 = rhB + bo;
        a.Nn = 512; a.K = 512;
        gemm_k<1,1,EPI_SEG3_B16_TR><<<dim3(64,12,1),256,0,stream>>>(a);
      }
      { GArgs a = GA();
        a.A0 = thh; a.sA = sAct; a.B0h = phh; a.sB = sAct;
        a.C0 = aff32; a.sC = sAff; a.alpha = scl; a.Nn = 1024; a.K = 512;
        gemm_k<1,1,EPI_F32_SCALE><<<dim3(8,8,B_),256,0,stream>>>(a); }
      softmax_rows<<<B_*N_, 256, 0, stream>>>(aff32, affh);
      { GArgs a = GA();
        a.A0 = affh; a.sA = sAff; a.B0h = rhTb; a.sB = sAct;
        a.C0 = acc1; a.sC = sAct; a.Nn = 512; a.K = 1024;
        gemm_k<1,1,EPI_F32_ACC><<<dim3(8,4,B_),256,0,stream>>>(a); }
    }
    split_f32<<<GE, 256, 0, stream>>>(acc1, inth, intl, 0.25f);
    { GArgs a = GA();
      a.A0 = inth; a.A1 = intl; a.B0h = inTh; a.B0l = inTl;
      a.C0 = tmpf; a.bias0 = inB; a.Rv = xf; a.Nn = 512; a.K = 512;
      gemm_k<2,2,EPI_F32_BIAS_RF32><<<dim3(64,4,1),256,0,stream>>>(a); }
    normalize(tmpf, resh, resl, resf);
    { GArgs a = GA();
      a.A0 = resh; a.A1 = resl; a.B0h = f1Th; a.B0l = f1Tl;
      a.C0 = hidh; a.C0b = hidl; a.bias0 = f1B; a.Nn = 512; a.K = 512;
      gemm_k<2,2,EPI_SPLIT_BIAS><<<dim3(64,4,1),256,0,stream>>>(a); }
    { GArgs a = GA();
      a.A0 = hidh; a.A1 = hidl; a.B0h = f2Th; a.B0l = f2Tl;
      a.C0 = tmpf; a.bias0 = f2B; a.Rv = resf; a.Nn = 512; a.K = 512;
      gemm_k<2,2,EPI_F32_LEAKY_BIAS_RF32><<<dim3(64,4,1),256,0,stream>>>(a); }
    normalize(tmpf, outb, outlo, outf);
  };

  agi(feed1, feed1f, a1_thT,F32P(17), a1_phT,F32P(19), a1_rhT,F32P(21),
      a1_intT_h,a1_intT_l,F32P(23), a1_f1T_h,a1_f1T_l,F32P(25),
      a1_f2T_h,a1_f2T_l,F32P(27), thh, thl, self1f);
  agi(feed2, feed2f, a1_thT,F32P(17), a1_phT,F32P(19), a1_rhT,F32P(21),
      a1_intT_h,a1_intT_l,F32P(23), a1_f1T_h,a1_f1T_l,F32P(25),
      a1_f2T_h,a1_f2T_l,F32P(27), thh, thl, self2f);
  add_both<<<GE, 256, 0, stream>>>(self1f, self2f, self1, sumf);
  agi(self1, sumf, a2_thT,F32P(29), a2_phT,F32P(31), a2_rhT,F32P(33),
      a2_intT_h,a2_intT_l,F32P(35), a2_f1T_h,a2_f1T_l,F32P(37),
      a2_f2T_h,a2_f2T_l,F32P(39), thh, thl, (float*)d_out);
}

// Round 7
// 2078.311 us; speedup vs baseline: 1.3335x; 1.2210x over previous
//
#include <hip/hip_runtime.h>

// ACGI_32195074850822 — round 6: round-5 fusion plan with 2 OOB fixes.
//  FIX 1: affU alloc was 64+16=80 MB (expr bug) -> exactly 32 MB (all three
//         tenants - affh+affl / aff16 / resf - are temporally disjoint).
//  FIX 2: norm_scale grid was NB*1024 (2x OOB) -> NB*512.
// Total workspace ~196 MB. GEMM inner loop unchanged (0 bank conflicts).

#define B_ 8
#define N_ 1024
#define D_ 512
#define L_ 4

typedef short s8v __attribute__((ext_vector_type(8)));
typedef short s4v __attribute__((ext_vector_type(4)));
typedef float f4v __attribute__((ext_vector_type(4)));

__device__ __forceinline__ unsigned short f2b(float f) {
  unsigned u = __builtin_bit_cast(unsigned, f);
  u += 0x7FFFu + ((u >> 16) & 1u);          // round-to-nearest-even
  return (unsigned short)(u >> 16);
}
__device__ __forceinline__ float b2f(short s) {
  unsigned u = ((unsigned)(unsigned short)s) << 16;
  return __builtin_bit_cast(float, u);
}

__device__ __forceinline__ void glds16(const short* g, short* l) {
  __builtin_amdgcn_global_load_lds(
      (const __attribute__((address_space(1))) void*)g,
      (__attribute__((address_space(3))) void*)l, 16, 0, 0);
}

enum {
  EPI_PROJ4 = 0,   // seg even: split(acc+bias)->C0/C1; seg odd: TR(acc+bias)->C0
  EPI_PROJ3,       // seg 0,1: bf16(acc+bias)->C0; seg 2: TR->C0
  EPI_SPLIT_SCALE, // C0 hi, C1 lo of acc*alpha
  EPI_B16_SCALE,   // C0 bf16 = acc*alpha
  EPI_ACC2,        // seg s: C0[s] f32 += acc   (z-batched)
  EPI_F32_ACC,     // C0[0] f32 += acc          (z-batched)
  EPI_F32_BIAS_R,  // C0 f32 = acc+bias+R; R base by z (Rv / Rv2), local idx
  EPI_SPLIT_BIAS,  // C0 hi, C1 lo of acc+bias
  EPI_BOTH_LEAKY,  // C0 bf16 AND C1 f32 = leaky(acc+bias)
  EPI_LEAKY_R      // C0 f32 = leaky(acc+bias) + R (flat)
};

struct GArgs {
  const short* Ah[4]; const short* Al[4];
  const short* Bh[4]; const short* Bl[4];
  long sA, sB;
  void* C0[4]; void* C1[4];
  long sC;
  const float* bias[4];
  const void* Rv; const void* Rv2;
  float alpha;
  int Nn, K;
};

// C = (ΣA_c)(ΣB_c)^T, bf16 comps, f32 accum; <2,2> drops Al*Bl.
// 128x128 tile, 4 waves, global_load_lds(16B) + both-sides XOR swizzle.
// Segmented variants: seg = tn>>9 picks operand/output set (512-wide segs).
template<int AS, int BS, int EPI>
__global__ __launch_bounds__(256) void gemm_k(GArgs g) {
  __shared__ short lA[AS][128][32];
  __shared__ short lB[BS][128][32];
  constexpr bool SEG = (EPI == EPI_PROJ4 || EPI == EPI_PROJ3 || EPI == EPI_ACC2);
  const int z = blockIdx.z;
  const int tm = blockIdx.x * 128;
  const int tn = blockIdx.y * 128;
  const int tid = threadIdx.x;
  const int lane = tid & 63;
  const int w = tid >> 6;
  const int wr = (w >> 1) * 64, wc = (w & 1) * 64;
  const int r16 = lane & 15, kg = lane >> 4;
  const int K = g.K;

  int seg = 0, tnl = tn;
  if constexpr (SEG) { seg = tn >> 9; tnl = tn & 511; }
  const short* Ah = g.Ah[seg];
  const short* Al = (AS == 2) ? g.Al[seg] : nullptr;
  const short* Bh = g.Bh[seg];
  const short* Bl = (BS == 2) ? g.Bl[seg] : nullptr;

  const int srow = lane >> 2;
  const int scol = ((lane & 3) ^ ((lane >> 3) & 3)) * 8;
  const short* gA[2]; const short* gB[2];
  gA[0] = Ah + (size_t)z * g.sA + (size_t)(tm + w * 16 + srow) * K + scol;
  if constexpr (AS == 2)
    gA[1] = Al + (size_t)z * g.sA + (size_t)(tm + w * 16 + srow) * K + scol;
  gB[0] = Bh + (size_t)z * g.sB + (size_t)(tnl + w * 16 + srow) * K + scol;
  if constexpr (BS == 2)
    gB[1] = Bl + (size_t)z * g.sB + (size_t)(tnl + w * 16 + srow) * K + scol;
  const size_t hoff = (size_t)64 * K;

  short* la[2][2]; short* lb[2][2];
  #pragma unroll
  for (int c = 0; c < AS; c++) {
    la[c][0] = &lA[c][w * 16][0];
    la[c][1] = &lA[c][64 + w * 16][0];
  }
  #pragma unroll
  for (int c = 0; c < BS; c++) {
    lb[c][0] = &lB[c][w * 16][0];
    lb[c][1] = &lB[c][64 + w * 16][0];
  }

  f4v acc[4][4];
  #pragma unroll
  for (int i = 0; i < 4; i++)
    #pragma unroll
    for (int j = 0; j < 4; j++) acc[i][j] = (f4v)0.f;

  const int rc = (kg ^ ((r16 >> 1) & 3)) * 8;

  for (int k0 = 0; k0 < K; k0 += 32) {
    #pragma unroll
    for (int c = 0; c < AS; c++) {
      glds16(gA[c] + k0, la[c][0]);
      glds16(gA[c] + hoff + k0, la[c][1]);
    }
    #pragma unroll
    for (int c = 0; c < BS; c++) {
      glds16(gB[c] + k0, lb[c][0]);
      glds16(gB[c] + hoff + k0, lb[c][1]);
    }
    __syncthreads();
    s8v va[2][4], vb[2][4];
    #pragma unroll
    for (int c = 0; c < AS; c++)
      #pragma unroll
      for (int i = 0; i < 4; i++)
        va[c][i] = *(const s8v*)&lA[c][wr + i * 16 + r16][rc];
    #pragma unroll
    for (int c = 0; c < BS; c++)
      #pragma unroll
      for (int i = 0; i < 4; i++)
        vb[c][i] = *(const s8v*)&lB[c][wc + i * 16 + r16][rc];
    #pragma unroll
    for (int ca = 0; ca < AS; ca++)
      #pragma unroll
      for (int cb = 0; cb < BS; cb++) {
        if (ca == 1 && cb == 1) continue;   // drop lo*lo
        #pragma unroll
        for (int mi = 0; mi < 4; mi++)
          #pragma unroll
          for (int ni = 0; ni < 4; ni++)
            acc[mi][ni] = __builtin_amdgcn_mfma_f32_16x16x32_bf16(
                va[ca][mi], vb[cb][ni], acc[mi][ni], 0, 0, 0);
      }
    __syncthreads();
  }

  short* C0s = (short*)g.C0[seg];  float* C0f = (float*)g.C0[seg];
  short* C1s = (short*)g.C1[seg];  float* C1f = (float*)g.C1[seg];
  const float* biasp = g.bias[seg];

  #pragma unroll
  for (int mi = 0; mi < 4; mi++) {
    #pragma unroll
    for (int ni = 0; ni < 4; ni++) {
      const int colL = tnl + wc + ni * 16 + r16;
      const int grow0 = tm + wr + mi * 16 + kg * 4;   // verified C/D layout
      if constexpr (EPI == EPI_PROJ4 || EPI == EPI_PROJ3) {
        const bool tr = (EPI == EPI_PROJ4) ? ((seg & 1) == 1) : (seg == 2);
        const float bv = biasp[colL];
        if (tr) {
          s4v o;
          #pragma unroll
          for (int r = 0; r < 4; r++) o[r] = (short)f2b(acc[mi][ni][r] + bv);
          const int b = grow0 >> 10, n = grow0 & 1023;
          *(s4v*)&C0s[((size_t)b * 512 + colL) * 1024 + n] = o;
        } else if constexpr (EPI == EPI_PROJ4) {
          #pragma unroll
          for (int r = 0; r < 4; r++) {
            const size_t idx = (size_t)(grow0 + r) * 512 + colL;
            float t = acc[mi][ni][r] + bv;
            short h = (short)f2b(t);
            C0s[idx] = h;
            C1s[idx] = (short)f2b(t - b2f(h));
          }
        } else {
          #pragma unroll
          for (int r = 0; r < 4; r++)
            C0s[(size_t)(grow0 + r) * 512 + colL] = (short)f2b(acc[mi][ni][r] + bv);
        }
      } else if constexpr (EPI == EPI_ACC2) {
        #pragma unroll
        for (int r = 0; r < 4; r++)
          C0f[(size_t)z * g.sC + (size_t)(grow0 + r) * 512 + colL] += acc[mi][ni][r];
      } else {
        float bv = 0.f;
        if constexpr (EPI == EPI_F32_BIAS_R || EPI == EPI_SPLIT_BIAS ||
                      EPI == EPI_BOTH_LEAKY || EPI == EPI_LEAKY_R)
          bv = biasp[colL];
        #pragma unroll
        for (int r = 0; r < 4; r++) {
          const size_t lidx = (size_t)(grow0 + r) * g.Nn + colL;
          const size_t idx = (size_t)z * g.sC + lidx;
          const float v = acc[mi][ni][r];
          if constexpr (EPI == EPI_SPLIT_SCALE) {
            float t = v * g.alpha;
            short h = (short)f2b(t);
            C0s[idx] = h;
            C1s[idx] = (short)f2b(t - b2f(h));
          } else if constexpr (EPI == EPI_B16_SCALE) {
            C0s[idx] = (short)f2b(v * g.alpha);
          } else if constexpr (EPI == EPI_F32_ACC) {
            C0f[idx] += v;
          } else if constexpr (EPI == EPI_F32_BIAS_R) {
            const float* Rf = (const float*)(z == 0 ? g.Rv : g.Rv2);
            C0f[idx] = v + bv + Rf[lidx];
          } else if constexpr (EPI == EPI_SPLIT_BIAS) {
            float t = v + bv;
            short h = (short)f2b(t);
            C0s[idx] = h;
            C1s[idx] = (short)f2b(t - b2f(h));
          } else if constexpr (EPI == EPI_BOTH_LEAKY) {
            float t = v + bv; t = (t >= 0.f) ? t : 0.01f * t;
            C0s[idx] = (short)f2b(t);
            C1f[idx] = t;
          } else { // EPI_LEAKY_R
            float t = v + bv; t = (t >= 0.f) ? t : 0.01f * t;
            C0f[idx] = t + ((const float*)g.Rv)[idx];
          }
        }
      }
    }
  }
}

// f32 (z,D,D) -> bf16 transposed, single
__global__ __launch_bounds__(256) void wt_cvt_t(const float* __restrict__ src,
                                                short* __restrict__ dst) {
  __shared__ float t[32][33];
  const int bx = blockIdx.x * 32, by = blockIdx.y * 32;
  const size_t zo = (size_t)blockIdx.z * D_ * D_;
  const int tx = threadIdx.x, ty = threadIdx.y;
  #pragma unroll
  for (int k = 0; k < 4; k++)
    t[ty + 8 * k][tx] = src[zo + (size_t)(by + ty + 8 * k) * D_ + bx + tx];
  __syncthreads();
  #pragma unroll
  for (int k = 0; k < 4; k++)
    dst[zo + (size_t)(bx + ty + 8 * k) * D_ + by + tx] = (short)f2b(t[tx][ty + 8 * k]);
}

// f32 (z,D,D) -> bf16 transposed hi+lo
__global__ __launch_bounds__(256) void wt_cvt_t2(const float* __restrict__ src,
                                                 short* __restrict__ hi,
                                                 short* __restrict__ lo) {
  __shared__ float t[32][33];
  const int bx = blockIdx.x * 32, by = blockIdx.y * 32;
  const size_t zo = (size_t)blockIdx.z * D_ * D_;
  const int tx = threadIdx.x, ty = threadIdx.y;
  #pragma unroll
  for (int k = 0; k < 4; k++)
    t[ty + 8 * k][tx] = src[zo + (size_t)(by + ty + 8 * k) * D_ + bx + tx];
  __syncthreads();
  #pragma unroll
  for (int k = 0; k < 4; k++) {
    const size_t o = zo + (size_t)(bx + ty + 8 * k) * D_ + by + tx;
    float v = t[tx][ty + 8 * k];
    short h = (short)f2b(v);
    hi[o] = h;
    lo[o] = (short)f2b(v - b2f(h));
  }
}

// f32 * scale -> hi bf16 + lo bf16
__global__ __launch_bounds__(256) void split_f32(const float* __restrict__ src,
                                                 short* __restrict__ hi,
                                                 short* __restrict__ lo, float scale) {
  const size_t i = ((size_t)blockIdx.x * 256 + threadIdx.x) * 4;
  f4v v = *(const f4v*)(src + i);
  s4v h, l;
  #pragma unroll
  for (int j = 0; j < 4; j++) {
    float t = v[j] * scale;
    h[j] = (short)f2b(t);
    l[j] = (short)f2b(t - b2f(h[j]));
  }
  *(s4v*)(hi + i) = h;
  *(s4v*)(lo + i) = l;
}

// sum = a + b (f32) elementwise; write bf16 + f32 (outf may alias a)
__global__ __launch_bounds__(256) void add_both(const float* __restrict__ a,
                                                const float* __restrict__ b,
                                                short* __restrict__ outb,
                                                float* outf) {
  const size_t i = ((size_t)blockIdx.x * 256 + threadIdx.x) * 4;
  f4v av = *(const f4v*)(a + i);
  f4v bv = *(const f4v*)(b + i);
  f4v s; s4v o;
  #pragma unroll
  for (int j = 0; j < 4; j++) { s[j] = av[j] + bv[j]; o[j] = (short)f2b(s[j]); }
  *(f4v*)(outf + i) = s;
  *(s4v*)(outb + i) = o;
}

// in-place softmax over bf16 rows of 1024; one wave per row, shuffle reduce
__global__ __launch_bounds__(256) void softmax_rows_b16(short* __restrict__ p) {
  const int row = blockIdx.x * 4 + (threadIdx.x >> 6);
  const int lane = threadIdx.x & 63;
  short* rp = p + (size_t)row * 1024 + lane * 16;
  s8v v0 = *(s8v*)rp, v1 = *(s8v*)(rp + 8);
  float f[16];
  #pragma unroll
  for (int j = 0; j < 8; j++) { f[j] = b2f(v0[j]); f[8 + j] = b2f(v1[j]); }
  float m = f[0];
  #pragma unroll
  for (int j = 1; j < 16; j++) m = fmaxf(m, f[j]);
  #pragma unroll
  for (int s = 32; s; s >>= 1) m = fmaxf(m, __shfl_xor(m, s, 64));
  float sum = 0.f;
  #pragma unroll
  for (int j = 0; j < 16; j++) { f[j] = __expf(f[j] - m); sum += f[j]; }
  #pragma unroll
  for (int s = 32; s; s >>= 1) sum += __shfl_xor(sum, s, 64);
  const float inv = 1.f / sum;
  #pragma unroll
  for (int j = 0; j < 8; j++) {
    v0[j] = (short)f2b(f[j] * inv);
    v1[j] = (short)f2b(f[8 + j] * inv);
  }
  *(s8v*)rp = v0; *(s8v*)(rp + 8) = v1;
}

// L2-normalize over axis=1 (N) of (NB,N,D) f32; deterministic 3-phase.
#define NCHUNK 16
__global__ __launch_bounds__(256) void norm_part(const float* __restrict__ t,
                                                 float* __restrict__ part, int NB) {
  const int d = blockIdx.x * 256 + threadIdx.x;
  const int b = blockIdx.y;
  const int c = blockIdx.z;
  const int n0 = c * (N_ / NCHUNK);
  const float* p = t + ((size_t)b * N_ + n0) * D_ + d;
  float ss = 0.f;
  for (int n = 0; n < N_ / NCHUNK; n++) { float v = p[(size_t)n * D_]; ss += v * v; }
  part[((size_t)c * NB + b) * D_ + d] = ss;
}
__global__ __launch_bounds__(256) void norm_inv(const float* __restrict__ part,
                                                float* __restrict__ inv, int NB) {
  const int i = blockIdx.x * 256 + threadIdx.x;   // b*D + d
  float ss = 0.f;
  for (int c = 0; c < NCHUNK; c++) ss += part[(size_t)c * (NB * D_) + i];
  inv[i] = 1.f / fmaxf(sqrtf(ss), 1e-12f);
}
__global__ __launch_bounds__(256) void norm_scale(const float* __restrict__ t,
                                                  const float* __restrict__ inv,
                                                  short* __restrict__ outh,
                                                  short* __restrict__ outl,
                                                  float* __restrict__ outf) {
  const size_t i = ((size_t)blockIdx.x * 256 + threadIdx.x) * 4;
  const int b = (int)(i >> 19);        // N_*D_ = 2^19
  const int d = (int)(i & (D_ - 1));
  f4v v = *(const f4v*)(t + i);
  f4v w = *(const f4v*)(inv + (size_t)b * D_ + d);
  f4v o; s4v oh, ol;
  #pragma unroll
  for (int j = 0; j < 4; j++) {
    o[j] = v[j] * w[j];
    oh[j] = (short)f2b(o[j]);
    ol[j] = (short)f2b(o[j] - b2f(oh[j]));
  }
  *(f4v*)(outf + i) = o;
  *(s4v*)(outh + i) = oh;
  *(s4v*)(outl + i) = ol;
}

extern "C" void kernel_launch(void* const* d_in, const int* in_sizes, int n_in,
                              void* d_out, int out_size, void* d_ws, size_t ws_size,
                              hipStream_t stream) {
  (void)in_sizes; (void)n_in; (void)out_size; (void)ws_size;
  const float* in1f = (const float*)d_in[0];
  const float* in2f = (const float*)d_in[1];

  const size_t SB = (size_t)B_ * N_ * D_ * 2;      // 8 MB
  const size_t SF = (size_t)B_ * N_ * D_ * 4;      // 16 MB
  const size_t WL = (size_t)L_ * D_ * D_ * 2;
  const size_t W1 = (size_t)D_ * D_ * 2;
  const long SBel = (long)B_ * N_ * D_;            // 4194304 elems
  const long sAct = (long)N_ * D_;
  const long sAff = (long)N_ * N_;

  char* ws = (char*)d_ws;
  size_t off = 0;
  auto alloc = [&](size_t bytes) -> char* {
    char* p = ws + off;
    off += (bytes + 255) & ~(size_t)255;
    return p;
  };

  // ---- weight region (19 MB); a1/a2 overlay after stage 1 ----
  char* wreg = alloc(8 * WL + 6 * W1);
  short* c_thT_h = (short*)(wreg);
  short* c_thT_l = (short*)(wreg + WL);
  short* c_phT_h = (short*)(wreg + 2 * WL);
  short* c_phT_l = (short*)(wreg + 3 * WL);
  short* c_rhT_h = (short*)(wreg + 4 * WL);
  short* c_rhT_l = (short*)(wreg + 5 * WL);
  short* c_psT_h = (short*)(wreg + 6 * WL);
  short* c_psT_l = (short*)(wreg + 7 * WL);
  short* c_intT_h = (short*)(wreg + 8 * WL);
  short* c_intT_l = (short*)(wreg + 8 * WL + W1);
  short* c_f1T_h  = (short*)(wreg + 8 * WL + 2 * W1);
  short* c_f1T_l  = (short*)(wreg + 8 * WL + 3 * W1);
  short* c_f2T_h  = (short*)(wreg + 8 * WL + 4 * W1);
  short* c_f2T_l  = (short*)(wreg + 8 * WL + 5 * W1);
  short* a1_thT = (short*)(wreg);
  short* a1_phT = (short*)(wreg + WL);
  short* a1_rhT = (short*)(wreg + 2 * WL);
  short* a2_thT = (short*)(wreg + 3 * WL);
  short* a2_phT = (short*)(wreg + 4 * WL);
  short* a2_rhT = (short*)(wreg + 5 * WL);
  char*  aw = wreg + 6 * WL;
  short* a1_intT_h = (short*)(aw);
  short* a1_intT_l = (short*)(aw + W1);
  short* a1_f1T_h  = (short*)(aw + 2 * W1);
  short* a1_f1T_l  = (short*)(aw + 3 * W1);
  short* a1_f2T_h  = (short*)(aw + 4 * W1);
  short* a1_f2T_l  = (short*)(aw + 5 * W1);
  short* a2_intT_h = (short*)(aw + 6 * W1);
  short* a2_intT_l = (short*)(aw + 7 * W1);
  short* a2_f1T_h  = (short*)(aw + 8 * W1);
  short* a2_f1T_l  = (short*)(aw + 9 * W1);
  short* a2_f2T_h  = (short*)(aw + 10 * W1);
  short* a2_f2T_l  = (short*)(aw + 11 * W1);

  // ---- pair-contiguous activation regions (2*SB each = 16 MB) ----
  short* in12h = (short*)alloc(2 * SB);   // in1h|in2h -> feed12b -> sumb
  short* in12l = (short*)alloc(2 * SB);   // in1l|in2l -> resh
  short* bufA  = (short*)alloc(2 * SB);   // thh|thl -> inth -> hidh
  short* bufB  = (short*)alloc(2 * SB);   // phh|phl -> intl -> hidl
  short* bufC  = (short*)alloc(2 * SB);   // rhT|psT -> resl
  char*  affU  = alloc((size_t)32 * 1024 * 1024);  // FIX 1: exactly 32 MB
  float* accR  = (float*)alloc(2 * SF);   // acc1|acc2 / acc16 / tmpf
  float* feedfR = (float*)alloc(2 * SF);  // feed12f -> self12f -> sumf
  float* npart = (float*)alloc((size_t)NCHUNK * 16 * D_ * 4);
  float* ninv  = (float*)alloc((size_t)16 * D_ * 4);
  // total: 19 + 5*16 + 32 + 32 + 32 + 0.6 ≈ 196 MB (< proven 217)

  short* in1h = in12h;        short* in2h = in12h + SBel;
  short* in1l = in12l;        short* in2l = in12l + SBel;
  short* thh = bufA;          short* thl = bufA + SBel;
  short* phh = bufB;          short* phl = bufB + SBel;
  short* rhT = bufC;          short* psT = bufC + SBel;
  short* affh = (short*)affU;                   // [0,16 MB)
  short* affl = affh + SBel * 2;                // [16,32 MB)
  short* aff16 = (short*)affU;                  // 32 MB bf16 batch-16 logits
  float* resfP = (float*)affU;                  // 32 MB f32 res (affs dead)
  float* acc1 = accR;         float* acc2 = accR + SBel;

  const float scl = 0.04419417382415922f;   // 512^-0.5
  dim3 tb(32, 8);
  const int GE = (B_ * N_ * D_) / (4 * 256);     // 4096
  #define F32P(i) ((const float*)d_in[i])

  auto GA = [&]() { GArgs a; __builtin_memset(&a, 0, sizeof(a)); return a; };
  auto normalize = [&](const float* src, int NB, short* outh, short* outl, float* outf) {
    norm_part<<<dim3(D_/256, NB, NCHUNK), 256, 0, stream>>>(src, npart, NB);
    norm_inv<<<(NB * D_) / 256, 256, 0, stream>>>(npart, ninv, NB);
    norm_scale<<<NB * 512, 256, 0, stream>>>(src, ninv, outh, outl, outf);  // FIX 2
  };

  // ---- stage-1 weights + input split ----
  wt_cvt_t2<<<dim3(16,16,L_), tb, 0, stream>>>(F32P(2),  c_thT_h, c_thT_l);
  wt_cvt_t2<<<dim3(16,16,L_), tb, 0, stream>>>(F32P(4),  c_phT_h, c_phT_l);
  wt_cvt_t2<<<dim3(16,16,L_), tb, 0, stream>>>(F32P(6),  c_rhT_h, c_rhT_l);
  wt_cvt_t2<<<dim3(16,16,L_), tb, 0, stream>>>(F32P(8),  c_psT_h, c_psT_l);
  wt_cvt_t2<<<dim3(16,16,1),  tb, 0, stream>>>(F32P(10), c_intT_h, c_intT_l);
  wt_cvt_t2<<<dim3(16,16,1),  tb, 0, stream>>>(F32P(12), c_f1T_h, c_f1T_l);
  wt_cvt_t2<<<dim3(16,16,1),  tb, 0, stream>>>(F32P(14), c_f2T_h, c_f2T_l);
  split_f32<<<GE, 256, 0, stream>>>(in1f, in1h, in1l, 1.0f);
  split_f32<<<GE, 256, 0, stream>>>(in2f, in2h, in2l, 1.0f);
  hipMemsetAsync(accR, 0, 2 * SF, stream);

  // ---- stage 1: 4-seg proj -> split affinity -> 2-seg apply ----
  for (int i = 0; i < L_; i++) {
    const size_t wo = (size_t)i * D_ * D_;
    const size_t bo = (size_t)i * D_;
    { GArgs a = GA();
      a.Ah[0] = in1h; a.Ah[1] = in1h; a.Ah[2] = in2h; a.Ah[3] = in2h;
      a.Al[0] = in1l; a.Al[1] = in1l; a.Al[2] = in2l; a.Al[3] = in2l;
      a.Bh[0] = c_thT_h + wo; a.Bh[1] = c_rhT_h + wo;
      a.Bh[2] = c_phT_h + wo; a.Bh[3] = c_psT_h + wo;
      a.Bl[0] = c_thT_l + wo; a.Bl[1] = c_rhT_l + wo;
      a.Bl[2] = c_phT_l + wo; a.Bl[3] = c_psT_l + wo;
      a.C0[0] = thh; a.C0[1] = rhT; a.C0[2] = phh; a.C0[3] = psT;
      a.C1[0] = thl; a.C1[2] = phl;
      a.bias[0] = F32P(3) + bo; a.bias[1] = F32P(7) + bo;
      a.bias[2] = F32P(5) + bo; a.bias[3] = F32P(9) + bo;
      a.Nn = 512; a.K = 512;
      gemm_k<2,2,EPI_PROJ4><<<dim3(64,16,1),256,0,stream>>>(a); }
    { GArgs a = GA();
      a.Ah[0] = thh; a.Al[0] = thl; a.sA = sAct;
      a.Bh[0] = phh; a.Bl[0] = phl; a.sB = sAct;
      a.C0[0] = affh; a.C1[0] = affl; a.sC = sAff;
      a.alpha = scl; a.Nn = 1024; a.K = 512;
      gemm_k<2,2,EPI_SPLIT_SCALE><<<dim3(8,8,B_),256,0,stream>>>(a); }
    { GArgs a = GA();
      a.Ah[0] = affh; a.Ah[1] = affh; a.Al[0] = affl; a.Al[1] = affl; a.sA = sAff;
      a.Bh[0] = rhT; a.Bh[1] = psT; a.sB = sAct;
      a.C0[0] = acc1; a.C0[1] = acc2; a.sC = sAct;
      a.Nn = 512; a.K = 1024;
      gemm_k<2,1,EPI_ACC2><<<dim3(8,8,B_),256,0,stream>>>(a); }
  }

  // ---- stage-1 epilogue, both streams batched (z=2 / M=16384) ----
  split_f32<<<2 * GE, 256, 0, stream>>>(accR, bufA, bufB, 0.25f);   // inth|intl
  { GArgs a = GA();
    a.Ah[0] = bufA; a.Al[0] = bufB; a.sA = SBel;
    a.Bh[0] = c_intT_h; a.Bl[0] = c_intT_l;
    a.C0[0] = accR; a.sC = SBel;
    a.bias[0] = F32P(11); a.Rv = in1f; a.Rv2 = in2f;
    a.Nn = 512; a.K = 512;
    gemm_k<2,2,EPI_F32_BIAS_R><<<dim3(64,4,2),256,0,stream>>>(a); }
  normalize(accR, 16, in12l, bufA, resfP);       // resh|resl (resf scratch)
  { GArgs a = GA();
    a.Ah[0] = in12l; a.Al[0] = bufA;
    a.Bh[0] = c_f1T_h; a.Bl[0] = c_f1T_l;
    a.C0[0] = bufB; a.C1[0] = bufC;              // hidh|hidl
    a.bias[0] = F32P(13); a.Nn = 512; a.K = 512;
    gemm_k<2,2,EPI_SPLIT_BIAS><<<dim3(128,4,1),256,0,stream>>>(a); }
  { GArgs a = GA();
    a.Ah[0] = bufB; a.Al[0] = bufC;
    a.Bh[0] = c_f2T_h; a.Bl[0] = c_f2T_l;
    a.C0[0] = in12h; a.C1[0] = feedfR;           // feed12b | feed12f
    a.bias[0] = F32P(15); a.Nn = 512; a.K = 512;
    gemm_k<2,2,EPI_BOTH_LEAKY><<<dim3(128,4,1),256,0,stream>>>(a); }

  // ---- a1/a2 weights (overlay dead stage-1 weights) ----
  wt_cvt_t<<<dim3(16,16,L_), tb, 0, stream>>>(F32P(16), a1_thT);
  wt_cvt_t<<<dim3(16,16,L_), tb, 0, stream>>>(F32P(18), a1_phT);
  wt_cvt_t<<<dim3(16,16,L_), tb, 0, stream>>>(F32P(20), a1_rhT);
  wt_cvt_t2<<<dim3(16,16,1), tb, 0, stream>>>(F32P(22), a1_intT_h, a1_intT_l);
  wt_cvt_t2<<<dim3(16,16,1), tb, 0, stream>>>(F32P(24), a1_f1T_h, a1_f1T_l);
  wt_cvt_t2<<<dim3(16,16,1), tb, 0, stream>>>(F32P(26), a1_f2T_h, a1_f2T_l);
  wt_cvt_t<<<dim3(16,16,L_), tb, 0, stream>>>(F32P(28), a2_thT);
  wt_cvt_t<<<dim3(16,16,L_), tb, 0, stream>>>(F32P(30), a2_phT);
  wt_cvt_t<<<dim3(16,16,L_), tb, 0, stream>>>(F32P(32), a2_rhT);
  wt_cvt_t2<<<dim3(16,16,1), tb, 0, stream>>>(F32P(34), a2_intT_h, a2_intT_l);
  wt_cvt_t2<<<dim3(16,16,1), tb, 0, stream>>>(F32P(36), a2_f1T_h, a2_f1T_l);
  wt_cvt_t2<<<dim3(16,16,1), tb, 0, stream>>>(F32P(38), a2_f2T_h, a2_f2T_l);

  // ---- generic agi chain over NZ batches (NZ=16 pair, NZ=8 final) ----
  auto agi = [&](int NZ, const short* xb, const float* xf,
                 const short* thT, const float* thB,
                 const short* phT, const float* phB,
                 const short* rhT_, const float* rhB,
                 const short* inTh, const short* inTl, const float* inB,
                 const short* f1Th, const short* f1Tl, const float* f1B,
                 const short* f2Th, const short* f2Tl, const float* f2B,
                 float* outf) {
    const int MB = NZ / B_;                  // 2 or 1 (stream multiplier)
    hipMemsetAsync(accR, 0, MB * SF, stream);
    for (int i = 0; i < L_; i++) {
      const size_t wo = (size_t)i * D_ * D_;
      const size_t bo = (size_t)i * D_;
      { GArgs a = GA();
        a.Ah[0] = xb; a.Ah[1] = xb; a.Ah[2] = xb;
        a.Bh[0] = thT + wo; a.Bh[1] = phT + wo; a.Bh[2] = rhT_ + wo;
        a.C0[0] = bufA; a.C0[1] = bufB; a.C0[2] = bufC;
        a.bias[0] = thB + bo; a.bias[1] = phB + bo; a.bias[2] = rhB + bo;
        a.Nn = 512; a.K = 512;
        gemm_k<1,1,EPI_PROJ3><<<dim3(64*MB,12,1),256,0,stream>>>(a); }
      { GArgs a = GA();
        a.Ah[0] = bufA; a.sA = sAct; a.Bh[0] = bufB; a.sB = sAct;
        a.C0[0] = aff16; a.sC = sAff; a.alpha = scl; a.Nn = 1024; a.K = 512;
        gemm_k<1,1,EPI_B16_SCALE><<<dim3(8,8,NZ),256,0,stream>>>(a); }
      softmax_rows_b16<<<NZ * 256, 256, 0, stream>>>(aff16);
      { GArgs a = GA();
        a.Ah[0] = aff16; a.sA = sAff; a.Bh[0] = bufC; a.sB = sAct;
        a.C0[0] = accR; a.sC = sAct; a.Nn = 512; a.K = 1024;
        gemm_k<1,1,EPI_F32_ACC><<<dim3(8,4,NZ),256,0,stream>>>(a); }
    }
    split_f32<<<MB * GE, 256, 0, stream>>>(accR, bufA, bufB, 0.25f);
    { GArgs a = GA();
      a.Ah[0] = bufA; a.Al[0] = bufB;
      a.Bh[0] = inTh; a.Bl[0] = inTl;
      a.C0[0] = accR; a.bias[0] = inB; a.Rv = xf; a.Rv2 = xf;
      a.Nn = 512; a.K = 512;
      gemm_k<2,2,EPI_F32_BIAS_R><<<dim3(64*MB,4,1),256,0,stream>>>(a); }
    normalize(accR, NZ, in12l, bufC, resfP);     // resh|resl, resf -> affU
    { GArgs a = GA();
      a.Ah[0] = in12l; a.Al[0] = bufC;
      a.Bh[0] = f1Th; a.Bl[0] = f1Tl;
      a.C0[0] = bufA; a.C1[0] = bufB;            // hidh|hidl
      a.bias[0] = f1B; a.Nn = 512; a.K = 512;
      gemm_k<2,2,EPI_SPLIT_BIAS><<<dim3(64*MB,4,1),256,0,stream>>>(a); }
    { GArgs a = GA();
      a.Ah[0] = bufA; a.Al[0] = bufB;
      a.Bh[0] = f2Th; a.Bl[0] = f2Tl;
      a.C0[0] = accR; a.bias[0] = f2B; a.Rv = resfP;
      a.Nn = 512; a.K = 512;
      gemm_k<2,2,EPI_LEAKY_R><<<dim3(64*MB,4,1),256,0,stream>>>(a); }
    normalize(accR, NZ, bufA, bufB, outf);       // bf16 outs are scratch
  };

  // agi1 on feed1+feed2 as one batch-16 chain (shared AGI_1 weights)
  agi(16, in12h, feedfR,
      a1_thT, F32P(17), a1_phT, F32P(19), a1_rhT, F32P(21),
      a1_intT_h, a1_intT_l, F32P(23), a1_f1T_h, a1_f1T_l, F32P(25),
      a1_f2T_h, a1_f2T_l, F32P(27), feedfR);     // self12f -> feedfR

  add_both<<<GE, 256, 0, stream>>>(feedfR, feedfR + SBel, in12h, feedfR);

  agi(8, in12h, feedfR,
      a2_thT, F32P(29), a2_phT, F32P(31), a2_rhT, F32P(33),
      a2_intT_h, a2_intT_l, F32P(35), a2_f1T_h, a2_f1T_l, F32P(37),
      a2_f2T_h, a2_f2T_l, F32P(39), (float*)d_out);
}

// Round 8
// 2072.197 us; speedup vs baseline: 1.3374x; 1.0030x over previous
//
#include <hip/hip_runtime.h>

// ACGI_32195074850822 — round 7: vectorized bf16 epilogue via LDS restage.
//  * bf16 C-writes were 2B scattered (32B/16-lane group = half cacheline ->
//    2x write amplification, store-issue bound). Now: acc -> LDS strips ->
//    16B coalesced stores. LDS reused from staging (no growth).
//  * last apply layer fuses the acc split (EPI_ACC2_SPLIT / EPI_ACC_SPLIT),
//    removing split_f32 passes. Numerics bit-identical to round 6.

#define B_ 8
#define N_ 1024
#define D_ 512
#define L_ 4

typedef short s8v __attribute__((ext_vector_type(8)));
typedef short s4v __attribute__((ext_vector_type(4)));
typedef float f4v __attribute__((ext_vector_type(4)));

__device__ __forceinline__ unsigned short f2b(float f) {
  unsigned u = __builtin_bit_cast(unsigned, f);
  u += 0x7FFFu + ((u >> 16) & 1u);          // round-to-nearest-even
  return (unsigned short)(u >> 16);
}
__device__ __forceinline__ float b2f(short s) {
  unsigned u = ((unsigned)(unsigned short)s) << 16;
  return __builtin_bit_cast(float, u);
}

__device__ __forceinline__ void glds16(const short* g, short* l) {
  __builtin_amdgcn_global_load_lds(
      (const __attribute__((address_space(1))) void*)g,
      (__attribute__((address_space(3))) void*)l, 16, 0, 0);
}

enum {
  EPI_PROJ4 = 0,   // seg even: split(acc+bias)->C0/C1; seg odd: TR(acc+bias)->C0
  EPI_PROJ3,       // seg 0,1: bf16(acc+bias)->C0; seg 2: TR->C0
  EPI_SPLIT_SCALE, // C0 hi, C1 lo of acc*alpha
  EPI_B16_SCALE,   // C0 bf16 = acc*alpha
  EPI_ACC2,        // seg s: C0[s] f32 += acc   (z-batched)
  EPI_F32_ACC,     // C0[0] f32 += acc          (z-batched)
  EPI_F32_BIAS_R,  // C0 f32 = acc+bias+R; R base by z (Rv / Rv2), local idx
  EPI_SPLIT_BIAS,  // C0 hi, C1 lo of acc+bias
  EPI_BOTH_LEAKY,  // C0 bf16 AND C1 f32 = leaky(acc+bias)
  EPI_LEAKY_R,     // C0 f32 = leaky(acc+bias) + R (flat)
  EPI_ACC2_SPLIT,  // seg s: t=(C0[s]+acc)*alpha; hi->C1[s], lo->C1[2+s]
  EPI_ACC_SPLIT    // t=(C0[0]+acc)*alpha; hi->C1[0], lo->C1[1] (z-batched)
};

struct GArgs {
  const short* Ah[4]; const short* Al[4];
  const short* Bh[4]; const short* Bl[4];
  long sA, sB;
  void* C0[4]; void* C1[4];
  long sC;
  const float* bias[4];
  const void* Rv; const void* Rv2;
  float alpha;
  int Nn, K;
};

// C = (ΣA_c)(ΣB_c)^T, bf16 comps, f32 accum; <2,2> drops Al*Bl.
// 128x128 tile, 4 waves, global_load_lds(16B) + both-sides XOR swizzle.
// Segmented variants: seg = tn>>9 picks operand/output set (512-wide segs).
template<int AS, int BS, int EPI>
__global__ __launch_bounds__(256) void gemm_k(GArgs g) {
  __shared__ short smem[(AS + BS) * 128 * 32];
  constexpr bool SEG = (EPI == EPI_PROJ4 || EPI == EPI_PROJ3 ||
                        EPI == EPI_ACC2 || EPI == EPI_ACC2_SPLIT);
  constexpr bool LDSOUT = (EPI == EPI_PROJ4 || EPI == EPI_PROJ3 ||
                           EPI == EPI_SPLIT_SCALE || EPI == EPI_B16_SCALE ||
                           EPI == EPI_SPLIT_BIAS || EPI == EPI_BOTH_LEAKY ||
                           EPI == EPI_ACC2_SPLIT || EPI == EPI_ACC_SPLIT);
  constexpr int CC = (EPI == EPI_PROJ4 || EPI == EPI_SPLIT_SCALE ||
                      EPI == EPI_SPLIT_BIAS || EPI == EPI_ACC2_SPLIT ||
                      EPI == EPI_ACC_SPLIT) ? 2 : 1;
  const int z = blockIdx.z;
  const int tm = blockIdx.x * 128;
  const int tn = blockIdx.y * 128;
  const int tid = threadIdx.x;
  const int lane = tid & 63;
  const int w = tid >> 6;
  const int wr = (w >> 1) * 64, wc = (w & 1) * 64;
  const int r16 = lane & 15, kg = lane >> 4;
  const int K = g.K;

  int seg = 0, tnl = tn;
  if constexpr (SEG) { seg = tn >> 9; tnl = tn & 511; }
  const short* Ah = g.Ah[seg];
  const short* Al = (AS == 2) ? g.Al[seg] : nullptr;
  const short* Bh = g.Bh[seg];
  const short* Bl = (BS == 2) ? g.Bl[seg] : nullptr;

  const int srow = lane >> 2;
  const int scol = ((lane & 3) ^ ((lane >> 3) & 3)) * 8;
  const short* gA[2]; const short* gB[2];
  gA[0] = Ah + (size_t)z * g.sA + (size_t)(tm + w * 16 + srow) * K + scol;
  if constexpr (AS == 2)
    gA[1] = Al + (size_t)z * g.sA + (size_t)(tm + w * 16 + srow) * K + scol;
  gB[0] = Bh + (size_t)z * g.sB + (size_t)(tnl + w * 16 + srow) * K + scol;
  if constexpr (BS == 2)
    gB[1] = Bl + (size_t)z * g.sB + (size_t)(tnl + w * 16 + srow) * K + scol;
  const size_t hoff = (size_t)64 * K;

  short* la[2][2]; short* lb[2][2];
  #pragma unroll
  for (int c = 0; c < AS; c++) {
    la[c][0] = &smem[c * 4096 + (w * 16) * 32];
    la[c][1] = &smem[c * 4096 + (64 + w * 16) * 32];
  }
  #pragma unroll
  for (int c = 0; c < BS; c++) {
    lb[c][0] = &smem[(AS + c) * 4096 + (w * 16) * 32];
    lb[c][1] = &smem[(AS + c) * 4096 + (64 + w * 16) * 32];
  }

  f4v acc[4][4];
  #pragma unroll
  for (int i = 0; i < 4; i++)
    #pragma unroll
    for (int j = 0; j < 4; j++) acc[i][j] = (f4v)0.f;

  const int rc = (kg ^ ((r16 >> 1) & 3)) * 8;

  for (int k0 = 0; k0 < K; k0 += 32) {
    #pragma unroll
    for (int c = 0; c < AS; c++) {
      glds16(gA[c] + k0, la[c][0]);
      glds16(gA[c] + hoff + k0, la[c][1]);
    }
    #pragma unroll
    for (int c = 0; c < BS; c++) {
      glds16(gB[c] + k0, lb[c][0]);
      glds16(gB[c] + hoff + k0, lb[c][1]);
    }
    __syncthreads();
    s8v va[2][4], vb[2][4];
    #pragma unroll
    for (int c = 0; c < AS; c++)
      #pragma unroll
      for (int i = 0; i < 4; i++)
        va[c][i] = *(const s8v*)&smem[c * 4096 + (wr + i * 16 + r16) * 32 + rc];
    #pragma unroll
    for (int c = 0; c < BS; c++)
      #pragma unroll
      for (int i = 0; i < 4; i++)
        vb[c][i] = *(const s8v*)&smem[(AS + c) * 4096 + (wc + i * 16 + r16) * 32 + rc];
    #pragma unroll
    for (int ca = 0; ca < AS; ca++)
      #pragma unroll
      for (int cb = 0; cb < BS; cb++) {
        if (ca == 1 && cb == 1) continue;   // drop lo*lo
        #pragma unroll
        for (int mi = 0; mi < 4; mi++)
          #pragma unroll
          for (int ni = 0; ni < 4; ni++)
            acc[mi][ni] = __builtin_amdgcn_mfma_f32_16x16x32_bf16(
                va[ca][mi], vb[cb][ni], acc[mi][ni], 0, 0, 0);
      }
    __syncthreads();
  }

  short* C0s = (short*)g.C0[seg];  float* C0f = (float*)g.C0[seg];
  short* C1s = (short*)g.C1[seg];  float* C1f = (float*)g.C1[seg];
  const float* biasp = g.bias[seg];
  const int NnL = g.Nn;

  if constexpr (LDSOUT) {
    bool tr = false;
    if constexpr (EPI == EPI_PROJ4) tr = (seg & 1);
    if constexpr (EPI == EPI_PROJ3) tr = (seg == 2);
    if (tr) {
      // transposed write (s4v along n, already 8B-coalesced)
      #pragma unroll
      for (int mi = 0; mi < 4; mi++) {
        #pragma unroll
        for (int ni = 0; ni < 4; ni++) {
          const int colL = tnl + wc + ni * 16 + r16;
          const int grow0 = tm + wr + mi * 16 + kg * 4;
          const float bv = biasp[colL];
          s4v o;
          #pragma unroll
          for (int r = 0; r < 4; r++) o[r] = (short)f2b(acc[mi][ni][r] + bv);
          const int b = grow0 >> 10, n = grow0 & 1023;
          *(s4v*)&C0s[((size_t)b * 512 + colL) * 1024 + n] = o;
        }
      }
    } else {
      short* D0 = nullptr; short* D1 = nullptr;
      if constexpr (EPI == EPI_PROJ4 || EPI == EPI_PROJ3) {
        D0 = C0s; D1 = C1s;
      } else if constexpr (EPI == EPI_SPLIT_SCALE || EPI == EPI_SPLIT_BIAS) {
        D0 = C0s + (size_t)z * g.sC; D1 = C1s + (size_t)z * g.sC;
      } else if constexpr (EPI == EPI_B16_SCALE || EPI == EPI_BOTH_LEAKY) {
        D0 = C0s + (size_t)z * g.sC;
      } else if constexpr (EPI == EPI_ACC2_SPLIT) {
        D0 = (short*)g.C1[seg] + (size_t)z * g.sC;
        D1 = (short*)g.C1[2 + seg] + (size_t)z * g.sC;
      } else { // EPI_ACC_SPLIT
        D0 = (short*)g.C1[0] + (size_t)z * g.sC;
        D1 = (short*)g.C1[1] + (size_t)z * g.sC;
      }
      for (int mi = 0; mi < 4; mi++) {
        #pragma unroll
        for (int ni = 0; ni < 4; ni++) {
          const int lcol = wc + ni * 16 + r16;
          const int colL = tnl + lcol;
          float bv = 0.f;
          if constexpr (EPI == EPI_PROJ4 || EPI == EPI_PROJ3 ||
                        EPI == EPI_SPLIT_BIAS || EPI == EPI_BOTH_LEAKY)
            bv = biasp[colL];
          #pragma unroll
          for (int r = 0; r < 4; r++) {
            const int grow = tm + wr + mi * 16 + kg * 4 + r;
            const float v = acc[mi][ni][r];
            float t;
            if constexpr (EPI == EPI_SPLIT_SCALE || EPI == EPI_B16_SCALE)
              t = v * g.alpha;
            else if constexpr (EPI == EPI_ACC2_SPLIT || EPI == EPI_ACC_SPLIT)
              t = (C0f[(size_t)z * g.sC + (size_t)grow * NnL + colL] + v) * g.alpha;
            else if constexpr (EPI == EPI_BOTH_LEAKY) {
              t = v + bv; t = (t >= 0.f) ? t : 0.01f * t;
              C1f[(size_t)z * g.sC + (size_t)grow * NnL + colL] = t;
            } else
              t = v + bv;
            const int li = ((w >> 1) * 16 + kg * 4 + r) * 128 + lcol;
            const short h = (short)f2b(t);
            smem[li] = h;
            if constexpr (CC == 2) smem[4096 + li] = (short)f2b(t - b2f(h));
          }
        }
        __syncthreads();
        #pragma unroll
        for (int c2 = 0; c2 < CC; c2++) {
          short* D = c2 ? D1 : D0;
          #pragma unroll
          for (int half = 0; half < 2; half++) {
            const int e = (tid + half * 256) * 8;
            const int strip = e >> 11, rowin = (e >> 7) & 15, col = e & 127;
            const int grow = tm + strip * 64 + mi * 16 + rowin;
            *(s8v*)&D[(size_t)grow * NnL + tnl + col] =
                *(const s8v*)&smem[c2 * 4096 + e];
          }
        }
        __syncthreads();
      }
    }
  } else {
    // direct f32 epilogues (coalesced 64B/group)
    #pragma unroll
    for (int mi = 0; mi < 4; mi++) {
      #pragma unroll
      for (int ni = 0; ni < 4; ni++) {
        const int colL = tnl + wc + ni * 16 + r16;
        const int grow0 = tm + wr + mi * 16 + kg * 4;
        float bv = 0.f;
        if constexpr (EPI == EPI_F32_BIAS_R || EPI == EPI_LEAKY_R)
          bv = biasp[colL];
        #pragma unroll
        for (int r = 0; r < 4; r++) {
          const size_t lidx = (size_t)(grow0 + r) * NnL + colL;
          const size_t idx = (size_t)z * g.sC + lidx;
          const float v = acc[mi][ni][r];
          if constexpr (EPI == EPI_ACC2) {
            C0f[(size_t)z * g.sC + (size_t)(grow0 + r) * 512 + colL] += v;
          } else if constexpr (EPI == EPI_F32_ACC) {
            C0f[idx] += v;
          } else if constexpr (EPI == EPI_F32_BIAS_R) {
            const float* Rf = (const float*)(z == 0 ? g.Rv : g.Rv2);
            C0f[idx] = v + bv + Rf[lidx];
          } else { // EPI_LEAKY_R
            float t = v + bv; t = (t >= 0.f) ? t : 0.01f * t;
            C0f[idx] = t + ((const float*)g.Rv)[idx];
          }
        }
      }
    }
  }
}

// f32 (z,D,D) -> bf16 transposed, single
__global__ __launch_bounds__(256) void wt_cvt_t(const float* __restrict__ src,
                                                short* __restrict__ dst) {
  __shared__ float t[32][33];
  const int bx = blockIdx.x * 32, by = blockIdx.y * 32;
  const size_t zo = (size_t)blockIdx.z * D_ * D_;
  const int tx = threadIdx.x, ty = threadIdx.y;
  #pragma unroll
  for (int k = 0; k < 4; k++)
    t[ty + 8 * k][tx] = src[zo + (size_t)(by + ty + 8 * k) * D_ + bx + tx];
  __syncthreads();
  #pragma unroll
  for (int k = 0; k < 4; k++)
    dst[zo + (size_t)(bx + ty + 8 * k) * D_ + by + tx] = (short)f2b(t[tx][ty + 8 * k]);
}

// f32 (z,D,D) -> bf16 transposed hi+lo
__global__ __launch_bounds__(256) void wt_cvt_t2(const float* __restrict__ src,
                                                 short* __restrict__ hi,
                                                 short* __restrict__ lo) {
  __shared__ float t[32][33];
  const int bx = blockIdx.x * 32, by = blockIdx.y * 32;
  const size_t zo = (size_t)blockIdx.z * D_ * D_;
  const int tx = threadIdx.x, ty = threadIdx.y;
  #pragma unroll
  for (int k = 0; k < 4; k++)
    t[ty + 8 * k][tx] = src[zo + (size_t)(by + ty + 8 * k) * D_ + bx + tx];
  __syncthreads();
  #pragma unroll
  for (int k = 0; k < 4; k++) {
    const size_t o = zo + (size_t)(bx + ty + 8 * k) * D_ + by + tx;
    float v = t[tx][ty + 8 * k];
    short h = (short)f2b(v);
    hi[o] = h;
    lo[o] = (short)f2b(v - b2f(h));
  }
}

// f32 * scale -> hi bf16 + lo bf16
__global__ __launch_bounds__(256) void split_f32(const float* __restrict__ src,
                                                 short* __restrict__ hi,
                                                 short* __restrict__ lo, float scale) {
  const size_t i = ((size_t)blockIdx.x * 256 + threadIdx.x) * 4;
  f4v v = *(const f4v*)(src + i);
  s4v h, l;
  #pragma unroll
  for (int j = 0; j < 4; j++) {
    float t = v[j] * scale;
    h[j] = (short)f2b(t);
    l[j] = (short)f2b(t - b2f(h[j]));
  }
  *(s4v*)(hi + i) = h;
  *(s4v*)(lo + i) = l;
}

// sum = a + b (f32) elementwise; write bf16 + f32 (outf may alias a)
__global__ __launch_bounds__(256) void add_both(const float* __restrict__ a,
                                                const float* __restrict__ b,
                                                short* __restrict__ outb,
                                                float* outf) {
  const size_t i = ((size_t)blockIdx.x * 256 + threadIdx.x) * 4;
  f4v av = *(const f4v*)(a + i);
  f4v bv = *(const f4v*)(b + i);
  f4v s; s4v o;
  #pragma unroll
  for (int j = 0; j < 4; j++) { s[j] = av[j] + bv[j]; o[j] = (short)f2b(s[j]); }
  *(f4v*)(outf + i) = s;
  *(s4v*)(outb + i) = o;
}

// in-place softmax over bf16 rows of 1024; one wave per row, shuffle reduce
__global__ __launch_bounds__(256) void softmax_rows_b16(short* __restrict__ p) {
  const int row = blockIdx.x * 4 + (threadIdx.x >> 6);
  const int lane = threadIdx.x & 63;
  short* rp = p + (size_t)row * 1024 + lane * 16;
  s8v v0 = *(s8v*)rp, v1 = *(s8v*)(rp + 8);
  float f[16];
  #pragma unroll
  for (int j = 0; j < 8; j++) { f[j] = b2f(v0[j]); f[8 + j] = b2f(v1[j]); }
  float m = f[0];
  #pragma unroll
  for (int j = 1; j < 16; j++) m = fmaxf(m, f[j]);
  #pragma unroll
  for (int s = 32; s; s >>= 1) m = fmaxf(m, __shfl_xor(m, s, 64));
  float sum = 0.f;
  #pragma unroll
  for (int j = 0; j < 16; j++) { f[j] = __expf(f[j] - m); sum += f[j]; }
  #pragma unroll
  for (int s = 32; s; s >>= 1) sum += __shfl_xor(sum, s, 64);
  const float inv = 1.f / sum;
  #pragma unroll
  for (int j = 0; j < 8; j++) {
    v0[j] = (short)f2b(f[j] * inv);
    v1[j] = (short)f2b(f[8 + j] * inv);
  }
  *(s8v*)rp = v0; *(s8v*)(rp + 8) = v1;
}

// L2-normalize over axis=1 (N) of (NB,N,D) f32; deterministic 3-phase.
#define NCHUNK 16
__global__ __launch_bounds__(256) void norm_part(const float* __restrict__ t,
                                                 float* __restrict__ part, int NB) {
  const int d = blockIdx.x * 256 + threadIdx.x;
  const int b = blockIdx.y;
  const int c = blockIdx.z;
  const int n0 = c * (N_ / NCHUNK);
  const float* p = t + ((size_t)b * N_ + n0) * D_ + d;
  float ss = 0.f;
  for (int n = 0; n < N_ / NCHUNK; n++) { float v = p[(size_t)n * D_]; ss += v * v; }
  part[((size_t)c * NB + b) * D_ + d] = ss;
}
__global__ __launch_bounds__(256) void norm_inv(const float* __restrict__ part,
                                                float* __restrict__ inv, int NB) {
  const int i = blockIdx.x * 256 + threadIdx.x;   // b*D + d
  float ss = 0.f;
  for (int c = 0; c < NCHUNK; c++) ss += part[(size_t)c * (NB * D_) + i];
  inv[i] = 1.f / fmaxf(sqrtf(ss), 1e-12f);
}
__global__ __launch_bounds__(256) void norm_scale(const float* __restrict__ t,
                                                  const float* __restrict__ inv,
                                                  short* __restrict__ outh,
                                                  short* __restrict__ outl,
                                                  float* __restrict__ outf) {
  const size_t i = ((size_t)blockIdx.x * 256 + threadIdx.x) * 4;
  const int b = (int)(i >> 19);        // N_*D_ = 2^19
  const int d = (int)(i & (D_ - 1));
  f4v v = *(const f4v*)(t + i);
  f4v w = *(const f4v*)(inv + (size_t)b * D_ + d);
  f4v o; s4v oh, ol;
  #pragma unroll
  for (int j = 0; j < 4; j++) {
    o[j] = v[j] * w[j];
    oh[j] = (short)f2b(o[j]);
    ol[j] = (short)f2b(o[j] - b2f(oh[j]));
  }
  *(f4v*)(outf + i) = o;
  *(s4v*)(outh + i) = oh;
  *(s4v*)(outl + i) = ol;
}

extern "C" void kernel_launch(void* const* d_in, const int* in_sizes, int n_in,
                              void* d_out, int out_size, void* d_ws, size_t ws_size,
                              hipStream_t stream) {
  (void)in_sizes; (void)n_in; (void)out_size; (void)ws_size;
  const float* in1f = (const float*)d_in[0];
  const float* in2f = (const float*)d_in[1];

  const size_t SB = (size_t)B_ * N_ * D_ * 2;      // 8 MB
  const size_t SF = (size_t)B_ * N_ * D_ * 4;      // 16 MB
  const size_t WL = (size_t)L_ * D_ * D_ * 2;
  const size_t W1 = (size_t)D_ * D_ * 2;
  const long SBel = (long)B_ * N_ * D_;            // 4194304 elems
  const long sAct = (long)N_ * D_;
  const long sAff = (long)N_ * N_;

  char* ws = (char*)d_ws;
  size_t off = 0;
  auto alloc = [&](size_t bytes) -> char* {
    char* p = ws + off;
    off += (bytes + 255) & ~(size_t)255;
    return p;
  };

  // ---- weight region (19 MB); a1/a2 overlay after stage 1 ----
  char* wreg = alloc(8 * WL + 6 * W1);
  short* c_thT_h = (short*)(wreg);
  short* c_thT_l = (short*)(wreg + WL);
  short* c_phT_h = (short*)(wreg + 2 * WL);
  short* c_phT_l = (short*)(wreg + 3 * WL);
  short* c_rhT_h = (short*)(wreg + 4 * WL);
  short* c_rhT_l = (short*)(wreg + 5 * WL);
  short* c_psT_h = (short*)(wreg + 6 * WL);
  short* c_psT_l = (short*)(wreg + 7 * WL);
  short* c_intT_h = (short*)(wreg + 8 * WL);
  short* c_intT_l = (short*)(wreg + 8 * WL + W1);
  short* c_f1T_h  = (short*)(wreg + 8 * WL + 2 * W1);
  short* c_f1T_l  = (short*)(wreg + 8 * WL + 3 * W1);
  short* c_f2T_h  = (short*)(wreg + 8 * WL + 4 * W1);
  short* c_f2T_l  = (short*)(wreg + 8 * WL + 5 * W1);
  short* a1_thT = (short*)(wreg);
  short* a1_phT = (short*)(wreg + WL);
  short* a1_rhT = (short*)(wreg + 2 * WL);
  short* a2_thT = (short*)(wreg + 3 * WL);
  short* a2_phT = (short*)(wreg + 4 * WL);
  short* a2_rhT = (short*)(wreg + 5 * WL);
  char*  aw = wreg + 6 * WL;
  short* a1_intT_h = (short*)(aw);
  short* a1_intT_l = (short*)(aw + W1);
  short* a1_f1T_h  = (short*)(aw + 2 * W1);
  short* a1_f1T_l  = (short*)(aw + 3 * W1);
  short* a1_f2T_h  = (short*)(aw + 4 * W1);
  short* a1_f2T_l  = (short*)(aw + 5 * W1);
  short* a2_intT_h = (short*)(aw + 6 * W1);
  short* a2_intT_l = (short*)(aw + 7 * W1);
  short* a2_f1T_h  = (short*)(aw + 8 * W1);
  short* a2_f1T_l  = (short*)(aw + 9 * W1);
  short* a2_f2T_h  = (short*)(aw + 10 * W1);
  short* a2_f2T_l  = (short*)(aw + 11 * W1);

  // ---- pair-contiguous activation regions (2*SB each = 16 MB) ----
  short* in12h = (short*)alloc(2 * SB);   // in1h|in2h -> feed12b -> sumb
  short* in12l = (short*)alloc(2 * SB);   // in1l|in2l -> resh
  short* bufA  = (short*)alloc(2 * SB);   // thh|thl -> inth -> hidh
  short* bufB  = (short*)alloc(2 * SB);   // phh|phl -> intl -> hidl
  short* bufC  = (short*)alloc(2 * SB);   // rhT|psT -> resl
  char*  affU  = alloc((size_t)32 * 1024 * 1024);
  float* accR  = (float*)alloc(2 * SF);   // acc1|acc2 / acc16 / tmpf
  float* feedfR = (float*)alloc(2 * SF);  // feed12f -> self12f -> sumf
  float* npart = (float*)alloc((size_t)NCHUNK * 16 * D_ * 4);
  float* ninv  = (float*)alloc((size_t)16 * D_ * 4);
  // total ≈ 196 MB (< proven 217)

  short* in1h = in12h;        short* in2h = in12h + SBel;
  short* in1l = in12l;        short* in2l = in12l + SBel;
  short* thh = bufA;          short* thl = bufA + SBel;
  short* phh = bufB;          short* phl = bufB + SBel;
  short* rhT = bufC;          short* psT = bufC + SBel;
  short* affh = (short*)affU;                   // [0,16 MB)
  short* affl = affh + SBel * 2;                // [16,32 MB)
  short* aff16 = (short*)affU;                  // 32 MB bf16 batch-16 logits
  float* resfP = (float*)affU;                  // 32 MB f32 res (affs dead)
  float* acc1 = accR;         float* acc2 = accR + SBel;

  const float scl = 0.04419417382415922f;   // 512^-0.5
  dim3 tb(32, 8);
  const int GE = (B_ * N_ * D_) / (4 * 256);     // 4096
  #define F32P(i) ((const float*)d_in[i])

  auto GA = [&]() { GArgs a; __builtin_memset(&a, 0, sizeof(a)); return a; };
  auto normalize = [&](const float* src, int NB, short* outh, short* outl, float* outf) {
    norm_part<<<dim3(D_/256, NB, NCHUNK), 256, 0, stream>>>(src, npart, NB);
    norm_inv<<<(NB * D_) / 256, 256, 0, stream>>>(npart, ninv, NB);
    norm_scale<<<NB * 512, 256, 0, stream>>>(src, ninv, outh, outl, outf);
  };

  // ---- stage-1 weights + input split ----
  wt_cvt_t2<<<dim3(16,16,L_), tb, 0, stream>>>(F32P(2),  c_thT_h, c_thT_l);
  wt_cvt_t2<<<dim3(16,16,L_), tb, 0, stream>>>(F32P(4),  c_phT_h, c_phT_l);
  wt_cvt_t2<<<dim3(16,16,L_), tb, 0, stream>>>(F32P(6),  c_rhT_h, c_rhT_l);
  wt_cvt_t2<<<dim3(16,16,L_), tb, 0, stream>>>(F32P(8),  c_psT_h, c_psT_l);
  wt_cvt_t2<<<dim3(16,16,1),  tb, 0, stream>>>(F32P(10), c_intT_h, c_intT_l);
  wt_cvt_t2<<<dim3(16,16,1),  tb, 0, stream>>>(F32P(12), c_f1T_h, c_f1T_l);
  wt_cvt_t2<<<dim3(16,16,1),  tb, 0, stream>>>(F32P(14), c_f2T_h, c_f2T_l);
  split_f32<<<GE, 256, 0, stream>>>(in1f, in1h, in1l, 1.0f);
  split_f32<<<GE, 256, 0, stream>>>(in2f, in2h, in2l, 1.0f);
  hipMemsetAsync(accR, 0, 2 * SF, stream);

  // ---- stage 1: 4-seg proj -> split affinity -> 2-seg apply ----
  for (int i = 0; i < L_; i++) {
    const size_t wo = (size_t)i * D_ * D_;
    const size_t bo = (size_t)i * D_;
    { GArgs a = GA();
      a.Ah[0] = in1h; a.Ah[1] = in1h; a.Ah[2] = in2h; a.Ah[3] = in2h;
      a.Al[0] = in1l; a.Al[1] = in1l; a.Al[2] = in2l; a.Al[3] = in2l;
      a.Bh[0] = c_thT_h + wo; a.Bh[1] = c_rhT_h + wo;
      a.Bh[2] = c_phT_h + wo; a.Bh[3] = c_psT_h + wo;
      a.Bl[0] = c_thT_l + wo; a.Bl[1] = c_rhT_l + wo;
      a.Bl[2] = c_phT_l + wo; a.Bl[3] = c_psT_l + wo;
      a.C0[0] = thh; a.C0[1] = rhT; a.C0[2] = phh; a.C0[3] = psT;
      a.C1[0] = thl; a.C1[2] = phl;
      a.bias[0] = F32P(3) + bo; a.bias[1] = F32P(7) + bo;
      a.bias[2] = F32P(5) + bo; a.bias[3] = F32P(9) + bo;
      a.Nn = 512; a.K = 512;
      gemm_k<2,2,EPI_PROJ4><<<dim3(64,16,1),256,0,stream>>>(a); }
    { GArgs a = GA();
      a.Ah[0] = thh; a.Al[0] = thl; a.sA = sAct;
      a.Bh[0] = phh; a.Bl[0] = phl; a.sB = sAct;
      a.C0[0] = affh; a.C1[0] = affl; a.sC = sAff;
      a.alpha = scl; a.Nn = 1024; a.K = 512;
      gemm_k<2,2,EPI_SPLIT_SCALE><<<dim3(8,8,B_),256,0,stream>>>(a); }
    { GArgs a = GA();
      a.Ah[0] = affh; a.Ah[1] = affh; a.Al[0] = affl; a.Al[1] = affl; a.sA = sAff;
      a.Bh[0] = rhT; a.Bh[1] = psT; a.sB = sAct;
      a.C0[0] = acc1; a.C0[1] = acc2; a.sC = sAct;
      a.Nn = 512; a.K = 1024;
      if (i < L_ - 1) {
        gemm_k<2,1,EPI_ACC2><<<dim3(8,8,B_),256,0,stream>>>(a);
      } else {
        a.C1[0] = bufA; a.C1[1] = bufA + SBel;   // inth (stream1|stream2)
        a.C1[2] = bufB; a.C1[3] = bufB + SBel;   // intl
        a.alpha = 0.25f;
        gemm_k<2,1,EPI_ACC2_SPLIT><<<dim3(8,8,B_),256,0,stream>>>(a);
      } }
  }

  // ---- stage-1 epilogue, both streams batched (z=2 / M=16384) ----
  { GArgs a = GA();
    a.Ah[0] = bufA; a.Al[0] = bufB; a.sA = SBel;
    a.Bh[0] = c_intT_h; a.Bl[0] = c_intT_l;
    a.C0[0] = accR; a.sC = SBel;
    a.bias[0] = F32P(11); a.Rv = in1f; a.Rv2 = in2f;
    a.Nn = 512; a.K = 512;
    gemm_k<2,2,EPI_F32_BIAS_R><<<dim3(64,4,2),256,0,stream>>>(a); }
  normalize(accR, 16, in12l, bufA, resfP);       // resh|resl (resf scratch)
  { GArgs a = GA();
    a.Ah[0] = in12l; a.Al[0] = bufA;
    a.Bh[0] = c_f1T_h; a.Bl[0] = c_f1T_l;
    a.C0[0] = bufB; a.C1[0] = bufC;              // hidh|hidl
    a.bias[0] = F32P(13); a.Nn = 512; a.K = 512;
    gemm_k<2,2,EPI_SPLIT_BIAS><<<dim3(128,4,1),256,0,stream>>>(a); }
  { GArgs a = GA();
    a.Ah[0] = bufB; a.Al[0] = bufC;
    a.Bh[0] = c_f2T_h; a.Bl[0] = c_f2T_l;
    a.C0[0] = in12h; a.C1[0] = feedfR;           // feed12b | feed12f
    a.bias[0] = F32P(15); a.Nn = 512; a.K = 512;
    gemm_k<2,2,EPI_BOTH_LEAKY><<<dim3(128,4,1),256,0,stream>>>(a); }

  // ---- a1/a2 weights (overlay dead stage-1 weights) ----
  wt_cvt_t<<<dim3(16,16,L_), tb, 0, stream>>>(F32P(16), a1_thT);
  wt_cvt_t<<<dim3(16,16,L_), tb, 0, stream>>>(F32P(18), a1_phT);
  wt_cvt_t<<<dim3(16,16,L_), tb, 0, stream>>>(F32P(20), a1_rhT);
  wt_cvt_t2<<<dim3(16,16,1), tb, 0, stream>>>(F32P(22), a1_intT_h, a1_intT_l);
  wt_cvt_t2<<<dim3(16,16,1), tb, 0, stream>>>(F32P(24), a1_f1T_h, a1_f1T_l);
  wt_cvt_t2<<<dim3(16,16,1), tb, 0, stream>>>(F32P(26), a1_f2T_h, a1_f2T_l);
  wt_cvt_t<<<dim3(16,16,L_), tb, 0, stream>>>(F32P(28), a2_thT);
  wt_cvt_t<<<dim3(16,16,L_), tb, 0, stream>>>(F32P(30), a2_phT);
  wt_cvt_t<<<dim3(16,16,L_), tb, 0, stream>>>(F32P(32), a2_rhT);
  wt_cvt_t2<<<dim3(16,16,1), tb, 0, stream>>>(F32P(34), a2_intT_h, a2_intT_l);
  wt_cvt_t2<<<dim3(16,16,1), tb, 0, stream>>>(F32P(36), a2_f1T_h, a2_f1T_l);
  wt_cvt_t2<<<dim3(16,16,1), tb, 0, stream>>>(F32P(38), a2_f2T_h, a2_f2T_l);

  // ---- generic agi chain over NZ batches (NZ=16 pair, NZ=8 final) ----
  auto agi = [&](int NZ, const short* xb, const float* xf,
                 const short* thT, const float* thB,
                 const short* phT, const float* phB,
                 const short* rhT_, const float* rhB,
                 const short* inTh, const short* inTl, const float* inB,
                 const short* f1Th, const short* f1Tl, const float* f1B,
                 const short* f2Th, const short* f2Tl, const float* f2B,
                 float* outf) {
    const int MB = NZ / B_;                  // 2 or 1 (stream multiplier)
    hipMemsetAsync(accR, 0, MB * SF, stream);
    for (int i = 0; i < L_; i++) {
      const size_t wo = (size_t)i * D_ * D_;
      const size_t bo = (size_t)i * D_;
      { GArgs a = GA();
        a.Ah[0] = xb; a.Ah[1] = xb; a.Ah[2] = xb;
        a.Bh[0] = thT + wo; a.Bh[1] = phT + wo; a.Bh[2] = rhT_ + wo;
        a.C0[0] = bufA; a.C0[1] = bufB; a.C0[2] = bufC;
        a.bias[0] = thB + bo; a.bias[1] = phB + bo; a.bias[2] = rhB + bo;
        a.Nn = 512; a.K = 512;
        gemm_k<1,1,EPI_PROJ3><<<dim3(64*MB,12,1),256,0,stream>>>(a); }
      { GArgs a = GA();
        a.Ah[0] = bufA; a.sA = sAct; a.Bh[0] = bufB; a.sB = sAct;
        a.C0[0] = aff16; a.sC = sAff; a.alpha = scl; a.Nn = 1024; a.K = 512;
        gemm_k<1,1,EPI_B16_SCALE><<<dim3(8,8,NZ),256,0,stream>>>(a); }
      softmax_rows_b16<<<NZ * 256, 256, 0, stream>>>(aff16);
      { GArgs a = GA();
        a.Ah[0] = aff16; a.sA = sAff; a.Bh[0] = bufC; a.sB = sAct;
        a.C0[0] = accR; a.sC = sAct; a.Nn = 512; a.K = 1024;
        if (i < L_ - 1) {
          gemm_k<1,1,EPI_F32_ACC><<<dim3(8,4,NZ),256,0,stream>>>(a);
        } else {
          a.C1[0] = bufA; a.C1[1] = bufB; a.alpha = 0.25f;
          gemm_k<1,1,EPI_ACC_SPLIT><<<dim3(8,4,NZ),256,0,stream>>>(a);
        } }
    }
    { GArgs a = GA();
      a.Ah[0] = bufA; a.Al[0] = bufB;
      a.Bh[0] = inTh; a.Bl[0] = inTl;
      a.C0[0] = accR; a.bias[0] = inB; a.Rv = xf; a.Rv2 = xf;
      a.Nn = 512; a.K = 512;
      gemm_k<2,2,EPI_F32_BIAS_R><<<dim3(64*MB,4,1),256,0,stream>>>(a); }
    normalize(accR, NZ, in12l, bufC, resfP);     // resh|resl, resf -> affU
    { GArgs a = GA();
      a.Ah[0] = in12l; a.Al[0] = bufC;
      a.Bh[0] = f1Th; a.Bl[0] = f1Tl;
      a.C0[0] = bufA; a.C1[0] = bufB;            // hidh|hidl
      a.bias[0] = f1B; a.Nn = 512; a.K = 512;
      gemm_k<2,2,EPI_SPLIT_BIAS><<<dim3(64*MB,4,1),256,0,stream>>>(a); }
    { GArgs a = GA();
      a.Ah[0] = bufA; a.Al[0] = bufB;
      a.Bh[0] = f2Th; a.Bl[0] = f2Tl;
      a.C0[0] = accR; a.bias[0] = f2B; a.Rv = resfP;
      a.Nn = 512; a.K = 512;
      gemm_k<2,2,EPI_LEAKY_R><<<dim3(64*MB,4,1),256,0,stream>>>(a); }
    normalize(accR, NZ, bufA, bufB, outf);       // bf16 outs are scratch
  };

  // agi1 on feed1+feed2 as one batch-16 chain (shared AGI_1 weights)
  agi(16, in12h, feedfR,
      a1_thT, F32P(17), a1_phT, F32P(19), a1_rhT, F32P(21),
      a1_intT_h, a1_intT_l, F32P(23), a1_f1T_h, a1_f1T_l, F32P(25),
      a1_f2T_h, a1_f2T_l, F32P(27), feedfR);     // self12f -> feedfR

  add_both<<<GE, 256, 0, stream>>>(feedfR, feedfR + SBel, in12h, feedfR);

  agi(8, in12h, feedfR,
      a2_thT, F32P(29), a2_phT, F32P(31), a2_rhT, F32P(33),
      a2_intT_h, a2_intT_l, F32P(35), a2_f1T_h, a2_f1T_l, F32P(37),
      a2_f2T_h, a2_f2T_l, F32P(39), (float*)d_out);
}

// Round 9
// 1820.266 us; speedup vs baseline: 1.5225x; 1.1384x over previous
//
#include <hip/hip_runtime.h>

// ACGI_32195074850822 — round 8: latency-hiding K-loop.
//  * DB=1: double-buffered LDS staging, ONE barrier per K-step; next tile's
//    global_load_lds issued before the MFMAs (syncthreads drains vmcnt).
//    PROJ4 keeps DB=0 (64 KB LDS would halve its 4-blocks/CU occupancy).
//  * epilogue strip swizzle (col ^ ((lrow>>2)&3)<<4) kills the 4-way LDS
//    write conflicts from round 7.
//  * layer-0 applies STORE (no +=) -> memsets and one acc read-pass dropped.
// Numerics bit-identical to rounds 6/7 (absmax canary 2.441e-3).

#define B_ 8
#define N_ 1024
#define D_ 512
#define L_ 4

typedef short s8v __attribute__((ext_vector_type(8)));
typedef short s4v __attribute__((ext_vector_type(4)));
typedef float f4v __attribute__((ext_vector_type(4)));

__device__ __forceinline__ unsigned short f2b(float f) {
  unsigned u = __builtin_bit_cast(unsigned, f);
  u += 0x7FFFu + ((u >> 16) & 1u);          // round-to-nearest-even
  return (unsigned short)(u >> 16);
}
__device__ __forceinline__ float b2f(short s) {
  unsigned u = ((unsigned)(unsigned short)s) << 16;
  return __builtin_bit_cast(float, u);
}

__device__ __forceinline__ void glds16(const short* g, short* l) {
  __builtin_amdgcn_global_load_lds(
      (const __attribute__((address_space(1))) void*)g,
      (__attribute__((address_space(3))) void*)l, 16, 0, 0);
}

enum {
  EPI_PROJ4 = 0,   // seg even: split(acc+bias)->C0/C1; seg odd: TR(acc+bias)->C0
  EPI_PROJ3,       // seg 0,1: bf16(acc+bias)->C0; seg 2: TR->C0
  EPI_SPLIT_SCALE, // C0 hi, C1 lo of acc*alpha
  EPI_B16_SCALE,   // C0 bf16 = acc*alpha
  EPI_ACC2,        // seg s: C0[s] f32 += acc   (z-batched)
  EPI_ACC2_ST,     // seg s: C0[s] f32 = acc    (layer 0)
  EPI_F32_ACC,     // C0[0] f32 += acc          (z-batched)
  EPI_F32_ST,      // C0[0] f32 = acc           (layer 0)
  EPI_F32_BIAS_R,  // C0 f32 = acc+bias+R; R base by z (Rv / Rv2), local idx
  EPI_SPLIT_BIAS,  // C0 hi, C1 lo of acc+bias
  EPI_BOTH_LEAKY,  // C0 bf16 AND C1 f32 = leaky(acc+bias)
  EPI_LEAKY_R,     // C0 f32 = leaky(acc+bias) + R (flat)
  EPI_ACC2_SPLIT,  // seg s: t=(C0[s]+acc)*alpha; hi->C1[s], lo->C1[2+s]
  EPI_ACC_SPLIT    // t=(C0[0]+acc)*alpha; hi->C1[0], lo->C1[1] (z-batched)
};

struct GArgs {
  const short* Ah[4]; const short* Al[4];
  const short* Bh[4]; const short* Bl[4];
  long sA, sB;
  void* C0[4]; void* C1[4];
  long sC;
  const float* bias[4];
  const void* Rv; const void* Rv2;
  float alpha;
  int Nn, K;
};

// C = (ΣA_c)(ΣB_c)^T, bf16 comps, f32 accum; <2,2> drops Al*Bl.
// 128x128 tile, 4 waves, global_load_lds(16B) + both-sides XOR swizzle.
// DB=1: double-buffered staging, 1 barrier per K-step.
template<int AS, int BS, int EPI, int DB>
__global__ __launch_bounds__(256) void gemm_k(GArgs g) {
  constexpr int TILE = (AS + BS) * 4096;        // shorts per staging buffer
  __shared__ short smem[TILE * (DB ? 2 : 1)];
  constexpr bool SEG = (EPI == EPI_PROJ4 || EPI == EPI_PROJ3 ||
                        EPI == EPI_ACC2 || EPI == EPI_ACC2_ST ||
                        EPI == EPI_ACC2_SPLIT);
  constexpr bool LDSOUT = (EPI == EPI_PROJ4 || EPI == EPI_PROJ3 ||
                           EPI == EPI_SPLIT_SCALE || EPI == EPI_B16_SCALE ||
                           EPI == EPI_SPLIT_BIAS || EPI == EPI_BOTH_LEAKY ||
                           EPI == EPI_ACC2_SPLIT || EPI == EPI_ACC_SPLIT);
  constexpr int CC = (EPI == EPI_PROJ4 || EPI == EPI_SPLIT_SCALE ||
                      EPI == EPI_SPLIT_BIAS || EPI == EPI_ACC2_SPLIT ||
                      EPI == EPI_ACC_SPLIT) ? 2 : 1;
  const int z = blockIdx.z;
  const int tm = blockIdx.x * 128;
  const int tn = blockIdx.y * 128;
  const int tid = threadIdx.x;
  const int lane = tid & 63;
  const int w = tid >> 6;
  const int wr = (w >> 1) * 64, wc = (w & 1) * 64;
  const int r16 = lane & 15, kg = lane >> 4;
  const int K = g.K;

  int seg = 0, tnl = tn;
  if constexpr (SEG) { seg = tn >> 9; tnl = tn & 511; }
  const short* Ah = g.Ah[seg];
  const short* Al = (AS == 2) ? g.Al[seg] : nullptr;
  const short* Bh = g.Bh[seg];
  const short* Bl = (BS == 2) ? g.Bl[seg] : nullptr;

  const int srow = lane >> 2;
  const int scol = ((lane & 3) ^ ((lane >> 3) & 3)) * 8;
  const short* gA[2]; const short* gB[2];
  gA[0] = Ah + (size_t)z * g.sA + (size_t)(tm + w * 16 + srow) * K + scol;
  if constexpr (AS == 2)
    gA[1] = Al + (size_t)z * g.sA + (size_t)(tm + w * 16 + srow) * K + scol;
  gB[0] = Bh + (size_t)z * g.sB + (size_t)(tnl + w * 16 + srow) * K + scol;
  if constexpr (BS == 2)
    gB[1] = Bl + (size_t)z * g.sB + (size_t)(tnl + w * 16 + srow) * K + scol;
  const size_t hoff = (size_t)64 * K;

  auto stage = [&](int k0, int buf) {
    short* base = smem + buf * TILE;
    #pragma unroll
    for (int c = 0; c < AS; c++) {
      glds16(gA[c] + k0, base + c * 4096 + (w * 16) * 32);
      glds16(gA[c] + hoff + k0, base + c * 4096 + (64 + w * 16) * 32);
    }
    #pragma unroll
    for (int c = 0; c < BS; c++) {
      glds16(gB[c] + k0, base + (AS + c) * 4096 + (w * 16) * 32);
      glds16(gB[c] + hoff + k0, base + (AS + c) * 4096 + (64 + w * 16) * 32);
    }
  };

  f4v acc[4][4];
  #pragma unroll
  for (int i = 0; i < 4; i++)
    #pragma unroll
    for (int j = 0; j < 4; j++) acc[i][j] = (f4v)0.f;

  const int rc = (kg ^ ((r16 >> 1) & 3)) * 8;

  auto compute = [&](int buf) {
    const short* base = smem + buf * TILE;
    s8v va[2][4], vb[2][4];
    #pragma unroll
    for (int c = 0; c < AS; c++)
      #pragma unroll
      for (int i = 0; i < 4; i++)
        va[c][i] = *(const s8v*)&base[c * 4096 + (wr + i * 16 + r16) * 32 + rc];
    #pragma unroll
    for (int c = 0; c < BS; c++)
      #pragma unroll
      for (int i = 0; i < 4; i++)
        vb[c][i] = *(const s8v*)&base[(AS + c) * 4096 + (wc + i * 16 + r16) * 32 + rc];
    #pragma unroll
    for (int ca = 0; ca < AS; ca++)
      #pragma unroll
      for (int cb = 0; cb < BS; cb++) {
        if (ca == 1 && cb == 1) continue;   // drop lo*lo
        #pragma unroll
        for (int mi = 0; mi < 4; mi++)
          #pragma unroll
          for (int ni = 0; ni < 4; ni++)
            acc[mi][ni] = __builtin_amdgcn_mfma_f32_16x16x32_bf16(
                va[ca][mi], vb[cb][ni], acc[mi][ni], 0, 0, 0);
      }
  };

  const int nt = K >> 5;
  if constexpr (DB) {
    stage(0, 0);
    __syncthreads();                  // buf0 landed (vmcnt drained by barrier)
    int buf = 0;
    for (int t = 0; t < nt; t++) {
      if (t + 1 < nt) stage((t + 1) * 32, buf ^ 1);  // fly under the MFMAs
      compute(buf);
      __syncthreads();                // drains vmcnt+lgkm; next buf ready
      buf ^= 1;
    }
  } else {
    for (int t = 0; t < nt; t++) {
      stage(t * 32, 0);
      __syncthreads();
      compute(0);
      __syncthreads();
    }
  }

  short* C0s = (short*)g.C0[seg];  float* C0f = (float*)g.C0[seg];
  short* C1s = (short*)g.C1[seg];  float* C1f = (float*)g.C1[seg];
  const float* biasp = g.bias[seg];
  const int NnL = g.Nn;

  if constexpr (LDSOUT) {
    bool tr = false;
    if constexpr (EPI == EPI_PROJ4) tr = (seg & 1);
    if constexpr (EPI == EPI_PROJ3) tr = (seg == 2);
    if (tr) {
      // transposed write (s4v along n, 8B-coalesced)
      #pragma unroll
      for (int mi = 0; mi < 4; mi++) {
        #pragma unroll
        for (int ni = 0; ni < 4; ni++) {
          const int colL = tnl + wc + ni * 16 + r16;
          const int grow0 = tm + wr + mi * 16 + kg * 4;
          const float bv = biasp[colL];
          s4v o;
          #pragma unroll
          for (int r = 0; r < 4; r++) o[r] = (short)f2b(acc[mi][ni][r] + bv);
          const int b = grow0 >> 10, n = grow0 & 1023;
          *(s4v*)&C0s[((size_t)b * 512 + colL) * 1024 + n] = o;
        }
      }
    } else {
      short* D0 = nullptr; short* D1 = nullptr;
      if constexpr (EPI == EPI_PROJ4 || EPI == EPI_PROJ3) {
        D0 = C0s; D1 = C1s;
      } else if constexpr (EPI == EPI_SPLIT_SCALE || EPI == EPI_SPLIT_BIAS) {
        D0 = C0s + (size_t)z * g.sC; D1 = C1s + (size_t)z * g.sC;
      } else if constexpr (EPI == EPI_B16_SCALE || EPI == EPI_BOTH_LEAKY) {
        D0 = C0s + (size_t)z * g.sC;
      } else if constexpr (EPI == EPI_ACC2_SPLIT) {
        D0 = (short*)g.C1[seg] + (size_t)z * g.sC;
        D1 = (short*)g.C1[2 + seg] + (size_t)z * g.sC;
      } else { // EPI_ACC_SPLIT
        D0 = (short*)g.C1[0] + (size_t)z * g.sC;
        D1 = (short*)g.C1[1] + (size_t)z * g.sC;
      }
      for (int mi = 0; mi < 4; mi++) {
        #pragma unroll
        for (int ni = 0; ni < 4; ni++) {
          const int lcol = wc + ni * 16 + r16;
          const int colL = tnl + lcol;
          float bv = 0.f;
          if constexpr (EPI == EPI_PROJ4 || EPI == EPI_PROJ3 ||
                        EPI == EPI_SPLIT_BIAS || EPI == EPI_BOTH_LEAKY)
            bv = biasp[colL];
          #pragma unroll
          for (int r = 0; r < 4; r++) {
            const int grow = tm + wr + mi * 16 + kg * 4 + r;
            const float v = acc[mi][ni][r];
            float t;
            if constexpr (EPI == EPI_SPLIT_SCALE || EPI == EPI_B16_SCALE)
              t = v * g.alpha;
            else if constexpr (EPI == EPI_ACC2_SPLIT || EPI == EPI_ACC_SPLIT)
              t = (C0f[(size_t)z * g.sC + (size_t)grow * NnL + colL] + v) * g.alpha;
            else if constexpr (EPI == EPI_BOTH_LEAKY) {
              t = v + bv; t = (t >= 0.f) ? t : 0.01f * t;
              C1f[(size_t)z * g.sC + (size_t)grow * NnL + colL] = t;
            } else
              t = v + bv;
            const int lrow = (w >> 1) * 16 + kg * 4 + r;
            const int sw = ((lrow >> 2) & 3) << 4;          // bank swizzle
            const int li = lrow * 128 + (lcol ^ sw);
            const short h = (short)f2b(t);
            smem[li] = h;
            if constexpr (CC == 2) smem[4096 + li] = (short)f2b(t - b2f(h));
          }
        }
        __syncthreads();
        #pragma unroll
        for (int c2 = 0; c2 < CC; c2++) {
          short* D = c2 ? D1 : D0;
          #pragma unroll
          for (int half = 0; half < 2; half++) {
            const int e = (tid + half * 256) * 8;
            const int lrow2 = e >> 7, col = e & 127;
            const int sw2 = ((lrow2 >> 2) & 3) << 4;
            const int grow = tm + (lrow2 >> 4) * 64 + mi * 16 + (lrow2 & 15);
            *(s8v*)&D[(size_t)grow * NnL + tnl + col] =
                *(const s8v*)&smem[c2 * 4096 + (lrow2 << 7) + (col ^ sw2)];
          }
        }
        __syncthreads();
      }
    }
  } else {
    // direct f32 epilogues (coalesced 64B/group)
    #pragma unroll
    for (int mi = 0; mi < 4; mi++) {
      #pragma unroll
      for (int ni = 0; ni < 4; ni++) {
        const int colL = tnl + wc + ni * 16 + r16;
        const int grow0 = tm + wr + mi * 16 + kg * 4;
        float bv = 0.f;
        if constexpr (EPI == EPI_F32_BIAS_R || EPI == EPI_LEAKY_R)
          bv = biasp[colL];
        #pragma unroll
        for (int r = 0; r < 4; r++) {
          const size_t lidx = (size_t)(grow0 + r) * NnL + colL;
          const size_t idx = (size_t)z * g.sC + lidx;
          const float v = acc[mi][ni][r];
          if constexpr (EPI == EPI_ACC2) {
            C0f[(size_t)z * g.sC + (size_t)(grow0 + r) * 512 + colL] += v;
          } else if constexpr (EPI == EPI_ACC2_ST) {
            C0f[(size_t)z * g.sC + (size_t)(grow0 + r) * 512 + colL] = v;
          } else if constexpr (EPI == EPI_F32_ACC) {
            C0f[idx] += v;
          } else if constexpr (EPI == EPI_F32_ST) {
            C0f[idx] = v;
          } else if constexpr (EPI == EPI_F32_BIAS_R) {
            const float* Rf = (const float*)(z == 0 ? g.Rv : g.Rv2);
            C0f[idx] = v + bv + Rf[lidx];
          } else { // EPI_LEAKY_R
            float t = v + bv; t = (t >= 0.f) ? t : 0.01f * t;
            C0f[idx] = t + ((const float*)g.Rv)[idx];
          }
        }
      }
    }
  }
}

// f32 (z,D,D) -> bf16 transposed, single
__global__ __launch_bounds__(256) void wt_cvt_t(const float* __restrict__ src,
                                                short* __restrict__ dst) {
  __shared__ float t[32][33];
  const int bx = blockIdx.x * 32, by = blockIdx.y * 32;
  const size_t zo = (size_t)blockIdx.z * D_ * D_;
  const int tx = threadIdx.x, ty = threadIdx.y;
  #pragma unroll
  for (int k = 0; k < 4; k++)
    t[ty + 8 * k][tx] = src[zo + (size_t)(by + ty + 8 * k) * D_ + bx + tx];
  __syncthreads();
  #pragma unroll
  for (int k = 0; k < 4; k++)
    dst[zo + (size_t)(bx + ty + 8 * k) * D_ + by + tx] = (short)f2b(t[tx][ty + 8 * k]);
}

// f32 (z,D,D) -> bf16 transposed hi+lo
__global__ __launch_bounds__(256) void wt_cvt_t2(const float* __restrict__ src,
                                                 short* __restrict__ hi,
                                                 short* __restrict__ lo) {
  __shared__ float t[32][33];
  const int bx = blockIdx.x * 32, by = blockIdx.y * 32;
  const size_t zo = (size_t)blockIdx.z * D_ * D_;
  const int tx = threadIdx.x, ty = threadIdx.y;
  #pragma unroll
  for (int k = 0; k < 4; k++)
    t[ty + 8 * k][tx] = src[zo + (size_t)(by + ty + 8 * k) * D_ + bx + tx];
  __syncthreads();
  #pragma unroll
  for (int k = 0; k < 4; k++) {
    const size_t o = zo + (size_t)(bx + ty + 8 * k) * D_ + by + tx;
    float v = t[tx][ty + 8 * k];
    short h = (short)f2b(v);
    hi[o] = h;
    lo[o] = (short)f2b(v - b2f(h));
  }
}

// f32 * scale -> hi bf16 + lo bf16
__global__ __launch_bounds__(256) void split_f32(const float* __restrict__ src,
                                                 short* __restrict__ hi,
                                                 short* __restrict__ lo, float scale) {
  const size_t i = ((size_t)blockIdx.x * 256 + threadIdx.x) * 4;
  f4v v = *(const f4v*)(src + i);
  s4v h, l;
  #pragma unroll
  for (int j = 0; j < 4; j++) {
    float t = v[j] * scale;
    h[j] = (short)f2b(t);
    l[j] = (short)f2b(t - b2f(h[j]));
  }
  *(s4v*)(hi + i) = h;
  *(s4v*)(lo + i) = l;
}

// sum = a + b (f32) elementwise; write bf16 + f32 (outf may alias a)
__global__ __launch_bounds__(256) void add_both(const float* __restrict__ a,
                                                const float* __restrict__ b,
                                                short* __restrict__ outb,
                                                float* outf) {
  const size_t i = ((size_t)blockIdx.x * 256 + threadIdx.x) * 4;
  f4v av = *(const f4v*)(a + i);
  f4v bv = *(const f4v*)(b + i);
  f4v s; s4v o;
  #pragma unroll
  for (int j = 0; j < 4; j++) { s[j] = av[j] + bv[j]; o[j] = (short)f2b(s[j]); }
  *(f4v*)(outf + i) = s;
  *(s4v*)(outb + i) = o;
}

// in-place softmax over bf16 rows of 1024; one wave per row, shuffle reduce
__global__ __launch_bounds__(256) void softmax_rows_b16(short* __restrict__ p) {
  const int row = blockIdx.x * 4 + (threadIdx.x >> 6);
  const int lane = threadIdx.x & 63;
  short* rp = p + (size_t)row * 1024 + lane * 16;
  s8v v0 = *(s8v*)rp, v1 = *(s8v*)(rp + 8);
  float f[16];
  #pragma unroll
  for (int j = 0; j < 8; j++) { f[j] = b2f(v0[j]); f[8 + j] = b2f(v1[j]); }
  float m = f[0];
  #pragma unroll
  for (int j = 1; j < 16; j++) m = fmaxf(m, f[j]);
  #pragma unroll
  for (int s = 32; s; s >>= 1) m = fmaxf(m, __shfl_xor(m, s, 64));
  float sum = 0.f;
  #pragma unroll
  for (int j = 0; j < 16; j++) { f[j] = __expf(f[j] - m); sum += f[j]; }
  #pragma unroll
  for (int s = 32; s; s >>= 1) sum += __shfl_xor(sum, s, 64);
  const float inv = 1.f / sum;
  #pragma unroll
  for (int j = 0; j < 8; j++) {
    v0[j] = (short)f2b(f[j] * inv);
    v1[j] = (short)f2b(f[8 + j] * inv);
  }
  *(s8v*)rp = v0; *(s8v*)(rp + 8) = v1;
}

// L2-normalize over axis=1 (N) of (NB,N,D) f32; deterministic 3-phase.
#define NCHUNK 16
__global__ __launch_bounds__(256) void norm_part(const float* __restrict__ t,
                                                 float* __restrict__ part, int NB) {
  const int d = blockIdx.x * 256 + threadIdx.x;
  const int b = blockIdx.y;
  const int c = blockIdx.z;
  const int n0 = c * (N_ / NCHUNK);
  const float* p = t + ((size_t)b * N_ + n0) * D_ + d;
  float ss = 0.f;
  for (int n = 0; n < N_ / NCHUNK; n++) { float v = p[(size_t)n * D_]; ss += v * v; }
  part[((size_t)c * NB + b) * D_ + d] = ss;
}
__global__ __launch_bounds__(256) void norm_inv(const float* __restrict__ part,
                                                float* __restrict__ inv, int NB) {
  const int i = blockIdx.x * 256 + threadIdx.x;   // b*D + d
  float ss = 0.f;
  for (int c = 0; c < NCHUNK; c++) ss += part[(size_t)c * (NB * D_) + i];
  inv[i] = 1.f / fmaxf(sqrtf(ss), 1e-12f);
}
__global__ __launch_bounds__(256) void norm_scale(const float* __restrict__ t,
                                                  const float* __restrict__ inv,
                                                  short* __restrict__ outh,
                                                  short* __restrict__ outl,
                                                  float* __restrict__ outf) {
  const size_t i = ((size_t)blockIdx.x * 256 + threadIdx.x) * 4;
  const int b = (int)(i >> 19);        // N_*D_ = 2^19
  const int d = (int)(i & (D_ - 1));
  f4v v = *(const f4v*)(t + i);
  f4v w = *(const f4v*)(inv + (size_t)b * D_ + d);
  f4v o; s4v oh, ol;
  #pragma unroll
  for (int j = 0; j < 4; j++) {
    o[j] = v[j] * w[j];
    oh[j] = (short)f2b(o[j]);
    ol[j] = (short)f2b(o[j] - b2f(oh[j]));
  }
  *(f4v*)(outf + i) = o;
  *(s4v*)(outh + i) = oh;
  *(s4v*)(outl + i) = ol;
}

extern "C" void kernel_launch(void* const* d_in, const int* in_sizes, int n_in,
                              void* d_out, int out_size, void* d_ws, size_t ws_size,
                              hipStream_t stream) {
  (void)in_sizes; (void)n_in; (void)out_size; (void)ws_size;
  const float* in1f = (const float*)d_in[0];
  const float* in2f = (const float*)d_in[1];

  const size_t SB = (size_t)B_ * N_ * D_ * 2;      // 8 MB
  const size_t SF = (size_t)B_ * N_ * D_ * 4;      // 16 MB
  const size_t WL = (size_t)L_ * D_ * D_ * 2;
  const size_t W1 = (size_t)D_ * D_ * 2;
  const long SBel = (long)B_ * N_ * D_;            // 4194304 elems
  const long sAct = (long)N_ * D_;
  const long sAff = (long)N_ * N_;

  char* ws = (char*)d_ws;
  size_t off = 0;
  auto alloc = [&](size_t bytes) -> char* {
    char* p = ws + off;
    off += (bytes + 255) & ~(size_t)255;
    return p;
  };

  // ---- weight region (19 MB); a1/a2 overlay after stage 1 ----
  char* wreg = alloc(8 * WL + 6 * W1);
  short* c_thT_h = (short*)(wreg);
  short* c_thT_l = (short*)(wreg + WL);
  short* c_phT_h = (short*)(wreg + 2 * WL);
  short* c_phT_l = (short*)(wreg + 3 * WL);
  short* c_rhT_h = (short*)(wreg + 4 * WL);
  short* c_rhT_l = (short*)(wreg + 5 * WL);
  short* c_psT_h = (short*)(wreg + 6 * WL);
  short* c_psT_l = (short*)(wreg + 7 * WL);
  short* c_intT_h = (short*)(wreg + 8 * WL);
  short* c_intT_l = (short*)(wreg + 8 * WL + W1);
  short* c_f1T_h  = (short*)(wreg + 8 * WL + 2 * W1);
  short* c_f1T_l  = (short*)(wreg + 8 * WL + 3 * W1);
  short* c_f2T_h  = (short*)(wreg + 8 * WL + 4 * W1);
  short* c_f2T_l  = (short*)(wreg + 8 * WL + 5 * W1);
  short* a1_thT = (short*)(wreg);
  short* a1_phT = (short*)(wreg + WL);
  short* a1_rhT = (short*)(wreg + 2 * WL);
  short* a2_thT = (short*)(wreg + 3 * WL);
  short* a2_phT = (short*)(wreg + 4 * WL);
  short* a2_rhT = (short*)(wreg + 5 * WL);
  char*  aw = wreg + 6 * WL;
  short* a1_intT_h = (short*)(aw);
  short* a1_intT_l = (short*)(aw + W1);
  short* a1_f1T_h  = (short*)(aw + 2 * W1);
  short* a1_f1T_l  = (short*)(aw + 3 * W1);
  short* a1_f2T_h  = (short*)(aw + 4 * W1);
  short* a1_f2T_l  = (short*)(aw + 5 * W1);
  short* a2_intT_h = (short*)(aw + 6 * W1);
  short* a2_intT_l = (short*)(aw + 7 * W1);
  short* a2_f1T_h  = (short*)(aw + 8 * W1);
  short* a2_f1T_l  = (short*)(aw + 9 * W1);
  short* a2_f2T_h  = (short*)(aw + 10 * W1);
  short* a2_f2T_l  = (short*)(aw + 11 * W1);

  // ---- pair-contiguous activation regions (2*SB each = 16 MB) ----
  short* in12h = (short*)alloc(2 * SB);   // in1h|in2h -> feed12b -> sumb
  short* in12l = (short*)alloc(2 * SB);   // in1l|in2l -> resh
  short* bufA  = (short*)alloc(2 * SB);   // thh|thl -> inth -> hidh
  short* bufB  = (short*)alloc(2 * SB);   // phh|phl -> intl -> hidl
  short* bufC  = (short*)alloc(2 * SB);   // rhT|psT -> resl
  char*  affU  = alloc((size_t)32 * 1024 * 1024);
  float* accR  = (float*)alloc(2 * SF);   // acc1|acc2 / acc16 / tmpf
  float* feedfR = (float*)alloc(2 * SF);  // feed12f -> self12f -> sumf
  float* npart = (float*)alloc((size_t)NCHUNK * 16 * D_ * 4);
  float* ninv  = (float*)alloc((size_t)16 * D_ * 4);
  // total ≈ 196 MB (< proven 217)

  short* in1h = in12h;        short* in2h = in12h + SBel;
  short* in1l = in12l;        short* in2l = in12l + SBel;
  short* thh = bufA;          short* thl = bufA + SBel;
  short* phh = bufB;          short* phl = bufB + SBel;
  short* rhT = bufC;          short* psT = bufC + SBel;
  short* affh = (short*)affU;                   // [0,16 MB)
  short* affl = affh + SBel * 2;                // [16,32 MB)
  short* aff16 = (short*)affU;                  // 32 MB bf16 batch-16 logits
  float* resfP = (float*)affU;                  // 32 MB f32 res (affs dead)
  float* acc1 = accR;         float* acc2 = accR + SBel;

  const float scl = 0.04419417382415922f;   // 512^-0.5
  dim3 tb(32, 8);
  const int GE = (B_ * N_ * D_) / (4 * 256);     // 4096
  #define F32P(i) ((const float*)d_in[i])

  auto GA = [&]() { GArgs a; __builtin_memset(&a, 0, sizeof(a)); return a; };
  auto normalize = [&](const float* src, int NB, short* outh, short* outl, float* outf) {
    norm_part<<<dim3(D_/256, NB, NCHUNK), 256, 0, stream>>>(src, npart, NB);
    norm_inv<<<(NB * D_) / 256, 256, 0, stream>>>(npart, ninv, NB);
    norm_scale<<<NB * 512, 256, 0, stream>>>(src, ninv, outh, outl, outf);
  };

  // ---- stage-1 weights + input split ----
  wt_cvt_t2<<<dim3(16,16,L_), tb, 0, stream>>>(F32P(2),  c_thT_h, c_thT_l);
  wt_cvt_t2<<<dim3(16,16,L_), tb, 0, stream>>>(F32P(4),  c_phT_h, c_phT_l);
  wt_cvt_t2<<<dim3(16,16,L_), tb, 0, stream>>>(F32P(6),  c_rhT_h, c_rhT_l);
  wt_cvt_t2<<<dim3(16,16,L_), tb, 0, stream>>>(F32P(8),  c_psT_h, c_psT_l);
  wt_cvt_t2<<<dim3(16,16,1),  tb, 0, stream>>>(F32P(10), c_intT_h, c_intT_l);
  wt_cvt_t2<<<dim3(16,16,1),  tb, 0, stream>>>(F32P(12), c_f1T_h, c_f1T_l);
  wt_cvt_t2<<<dim3(16,16,1),  tb, 0, stream>>>(F32P(14), c_f2T_h, c_f2T_l);
  split_f32<<<GE, 256, 0, stream>>>(in1f, in1h, in1l, 1.0f);
  split_f32<<<GE, 256, 0, stream>>>(in2f, in2h, in2l, 1.0f);

  // ---- stage 1: 4-seg proj -> split affinity -> 2-seg apply ----
  for (int i = 0; i < L_; i++) {
    const size_t wo = (size_t)i * D_ * D_;
    const size_t bo = (size_t)i * D_;
    { GArgs a = GA();
      a.Ah[0] = in1h; a.Ah[1] = in1h; a.Ah[2] = in2h; a.Ah[3] = in2h;
      a.Al[0] = in1l; a.Al[1] = in1l; a.Al[2] = in2l; a.Al[3] = in2l;
      a.Bh[0] = c_thT_h + wo; a.Bh[1] = c_rhT_h + wo;
      a.Bh[2] = c_phT_h + wo; a.Bh[3] = c_psT_h + wo;
      a.Bl[0] = c_thT_l + wo; a.Bl[1] = c_rhT_l + wo;
      a.Bl[2] = c_phT_l + wo; a.Bl[3] = c_psT_l + wo;
      a.C0[0] = thh; a.C0[1] = rhT; a.C0[2] = phh; a.C0[3] = psT;
      a.C1[0] = thl; a.C1[2] = phl;
      a.bias[0] = F32P(3) + bo; a.bias[1] = F32P(7) + bo;
      a.bias[2] = F32P(5) + bo; a.bias[3] = F32P(9) + bo;
      a.Nn = 512; a.K = 512;
      gemm_k<2,2,EPI_PROJ4,0><<<dim3(64,16,1),256,0,stream>>>(a); }
    { GArgs a = GA();
      a.Ah[0] = thh; a.Al[0] = thl; a.sA = sAct;
      a.Bh[0] = phh; a.Bl[0] = phl; a.sB = sAct;
      a.C0[0] = affh; a.C1[0] = affl; a.sC = sAff;
      a.alpha = scl; a.Nn = 1024; a.K = 512;
      gemm_k<2,2,EPI_SPLIT_SCALE,1><<<dim3(8,8,B_),256,0,stream>>>(a); }
    { GArgs a = GA();
      a.Ah[0] = affh; a.Ah[1] = affh; a.Al[0] = affl; a.Al[1] = affl; a.sA = sAff;
      a.Bh[0] = rhT; a.Bh[1] = psT; a.sB = sAct;
      a.C0[0] = acc1; a.C0[1] = acc2; a.sC = sAct;
      a.Nn = 512; a.K = 1024;
      if (i == 0) {
        gemm_k<2,1,EPI_ACC2_ST,1><<<dim3(8,8,B_),256,0,stream>>>(a);
      } else if (i < L_ - 1) {
        gemm_k<2,1,EPI_ACC2,1><<<dim3(8,8,B_),256,0,stream>>>(a);
      } else {
        a.C1[0] = bufA; a.C1[1] = bufA + SBel;   // inth (stream1|stream2)
        a.C1[2] = bufB; a.C1[3] = bufB + SBel;   // intl
        a.alpha = 0.25f;
        gemm_k<2,1,EPI_ACC2_SPLIT,1><<<dim3(8,8,B_),256,0,stream>>>(a);
      } }
  }

  // ---- stage-1 epilogue, both streams batched (z=2 / M=16384) ----
  { GArgs a = GA();
    a.Ah[0] = bufA; a.Al[0] = bufB; a.sA = SBel;
    a.Bh[0] = c_intT_h; a.Bl[0] = c_intT_l;
    a.C0[0] = accR; a.sC = SBel;
    a.bias[0] = F32P(11); a.Rv = in1f; a.Rv2 = in2f;
    a.Nn = 512; a.K = 512;
    gemm_k<2,2,EPI_F32_BIAS_R,1><<<dim3(64,4,2),256,0,stream>>>(a); }
  normalize(accR, 16, in12l, bufA, resfP);       // resh|resl (resf scratch)
  { GArgs a = GA();
    a.Ah[0] = in12l; a.Al[0] = bufA;
    a.Bh[0] = c_f1T_h; a.Bl[0] = c_f1T_l;
    a.C0[0] = bufB; a.C1[0] = bufC;              // hidh|hidl
    a.bias[0] = F32P(13); a.Nn = 512; a.K = 512;
    gemm_k<2,2,EPI_SPLIT_BIAS,1><<<dim3(128,4,1),256,0,stream>>>(a); }
  { GArgs a = GA();
    a.Ah[0] = bufB; a.Al[0] = bufC;
    a.Bh[0] = c_f2T_h; a.Bl[0] = c_f2T_l;
    a.C0[0] = in12h; a.C1[0] = feedfR;           // feed12b | feed12f
    a.bias[0] = F32P(15); a.Nn = 512; a.K = 512;
    gemm_k<2,2,EPI_BOTH_LEAKY,1><<<dim3(128,4,1),256,0,stream>>>(a); }

  // ---- a1/a2 weights (overlay dead stage-1 weights) ----
  wt_cvt_t<<<dim3(16,16,L_), tb, 0, stream>>>(F32P(16), a1_thT);
  wt_cvt_t<<<dim3(16,16,L_), tb, 0, stream>>>(F32P(18), a1_phT);
  wt_cvt_t<<<dim3(16,16,L_), tb, 0, stream>>>(F32P(20), a1_rhT);
  wt_cvt_t2<<<dim3(16,16,1), tb, 0, stream>>>(F32P(22), a1_intT_h, a1_intT_l);
  wt_cvt_t2<<<dim3(16,16,1), tb, 0, stream>>>(F32P(24), a1_f1T_h, a1_f1T_l);
  wt_cvt_t2<<<dim3(16,16,1), tb, 0, stream>>>(F32P(26), a1_f2T_h, a1_f2T_l);
  wt_cvt_t<<<dim3(16,16,L_), tb, 0, stream>>>(F32P(28), a2_thT);
  wt_cvt_t<<<dim3(16,16,L_), tb, 0, stream>>>(F32P(30), a2_phT);
  wt_cvt_t<<<dim3(16,16,L_), tb, 0, stream>>>(F32P(32), a2_rhT);
  wt_cvt_t2<<<dim3(16,16,1), tb, 0, stream>>>(F32P(34), a2_intT_h, a2_intT_l);
  wt_cvt_t2<<<dim3(16,16,1), tb, 0, stream>>>(F32P(36), a2_f1T_h, a2_f1T_l);
  wt_cvt_t2<<<dim3(16,16,1), tb, 0, stream>>>(F32P(38), a2_f2T_h, a2_f2T_l);

  // ---- generic agi chain over NZ batches (NZ=16 pair, NZ=8 final) ----
  auto agi = [&](int NZ, const short* xb, const float* xf,
                 const short* thT, const float* thB,
                 const short* phT, const float* phB,
                 const short* rhT_, const float* rhB,
                 const short* inTh, const short* inTl, const float* inB,
                 const short* f1Th, const short* f1Tl, const float* f1B,
                 const short* f2Th, const short* f2Tl, const float* f2B,
                 float* outf) {
    const int MB = NZ / B_;                  // 2 or 1 (stream multiplier)
    for (int i = 0; i < L_; i++) {
      const size_t wo = (size_t)i * D_ * D_;
      const size_t bo = (size_t)i * D_;
      { GArgs a = GA();
        a.Ah[0] = xb; a.Ah[1] = xb; a.Ah[2] = xb;
        a.Bh[0] = thT + wo; a.Bh[1] = phT + wo; a.Bh[2] = rhT_ + wo;
        a.C0[0] = bufA; a.C0[1] = bufB; a.C0[2] = bufC;
        a.bias[0] = thB + bo; a.bias[1] = phB + bo; a.bias[2] = rhB + bo;
        a.Nn = 512; a.K = 512;
        gemm_k<1,1,EPI_PROJ3,1><<<dim3(64*MB,12,1),256,0,stream>>>(a); }
      { GArgs a = GA();
        a.Ah[0] = bufA; a.sA = sAct; a.Bh[0] = bufB; a.sB = sAct;
        a.C0[0] = aff16; a.sC = sAff; a.alpha = scl; a.Nn = 1024; a.K = 512;
        gemm_k<1,1,EPI_B16_SCALE,1><<<dim3(8,8,NZ),256,0,stream>>>(a); }
      softmax_rows_b16<<<NZ * 256, 256, 0, stream>>>(aff16);
      { GArgs a = GA();
        a.Ah[0] = aff16; a.sA = sAff; a.Bh[0] = bufC; a.sB = sAct;
        a.C0[0] = accR; a.sC = sAct; a.Nn = 512; a.K = 1024;
        if (i == 0) {
          gemm_k<1,1,EPI_F32_ST,1><<<dim3(8,4,NZ),256,0,stream>>>(a);
        } else if (i < L_ - 1) {
          gemm_k<1,1,EPI_F32_ACC,1><<<dim3(8,4,NZ),256,0,stream>>>(a);
        } else {
          a.C1[0] = bufA; a.C1[1] = bufB; a.alpha = 0.25f;
          gemm_k<1,1,EPI_ACC_SPLIT,1><<<dim3(8,4,NZ),256,0,stream>>>(a);
        } }
    }
    { GArgs a = GA();
      a.Ah[0] = bufA; a.Al[0] = bufB;
      a.Bh[0] = inTh; a.Bl[0] = inTl;
      a.C0[0] = accR; a.bias[0] = inB; a.Rv = xf; a.Rv2 = xf;
      a.Nn = 512; a.K = 512;
      gemm_k<2,2,EPI_F32_BIAS_R,1><<<dim3(64*MB,4,1),256,0,stream>>>(a); }
    normalize(accR, NZ, in12l, bufC, resfP);     // resh|resl, resf -> affU
    { GArgs a = GA();
      a.Ah[0] = in12l; a.Al[0] = bufC;
      a.Bh[0] = f1Th; a.Bl[0] = f1Tl;
      a.C0[0] = bufA; a.C1[0] = bufB;            // hidh|hidl
      a.bias[0] = f1B; a.Nn = 512; a.K = 512;
      gemm_k<2,2,EPI_SPLIT_BIAS,1><<<dim3(64*MB,4,1),256,0,stream>>>(a); }
    { GArgs a = GA();
      a.Ah[0] = bufA; a.Al[0] = bufB;
      a.Bh[0] = f2Th; a.Bl[0] = f2Tl;
      a.C0[0] = accR; a.bias[0] = f2B; a.Rv = resfP;
      a.Nn = 512; a.K = 512;
      gemm_k<2,2,EPI_LEAKY_R,1><<<dim3(64*MB,4,1),256,0,stream>>>(a); }
    normalize(accR, NZ, bufA, bufB, outf);       // bf16 outs are scratch
  };

  // agi1 on feed1+feed2 as one batch-16 chain (shared AGI_1 weights)
  agi(16, in12h, feedfR,
      a1_thT, F32P(17), a1_phT, F32P(19), a1_rhT, F32P(21),
      a1_intT_h, a1_intT_l, F32P(23), a1_f1T_h, a1_f1T_l, F32P(25),
      a1_f2T_h, a1_f2T_l, F32P(27), feedfR);     // self12f -> feedfR

  add_both<<<GE, 256, 0, stream>>>(feedfR, feedfR + SBel, in12h, feedfR);

  agi(8, in12h, feedfR,
      a2_thT, F32P(29), a2_phT, F32P(31), a2_rhT, F32P(33),
      a2_intT_h, a2_intT_l, F32P(35), a2_f1T_h, a2_f1T_l, F32P(37),
      a2_f2T_h, a2_f2T_l, F32P(39), (float*)d_out);
}

// Round 10
// 1778.430 us; speedup vs baseline: 1.5583x; 1.0235x over previous
//
#include <hip/hip_runtime.h>

// ACGI_32195074850822 — round 9: counted-vmcnt double-buffered K-loop (T4).
//  Round-8's __syncthreads drained vmcnt(0) -> prefetched tile forced to
//  COMPLETE at the barrier (no overlap). Now: raw s_barrier + inline
//  s_waitcnt vmcnt(NLD) keeps the next tile's global_load_lds in flight
//  across the MFMAs. NLD = loads/stage (compile-time). Everything else
//  identical to round 8. Numerics bit-identical (canary 2.441406e-3).

#define B_ 8
#define N_ 1024
#define D_ 512
#define L_ 4

typedef short s8v __attribute__((ext_vector_type(8)));
typedef short s4v __attribute__((ext_vector_type(4)));
typedef float f4v __attribute__((ext_vector_type(4)));

__device__ __forceinline__ unsigned short f2b(float f) {
  unsigned u = __builtin_bit_cast(unsigned, f);
  u += 0x7FFFu + ((u >> 16) & 1u);          // round-to-nearest-even
  return (unsigned short)(u >> 16);
}
__device__ __forceinline__ float b2f(short s) {
  unsigned u = ((unsigned)(unsigned short)s) << 16;
  return __builtin_bit_cast(float, u);
}

__device__ __forceinline__ void glds16(const short* g, short* l) {
  __builtin_amdgcn_global_load_lds(
      (const __attribute__((address_space(1))) void*)g,
      (__attribute__((address_space(3))) void*)l, 16, 0, 0);
}

enum {
  EPI_PROJ4 = 0,   // seg even: split(acc+bias)->C0/C1; seg odd: TR(acc+bias)->C0
  EPI_PROJ3,       // seg 0,1: bf16(acc+bias)->C0; seg 2: TR->C0
  EPI_SPLIT_SCALE, // C0 hi, C1 lo of acc*alpha
  EPI_B16_SCALE,   // C0 bf16 = acc*alpha
  EPI_ACC2,        // seg s: C0[s] f32 += acc   (z-batched)
  EPI_ACC2_ST,     // seg s: C0[s] f32 = acc    (layer 0)
  EPI_F32_ACC,     // C0[0] f32 += acc          (z-batched)
  EPI_F32_ST,      // C0[0] f32 = acc           (layer 0)
  EPI_F32_BIAS_R,  // C0 f32 = acc+bias+R; R base by z (Rv / Rv2), local idx
  EPI_SPLIT_BIAS,  // C0 hi, C1 lo of acc+bias
  EPI_BOTH_LEAKY,  // C0 bf16 AND C1 f32 = leaky(acc+bias)
  EPI_LEAKY_R,     // C0 f32 = leaky(acc+bias) + R (flat)
  EPI_ACC2_SPLIT,  // seg s: t=(C0[s]+acc)*alpha; hi->C1[s], lo->C1[2+s]
  EPI_ACC_SPLIT    // t=(C0[0]+acc)*alpha; hi->C1[0], lo->C1[1] (z-batched)
};

struct GArgs {
  const short* Ah[4]; const short* Al[4];
  const short* Bh[4]; const short* Bl[4];
  long sA, sB;
  void* C0[4]; void* C1[4];
  long sC;
  const float* bias[4];
  const void* Rv; const void* Rv2;
  float alpha;
  int Nn, K;
};

// C = (ΣA_c)(ΣB_c)^T, bf16 comps, f32 accum; <2,2> drops Al*Bl.
// 128x128 tile, 4 waves, global_load_lds(16B) + both-sides XOR swizzle.
// DB=1: double-buffered staging, counted vmcnt (loads stay in flight).
template<int AS, int BS, int EPI, int DB>
__global__ __launch_bounds__(256) void gemm_k(GArgs g) {
  constexpr int TILE = (AS + BS) * 4096;        // shorts per staging buffer
  __shared__ short smem[TILE * (DB ? 2 : 1)];
  constexpr bool SEG = (EPI == EPI_PROJ4 || EPI == EPI_PROJ3 ||
                        EPI == EPI_ACC2 || EPI == EPI_ACC2_ST ||
                        EPI == EPI_ACC2_SPLIT);
  constexpr bool LDSOUT = (EPI == EPI_PROJ4 || EPI == EPI_PROJ3 ||
                           EPI == EPI_SPLIT_SCALE || EPI == EPI_B16_SCALE ||
                           EPI == EPI_SPLIT_BIAS || EPI == EPI_BOTH_LEAKY ||
                           EPI == EPI_ACC2_SPLIT || EPI == EPI_ACC_SPLIT);
  constexpr int CC = (EPI == EPI_PROJ4 || EPI == EPI_SPLIT_SCALE ||
                      EPI == EPI_SPLIT_BIAS || EPI == EPI_ACC2_SPLIT ||
                      EPI == EPI_ACC_SPLIT) ? 2 : 1;
  const int z = blockIdx.z;
  const int tm = blockIdx.x * 128;
  const int tn = blockIdx.y * 128;
  const int tid = threadIdx.x;
  const int lane = tid & 63;
  const int w = tid >> 6;
  const int wr = (w >> 1) * 64, wc = (w & 1) * 64;
  const int r16 = lane & 15, kg = lane >> 4;
  const int K = g.K;

  int seg = 0, tnl = tn;
  if constexpr (SEG) { seg = tn >> 9; tnl = tn & 511; }
  const short* Ah = g.Ah[seg];
  const short* Al = (AS == 2) ? g.Al[seg] : nullptr;
  const short* Bh = g.Bh[seg];
  const short* Bl = (BS == 2) ? g.Bl[seg] : nullptr;

  const int srow = lane >> 2;
  const int scol = ((lane & 3) ^ ((lane >> 3) & 3)) * 8;
  const short* gA[2]; const short* gB[2];
  gA[0] = Ah + (size_t)z * g.sA + (size_t)(tm + w * 16 + srow) * K + scol;
  if constexpr (AS == 2)
    gA[1] = Al + (size_t)z * g.sA + (size_t)(tm + w * 16 + srow) * K + scol;
  gB[0] = Bh + (size_t)z * g.sB + (size_t)(tnl + w * 16 + srow) * K + scol;
  if constexpr (BS == 2)
    gB[1] = Bl + (size_t)z * g.sB + (size_t)(tnl + w * 16 + srow) * K + scol;
  const size_t hoff = (size_t)64 * K;

  auto stage = [&](int k0, int buf) {
    short* base = smem + buf * TILE;
    #pragma unroll
    for (int c = 0; c < AS; c++) {
      glds16(gA[c] + k0, base + c * 4096 + (w * 16) * 32);
      glds16(gA[c] + hoff + k0, base + c * 4096 + (64 + w * 16) * 32);
    }
    #pragma unroll
    for (int c = 0; c < BS; c++) {
      glds16(gB[c] + k0, base + (AS + c) * 4096 + (w * 16) * 32);
      glds16(gB[c] + hoff + k0, base + (AS + c) * 4096 + (64 + w * 16) * 32);
    }
  };

  f4v acc[4][4];
  #pragma unroll
  for (int i = 0; i < 4; i++)
    #pragma unroll
    for (int j = 0; j < 4; j++) acc[i][j] = (f4v)0.f;

  const int rc = (kg ^ ((r16 >> 1) & 3)) * 8;

  auto compute = [&](int buf) {
    const short* base = smem + buf * TILE;
    s8v va[2][4], vb[2][4];
    #pragma unroll
    for (int c = 0; c < AS; c++)
      #pragma unroll
      for (int i = 0; i < 4; i++)
        va[c][i] = *(const s8v*)&base[c * 4096 + (wr + i * 16 + r16) * 32 + rc];
    #pragma unroll
    for (int c = 0; c < BS; c++)
      #pragma unroll
      for (int i = 0; i < 4; i++)
        vb[c][i] = *(const s8v*)&base[(AS + c) * 4096 + (wc + i * 16 + r16) * 32 + rc];
    #pragma unroll
    for (int ca = 0; ca < AS; ca++)
      #pragma unroll
      for (int cb = 0; cb < BS; cb++) {
        if (ca == 1 && cb == 1) continue;   // drop lo*lo
        #pragma unroll
        for (int mi = 0; mi < 4; mi++)
          #pragma unroll
          for (int ni = 0; ni < 4; ni++)
            acc[mi][ni] = __builtin_amdgcn_mfma_f32_16x16x32_bf16(
                va[ca][mi], vb[cb][ni], acc[mi][ni], 0, 0, 0);
      }
  };

  const int nt = K >> 5;
  if constexpr (DB) {
    constexpr int NLD = (AS + BS) * 2;        // vmcnt events per stage
    stage(0, 0);                              // NLD in flight
    int buf = 0;
    for (int t = 0; t < nt; t++) {
      if (t + 1 < nt) {
        stage((t + 1) * 32, buf ^ 1);         // + NLD (2*NLD total)
        // wait ONLY for tile t (oldest NLD); tile t+1 stays in flight
        if constexpr (NLD == 8)      asm volatile("s_waitcnt vmcnt(8)" ::: "memory");
        else if constexpr (NLD == 6) asm volatile("s_waitcnt vmcnt(6)" ::: "memory");
        else                         asm volatile("s_waitcnt vmcnt(4)" ::: "memory");
      } else {
        asm volatile("s_waitcnt vmcnt(0)" ::: "memory");
      }
      __builtin_amdgcn_sched_barrier(0);      // rule-18 fence
      __builtin_amdgcn_s_barrier();           // raw: no vmcnt drain
      compute(buf);
      __builtin_amdgcn_s_barrier();           // reads done before overwrite
      buf ^= 1;
    }
  } else {
    for (int t = 0; t < nt; t++) {
      stage(t * 32, 0);
      __syncthreads();
      compute(0);
      __syncthreads();
    }
  }

  short* C0s = (short*)g.C0[seg];  float* C0f = (float*)g.C0[seg];
  short* C1s = (short*)g.C1[seg];  float* C1f = (float*)g.C1[seg];
  const float* biasp = g.bias[seg];
  const int NnL = g.Nn;

  if constexpr (LDSOUT) {
    bool tr = false;
    if constexpr (EPI == EPI_PROJ4) tr = (seg & 1);
    if constexpr (EPI == EPI_PROJ3) tr = (seg == 2);
    if (tr) {
      // transposed write (s4v along n, 8B-coalesced)
      #pragma unroll
      for (int mi = 0; mi < 4; mi++) {
        #pragma unroll
        for (int ni = 0; ni < 4; ni++) {
          const int colL = tnl + wc + ni * 16 + r16;
          const int grow0 = tm + wr + mi * 16 + kg * 4;
          const float bv = biasp[colL];
          s4v o;
          #pragma unroll
          for (int r = 0; r < 4; r++) o[r] = (short)f2b(acc[mi][ni][r] + bv);
          const int b = grow0 >> 10, n = grow0 & 1023;
          *(s4v*)&C0s[((size_t)b * 512 + colL) * 1024 + n] = o;
        }
      }
    } else {
      short* D0 = nullptr; short* D1 = nullptr;
      if constexpr (EPI == EPI_PROJ4 || EPI == EPI_PROJ3) {
        D0 = C0s; D1 = C1s;
      } else if constexpr (EPI == EPI_SPLIT_SCALE || EPI == EPI_SPLIT_BIAS) {
        D0 = C0s + (size_t)z * g.sC; D1 = C1s + (size_t)z * g.sC;
      } else if constexpr (EPI == EPI_B16_SCALE || EPI == EPI_BOTH_LEAKY) {
        D0 = C0s + (size_t)z * g.sC;
      } else if constexpr (EPI == EPI_ACC2_SPLIT) {
        D0 = (short*)g.C1[seg] + (size_t)z * g.sC;
        D1 = (short*)g.C1[2 + seg] + (size_t)z * g.sC;
      } else { // EPI_ACC_SPLIT
        D0 = (short*)g.C1[0] + (size_t)z * g.sC;
        D1 = (short*)g.C1[1] + (size_t)z * g.sC;
      }
      for (int mi = 0; mi < 4; mi++) {
        #pragma unroll
        for (int ni = 0; ni < 4; ni++) {
          const int lcol = wc + ni * 16 + r16;
          const int colL = tnl + lcol;
          float bv = 0.f;
          if constexpr (EPI == EPI_PROJ4 || EPI == EPI_PROJ3 ||
                        EPI == EPI_SPLIT_BIAS || EPI == EPI_BOTH_LEAKY)
            bv = biasp[colL];
          #pragma unroll
          for (int r = 0; r < 4; r++) {
            const int grow = tm + wr + mi * 16 + kg * 4 + r;
            const float v = acc[mi][ni][r];
            float t;
            if constexpr (EPI == EPI_SPLIT_SCALE || EPI == EPI_B16_SCALE)
              t = v * g.alpha;
            else if constexpr (EPI == EPI_ACC2_SPLIT || EPI == EPI_ACC_SPLIT)
              t = (C0f[(size_t)z * g.sC + (size_t)grow * NnL + colL] + v) * g.alpha;
            else if constexpr (EPI == EPI_BOTH_LEAKY) {
              t = v + bv; t = (t >= 0.f) ? t : 0.01f * t;
              C1f[(size_t)z * g.sC + (size_t)grow * NnL + colL] = t;
            } else
              t = v + bv;
            const int lrow = (w >> 1) * 16 + kg * 4 + r;
            const int sw = ((lrow >> 2) & 3) << 4;          // bank swizzle
            const int li = lrow * 128 + (lcol ^ sw);
            const short h = (short)f2b(t);
            smem[li] = h;
            if constexpr (CC == 2) smem[4096 + li] = (short)f2b(t - b2f(h));
          }
        }
        __syncthreads();
        #pragma unroll
        for (int c2 = 0; c2 < CC; c2++) {
          short* D = c2 ? D1 : D0;
          #pragma unroll
          for (int half = 0; half < 2; half++) {
            const int e = (tid + half * 256) * 8;
            const int lrow2 = e >> 7, col = e & 127;
            const int sw2 = ((lrow2 >> 2) & 3) << 4;
            const int grow = tm + (lrow2 >> 4) * 64 + mi * 16 + (lrow2 & 15);
            *(s8v*)&D[(size_t)grow * NnL + tnl + col] =
                *(const s8v*)&smem[c2 * 4096 + (lrow2 << 7) + (col ^ sw2)];
          }
        }
        __syncthreads();
      }
    }
  } else {
    // direct f32 epilogues (coalesced 64B/group)
    #pragma unroll
    for (int mi = 0; mi < 4; mi++) {
      #pragma unroll
      for (int ni = 0; ni < 4; ni++) {
        const int colL = tnl + wc + ni * 16 + r16;
        const int grow0 = tm + wr + mi * 16 + kg * 4;
        float bv = 0.f;
        if constexpr (EPI == EPI_F32_BIAS_R || EPI == EPI_LEAKY_R)
          bv = biasp[colL];
        #pragma unroll
        for (int r = 0; r < 4; r++) {
          const size_t lidx = (size_t)(grow0 + r) * NnL + colL;
          const size_t idx = (size_t)z * g.sC + lidx;
          const float v = acc[mi][ni][r];
          if constexpr (EPI == EPI_ACC2) {
            C0f[(size_t)z * g.sC + (size_t)(grow0 + r) * 512 + colL] += v;
          } else if constexpr (EPI == EPI_ACC2_ST) {
            C0f[(size_t)z * g.sC + (size_t)(grow0 + r) * 512 + colL] = v;
          } else if constexpr (EPI == EPI_F32_ACC) {
            C0f[idx] += v;
          } else if constexpr (EPI == EPI_F32_ST) {
            C0f[idx] = v;
          } else if constexpr (EPI == EPI_F32_BIAS_R) {
            const float* Rf = (const float*)(z == 0 ? g.Rv : g.Rv2);
            C0f[idx] = v + bv + Rf[lidx];
          } else { // EPI_LEAKY_R
            float t = v + bv; t = (t >= 0.f) ? t : 0.01f * t;
            C0f[idx] = t + ((const float*)g.Rv)[idx];
          }
        }
      }
    }
  }
}

// f32 (z,D,D) -> bf16 transposed, single
__global__ __launch_bounds__(256) void wt_cvt_t(const float* __restrict__ src,
                                                short* __restrict__ dst) {
  __shared__ float t[32][33];
  const int bx = blockIdx.x * 32, by = blockIdx.y * 32;
  const size_t zo = (size_t)blockIdx.z * D_ * D_;
  const int tx = threadIdx.x, ty = threadIdx.y;
  #pragma unroll
  for (int k = 0; k < 4; k++)
    t[ty + 8 * k][tx] = src[zo + (size_t)(by + ty + 8 * k) * D_ + bx + tx];
  __syncthreads();
  #pragma unroll
  for (int k = 0; k < 4; k++)
    dst[zo + (size_t)(bx + ty + 8 * k) * D_ + by + tx] = (short)f2b(t[tx][ty + 8 * k]);
}

// f32 (z,D,D) -> bf16 transposed hi+lo
__global__ __launch_bounds__(256) void wt_cvt_t2(const float* __restrict__ src,
                                                 short* __restrict__ hi,
                                                 short* __restrict__ lo) {
  __shared__ float t[32][33];
  const int bx = blockIdx.x * 32, by = blockIdx.y * 32;
  const size_t zo = (size_t)blockIdx.z * D_ * D_;
  const int tx = threadIdx.x, ty = threadIdx.y;
  #pragma unroll
  for (int k = 0; k < 4; k++)
    t[ty + 8 * k][tx] = src[zo + (size_t)(by + ty + 8 * k) * D_ + bx + tx];
  __syncthreads();
  #pragma unroll
  for (int k = 0; k < 4; k++) {
    const size_t o = zo + (size_t)(bx + ty + 8 * k) * D_ + by + tx;
    float v = t[tx][ty + 8 * k];
    short h = (short)f2b(v);
    hi[o] = h;
    lo[o] = (short)f2b(v - b2f(h));
  }
}

// f32 * scale -> hi bf16 + lo bf16
__global__ __launch_bounds__(256) void split_f32(const float* __restrict__ src,
                                                 short* __restrict__ hi,
                                                 short* __restrict__ lo, float scale) {
  const size_t i = ((size_t)blockIdx.x * 256 + threadIdx.x) * 4;
  f4v v = *(const f4v*)(src + i);
  s4v h, l;
  #pragma unroll
  for (int j = 0; j < 4; j++) {
    float t = v[j] * scale;
    h[j] = (short)f2b(t);
    l[j] = (short)f2b(t - b2f(h[j]));
  }
  *(s4v*)(hi + i) = h;
  *(s4v*)(lo + i) = l;
}

// sum = a + b (f32) elementwise; write bf16 + f32 (outf may alias a)
__global__ __launch_bounds__(256) void add_both(const float* __restrict__ a,
                                                const float* __restrict__ b,
                                                short* __restrict__ outb,
                                                float* outf) {
  const size_t i = ((size_t)blockIdx.x * 256 + threadIdx.x) * 4;
  f4v av = *(const f4v*)(a + i);
  f4v bv = *(const f4v*)(b + i);
  f4v s; s4v o;
  #pragma unroll
  for (int j = 0; j < 4; j++) { s[j] = av[j] + bv[j]; o[j] = (short)f2b(s[j]); }
  *(f4v*)(outf + i) = s;
  *(s4v*)(outb + i) = o;
}

// in-place softmax over bf16 rows of 1024; one wave per row, shuffle reduce
__global__ __launch_bounds__(256) void softmax_rows_b16(short* __restrict__ p) {
  const int row = blockIdx.x * 4 + (threadIdx.x >> 6);
  const int lane = threadIdx.x & 63;
  short* rp = p + (size_t)row * 1024 + lane * 16;
  s8v v0 = *(s8v*)rp, v1 = *(s8v*)(rp + 8);
  float f[16];
  #pragma unroll
  for (int j = 0; j < 8; j++) { f[j] = b2f(v0[j]); f[8 + j] = b2f(v1[j]); }
  float m = f[0];
  #pragma unroll
  for (int j = 1; j < 16; j++) m = fmaxf(m, f[j]);
  #pragma unroll
  for (int s = 32; s; s >>= 1) m = fmaxf(m, __shfl_xor(m, s, 64));
  float sum = 0.f;
  #pragma unroll
  for (int j = 0; j < 16; j++) { f[j] = __expf(f[j] - m); sum += f[j]; }
  #pragma unroll
  for (int s = 32; s; s >>= 1) sum += __shfl_xor(sum, s, 64);
  const float inv = 1.f / sum;
  #pragma unroll
  for (int j = 0; j < 8; j++) {
    v0[j] = (short)f2b(f[j] * inv);
    v1[j] = (short)f2b(f[8 + j] * inv);
  }
  *(s8v*)rp = v0; *(s8v*)(rp + 8) = v1;
}

// L2-normalize over axis=1 (N) of (NB,N,D) f32; deterministic 3-phase.
#define NCHUNK 16
__global__ __launch_bounds__(256) void norm_part(const float* __restrict__ t,
                                                 float* __restrict__ part, int NB) {
  const int d = blockIdx.x * 256 + threadIdx.x;
  const int b = blockIdx.y;
  const int c = blockIdx.z;
  const int n0 = c * (N_ / NCHUNK);
  const float* p = t + ((size_t)b * N_ + n0) * D_ + d;
  float ss = 0.f;
  for (int n = 0; n < N_ / NCHUNK; n++) { float v = p[(size_t)n * D_]; ss += v * v; }
  part[((size_t)c * NB + b) * D_ + d] = ss;
}
__global__ __launch_bounds__(256) void norm_inv(const float* __restrict__ part,
                                                float* __restrict__ inv, int NB) {
  const int i = blockIdx.x * 256 + threadIdx.x;   // b*D + d
  float ss = 0.f;
  for (int c = 0; c < NCHUNK; c++) ss += part[(size_t)c * (NB * D_) + i];
  inv[i] = 1.f / fmaxf(sqrtf(ss), 1e-12f);
}
__global__ __launch_bounds__(256) void norm_scale(const float* __restrict__ t,
                                                  const float* __restrict__ inv,
                                                  short* __restrict__ outh,
                                                  short* __restrict__ outl,
                                                  float* __restrict__ outf) {
  const size_t i = ((size_t)blockIdx.x * 256 + threadIdx.x) * 4;
  const int b = (int)(i >> 19);        // N_*D_ = 2^19
  const int d = (int)(i & (D_ - 1));
  f4v v = *(const f4v*)(t + i);
  f4v w = *(const f4v*)(inv + (size_t)b * D_ + d);
  f4v o; s4v oh, ol;
  #pragma unroll
  for (int j = 0; j < 4; j++) {
    o[j] = v[j] * w[j];
    oh[j] = (short)f2b(o[j]);
    ol[j] = (short)f2b(o[j] - b2f(oh[j]));
  }
  *(f4v*)(outf + i) = o;
  *(s4v*)(outh + i) = oh;
  *(s4v*)(outl + i) = ol;
}

extern "C" void kernel_launch(void* const* d_in, const int* in_sizes, int n_in,
                              void* d_out, int out_size, void* d_ws, size_t ws_size,
                              hipStream_t stream) {
  (void)in_sizes; (void)n_in; (void)out_size; (void)ws_size;
  const float* in1f = (const float*)d_in[0];
  const float* in2f = (const float*)d_in[1];

  const size_t SB = (size_t)B_ * N_ * D_ * 2;      // 8 MB
  const size_t SF = (size_t)B_ * N_ * D_ * 4;      // 16 MB
  const size_t WL = (size_t)L_ * D_ * D_ * 2;
  const size_t W1 = (size_t)D_ * D_ * 2;
  const long SBel = (long)B_ * N_ * D_;            // 4194304 elems
  const long sAct = (long)N_ * D_;
  const long sAff = (long)N_ * N_;

  char* ws = (char*)d_ws;
  size_t off = 0;
  auto alloc = [&](size_t bytes) -> char* {
    char* p = ws + off;
    off += (bytes + 255) & ~(size_t)255;
    return p;
  };

  // ---- weight region (19 MB); a1/a2 overlay after stage 1 ----
  char* wreg = alloc(8 * WL + 6 * W1);
  short* c_thT_h = (short*)(wreg);
  short* c_thT_l = (short*)(wreg + WL);
  short* c_phT_h = (short*)(wreg + 2 * WL);
  short* c_phT_l = (short*)(wreg + 3 * WL);
  short* c_rhT_h = (short*)(wreg + 4 * WL);
  short* c_rhT_l = (short*)(wreg + 5 * WL);
  short* c_psT_h = (short*)(wreg + 6 * WL);
  short* c_psT_l = (short*)(wreg + 7 * WL);
  short* c_intT_h = (short*)(wreg + 8 * WL);
  short* c_intT_l = (short*)(wreg + 8 * WL + W1);
  short* c_f1T_h  = (short*)(wreg + 8 * WL + 2 * W1);
  short* c_f1T_l  = (short*)(wreg + 8 * WL + 3 * W1);
  short* c_f2T_h  = (short*)(wreg + 8 * WL + 4 * W1);
  short* c_f2T_l  = (short*)(wreg + 8 * WL + 5 * W1);
  short* a1_thT = (short*)(wreg);
  short* a1_phT = (short*)(wreg + WL);
  short* a1_rhT = (short*)(wreg + 2 * WL);
  short* a2_thT = (short*)(wreg + 3 * WL);
  short* a2_phT = (short*)(wreg + 4 * WL);
  short* a2_rhT = (short*)(wreg + 5 * WL);
  char*  aw = wreg + 6 * WL;
  short* a1_intT_h = (short*)(aw);
  short* a1_intT_l = (short*)(aw + W1);
  short* a1_f1T_h  = (short*)(aw + 2 * W1);
  short* a1_f1T_l  = (short*)(aw + 3 * W1);
  short* a1_f2T_h  = (short*)(aw + 4 * W1);
  short* a1_f2T_l  = (short*)(aw + 5 * W1);
  short* a2_intT_h = (short*)(aw + 6 * W1);
  short* a2_intT_l = (short*)(aw + 7 * W1);
  short* a2_f1T_h  = (short*)(aw + 8 * W1);
  short* a2_f1T_l  = (short*)(aw + 9 * W1);
  short* a2_f2T_h  = (short*)(aw + 10 * W1);
  short* a2_f2T_l  = (short*)(aw + 11 * W1);

  // ---- pair-contiguous activation regions (2*SB each = 16 MB) ----
  short* in12h = (short*)alloc(2 * SB);   // in1h|in2h -> feed12b -> sumb
  short* in12l = (short*)alloc(2 * SB);   // in1l|in2l -> resh
  short* bufA  = (short*)alloc(2 * SB);   // thh|thl -> inth -> hidh
  short* bufB  = (short*)alloc(2 * SB);   // phh|phl -> intl -> hidl
  short* bufC  = (short*)alloc(2 * SB);   // rhT|psT -> resl
  char*  affU  = alloc((size_t)32 * 1024 * 1024);
  float* accR  = (float*)alloc(2 * SF);   // acc1|acc2 / acc16 / tmpf
  float* feedfR = (float*)alloc(2 * SF);  // feed12f -> self12f -> sumf
  float* npart = (float*)alloc((size_t)NCHUNK * 16 * D_ * 4);
  float* ninv  = (float*)alloc((size_t)16 * D_ * 4);
  // total ≈ 196 MB (< proven 217)

  short* in1h = in12h;        short* in2h = in12h + SBel;
  short* in1l = in12l;        short* in2l = in12l + SBel;
  short* thh = bufA;          short* thl = bufA + SBel;
  short* phh = bufB;          short* phl = bufB + SBel;
  short* rhT = bufC;          short* psT = bufC + SBel;
  short* affh = (short*)affU;                   // [0,16 MB)
  short* affl = affh + SBel * 2;                // [16,32 MB)
  short* aff16 = (short*)affU;                  // 32 MB bf16 batch-16 logits
  float* resfP = (float*)affU;                  // 32 MB f32 res (affs dead)
  float* acc1 = accR;         float* acc2 = accR + SBel;

  const float scl = 0.04419417382415922f;   // 512^-0.5
  dim3 tb(32, 8);
  const int GE = (B_ * N_ * D_) / (4 * 256);     // 4096
  #define F32P(i) ((const float*)d_in[i])

  auto GA = [&]() { GArgs a; __builtin_memset(&a, 0, sizeof(a)); return a; };
  auto normalize = [&](const float* src, int NB, short* outh, short* outl, float* outf) {
    norm_part<<<dim3(D_/256, NB, NCHUNK), 256, 0, stream>>>(src, npart, NB);
    norm_inv<<<(NB * D_) / 256, 256, 0, stream>>>(npart, ninv, NB);
    norm_scale<<<NB * 512, 256, 0, stream>>>(src, ninv, outh, outl, outf);
  };

  // ---- stage-1 weights + input split ----
  wt_cvt_t2<<<dim3(16,16,L_), tb, 0, stream>>>(F32P(2),  c_thT_h, c_thT_l);
  wt_cvt_t2<<<dim3(16,16,L_), tb, 0, stream>>>(F32P(4),  c_phT_h, c_phT_l);
  wt_cvt_t2<<<dim3(16,16,L_), tb, 0, stream>>>(F32P(6),  c_rhT_h, c_rhT_l);
  wt_cvt_t2<<<dim3(16,16,L_), tb, 0, stream>>>(F32P(8),  c_psT_h, c_psT_l);
  wt_cvt_t2<<<dim3(16,16,1),  tb, 0, stream>>>(F32P(10), c_intT_h, c_intT_l);
  wt_cvt_t2<<<dim3(16,16,1),  tb, 0, stream>>>(F32P(12), c_f1T_h, c_f1T_l);
  wt_cvt_t2<<<dim3(16,16,1),  tb, 0, stream>>>(F32P(14), c_f2T_h, c_f2T_l);
  split_f32<<<GE, 256, 0, stream>>>(in1f, in1h, in1l, 1.0f);
  split_f32<<<GE, 256, 0, stream>>>(in2f, in2h, in2l, 1.0f);

  // ---- stage 1: 4-seg proj -> split affinity -> 2-seg apply ----
  for (int i = 0; i < L_; i++) {
    const size_t wo = (size_t)i * D_ * D_;
    const size_t bo = (size_t)i * D_;
    { GArgs a = GA();
      a.Ah[0] = in1h; a.Ah[1] = in1h; a.Ah[2] = in2h; a.Ah[3] = in2h;
      a.Al[0] = in1l; a.Al[1] = in1l; a.Al[2] = in2l; a.Al[3] = in2l;
      a.Bh[0] = c_thT_h + wo; a.Bh[1] = c_rhT_h + wo;
      a.Bh[2] = c_phT_h + wo; a.Bh[3] = c_psT_h + wo;
      a.Bl[0] = c_thT_l + wo; a.Bl[1] = c_rhT_l + wo;
      a.Bl[2] = c_phT_l + wo; a.Bl[3] = c_psT_l + wo;
      a.C0[0] = thh; a.C0[1] = rhT; a.C0[2] = phh; a.C0[3] = psT;
      a.C1[0] = thl; a.C1[2] = phl;
      a.bias[0] = F32P(3) + bo; a.bias[1] = F32P(7) + bo;
      a.bias[2] = F32P(5) + bo; a.bias[3] = F32P(9) + bo;
      a.Nn = 512; a.K = 512;
      gemm_k<2,2,EPI_PROJ4,0><<<dim3(64,16,1),256,0,stream>>>(a); }
    { GArgs a = GA();
      a.Ah[0] = thh; a.Al[0] = thl; a.sA = sAct;
      a.Bh[0] = phh; a.Bl[0] = phl; a.sB = sAct;
      a.C0[0] = affh; a.C1[0] = affl; a.sC = sAff;
      a.alpha = scl; a.Nn = 1024; a.K = 512;
      gemm_k<2,2,EPI_SPLIT_SCALE,1><<<dim3(8,8,B_),256,0,stream>>>(a); }
    { GArgs a = GA();
      a.Ah[0] = affh; a.Ah[1] = affh; a.Al[0] = affl; a.Al[1] = affl; a.sA = sAff;
      a.Bh[0] = rhT; a.Bh[1] = psT; a.sB = sAct;
      a.C0[0] = acc1; a.C0[1] = acc2; a.sC = sAct;
      a.Nn = 512; a.K = 1024;
      if (i == 0) {
        gemm_k<2,1,EPI_ACC2_ST,1><<<dim3(8,8,B_),256,0,stream>>>(a);
      } else if (i < L_ - 1) {
        gemm_k<2,1,EPI_ACC2,1><<<dim3(8,8,B_),256,0,stream>>>(a);
      } else {
        a.C1[0] = bufA; a.C1[1] = bufA + SBel;   // inth (stream1|stream2)
        a.C1[2] = bufB; a.C1[3] = bufB + SBel;   // intl
        a.alpha = 0.25f;
        gemm_k<2,1,EPI_ACC2_SPLIT,1><<<dim3(8,8,B_),256,0,stream>>>(a);
      } }
  }

  // ---- stage-1 epilogue, both streams batched (z=2 / M=16384) ----
  { GArgs a = GA();
    a.Ah[0] = bufA; a.Al[0] = bufB; a.sA = SBel;
    a.Bh[0] = c_intT_h; a.Bl[0] = c_intT_l;
    a.C0[0] = accR; a.sC = SBel;
    a.bias[0] = F32P(11); a.Rv = in1f; a.Rv2 = in2f;
    a.Nn = 512; a.K = 512;
    gemm_k<2,2,EPI_F32_BIAS_R,1><<<dim3(64,4,2),256,0,stream>>>(a); }
  normalize(accR, 16, in12l, bufA, resfP);       // resh|resl (resf scratch)
  { GArgs a = GA();
    a.Ah[0] = in12l; a.Al[0] = bufA;
    a.Bh[0] = c_f1T_h; a.Bl[0] = c_f1T_l;
    a.C0[0] = bufB; a.C1[0] = bufC;              // hidh|hidl
    a.bias[0] = F32P(13); a.Nn = 512; a.K = 512;
    gemm_k<2,2,EPI_SPLIT_BIAS,1><<<dim3(128,4,1),256,0,stream>>>(a); }
  { GArgs a = GA();
    a.Ah[0] = bufB; a.Al[0] = bufC;
    a.Bh[0] = c_f2T_h; a.Bl[0] = c_f2T_l;
    a.C0[0] = in12h; a.C1[0] = feedfR;           // feed12b | feed12f
    a.bias[0] = F32P(15); a.Nn = 512; a.K = 512;
    gemm_k<2,2,EPI_BOTH_LEAKY,1><<<dim3(128,4,1),256,0,stream>>>(a); }

  // ---- a1/a2 weights (overlay dead stage-1 weights) ----
  wt_cvt_t<<<dim3(16,16,L_), tb, 0, stream>>>(F32P(16), a1_thT);
  wt_cvt_t<<<dim3(16,16,L_), tb, 0, stream>>>(F32P(18), a1_phT);
  wt_cvt_t<<<dim3(16,16,L_), tb, 0, stream>>>(F32P(20), a1_rhT);
  wt_cvt_t2<<<dim3(16,16,1), tb, 0, stream>>>(F32P(22), a1_intT_h, a1_intT_l);
  wt_cvt_t2<<<dim3(16,16,1), tb, 0, stream>>>(F32P(24), a1_f1T_h, a1_f1T_l);
  wt_cvt_t2<<<dim3(16,16,1), tb, 0, stream>>>(F32P(26), a1_f2T_h, a1_f2T_l);
  wt_cvt_t<<<dim3(16,16,L_), tb, 0, stream>>>(F32P(28), a2_thT);
  wt_cvt_t<<<dim3(16,16,L_), tb, 0, stream>>>(F32P(30), a2_phT);
  wt_cvt_t<<<dim3(16,16,L_), tb, 0, stream>>>(F32P(32), a2_rhT);
  wt_cvt_t2<<<dim3(16,16,1), tb, 0, stream>>>(F32P(34), a2_intT_h, a2_intT_l);
  wt_cvt_t2<<<dim3(16,16,1), tb, 0, stream>>>(F32P(36), a2_f1T_h, a2_f1T_l);
  wt_cvt_t2<<<dim3(16,16,1), tb, 0, stream>>>(F32P(38), a2_f2T_h, a2_f2T_l);

  // ---- generic agi chain over NZ batches (NZ=16 pair, NZ=8 final) ----
  auto agi = [&](int NZ, const short* xb, const float* xf,
                 const short* thT, const float* thB,
                 const short* phT, const float* phB,
                 const short* rhT_, const float* rhB,
                 const short* inTh, const short* inTl, const float* inB,
                 const short* f1Th, const short* f1Tl, const float* f1B,
                 const short* f2Th, const short* f2Tl, const float* f2B,
                 float* outf) {
    const int MB = NZ / B_;                  // 2 or 1 (stream multiplier)
    for (int i = 0; i < L_; i++) {
      const size_t wo = (size_t)i * D_ * D_;
      const size_t bo = (size_t)i * D_;
      { GArgs a = GA();
        a.Ah[0] = xb; a.Ah[1] = xb; a.Ah[2] = xb;
        a.Bh[0] = thT + wo; a.Bh[1] = phT + wo; a.Bh[2] = rhT_ + wo;
        a.C0[0] = bufA; a.C0[1] = bufB; a.C0[2] = bufC;
        a.bias[0] = thB + bo; a.bias[1] = phB + bo; a.bias[2] = rhB + bo;
        a.Nn = 512; a.K = 512;
        gemm_k<1,1,EPI_PROJ3,1><<<dim3(64*MB,12,1),256,0,stream>>>(a); }
      { GArgs a = GA();
        a.Ah[0] = bufA; a.sA = sAct; a.Bh[0] = bufB; a.sB = sAct;
        a.C0[0] = aff16; a.sC = sAff; a.alpha = scl; a.Nn = 1024; a.K = 512;
        gemm_k<1,1,EPI_B16_SCALE,1><<<dim3(8,8,NZ),256,0,stream>>>(a); }
      softmax_rows_b16<<<NZ * 256, 256, 0, stream>>>(aff16);
      { GArgs a = GA();
        a.Ah[0] = aff16; a.sA = sAff; a.Bh[0] = bufC; a.sB = sAct;
        a.C0[0] = accR; a.sC = sAct; a.Nn = 512; a.K = 1024;
        if (i == 0) {
          gemm_k<1,1,EPI_F32_ST,1><<<dim3(8,4,NZ),256,0,stream>>>(a);
        } else if (i < L_ - 1) {
          gemm_k<1,1,EPI_F32_ACC,1><<<dim3(8,4,NZ),256,0,stream>>>(a);
        } else {
          a.C1[0] = bufA; a.C1[1] = bufB; a.alpha = 0.25f;
          gemm_k<1,1,EPI_ACC_SPLIT,1><<<dim3(8,4,NZ),256,0,stream>>>(a);
        } }
    }
    { GArgs a = GA();
      a.Ah[0] = bufA; a.Al[0] = bufB;
      a.Bh[0] = inTh; a.Bl[0] = inTl;
      a.C0[0] = accR; a.bias[0] = inB; a.Rv = xf; a.Rv2 = xf;
      a.Nn = 512; a.K = 512;
      gemm_k<2,2,EPI_F32_BIAS_R,1><<<dim3(64*MB,4,1),256,0,stream>>>(a); }
    normalize(accR, NZ, in12l, bufC, resfP);     // resh|resl, resf -> affU
    { GArgs a = GA();
      a.Ah[0] = in12l; a.Al[0] = bufC;
      a.Bh[0] = f1Th; a.Bl[0] = f1Tl;
      a.C0[0] = bufA; a.C1[0] = bufB;            // hidh|hidl
      a.bias[0] = f1B; a.Nn = 512; a.K = 512;
      gemm_k<2,2,EPI_SPLIT_BIAS,1><<<dim3(64*MB,4,1),256,0,stream>>>(a); }
    { GArgs a = GA();
      a.Ah[0] = bufA; a.Al[0] = bufB;
      a.Bh[0] = f2Th; a.Bl[0] = f2Tl;
      a.C0[0] = accR; a.bias[0] = f2B; a.Rv = resfP;
      a.Nn = 512; a.K = 512;
      gemm_k<2,2,EPI_LEAKY_R,1><<<dim3(64*MB,4,1),256,0,stream>>>(a); }
    normalize(accR, NZ, bufA, bufB, outf);       // bf16 outs are scratch
  };

  // agi1 on feed1+feed2 as one batch-16 chain (shared AGI_1 weights)
  agi(16, in12h, feedfR,
      a1_thT, F32P(17), a1_phT, F32P(19), a1_rhT, F32P(21),
      a1_intT_h, a1_intT_l, F32P(23), a1_f1T_h, a1_f1T_l, F32P(25),
      a1_f2T_h, a1_f2T_l, F32P(27), feedfR);     // self12f -> feedfR

  add_both<<<GE, 256, 0, stream>>>(feedfR, feedfR + SBel, in12h, feedfR);

  agi(8, in12h, feedfR,
      a2_thT, F32P(29), a2_phT, F32P(31), a2_rhT, F32P(33),
      a2_intT_h, a2_intT_l, F32P(35), a2_f1T_h, a2_f1T_l, F32P(37),
      a2_f2T_h, a2_f2T_l, F32P(39), (float*)d_out);
}

// Round 12
// 1735.914 us; speedup vs baseline: 1.5965x; 1.0245x over previous
//
#include <hip/hip_runtime.h>

// ACGI_32195074850822 — round 11: round-9 numerics + ONE trim only.
//  Round 10 bundled 3 trims -> absmax 1.07e-2 (fail). Revert agi paths to
//  split (round-9 exact); keep ONLY stage-1 single-bf16 P (drop affl,
//  apply (2,1)->(1,1)). Estimated +2-3e-3 on top of 2.44e-3 baseline.

#define B_ 8
#define N_ 1024
#define D_ 512
#define L_ 4

typedef short s8v __attribute__((ext_vector_type(8)));
typedef short s4v __attribute__((ext_vector_type(4)));
typedef float f4v __attribute__((ext_vector_type(4)));

__device__ __forceinline__ unsigned short f2b(float f) {
  unsigned u = __builtin_bit_cast(unsigned, f);
  u += 0x7FFFu + ((u >> 16) & 1u);          // round-to-nearest-even
  return (unsigned short)(u >> 16);
}
__device__ __forceinline__ float b2f(short s) {
  unsigned u = ((unsigned)(unsigned short)s) << 16;
  return __builtin_bit_cast(float, u);
}

__device__ __forceinline__ void glds16(const short* g, short* l) {
  __builtin_amdgcn_global_load_lds(
      (const __attribute__((address_space(1))) void*)g,
      (__attribute__((address_space(3))) void*)l, 16, 0, 0);
}

enum {
  EPI_PROJ4 = 0,   // seg even: split(acc+bias)->C0/C1; seg odd: TR(acc+bias)->C0
  EPI_PROJ3,       // seg 0,1: bf16(acc+bias)->C0; seg 2: TR->C0
  EPI_B16_SCALE,   // C0 bf16 = acc*alpha
  EPI_ACC2,        // seg s: C0[s] f32 += acc   (z-batched)
  EPI_ACC2_ST,     // seg s: C0[s] f32 = acc    (layer 0)
  EPI_F32_ACC,     // C0[0] f32 += acc          (z-batched)
  EPI_F32_ST,      // C0[0] f32 = acc           (layer 0)
  EPI_F32_BIAS_R,  // C0 f32 = acc+bias+R; R base by z (Rv / Rv2), local idx
  EPI_SPLIT_BIAS,  // C0 hi, C1 lo of acc+bias
  EPI_BOTH_LEAKY,  // C0 bf16 AND C1 f32 = leaky(acc+bias)
  EPI_LEAKY_R,     // C0 f32 = leaky(acc+bias) + R (flat)
  EPI_ACC2_SPLIT,  // seg s: t=(C0[s]+acc)*alpha; hi->C1[s], lo->C1[2+s]
  EPI_ACC_SPLIT    // t=(C0[0]+acc)*alpha; hi->C1[0], lo->C1[1] (z-batched)
};

struct GArgs {
  const short* Ah[4]; const short* Al[4];
  const short* Bh[4]; const short* Bl[4];
  long sA, sB;
  void* C0[4]; void* C1[4];
  long sC;
  const float* bias[4];
  const void* Rv; const void* Rv2;
  float alpha;
  int Nn, K;
};

// C = (ΣA_c)(ΣB_c)^T, bf16 comps, f32 accum; <2,2> drops Al*Bl.
// 128x128 tile, 4 waves, global_load_lds(16B) + both-sides XOR swizzle.
// DB=1: double-buffered staging, counted vmcnt (loads stay in flight).
template<int AS, int BS, int EPI, int DB>
__global__ __launch_bounds__(256) void gemm_k(GArgs g) {
  constexpr int TILE = (AS + BS) * 4096;        // shorts per staging buffer
  __shared__ short smem[TILE * (DB ? 2 : 1)];
  constexpr bool SEG = (EPI == EPI_PROJ4 || EPI == EPI_PROJ3 ||
                        EPI == EPI_ACC2 || EPI == EPI_ACC2_ST ||
                        EPI == EPI_ACC2_SPLIT);
  constexpr bool LDSOUT = (EPI == EPI_PROJ4 || EPI == EPI_PROJ3 ||
                           EPI == EPI_B16_SCALE || EPI == EPI_SPLIT_BIAS ||
                           EPI == EPI_BOTH_LEAKY || EPI == EPI_ACC2_SPLIT ||
                           EPI == EPI_ACC_SPLIT);
  constexpr int CC = (EPI == EPI_PROJ4 || EPI == EPI_SPLIT_BIAS ||
                      EPI == EPI_ACC2_SPLIT || EPI == EPI_ACC_SPLIT) ? 2 : 1;
  const int z = blockIdx.z;
  const int tm = blockIdx.x * 128;
  const int tn = blockIdx.y * 128;
  const int tid = threadIdx.x;
  const int lane = tid & 63;
  const int w = tid >> 6;
  const int wr = (w >> 1) * 64, wc = (w & 1) * 64;
  const int r16 = lane & 15, kg = lane >> 4;
  const int K = g.K;

  int seg = 0, tnl = tn;
  if constexpr (SEG) { seg = tn >> 9; tnl = tn & 511; }
  const short* Ah = g.Ah[seg];
  const short* Al = (AS == 2) ? g.Al[seg] : nullptr;
  const short* Bh = g.Bh[seg];
  const short* Bl = (BS == 2) ? g.Bl[seg] : nullptr;

  const int srow = lane >> 2;
  const int scol = ((lane & 3) ^ ((lane >> 3) & 3)) * 8;
  const short* gA[2]; const short* gB[2];
  gA[0] = Ah + (size_t)z * g.sA + (size_t)(tm + w * 16 + srow) * K + scol;
  if constexpr (AS == 2)
    gA[1] = Al + (size_t)z * g.sA + (size_t)(tm + w * 16 + srow) * K + scol;
  gB[0] = Bh + (size_t)z * g.sB + (size_t)(tnl + w * 16 + srow) * K + scol;
  if constexpr (BS == 2)
    gB[1] = Bl + (size_t)z * g.sB + (size_t)(tnl + w * 16 + srow) * K + scol;
  const size_t hoff = (size_t)64 * K;

  auto stage = [&](int k0, int buf) {
    short* base = smem + buf * TILE;
    #pragma unroll
    for (int c = 0; c < AS; c++) {
      glds16(gA[c] + k0, base + c * 4096 + (w * 16) * 32);
      glds16(gA[c] + hoff + k0, base + c * 4096 + (64 + w * 16) * 32);
    }
    #pragma unroll
    for (int c = 0; c < BS; c++) {
      glds16(gB[c] + k0, base + (AS + c) * 4096 + (w * 16) * 32);
      glds16(gB[c] + hoff + k0, base + (AS + c) * 4096 + (64 + w * 16) * 32);
    }
  };

  f4v acc[4][4];
  #pragma unroll
  for (int i = 0; i < 4; i++)
    #pragma unroll
    for (int j = 0; j < 4; j++) acc[i][j] = (f4v)0.f;

  const int rc = (kg ^ ((r16 >> 1) & 3)) * 8;

  auto compute = [&](int buf) {
    const short* base = smem + buf * TILE;
    s8v va[2][4], vb[2][4];
    #pragma unroll
    for (int c = 0; c < AS; c++)
      #pragma unroll
      for (int i = 0; i < 4; i++)
        va[c][i] = *(const s8v*)&base[c * 4096 + (wr + i * 16 + r16) * 32 + rc];
    #pragma unroll
    for (int c = 0; c < BS; c++)
      #pragma unroll
      for (int i = 0; i < 4; i++)
        vb[c][i] = *(const s8v*)&base[(AS + c) * 4096 + (wc + i * 16 + r16) * 32 + rc];
    #pragma unroll
    for (int ca = 0; ca < AS; ca++)
      #pragma unroll
      for (int cb = 0; cb < BS; cb++) {
        if (ca == 1 && cb == 1) continue;   // drop lo*lo
        #pragma unroll
        for (int mi = 0; mi < 4; mi++)
          #pragma unroll
          for (int ni = 0; ni < 4; ni++)
            acc[mi][ni] = __builtin_amdgcn_mfma_f32_16x16x32_bf16(
                va[ca][mi], vb[cb][ni], acc[mi][ni], 0, 0, 0);
      }
  };

  const int nt = K >> 5;
  if constexpr (DB) {
    constexpr int NLD = (AS + BS) * 2;        // vmcnt events per stage
    stage(0, 0);
    int buf = 0;
    for (int t = 0; t < nt; t++) {
      if (t + 1 < nt) {
        stage((t + 1) * 32, buf ^ 1);
        if constexpr (NLD == 8)      asm volatile("s_waitcnt vmcnt(8)" ::: "memory");
        else if constexpr (NLD == 6) asm volatile("s_waitcnt vmcnt(6)" ::: "memory");
        else                         asm volatile("s_waitcnt vmcnt(4)" ::: "memory");
      } else {
        asm volatile("s_waitcnt vmcnt(0)" ::: "memory");
      }
      __builtin_amdgcn_sched_barrier(0);
      __builtin_amdgcn_s_barrier();
      compute(buf);
      __builtin_amdgcn_s_barrier();
      buf ^= 1;
    }
  } else {
    for (int t = 0; t < nt; t++) {
      stage(t * 32, 0);
      __syncthreads();
      compute(0);
      __syncthreads();
    }
  }

  short* C0s = (short*)g.C0[seg];  float* C0f = (float*)g.C0[seg];
  short* C1s = (short*)g.C1[seg];  float* C1f = (float*)g.C1[seg];
  const float* biasp = g.bias[seg];
  const int NnL = g.Nn;

  if constexpr (LDSOUT) {
    bool tr = false;
    if constexpr (EPI == EPI_PROJ4) tr = (seg & 1);
    if constexpr (EPI == EPI_PROJ3) tr = (seg == 2);
    if (tr) {
      // transposed write (s4v along n, 8B-coalesced)
      #pragma unroll
      for (int mi = 0; mi < 4; mi++) {
        #pragma unroll
        for (int ni = 0; ni < 4; ni++) {
          const int colL = tnl + wc + ni * 16 + r16;
          const int grow0 = tm + wr + mi * 16 + kg * 4;
          const float bv = biasp[colL];
          s4v o;
          #pragma unroll
          for (int r = 0; r < 4; r++) o[r] = (short)f2b(acc[mi][ni][r] + bv);
          const int b = grow0 >> 10, n = grow0 & 1023;
          *(s4v*)&C0s[((size_t)b * 512 + colL) * 1024 + n] = o;
        }
      }
    } else {
      short* D0 = nullptr; short* D1 = nullptr;
      if constexpr (EPI == EPI_PROJ4 || EPI == EPI_PROJ3) {
        D0 = C0s; D1 = C1s;
      } else if constexpr (EPI == EPI_SPLIT_BIAS) {
        D0 = C0s + (size_t)z * g.sC; D1 = C1s + (size_t)z * g.sC;
      } else if constexpr (EPI == EPI_B16_SCALE || EPI == EPI_BOTH_LEAKY) {
        D0 = C0s + (size_t)z * g.sC;
      } else if constexpr (EPI == EPI_ACC2_SPLIT) {
        D0 = (short*)g.C1[seg] + (size_t)z * g.sC;
        D1 = (short*)g.C1[2 + seg] + (size_t)z * g.sC;
      } else { // EPI_ACC_SPLIT
        D0 = (short*)g.C1[0] + (size_t)z * g.sC;
        D1 = (short*)g.C1[1] + (size_t)z * g.sC;
      }
      for (int mi = 0; mi < 4; mi++) {
        #pragma unroll
        for (int ni = 0; ni < 4; ni++) {
          const int lcol = wc + ni * 16 + r16;
          const int colL = tnl + lcol;
          float bv = 0.f;
          if constexpr (EPI == EPI_PROJ4 || EPI == EPI_PROJ3 ||
                        EPI == EPI_SPLIT_BIAS || EPI == EPI_BOTH_LEAKY)
            bv = biasp[colL];
          #pragma unroll
          for (int r = 0; r < 4; r++) {
            const int grow = tm + wr + mi * 16 + kg * 4 + r;
            const float v = acc[mi][ni][r];
            float t;
            if constexpr (EPI == EPI_B16_SCALE)
              t = v * g.alpha;
            else if constexpr (EPI == EPI_ACC2_SPLIT || EPI == EPI_ACC_SPLIT)
              t = (C0f[(size_t)z * g.sC + (size_t)grow * NnL + colL] + v) * g.alpha;
            else if constexpr (EPI == EPI_BOTH_LEAKY) {
              t = v + bv; t = (t >= 0.f) ? t : 0.01f * t;
              C1f[(size_t)z * g.sC + (size_t)grow * NnL + colL] = t;
            } else
              t = v + bv;
            const int lrow = (w >> 1) * 16 + kg * 4 + r;
            const int sw = ((lrow >> 2) & 3) << 4;          // bank swizzle
            const int li = lrow * 128 + (lcol ^ sw);
            const short h = (short)f2b(t);
            smem[li] = h;
            if constexpr (CC == 2) smem[4096 + li] = (short)f2b(t - b2f(h));
          }
        }
        __syncthreads();
        #pragma unroll
        for (int c2 = 0; c2 < CC; c2++) {
          short* D = c2 ? D1 : D0;
          #pragma unroll
          for (int half = 0; half < 2; half++) {
            const int e = (tid + half * 256) * 8;
            const int lrow2 = e >> 7, col = e & 127;
            const int sw2 = ((lrow2 >> 2) & 3) << 4;
            const int grow = tm + (lrow2 >> 4) * 64 + mi * 16 + (lrow2 & 15);
            *(s8v*)&D[(size_t)grow * NnL + tnl + col] =
                *(const s8v*)&smem[c2 * 4096 + (lrow2 << 7) + (col ^ sw2)];
          }
        }
        __syncthreads();
      }
    }
  } else {
    // direct f32 epilogues (coalesced 64B/group)
    #pragma unroll
    for (int mi = 0; mi < 4; mi++) {
      #pragma unroll
      for (int ni = 0; ni < 4; ni++) {
        const int colL = tnl + wc + ni * 16 + r16;
        const int grow0 = tm + wr + mi * 16 + kg * 4;
        float bv = 0.f;
        if constexpr (EPI == EPI_F32_BIAS_R || EPI == EPI_LEAKY_R)
          bv = biasp[colL];
        #pragma unroll
        for (int r = 0; r < 4; r++) {
          const size_t lidx = (size_t)(grow0 + r) * NnL + colL;
          const size_t idx = (size_t)z * g.sC + lidx;
          const float v = acc[mi][ni][r];
          if constexpr (EPI == EPI_ACC2) {
            C0f[(size_t)z * g.sC + (size_t)(grow0 + r) * 512 + colL] += v;
          } else if constexpr (EPI == EPI_ACC2_ST) {
            C0f[(size_t)z * g.sC + (size_t)(grow0 + r) * 512 + colL] = v;
          } else if constexpr (EPI == EPI_F32_ACC) {
            C0f[idx] += v;
          } else if constexpr (EPI == EPI_F32_ST) {
            C0f[idx] = v;
          } else if constexpr (EPI == EPI_F32_BIAS_R) {
            const float* Rf = (const float*)(z == 0 ? g.Rv : g.Rv2);
            C0f[idx] = v + bv + Rf[lidx];
          } else { // EPI_LEAKY_R
            float t = v + bv; t = (t >= 0.f) ? t : 0.01f * t;
            C0f[idx] = t + ((const float*)g.Rv)[idx];
          }
        }
      }
    }
  }
}

// f32 (z,D,D) -> bf16 transposed, single
__global__ __launch_bounds__(256) void wt_cvt_t(const float* __restrict__ src,
                                                short* __restrict__ dst) {
  __shared__ float t[32][33];
  const int bx = blockIdx.x * 32, by = blockIdx.y * 32;
  const size_t zo = (size_t)blockIdx.z * D_ * D_;
  const int tx = threadIdx.x, ty = threadIdx.y;
  #pragma unroll
  for (int k = 0; k < 4; k++)
    t[ty + 8 * k][tx] = src[zo + (size_t)(by + ty + 8 * k) * D_ + bx + tx];
  __syncthreads();
  #pragma unroll
  for (int k = 0; k < 4; k++)
    dst[zo + (size_t)(bx + ty + 8 * k) * D_ + by + tx] = (short)f2b(t[tx][ty + 8 * k]);
}

// f32 (z,D,D) -> bf16 transposed hi+lo
__global__ __launch_bounds__(256) void wt_cvt_t2(const float* __restrict__ src,
                                                 short* __restrict__ hi,
                                                 short* __restrict__ lo) {
  __shared__ float t[32][33];
  const int bx = blockIdx.x * 32, by = blockIdx.y * 32;
  const size_t zo = (size_t)blockIdx.z * D_ * D_;
  const int tx = threadIdx.x, ty = threadIdx.y;
  #pragma unroll
  for (int k = 0; k < 4; k++)
    t[ty + 8 * k][tx] = src[zo + (size_t)(by + ty + 8 * k) * D_ + bx + tx];
  __syncthreads();
  #pragma unroll
  for (int k = 0; k < 4; k++) {
    const size_t o = zo + (size_t)(bx + ty + 8 * k) * D_ + by + tx;
    float v = t[tx][ty + 8 * k];
    short h = (short)f2b(v);
    hi[o] = h;
    lo[o] = (short)f2b(v - b2f(h));
  }
}

// f32 * scale -> hi bf16 + lo bf16
__global__ __launch_bounds__(256) void split_f32(const float* __restrict__ src,
                                                 short* __restrict__ hi,
                                                 short* __restrict__ lo, float scale) {
  const size_t i = ((size_t)blockIdx.x * 256 + threadIdx.x) * 4;
  f4v v = *(const f4v*)(src + i);
  s4v h, l;
  #pragma unroll
  for (int j = 0; j < 4; j++) {
    float t = v[j] * scale;
    h[j] = (short)f2b(t);
    l[j] = (short)f2b(t - b2f(h[j]));
  }
  *(s4v*)(hi + i) = h;
  *(s4v*)(lo + i) = l;
}

// sum = a + b (f32) elementwise; write bf16 + f32 (outf may alias a)
__global__ __launch_bounds__(256) void add_both(const float* __restrict__ a,
                                                const float* __restrict__ b,
                                                short* __restrict__ outb,
                                                float* outf) {
  const size_t i = ((size_t)blockIdx.x * 256 + threadIdx.x) * 4;
  f4v av = *(const f4v*)(a + i);
  f4v bv = *(const f4v*)(b + i);
  f4v s; s4v o;
  #pragma unroll
  for (int j = 0; j < 4; j++) { s[j] = av[j] + bv[j]; o[j] = (short)f2b(s[j]); }
  *(f4v*)(outf + i) = s;
  *(s4v*)(outb + i) = o;
}

// in-place softmax over bf16 rows of 1024; one wave per row, shuffle reduce
__global__ __launch_bounds__(256) void softmax_rows_b16(short* __restrict__ p) {
  const int row = blockIdx.x * 4 + (threadIdx.x >> 6);
  const int lane = threadIdx.x & 63;
  short* rp = p + (size_t)row * 1024 + lane * 16;
  s8v v0 = *(s8v*)rp, v1 = *(s8v*)(rp + 8);
  float f[16];
  #pragma unroll
  for (int j = 0; j < 8; j++) { f[j] = b2f(v0[j]); f[8 + j] = b2f(v1[j]); }
  float m = f[0];
  #pragma unroll
  for (int j = 1; j < 16; j++) m = fmaxf(m, f[j]);
  #pragma unroll
  for (int s = 32; s; s >>= 1) m = fmaxf(m, __shfl_xor(m, s, 64));
  float sum = 0.f;
  #pragma unroll
  for (int j = 0; j < 16; j++) { f[j] = __expf(f[j] - m); sum += f[j]; }
  #pragma unroll
  for (int s = 32; s; s >>= 1) sum += __shfl_xor(sum, s, 64);
  const float inv = 1.f / sum;
  #pragma unroll
  for (int j = 0; j < 8; j++) {
    v0[j] = (short)f2b(f[j] * inv);
    v1[j] = (short)f2b(f[8 + j] * inv);
  }
  *(s8v*)rp = v0; *(s8v*)(rp + 8) = v1;
}

// L2-normalize over axis=1 (N) of (NB,N,D) f32; deterministic 3-phase.
#define NCHUNK 16
__global__ __launch_bounds__(256) void norm_part(const float* __restrict__ t,
                                                 float* __restrict__ part, int NB) {
  const int d = blockIdx.x * 256 + threadIdx.x;
  const int b = blockIdx.y;
  const int c = blockIdx.z;
  const int n0 = c * (N_ / NCHUNK);
  const float* p = t + ((size_t)b * N_ + n0) * D_ + d;
  float ss = 0.f;
  for (int n = 0; n < N_ / NCHUNK; n++) { float v = p[(size_t)n * D_]; ss += v * v; }
  part[((size_t)c * NB + b) * D_ + d] = ss;
}
__global__ __launch_bounds__(256) void norm_inv(const float* __restrict__ part,
                                                float* __restrict__ inv, int NB) {
  const int i = blockIdx.x * 256 + threadIdx.x;   // b*D + d
  float ss = 0.f;
  for (int c = 0; c < NCHUNK; c++) ss += part[(size_t)c * (NB * D_) + i];
  inv[i] = 1.f / fmaxf(sqrtf(ss), 1e-12f);
}
__global__ __launch_bounds__(256) void norm_scale(const float* __restrict__ t,
                                                  const float* __restrict__ inv,
                                                  short* __restrict__ outh,
                                                  short* __restrict__ outl,
                                                  float* __restrict__ outf) {
  const size_t i = ((size_t)blockIdx.x * 256 + threadIdx.x) * 4;
  const int b = (int)(i >> 19);        // N_*D_ = 2^19
  const int d = (int)(i & (D_ - 1));
  f4v v = *(const f4v*)(t + i);
  f4v w = *(const f4v*)(inv + (size_t)b * D_ + d);
  f4v o; s4v oh, ol;
  #pragma unroll
  for (int j = 0; j < 4; j++) {
    o[j] = v[j] * w[j];
    oh[j] = (short)f2b(o[j]);
    ol[j] = (short)f2b(o[j] - b2f(oh[j]));
  }
  *(f4v*)(outf + i) = o;
  *(s4v*)(outh + i) = oh;
  *(s4v*)(outl + i) = ol;
}

extern "C" void kernel_launch(void* const* d_in, const int* in_sizes, int n_in,
                              void* d_out, int out_size, void* d_ws, size_t ws_size,
                              hipStream_t stream) {
  (void)in_sizes; (void)n_in; (void)out_size; (void)ws_size;
  const float* in1f = (const float*)d_in[0];
  const float* in2f = (const float*)d_in[1];

  const size_t SB = (size_t)B_ * N_ * D_ * 2;      // 8 MB
  const size_t SF = (size_t)B_ * N_ * D_ * 4;      // 16 MB
  const size_t WL = (size_t)L_ * D_ * D_ * 2;
  const size_t W1 = (size_t)D_ * D_ * 2;
  const long SBel = (long)B_ * N_ * D_;            // 4194304 elems
  const long sAct = (long)N_ * D_;
  const long sAff = (long)N_ * N_;

  char* ws = (char*)d_ws;
  size_t off = 0;
  auto alloc = [&](size_t bytes) -> char* {
    char* p = ws + off;
    off += (bytes + 255) & ~(size_t)255;
    return p;
  };

  // ---- weight region (19 MB); a1/a2 overlay after stage 1 ----
  char* wreg = alloc(8 * WL + 6 * W1);
  short* c_thT_h = (short*)(wreg);
  short* c_thT_l = (short*)(wreg + WL);
  short* c_phT_h = (short*)(wreg + 2 * WL);
  short* c_phT_l = (short*)(wreg + 3 * WL);
  short* c_rhT_h = (short*)(wreg + 4 * WL);
  short* c_rhT_l = (short*)(wreg + 5 * WL);
  short* c_psT_h = (short*)(wreg + 6 * WL);
  short* c_psT_l = (short*)(wreg + 7 * WL);
  short* c_intT_h = (short*)(wreg + 8 * WL);
  short* c_intT_l = (short*)(wreg + 8 * WL + W1);
  short* c_f1T_h  = (short*)(wreg + 8 * WL + 2 * W1);
  short* c_f1T_l  = (short*)(wreg + 8 * WL + 3 * W1);
  short* c_f2T_h  = (short*)(wreg + 8 * WL + 4 * W1);
  short* c_f2T_l  = (short*)(wreg + 8 * WL + 5 * W1);
  short* a1_thT = (short*)(wreg);
  short* a1_phT = (short*)(wreg + WL);
  short* a1_rhT = (short*)(wreg + 2 * WL);
  short* a2_thT = (short*)(wreg + 3 * WL);
  short* a2_phT = (short*)(wreg + 4 * WL);
  short* a2_rhT = (short*)(wreg + 5 * WL);
  char*  aw = wreg + 6 * WL;
  short* a1_intT_h = (short*)(aw);
  short* a1_intT_l = (short*)(aw + W1);
  short* a1_f1T_h  = (short*)(aw + 2 * W1);
  short* a1_f1T_l  = (short*)(aw + 3 * W1);
  short* a1_f2T_h  = (short*)(aw + 4 * W1);
  short* a1_f2T_l  = (short*)(aw + 5 * W1);
  short* a2_intT_h = (short*)(aw + 6 * W1);
  short* a2_intT_l = (short*)(aw + 7 * W1);
  short* a2_f1T_h  = (short*)(aw + 8 * W1);
  short* a2_f1T_l  = (short*)(aw + 9 * W1);
  short* a2_f2T_h  = (short*)(aw + 10 * W1);
  short* a2_f2T_l  = (short*)(aw + 11 * W1);

  // ---- pair-contiguous activation regions (2*SB each = 16 MB) ----
  short* in12h = (short*)alloc(2 * SB);   // in1h|in2h -> feed12b -> sumb
  short* in12l = (short*)alloc(2 * SB);   // in1l|in2l -> resh
  short* bufA  = (short*)alloc(2 * SB);   // thh|thl -> inth -> hidh
  short* bufB  = (short*)alloc(2 * SB);   // phh|phl -> intl -> hidl
  short* bufC  = (short*)alloc(2 * SB);   // rhT|psT -> resl
  char*  affU  = alloc((size_t)32 * 1024 * 1024);
  float* accR  = (float*)alloc(2 * SF);   // acc1|acc2 / acc16 / tmpf
  float* feedfR = (float*)alloc(2 * SF);  // feed12f -> self12f -> sumf
  float* npart = (float*)alloc((size_t)NCHUNK * 16 * D_ * 4);
  float* ninv  = (float*)alloc((size_t)16 * D_ * 4);
  // total ≈ 196 MB (< proven 217)

  short* in1h = in12h;        short* in2h = in12h + SBel;
  short* in1l = in12l;        short* in2l = in12l + SBel;
  short* thh = bufA;          short* thl = bufA + SBel;
  short* phh = bufB;          short* phl = bufB + SBel;
  short* rhT = bufC;          short* psT = bufC + SBel;
  short* affh = (short*)affU;                   // [0,16 MB)
  short* aff16 = (short*)affU;                  // 32 MB bf16 batch-16 logits
  float* resfP = (float*)affU;                  // 32 MB f32 res (affs dead)
  float* acc1 = accR;         float* acc2 = accR + SBel;

  const float scl = 0.04419417382415922f;   // 512^-0.5
  dim3 tb(32, 8);
  const int GE = (B_ * N_ * D_) / (4 * 256);     // 4096
  #define F32P(i) ((const float*)d_in[i])

  auto GA = [&]() { GArgs a; __builtin_memset(&a, 0, sizeof(a)); return a; };
  auto normalize = [&](const float* src, int NB, short* outh, short* outl, float* outf) {
    norm_part<<<dim3(D_/256, NB, NCHUNK), 256, 0, stream>>>(src, npart, NB);
    norm_inv<<<(NB * D_) / 256, 256, 0, stream>>>(npart, ninv, NB);
    norm_scale<<<NB * 512, 256, 0, stream>>>(src, ninv, outh, outl, outf);
  };

  // ---- stage-1 weights + input split ----
  wt_cvt_t2<<<dim3(16,16,L_), tb, 0, stream>>>(F32P(2),  c_thT_h, c_thT_l);
  wt_cvt_t2<<<dim3(16,16,L_), tb, 0, stream>>>(F32P(4),  c_phT_h, c_phT_l);
  wt_cvt_t2<<<dim3(16,16,L_), tb, 0, stream>>>(F32P(6),  c_rhT_h, c_rhT_l);
  wt_cvt_t2<<<dim3(16,16,L_), tb, 0, stream>>>(F32P(8),  c_psT_h, c_psT_l);
  wt_cvt_t2<<<dim3(16,16,1),  tb, 0, stream>>>(F32P(10), c_intT_h, c_intT_l);
  wt_cvt_t2<<<dim3(16,16,1),  tb, 0, stream>>>(F32P(12), c_f1T_h, c_f1T_l);
  wt_cvt_t2<<<dim3(16,16,1),  tb, 0, stream>>>(F32P(14), c_f2T_h, c_f2T_l);
  split_f32<<<GE, 256, 0, stream>>>(in1f, in1h, in1l, 1.0f);
  split_f32<<<GE, 256, 0, stream>>>(in2f, in2h, in2l, 1.0f);

  // ---- stage 1: 4-seg proj -> bf16 P (TRIM) -> (1,1) applies ----
  for (int i = 0; i < L_; i++) {
    const size_t wo = (size_t)i * D_ * D_;
    const size_t bo = (size_t)i * D_;
    { GArgs a = GA();
      a.Ah[0] = in1h; a.Ah[1] = in1h; a.Ah[2] = in2h; a.Ah[3] = in2h;
      a.Al[0] = in1l; a.Al[1] = in1l; a.Al[2] = in2l; a.Al[3] = in2l;
      a.Bh[0] = c_thT_h + wo; a.Bh[1] = c_rhT_h + wo;
      a.Bh[2] = c_phT_h + wo; a.Bh[3] = c_psT_h + wo;
      a.Bl[0] = c_thT_l + wo; a.Bl[1] = c_rhT_l + wo;
      a.Bl[2] = c_phT_l + wo; a.Bl[3] = c_psT_l + wo;
      a.C0[0] = thh; a.C0[1] = rhT; a.C0[2] = phh; a.C0[3] = psT;
      a.C1[0] = thl; a.C1[2] = phl;
      a.bias[0] = F32P(3) + bo; a.bias[1] = F32P(7) + bo;
      a.bias[2] = F32P(5) + bo; a.bias[3] = F32P(9) + bo;
      a.Nn = 512; a.K = 512;
      gemm_k<2,2,EPI_PROJ4,0><<<dim3(64,16,1),256,0,stream>>>(a); }
    { GArgs a = GA();                              // single-bf16 P (the trim)
      a.Ah[0] = thh; a.Al[0] = thl; a.sA = sAct;
      a.Bh[0] = phh; a.Bl[0] = phl; a.sB = sAct;
      a.C0[0] = affh; a.sC = sAff;
      a.alpha = scl; a.Nn = 1024; a.K = 512;
      gemm_k<2,2,EPI_B16_SCALE,1><<<dim3(8,8,B_),256,0,stream>>>(a); }
    { GArgs a = GA();                              // (1,1) applies (the trim)
      a.Ah[0] = affh; a.Ah[1] = affh; a.sA = sAff;
      a.Bh[0] = rhT; a.Bh[1] = psT; a.sB = sAct;
      a.C0[0] = acc1; a.C0[1] = acc2; a.sC = sAct;
      a.Nn = 512; a.K = 1024;
      if (i == 0) {
        gemm_k<1,1,EPI_ACC2_ST,1><<<dim3(8,8,B_),256,0,stream>>>(a);
      } else if (i < L_ - 1) {
        gemm_k<1,1,EPI_ACC2,1><<<dim3(8,8,B_),256,0,stream>>>(a);
      } else {
        a.C1[0] = bufA; a.C1[1] = bufA + SBel;   // inth (stream1|stream2)
        a.C1[2] = bufB; a.C1[3] = bufB + SBel;   // intl
        a.alpha = 0.25f;
        gemm_k<1,1,EPI_ACC2_SPLIT,1><<<dim3(8,8,B_),256,0,stream>>>(a);
      } }
  }

  // ---- stage-1 epilogue, both streams batched (z=2 / M=16384) ----
  { GArgs a = GA();
    a.Ah[0] = bufA; a.Al[0] = bufB; a.sA = SBel;
    a.Bh[0] = c_intT_h; a.Bl[0] = c_intT_l;
    a.C0[0] = accR; a.sC = SBel;
    a.bias[0] = F32P(11); a.Rv = in1f; a.Rv2 = in2f;
    a.Nn = 512; a.K = 512;
    gemm_k<2,2,EPI_F32_BIAS_R,1><<<dim3(64,4,2),256,0,stream>>>(a); }
  normalize(accR, 16, in12l, bufA, resfP);       // resh|resl (resf scratch)
  { GArgs a = GA();
    a.Ah[0] = in12l; a.Al[0] = bufA;
    a.Bh[0] = c_f1T_h; a.Bl[0] = c_f1T_l;
    a.C0[0] = bufB; a.C1[0] = bufC;              // hidh|hidl
    a.bias[0] = F32P(13); a.Nn = 512; a.K = 512;
    gemm_k<2,2,EPI_SPLIT_BIAS,1><<<dim3(128,4,1),256,0,stream>>>(a); }
  { GArgs a = GA();
    a.Ah[0] = bufB; a.Al[0] = bufC;
    a.Bh[0] = c_f2T_h; a.Bl[0] = c_f2T_l;
    a.C0[0] = in12h; a.C1[0] = feedfR;           // feed12b | feed12f
    a.bias[0] = F32P(15); a.Nn = 512; a.K = 512;
    gemm_k<2,2,EPI_BOTH_LEAKY,1><<<dim3(128,4,1),256,0,stream>>>(a); }

  // ---- a1/a2 weights (overlay dead stage-1 weights) ----
  wt_cvt_t<<<dim3(16,16,L_), tb, 0, stream>>>(F32P(16), a1_thT);
  wt_cvt_t<<<dim3(16,16,L_), tb, 0, stream>>>(F32P(18), a1_phT);
  wt_cvt_t<<<dim3(16,16,L_), tb, 0, stream>>>(F32P(20), a1_rhT);
  wt_cvt_t2<<<dim3(16,16,1), tb, 0, stream>>>(F32P(22), a1_intT_h, a1_intT_l);
  wt_cvt_t2<<<dim3(16,16,1), tb, 0, stream>>>(F32P(24), a1_f1T_h, a1_f1T_l);
  wt_cvt_t2<<<dim3(16,16,1), tb, 0, stream>>>(F32P(26), a1_f2T_h, a1_f2T_l);
  wt_cvt_t<<<dim3(16,16,L_), tb, 0, stream>>>(F32P(28), a2_thT);
  wt_cvt_t<<<dim3(16,16,L_), tb, 0, stream>>>(F32P(30), a2_phT);
  wt_cvt_t<<<dim3(16,16,L_), tb, 0, stream>>>(F32P(32), a2_rhT);
  wt_cvt_t2<<<dim3(16,16,1), tb, 0, stream>>>(F32P(34), a2_intT_h, a2_intT_l);
  wt_cvt_t2<<<dim3(16,16,1), tb, 0, stream>>>(F32P(36), a2_f1T_h, a2_f1T_l);
  wt_cvt_t2<<<dim3(16,16,1), tb, 0, stream>>>(F32P(38), a2_f2T_h, a2_f2T_l);

  // ---- generic agi chain (round-9 numerics: int/FFN split) ----
  auto agi = [&](int NZ, const short* xb, const float* xf,
                 const short* thT, const float* thB,
                 const short* phT, const float* phB,
                 const short* rhT_, const float* rhB,
                 const short* inTh, const short* inTl, const float* inB,
                 const short* f1Th, const short* f1Tl, const float* f1B,
                 const short* f2Th, const short* f2Tl, const float* f2B,
                 float* outf) {
    const int MB = NZ / B_;                  // 2 or 1 (stream multiplier)
    for (int i = 0; i < L_; i++) {
      const size_t wo = (size_t)i * D_ * D_;
      const size_t bo = (size_t)i * D_;
      { GArgs a = GA();
        a.Ah[0] = xb; a.Ah[1] = xb; a.Ah[2] = xb;
        a.Bh[0] = thT + wo; a.Bh[1] = phT + wo; a.Bh[2] = rhT_ + wo;
        a.C0[0] = bufA; a.C0[1] = bufB; a.C0[2] = bufC;
        a.bias[0] = thB + bo; a.bias[1] = phB + bo; a.bias[2] = rhB + bo;
        a.Nn = 512; a.K = 512;
        gemm_k<1,1,EPI_PROJ3,1><<<dim3(64*MB,12,1),256,0,stream>>>(a); }
      { GArgs a = GA();
        a.Ah[0] = bufA; a.sA = sAct; a.Bh[0] = bufB; a.sB = sAct;
        a.C0[0] = aff16; a.sC = sAff; a.alpha = scl; a.Nn = 1024; a.K = 512;
        gemm_k<1,1,EPI_B16_SCALE,1><<<dim3(8,8,NZ),256,0,stream>>>(a); }
      softmax_rows_b16<<<NZ * 256, 256, 0, stream>>>(aff16);
      { GArgs a = GA();
        a.Ah[0] = aff16; a.sA = sAff; a.Bh[0] = bufC; a.sB = sAct;
        a.C0[0] = accR; a.sC = sAct; a.Nn = 512; a.K = 1024;
        if (i == 0) {
          gemm_k<1,1,EPI_F32_ST,1><<<dim3(8,4,NZ),256,0,stream>>>(a);
        } else if (i < L_ - 1) {
          gemm_k<1,1,EPI_F32_ACC,1><<<dim3(8,4,NZ),256,0,stream>>>(a);
        } else {
          a.C1[0] = bufA; a.C1[1] = bufB; a.alpha = 0.25f;
          gemm_k<1,1,EPI_ACC_SPLIT,1><<<dim3(8,4,NZ),256,0,stream>>>(a);
        } }
    }
    { GArgs a = GA();
      a.Ah[0] = bufA; a.Al[0] = bufB;
      a.Bh[0] = inTh; a.Bl[0] = inTl;
      a.C0[0] = accR; a.bias[0] = inB; a.Rv = xf; a.Rv2 = xf;
      a.Nn = 512; a.K = 512;
      gemm_k<2,2,EPI_F32_BIAS_R,1><<<dim3(64*MB,4,1),256,0,stream>>>(a); }
    normalize(accR, NZ, in12l, bufC, resfP);     // resh|resl, resf -> affU
    { GArgs a = GA();
      a.Ah[0] = in12l; a.Al[0] = bufC;
      a.Bh[0] = f1Th; a.Bl[0] = f1Tl;
      a.C0[0] = bufA; a.C1[0] = bufB;            // hidh|hidl
      a.bias[0] = f1B; a.Nn = 512; a.K = 512;
      gemm_k<2,2,EPI_SPLIT_BIAS,1><<<dim3(64*MB,4,1),256,0,stream>>>(a); }
    { GArgs a = GA();
      a.Ah[0] = bufA; a.Al[0] = bufB;
      a.Bh[0] = f2Th; a.Bl[0] = f2Tl;
      a.C0[0] = accR; a.bias[0] = f2B; a.Rv = resfP;
      a.Nn = 512; a.K = 512;
      gemm_k<2,2,EPI_LEAKY_R,1><<<dim3(64*MB,4,1),256,0,stream>>>(a); }
    normalize(accR, NZ, bufA, bufB, outf);       // bf16 outs are scratch
  };

  // agi1 on feed1+feed2 as one batch-16 chain (shared AGI_1 weights)
  agi(16, in12h, feedfR,
      a1_thT, F32P(17), a1_phT, F32P(19), a1_rhT, F32P(21),
      a1_intT_h, a1_intT_l, F32P(23), a1_f1T_h, a1_f1T_l, F32P(25),
      a1_f2T_h, a1_f2T_l, F32P(27), feedfR);     // self12f -> feedfR

  add_both<<<GE, 256, 0, stream>>>(feedfR, feedfR + SBel, in12h, feedfR);

  agi(8, in12h, feedfR,
      a2_thT, F32P(29), a2_phT, F32P(31), a2_rhT, F32P(33),
      a2_intT_h, a2_intT_l, F32P(35), a2_f1T_h, a2_f1T_l, F32P(37),
      a2_f2T_h, a2_f2T_l, F32P(39), (float*)d_out);
}

// Round 13
// 1723.373 us; speedup vs baseline: 1.6081x; 1.0073x over previous
//
#include <hip/hip_runtime.h>

// ACGI_32195074850822 — round 12: L2-locality block swizzle.
//  Diagnosis: HW dispatches x-fastest; M-tile in x => A re-read GY times and
//  B re-read GX times THROUGH L3 (~500 MB/dispatch for PROJ4; ~65us at L3 BW
//  = the observed 68us). FETCH_SIZE (HBM-only) hid it.
//  Fix: XCD-chunked y-fastest swizzle in gemm_k (all grids nwg%8==0):
//    wgid=(orig&7)*(nwg/8)+orig/8; bx=wgid/GY; by=wgid%GY
//  Also: weight conversions merged into 2 table-driven dispatches.
//  Numerics bit-identical to round 12-pass (canary absmax 3.90625e-3).

#define B_ 8
#define N_ 1024
#define D_ 512
#define L_ 4

typedef short s8v __attribute__((ext_vector_type(8)));
typedef short s4v __attribute__((ext_vector_type(4)));
typedef float f4v __attribute__((ext_vector_type(4)));

__device__ __forceinline__ unsigned short f2b(float f) {
  unsigned u = __builtin_bit_cast(unsigned, f);
  u += 0x7FFFu + ((u >> 16) & 1u);          // round-to-nearest-even
  return (unsigned short)(u >> 16);
}
__device__ __forceinline__ float b2f(short s) {
  unsigned u = ((unsigned)(unsigned short)s) << 16;
  return __builtin_bit_cast(float, u);
}

__device__ __forceinline__ void glds16(const short* g, short* l) {
  __builtin_amdgcn_global_load_lds(
      (const __attribute__((address_space(1))) void*)g,
      (__attribute__((address_space(3))) void*)l, 16, 0, 0);
}

enum {
  EPI_PROJ4 = 0,   // seg even: split(acc+bias)->C0/C1; seg odd: TR(acc+bias)->C0
  EPI_PROJ3,       // seg 0,1: bf16(acc+bias)->C0; seg 2: TR->C0
  EPI_B16_SCALE,   // C0 bf16 = acc*alpha
  EPI_ACC2,        // seg s: C0[s] f32 += acc   (z-batched)
  EPI_ACC2_ST,     // seg s: C0[s] f32 = acc    (layer 0)
  EPI_F32_ACC,     // C0[0] f32 += acc          (z-batched)
  EPI_F32_ST,      // C0[0] f32 = acc           (layer 0)
  EPI_F32_BIAS_R,  // C0 f32 = acc+bias+R; R base by z (Rv / Rv2), local idx
  EPI_SPLIT_BIAS,  // C0 hi, C1 lo of acc+bias
  EPI_BOTH_LEAKY,  // C0 bf16 AND C1 f32 = leaky(acc+bias)
  EPI_LEAKY_R,     // C0 f32 = leaky(acc+bias) + R (flat)
  EPI_ACC2_SPLIT,  // seg s: t=(C0[s]+acc)*alpha; hi->C1[s], lo->C1[2+s]
  EPI_ACC_SPLIT    // t=(C0[0]+acc)*alpha; hi->C1[0], lo->C1[1] (z-batched)
};

struct GArgs {
  const short* Ah[4]; const short* Al[4];
  const short* Bh[4]; const short* Bl[4];
  long sA, sB;
  void* C0[4]; void* C1[4];
  long sC;
  const float* bias[4];
  const void* Rv; const void* Rv2;
  float alpha;
  int Nn, K;
};

// C = (ΣA_c)(ΣB_c)^T, bf16 comps, f32 accum; <2,2> drops Al*Bl.
// 128x128 tile, 4 waves, global_load_lds(16B) + both-sides XOR swizzle.
// DB=1: double-buffered staging, counted vmcnt. Block mapping: XCD-chunked,
// y-fastest (L2 reuse of A across GY consecutive blocks).
template<int AS, int BS, int EPI, int DB>
__global__ __launch_bounds__(256) void gemm_k(GArgs g) {
  constexpr int TILE = (AS + BS) * 4096;        // shorts per staging buffer
  __shared__ short smem[TILE * (DB ? 2 : 1)];
  constexpr bool SEG = (EPI == EPI_PROJ4 || EPI == EPI_PROJ3 ||
                        EPI == EPI_ACC2 || EPI == EPI_ACC2_ST ||
                        EPI == EPI_ACC2_SPLIT);
  constexpr bool LDSOUT = (EPI == EPI_PROJ4 || EPI == EPI_PROJ3 ||
                           EPI == EPI_B16_SCALE || EPI == EPI_SPLIT_BIAS ||
                           EPI == EPI_BOTH_LEAKY || EPI == EPI_ACC2_SPLIT ||
                           EPI == EPI_ACC_SPLIT);
  constexpr int CC = (EPI == EPI_PROJ4 || EPI == EPI_SPLIT_BIAS ||
                      EPI == EPI_ACC2_SPLIT || EPI == EPI_ACC_SPLIT) ? 2 : 1;
  const int z = blockIdx.z;

  // ---- L2-locality swizzle (all grids have nwg % 8 == 0) ----
  const int GX = gridDim.x, GY = gridDim.y;
  const int nwg = GX * GY;
  const int orig = blockIdx.y * GX + blockIdx.x;   // HW dispatch order (x fastest)
  const int wgid = (orig & 7) * (nwg >> 3) + (orig >> 3);
  const int bx = wgid / GY;                        // M-tile: shared by GY wgids
  const int by = wgid - bx * GY;
  const int tm = bx * 128;
  const int tn = by * 128;

  const int tid = threadIdx.x;
  const int lane = tid & 63;
  const int w = tid >> 6;
  const int wr = (w >> 1) * 64, wc = (w & 1) * 64;
  const int r16 = lane & 15, kg = lane >> 4;
  const int K = g.K;

  int seg = 0, tnl = tn;
  if constexpr (SEG) { seg = tn >> 9; tnl = tn & 511; }
  const short* Ah = g.Ah[seg];
  const short* Al = (AS == 2) ? g.Al[seg] : nullptr;
  const short* Bh = g.Bh[seg];
  const short* Bl = (BS == 2) ? g.Bl[seg] : nullptr;

  const int srow = lane >> 2;
  const int scol = ((lane & 3) ^ ((lane >> 3) & 3)) * 8;
  const short* gA[2]; const short* gB[2];
  gA[0] = Ah + (size_t)z * g.sA + (size_t)(tm + w * 16 + srow) * K + scol;
  if constexpr (AS == 2)
    gA[1] = Al + (size_t)z * g.sA + (size_t)(tm + w * 16 + srow) * K + scol;
  gB[0] = Bh + (size_t)z * g.sB + (size_t)(tnl + w * 16 + srow) * K + scol;
  if constexpr (BS == 2)
    gB[1] = Bl + (size_t)z * g.sB + (size_t)(tnl + w * 16 + srow) * K + scol;
  const size_t hoff = (size_t)64 * K;

  auto stage = [&](int k0, int buf) {
    short* base = smem + buf * TILE;
    #pragma unroll
    for (int c = 0; c < AS; c++) {
      glds16(gA[c] + k0, base + c * 4096 + (w * 16) * 32);
      glds16(gA[c] + hoff + k0, base + c * 4096 + (64 + w * 16) * 32);
    }
    #pragma unroll
    for (int c = 0; c < BS; c++) {
      glds16(gB[c] + k0, base + (AS + c) * 4096 + (w * 16) * 32);
      glds16(gB[c] + hoff + k0, base + (AS + c) * 4096 + (64 + w * 16) * 32);
    }
  };

  f4v acc[4][4];
  #pragma unroll
  for (int i = 0; i < 4; i++)
    #pragma unroll
    for (int j = 0; j < 4; j++) acc[i][j] = (f4v)0.f;

  const int rc = (kg ^ ((r16 >> 1) & 3)) * 8;

  auto compute = [&](int buf) {
    const short* base = smem + buf * TILE;
    s8v va[2][4], vb[2][4];
    #pragma unroll
    for (int c = 0; c < AS; c++)
      #pragma unroll
      for (int i = 0; i < 4; i++)
        va[c][i] = *(const s8v*)&base[c * 4096 + (wr + i * 16 + r16) * 32 + rc];
    #pragma unroll
    for (int c = 0; c < BS; c++)
      #pragma unroll
      for (int i = 0; i < 4; i++)
        vb[c][i] = *(const s8v*)&base[(AS + c) * 4096 + (wc + i * 16 + r16) * 32 + rc];
    #pragma unroll
    for (int ca = 0; ca < AS; ca++)
      #pragma unroll
      for (int cb = 0; cb < BS; cb++) {
        if (ca == 1 && cb == 1) continue;   // drop lo*lo
        #pragma unroll
        for (int mi = 0; mi < 4; mi++)
          #pragma unroll
          for (int ni = 0; ni < 4; ni++)
            acc[mi][ni] = __builtin_amdgcn_mfma_f32_16x16x32_bf16(
                va[ca][mi], vb[cb][ni], acc[mi][ni], 0, 0, 0);
      }
  };

  const int nt = K >> 5;
  if constexpr (DB) {
    constexpr int NLD = (AS + BS) * 2;        // vmcnt events per stage
    stage(0, 0);
    int buf = 0;
    for (int t = 0; t < nt; t++) {
      if (t + 1 < nt) {
        stage((t + 1) * 32, buf ^ 1);
        if constexpr (NLD == 8)      asm volatile("s_waitcnt vmcnt(8)" ::: "memory");
        else if constexpr (NLD == 6) asm volatile("s_waitcnt vmcnt(6)" ::: "memory");
        else                         asm volatile("s_waitcnt vmcnt(4)" ::: "memory");
      } else {
        asm volatile("s_waitcnt vmcnt(0)" ::: "memory");
      }
      __builtin_amdgcn_sched_barrier(0);
      __builtin_amdgcn_s_barrier();
      compute(buf);
      __builtin_amdgcn_s_barrier();
      buf ^= 1;
    }
  } else {
    for (int t = 0; t < nt; t++) {
      stage(t * 32, 0);
      __syncthreads();
      compute(0);
      __syncthreads();
    }
  }

  short* C0s = (short*)g.C0[seg];  float* C0f = (float*)g.C0[seg];
  short* C1s = (short*)g.C1[seg];  float* C1f = (float*)g.C1[seg];
  const float* biasp = g.bias[seg];
  const int NnL = g.Nn;

  if constexpr (LDSOUT) {
    bool tr = false;
    if constexpr (EPI == EPI_PROJ4) tr = (seg & 1);
    if constexpr (EPI == EPI_PROJ3) tr = (seg == 2);
    if (tr) {
      // transposed write (s4v along n, 8B-coalesced)
      #pragma unroll
      for (int mi = 0; mi < 4; mi++) {
        #pragma unroll
        for (int ni = 0; ni < 4; ni++) {
          const int colL = tnl + wc + ni * 16 + r16;
          const int grow0 = tm + wr + mi * 16 + kg * 4;
          const float bv = biasp[colL];
          s4v o;
          #pragma unroll
          for (int r = 0; r < 4; r++) o[r] = (short)f2b(acc[mi][ni][r] + bv);
          const int b = grow0 >> 10, n = grow0 & 1023;
          *(s4v*)&C0s[((size_t)b * 512 + colL) * 1024 + n] = o;
        }
      }
    } else {
      short* D0 = nullptr; short* D1 = nullptr;
      if constexpr (EPI == EPI_PROJ4 || EPI == EPI_PROJ3) {
        D0 = C0s; D1 = C1s;
      } else if constexpr (EPI == EPI_SPLIT_BIAS) {
        D0 = C0s + (size_t)z * g.sC; D1 = C1s + (size_t)z * g.sC;
      } else if constexpr (EPI == EPI_B16_SCALE || EPI == EPI_BOTH_LEAKY) {
        D0 = C0s + (size_t)z * g.sC;
      } else if constexpr (EPI == EPI_ACC2_SPLIT) {
        D0 = (short*)g.C1[seg] + (size_t)z * g.sC;
        D1 = (short*)g.C1[2 + seg] + (size_t)z * g.sC;
      } else { // EPI_ACC_SPLIT
        D0 = (short*)g.C1[0] + (size_t)z * g.sC;
        D1 = (short*)g.C1[1] + (size_t)z * g.sC;
      }
      for (int mi = 0; mi < 4; mi++) {
        #pragma unroll
        for (int ni = 0; ni < 4; ni++) {
          const int lcol = wc + ni * 16 + r16;
          const int colL = tnl + lcol;
          float bv = 0.f;
          if constexpr (EPI == EPI_PROJ4 || EPI == EPI_PROJ3 ||
                        EPI == EPI_SPLIT_BIAS || EPI == EPI_BOTH_LEAKY)
            bv = biasp[colL];
          #pragma unroll
          for (int r = 0; r < 4; r++) {
            const int grow = tm + wr + mi * 16 + kg * 4 + r;
            const float v = acc[mi][ni][r];
            float t;
            if constexpr (EPI == EPI_B16_SCALE)
              t = v * g.alpha;
            else if constexpr (EPI == EPI_ACC2_SPLIT || EPI == EPI_ACC_SPLIT)
              t = (C0f[(size_t)z * g.sC + (size_t)grow * NnL + colL] + v) * g.alpha;
            else if constexpr (EPI == EPI_BOTH_LEAKY) {
              t = v + bv; t = (t >= 0.f) ? t : 0.01f * t;
              C1f[(size_t)z * g.sC + (size_t)grow * NnL + colL] = t;
            } else
              t = v + bv;
            const int lrow = (w >> 1) * 16 + kg * 4 + r;
            const int sw = ((lrow >> 2) & 3) << 4;          // bank swizzle
            const int li = lrow * 128 + (lcol ^ sw);
            const short h = (short)f2b(t);
            smem[li] = h;
            if constexpr (CC == 2) smem[4096 + li] = (short)f2b(t - b2f(h));
          }
        }
        __syncthreads();
        #pragma unroll
        for (int c2 = 0; c2 < CC; c2++) {
          short* D = c2 ? D1 : D0;
          #pragma unroll
          for (int half = 0; half < 2; half++) {
            const int e = (tid + half * 256) * 8;
            const int lrow2 = e >> 7, col = e & 127;
            const int sw2 = ((lrow2 >> 2) & 3) << 4;
            const int grow = tm + (lrow2 >> 4) * 64 + mi * 16 + (lrow2 & 15);
            *(s8v*)&D[(size_t)grow * NnL + tnl + col] =
                *(const s8v*)&smem[c2 * 4096 + (lrow2 << 7) + (col ^ sw2)];
          }
        }
        __syncthreads();
      }
    }
  } else {
    // direct f32 epilogues (coalesced 64B/group)
    #pragma unroll
    for (int mi = 0; mi < 4; mi++) {
      #pragma unroll
      for (int ni = 0; ni < 4; ni++) {
        const int colL = tnl + wc + ni * 16 + r16;
        const int grow0 = tm + wr + mi * 16 + kg * 4;
        float bv = 0.f;
        if constexpr (EPI == EPI_F32_BIAS_R || EPI == EPI_LEAKY_R)
          bv = biasp[colL];
        #pragma unroll
        for (int r = 0; r < 4; r++) {
          const size_t lidx = (size_t)(grow0 + r) * NnL + colL;
          const size_t idx = (size_t)z * g.sC + lidx;
          const float v = acc[mi][ni][r];
          if constexpr (EPI == EPI_ACC2) {
            C0f[(size_t)z * g.sC + (size_t)(grow0 + r) * 512 + colL] += v;
          } else if constexpr (EPI == EPI_ACC2_ST) {
            C0f[(size_t)z * g.sC + (size_t)(grow0 + r) * 512 + colL] = v;
          } else if constexpr (EPI == EPI_F32_ACC) {
            C0f[idx] += v;
          } else if constexpr (EPI == EPI_F32_ST) {
            C0f[idx] = v;
          } else if constexpr (EPI == EPI_F32_BIAS_R) {
            const float* Rf = (const float*)(z == 0 ? g.Rv : g.Rv2);
            C0f[idx] = v + bv + Rf[lidx];
          } else { // EPI_LEAKY_R
            float t = v + bv; t = (t >= 0.f) ? t : 0.01f * t;
            C0f[idx] = t + ((const float*)g.Rv)[idx];
          }
        }
      }
    }
  }
}

// ---- merged weight conversion: z-indexed table of DxD transposes ----
struct WcvtArgs {
  const float* src[32];
  short* hi[32];
  short* lo[32];      // nullptr -> single bf16
  int n;
};
__global__ __launch_bounds__(256) void wt_cvt_all(WcvtArgs a) {
  __shared__ float t[32][33];
  const int zi = blockIdx.z;
  const int bx = blockIdx.x * 32, by = blockIdx.y * 32;
  const int tx = threadIdx.x, ty = threadIdx.y;
  const float* src = a.src[zi];
  #pragma unroll
  for (int k = 0; k < 4; k++)
    t[ty + 8 * k][tx] = src[(size_t)(by + ty + 8 * k) * D_ + bx + tx];
  __syncthreads();
  short* hi = a.hi[zi];
  short* lo = a.lo[zi];
  if (lo) {
    #pragma unroll
    for (int k = 0; k < 4; k++) {
      const size_t o = (size_t)(bx + ty + 8 * k) * D_ + by + tx;
      float v = t[tx][ty + 8 * k];
      short h = (short)f2b(v);
      hi[o] = h;
      lo[o] = (short)f2b(v - b2f(h));
    }
  } else {
    #pragma unroll
    for (int k = 0; k < 4; k++)
      hi[(size_t)(bx + ty + 8 * k) * D_ + by + tx] =
          (short)f2b(t[tx][ty + 8 * k]);
  }
}

// f32 * scale -> hi bf16 + lo bf16
__global__ __launch_bounds__(256) void split_f32(const float* __restrict__ src,
                                                 short* __restrict__ hi,
                                                 short* __restrict__ lo, float scale) {
  const size_t i = ((size_t)blockIdx.x * 256 + threadIdx.x) * 4;
  f4v v = *(const f4v*)(src + i);
  s4v h, l;
  #pragma unroll
  for (int j = 0; j < 4; j++) {
    float t = v[j] * scale;
    h[j] = (short)f2b(t);
    l[j] = (short)f2b(t - b2f(h[j]));
  }
  *(s4v*)(hi + i) = h;
  *(s4v*)(lo + i) = l;
}

// sum = a + b (f32) elementwise; write bf16 + f32 (outf may alias a)
__global__ __launch_bounds__(256) void add_both(const float* __restrict__ a,
                                                const float* __restrict__ b,
                                                short* __restrict__ outb,
                                                float* outf) {
  const size_t i = ((size_t)blockIdx.x * 256 + threadIdx.x) * 4;
  f4v av = *(const f4v*)(a + i);
  f4v bv = *(const f4v*)(b + i);
  f4v s; s4v o;
  #pragma unroll
  for (int j = 0; j < 4; j++) { s[j] = av[j] + bv[j]; o[j] = (short)f2b(s[j]); }
  *(f4v*)(outf + i) = s;
  *(s4v*)(outb + i) = o;
}

// in-place softmax over bf16 rows of 1024; one wave per row, shuffle reduce
__global__ __launch_bounds__(256) void softmax_rows_b16(short* __restrict__ p) {
  const int row = blockIdx.x * 4 + (threadIdx.x >> 6);
  const int lane = threadIdx.x & 63;
  short* rp = p + (size_t)row * 1024 + lane * 16;
  s8v v0 = *(s8v*)rp, v1 = *(s8v*)(rp + 8);
  float f[16];
  #pragma unroll
  for (int j = 0; j < 8; j++) { f[j] = b2f(v0[j]); f[8 + j] = b2f(v1[j]); }
  float m = f[0];
  #pragma unroll
  for (int j = 1; j < 16; j++) m = fmaxf(m, f[j]);
  #pragma unroll
  for (int s = 32; s; s >>= 1) m = fmaxf(m, __shfl_xor(m, s, 64));
  float sum = 0.f;
  #pragma unroll
  for (int j = 0; j < 16; j++) { f[j] = __expf(f[j] - m); sum += f[j]; }
  #pragma unroll
  for (int s = 32; s; s >>= 1) sum += __shfl_xor(sum, s, 64);
  const float inv = 1.f / sum;
  #pragma unroll
  for (int j = 0; j < 8; j++) {
    v0[j] = (short)f2b(f[j] * inv);
    v1[j] = (short)f2b(f[8 + j] * inv);
  }
  *(s8v*)rp = v0; *(s8v*)(rp + 8) = v1;
}

// L2-normalize over axis=1 (N) of (NB,N,D) f32; deterministic 3-phase.
#define NCHUNK 16
__global__ __launch_bounds__(256) void norm_part(const float* __restrict__ t,
                                                 float* __restrict__ part, int NB) {
  const int d = blockIdx.x * 256 + threadIdx.x;
  const int b = blockIdx.y;
  const int c = blockIdx.z;
  const int n0 = c * (N_ / NCHUNK);
  const float* p = t + ((size_t)b * N_ + n0) * D_ + d;
  float ss = 0.f;
  for (int n = 0; n < N_ / NCHUNK; n++) { float v = p[(size_t)n * D_]; ss += v * v; }
  part[((size_t)c * NB + b) * D_ + d] = ss;
}
__global__ __launch_bounds__(256) void norm_inv(const float* __restrict__ part,
                                                float* __restrict__ inv, int NB) {
  const int i = blockIdx.x * 256 + threadIdx.x;   // b*D + d
  float ss = 0.f;
  for (int c = 0; c < NCHUNK; c++) ss += part[(size_t)c * (NB * D_) + i];
  inv[i] = 1.f / fmaxf(sqrtf(ss), 1e-12f);
}
__global__ __launch_bounds__(256) void norm_scale(const float* __restrict__ t,
                                                  const float* __restrict__ inv,
                                                  short* __restrict__ outh,
                                                  short* __restrict__ outl,
                                                  float* __restrict__ outf) {
  const size_t i = ((size_t)blockIdx.x * 256 + threadIdx.x) * 4;
  const int b = (int)(i >> 19);        // N_*D_ = 2^19
  const int d = (int)(i & (D_ - 1));
  f4v v = *(const f4v*)(t + i);
  f4v w = *(const f4v*)(inv + (size_t)b * D_ + d);
  f4v o; s4v oh, ol;
  #pragma unroll
  for (int j = 0; j < 4; j++) {
    o[j] = v[j] * w[j];
    oh[j] = (short)f2b(o[j]);
    ol[j] = (short)f2b(o[j] - b2f(oh[j]));
  }
  *(f4v*)(outf + i) = o;
  *(s4v*)(outh + i) = oh;
  *(s4v*)(outl + i) = ol;
}

extern "C" void kernel_launch(void* const* d_in, const int* in_sizes, int n_in,
                              void* d_out, int out_size, void* d_ws, size_t ws_size,
                              hipStream_t stream) {
  (void)in_sizes; (void)n_in; (void)out_size; (void)ws_size;
  const float* in1f = (const float*)d_in[0];
  const float* in2f = (const float*)d_in[1];

  const size_t SB = (size_t)B_ * N_ * D_ * 2;      // 8 MB
  const size_t SF = (size_t)B_ * N_ * D_ * 4;      // 16 MB
  const size_t WL = (size_t)L_ * D_ * D_ * 2;
  const size_t W1 = (size_t)D_ * D_ * 2;
  const size_t WD = (size_t)D_ * D_;               // elems per DxD slice
  const long SBel = (long)B_ * N_ * D_;            // 4194304 elems
  const long sAct = (long)N_ * D_;
  const long sAff = (long)N_ * N_;

  char* ws = (char*)d_ws;
  size_t off = 0;
  auto alloc = [&](size_t bytes) -> char* {
    char* p = ws + off;
    off += (bytes + 255) & ~(size_t)255;
    return p;
  };

  // ---- weight region (19 MB); a1/a2 overlay after stage 1 ----
  char* wreg = alloc(8 * WL + 6 * W1);
  short* c_thT_h = (short*)(wreg);
  short* c_thT_l = (short*)(wreg + WL);
  short* c_phT_h = (short*)(wreg + 2 * WL);
  short* c_phT_l = (short*)(wreg + 3 * WL);
  short* c_rhT_h = (short*)(wreg + 4 * WL);
  short* c_rhT_l = (short*)(wreg + 5 * WL);
  short* c_psT_h = (short*)(wreg + 6 * WL);
  short* c_psT_l = (short*)(wreg + 7 * WL);
  short* c_intT_h = (short*)(wreg + 8 * WL);
  short* c_intT_l = (short*)(wreg + 8 * WL + W1);
  short* c_f1T_h  = (short*)(wreg + 8 * WL + 2 * W1);
  short* c_f1T_l  = (short*)(wreg + 8 * WL + 3 * W1);
  short* c_f2T_h  = (short*)(wreg + 8 * WL + 4 * W1);
  short* c_f2T_l  = (short*)(wreg + 8 * WL + 5 * W1);
  short* a1_thT = (short*)(wreg);
  short* a1_phT = (short*)(wreg + WL);
  short* a1_rhT = (short*)(wreg + 2 * WL);
  short* a2_thT = (short*)(wreg + 3 * WL);
  short* a2_phT = (short*)(wreg + 4 * WL);
  short* a2_rhT = (short*)(wreg + 5 * WL);
  char*  aw = wreg + 6 * WL;
  short* a1_intT_h = (short*)(aw);
  short* a1_intT_l = (short*)(aw + W1);
  short* a1_f1T_h  = (short*)(aw + 2 * W1);
  short* a1_f1T_l  = (short*)(aw + 3 * W1);
  short* a1_f2T_h  = (short*)(aw + 4 * W1);
  short* a1_f2T_l  = (short*)(aw + 5 * W1);
  short* a2_intT_h = (short*)(aw + 6 * W1);
  short* a2_intT_l = (short*)(aw + 7 * W1);
  short* a2_f1T_h  = (short*)(aw + 8 * W1);
  short* a2_f1T_l  = (short*)(aw + 9 * W1);
  short* a2_f2T_h  = (short*)(aw + 10 * W1);
  short* a2_f2T_l  = (short*)(aw + 11 * W1);

  // ---- pair-contiguous activation regions (2*SB each = 16 MB) ----
  short* in12h = (short*)alloc(2 * SB);   // in1h|in2h -> feed12b -> sumb
  short* in12l = (short*)alloc(2 * SB);   // in1l|in2l -> resh
  short* bufA  = (short*)alloc(2 * SB);   // thh|thl -> inth -> hidh
  short* bufB  = (short*)alloc(2 * SB);   // phh|phl -> intl -> hidl
  short* bufC  = (short*)alloc(2 * SB);   // rhT|psT -> resl
  char*  affU  = alloc((size_t)32 * 1024 * 1024);
  float* accR  = (float*)alloc(2 * SF);   // acc1|acc2 / acc16 / tmpf
  float* feedfR = (float*)alloc(2 * SF);  // feed12f -> self12f -> sumf
  float* npart = (float*)alloc((size_t)NCHUNK * 16 * D_ * 4);
  float* ninv  = (float*)alloc((size_t)16 * D_ * 4);
  // total ≈ 196 MB (< proven 217)

  short* in1h = in12h;        short* in2h = in12h + SBel;
  short* in1l = in12l;        short* in2l = in12l + SBel;
  short* thh = bufA;          short* thl = bufA + SBel;
  short* phh = bufB;          short* phl = bufB + SBel;
  short* rhT = bufC;          short* psT = bufC + SBel;
  short* affh = (short*)affU;                   // [0,16 MB)
  short* aff16 = (short*)affU;                  // 32 MB bf16 batch-16 logits
  float* resfP = (float*)affU;                  // 32 MB f32 res (affs dead)
  float* acc1 = accR;         float* acc2 = accR + SBel;

  const float scl = 0.04419417382415922f;   // 512^-0.5
  dim3 tb(32, 8);
  const int GE = (B_ * N_ * D_) / (4 * 256);     // 4096
  #define F32P(i) ((const float*)d_in[i])

  auto GA = [&]() { GArgs a; __builtin_memset(&a, 0, sizeof(a)); return a; };
  auto normalize = [&](const float* src, int NB, short* outh, short* outl, float* outf) {
    norm_part<<<dim3(D_/256, NB, NCHUNK), 256, 0, stream>>>(src, npart, NB);
    norm_inv<<<(NB * D_) / 256, 256, 0, stream>>>(npart, ninv, NB);
    norm_scale<<<NB * 512, 256, 0, stream>>>(src, ninv, outh, outl, outf);
  };

  // ---- stage-1 weights: ONE merged dispatch (19 split slices) ----
  {
    WcvtArgs wa; __builtin_memset(&wa, 0, sizeof(wa));
    int n = 0;
    auto addL = [&](const float* s, short* h, short* l, int nl) {
      for (int i = 0; i < nl; i++) {
        wa.src[n] = s + i * WD; wa.hi[n] = h + i * WD; wa.lo[n] = l + i * WD; n++;
      }
    };
    addL(F32P(2),  c_thT_h, c_thT_l, L_);
    addL(F32P(4),  c_phT_h, c_phT_l, L_);
    addL(F32P(6),  c_rhT_h, c_rhT_l, L_);
    addL(F32P(8),  c_psT_h, c_psT_l, L_);
    addL(F32P(10), c_intT_h, c_intT_l, 1);
    addL(F32P(12), c_f1T_h, c_f1T_l, 1);
    addL(F32P(14), c_f2T_h, c_f2T_l, 1);
    wa.n = n;
    wt_cvt_all<<<dim3(16, 16, n), tb, 0, stream>>>(wa);
  }
  split_f32<<<GE, 256, 0, stream>>>(in1f, in1h, in1l, 1.0f);
  split_f32<<<GE, 256, 0, stream>>>(in2f, in2h, in2l, 1.0f);

  // ---- stage 1: 4-seg proj -> bf16 P -> (1,1) applies ----
  for (int i = 0; i < L_; i++) {
    const size_t wo = (size_t)i * D_ * D_;
    const size_t bo = (size_t)i * D_;
    { GArgs a = GA();
      a.Ah[0] = in1h; a.Ah[1] = in1h; a.Ah[2] = in2h; a.Ah[3] = in2h;
      a.Al[0] = in1l; a.Al[1] = in1l; a.Al[2] = in2l; a.Al[3] = in2l;
      a.Bh[0] = c_thT_h + wo; a.Bh[1] = c_rhT_h + wo;
      a.Bh[2] = c_phT_h + wo; a.Bh[3] = c_psT_h + wo;
      a.Bl[0] = c_thT_l + wo; a.Bl[1] = c_rhT_l + wo;
      a.Bl[2] = c_phT_l + wo; a.Bl[3] = c_psT_l + wo;
      a.C0[0] = thh; a.C0[1] = rhT; a.C0[2] = phh; a.C0[3] = psT;
      a.C1[0] = thl; a.C1[2] = phl;
      a.bias[0] = F32P(3) + bo; a.bias[1] = F32P(7) + bo;
      a.bias[2] = F32P(5) + bo; a.bias[3] = F32P(9) + bo;
      a.Nn = 512; a.K = 512;
      gemm_k<2,2,EPI_PROJ4,0><<<dim3(64,16,1),256,0,stream>>>(a); }
    { GArgs a = GA();
      a.Ah[0] = thh; a.Al[0] = thl; a.sA = sAct;
      a.Bh[0] = phh; a.Bl[0] = phl; a.sB = sAct;
      a.C0[0] = affh; a.sC = sAff;
      a.alpha = scl; a.Nn = 1024; a.K = 512;
      gemm_k<2,2,EPI_B16_SCALE,1><<<dim3(8,8,B_),256,0,stream>>>(a); }
    { GArgs a = GA();
      a.Ah[0] = affh; a.Ah[1] = affh; a.sA = sAff;
      a.Bh[0] = rhT; a.Bh[1] = psT; a.sB = sAct;
      a.C0[0] = acc1; a.C0[1] = acc2; a.sC = sAct;
      a.Nn = 512; a.K = 1024;
      if (i == 0) {
        gemm_k<1,1,EPI_ACC2_ST,1><<<dim3(8,8,B_),256,0,stream>>>(a);
      } else if (i < L_ - 1) {
        gemm_k<1,1,EPI_ACC2,1><<<dim3(8,8,B_),256,0,stream>>>(a);
      } else {
        a.C1[0] = bufA; a.C1[1] = bufA + SBel;   // inth (stream1|stream2)
        a.C1[2] = bufB; a.C1[3] = bufB + SBel;   // intl
        a.alpha = 0.25f;
        gemm_k<1,1,EPI_ACC2_SPLIT,1><<<dim3(8,8,B_),256,0,stream>>>(a);
      } }
  }

  // ---- stage-1 epilogue, both streams batched (z=2 / M=16384) ----
  { GArgs a = GA();
    a.Ah[0] = bufA; a.Al[0] = bufB; a.sA = SBel;
    a.Bh[0] = c_intT_h; a.Bl[0] = c_intT_l;
    a.C0[0] = accR; a.sC = SBel;
    a.bias[0] = F32P(11); a.Rv = in1f; a.Rv2 = in2f;
    a.Nn = 512; a.K = 512;
    gemm_k<2,2,EPI_F32_BIAS_R,1><<<dim3(64,4,2),256,0,stream>>>(a); }
  normalize(accR, 16, in12l, bufA, resfP);       // resh|resl (resf scratch)
  { GArgs a = GA();
    a.Ah[0] = in12l; a.Al[0] = bufA;
    a.Bh[0] = c_f1T_h; a.Bl[0] = c_f1T_l;
    a.C0[0] = bufB; a.C1[0] = bufC;              // hidh|hidl
    a.bias[0] = F32P(13); a.Nn = 512; a.K = 512;
    gemm_k<2,2,EPI_SPLIT_BIAS,1><<<dim3(128,4,1),256,0,stream>>>(a); }
  { GArgs a = GA();
    a.Ah[0] = bufB; a.Al[0] = bufC;
    a.Bh[0] = c_f2T_h; a.Bl[0] = c_f2T_l;
    a.C0[0] = in12h; a.C1[0] = feedfR;           // feed12b | feed12f
    a.bias[0] = F32P(15); a.Nn = 512; a.K = 512;
    gemm_k<2,2,EPI_BOTH_LEAKY,1><<<dim3(128,4,1),256,0,stream>>>(a); }

  // ---- a1/a2 weights: ONE merged dispatch (24 single + 6 split slices) ----
  {
    WcvtArgs wa; __builtin_memset(&wa, 0, sizeof(wa));
    int n = 0;
    auto addS = [&](const float* s, short* h, int nl) {
      for (int i = 0; i < nl; i++) {
        wa.src[n] = s + i * WD; wa.hi[n] = h + i * WD; wa.lo[n] = nullptr; n++;
      }
    };
    auto add2 = [&](const float* s, short* h, short* l) {
      wa.src[n] = s; wa.hi[n] = h; wa.lo[n] = l; n++;
    };
    addS(F32P(16), a1_thT, L_);
    addS(F32P(18), a1_phT, L_);
    addS(F32P(20), a1_rhT, L_);
    addS(F32P(28), a2_thT, L_);
    addS(F32P(30), a2_phT, L_);
    addS(F32P(32), a2_rhT, L_);
    add2(F32P(22), a1_intT_h, a1_intT_l);
    add2(F32P(24), a1_f1T_h, a1_f1T_l);
    add2(F32P(26), a1_f2T_h, a1_f2T_l);
    add2(F32P(34), a2_intT_h, a2_intT_l);
    add2(F32P(36), a2_f1T_h, a2_f1T_l);
    add2(F32P(38), a2_f2T_h, a2_f2T_l);
    wa.n = n;                                    // 30 slices
    wt_cvt_all<<<dim3(16, 16, n), tb, 0, stream>>>(wa);
  }

  // ---- generic agi chain (round-12 numerics) ----
  auto agi = [&](int NZ, const short* xb, const float* xf,
                 const short* thT, const float* thB,
                 const short* phT, const float* phB,
                 const short* rhT_, const float* rhB,
                 const short* inTh, const short* inTl, const float* inB,
                 const short* f1Th, const short* f1Tl, const float* f1B,
                 const short* f2Th, const short* f2Tl, const float* f2B,
                 float* outf) {
    const int MB = NZ / B_;                  // 2 or 1 (stream multiplier)
    for (int i = 0; i < L_; i++) {
      const size_t wo = (size_t)i * D_ * D_;
      const size_t bo = (size_t)i * D_;
      { GArgs a = GA();
        a.Ah[0] = xb; a.Ah[1] = xb; a.Ah[2] = xb;
        a.Bh[0] = thT + wo; a.Bh[1] = phT + wo; a.Bh[2] = rhT_ + wo;
        a.C0[0] = bufA; a.C0[1] = bufB; a.C0[2] = bufC;
        a.bias[0] = thB + bo; a.bias[1] = phB + bo; a.bias[2] = rhB + bo;
        a.Nn = 512; a.K = 512;
        gemm_k<1,1,EPI_PROJ3,1><<<dim3(64*MB,12,1),256,0,stream>>>(a); }
      { GArgs a = GA();
        a.Ah[0] = bufA; a.sA = sAct; a.Bh[0] = bufB; a.sB = sAct;
        a.C0[0] = aff16; a.sC = sAff; a.alpha = scl; a.Nn = 1024; a.K = 512;
        gemm_k<1,1,EPI_B16_SCALE,1><<<dim3(8,8,NZ),256,0,stream>>>(a); }
      softmax_rows_b16<<<NZ * 256, 256, 0, stream>>>(aff16);
      { GArgs a = GA();
        a.Ah[0] = aff16; a.sA = sAff; a.Bh[0] = bufC; a.sB = sAct;
        a.C0[0] = accR; a.sC = sAct; a.Nn = 512; a.K = 1024;
        if (i == 0) {
          gemm_k<1,1,EPI_F32_ST,1><<<dim3(8,4,NZ),256,0,stream>>>(a);
        } else if (i < L_ - 1) {
          gemm_k<1,1,EPI_F32_ACC,1><<<dim3(8,4,NZ),256,0,stream>>>(a);
        } else {
          a.C1[0] = bufA; a.C1[1] = bufB; a.alpha = 0.25f;
          gemm_k<1,1,EPI_ACC_SPLIT,1><<<dim3(8,4,NZ),256,0,stream>>>(a);
        } }
    }
    { GArgs a = GA();
      a.Ah[0] = bufA; a.Al[0] = bufB;
      a.Bh[0] = inTh; a.Bl[0] = inTl;
      a.C0[0] = accR; a.bias[0] = inB; a.Rv = xf; a.Rv2 = xf;
      a.Nn = 512; a.K = 512;
      gemm_k<2,2,EPI_F32_BIAS_R,1><<<dim3(64*MB,4,1),256,0,stream>>>(a); }
    normalize(accR, NZ, in12l, bufC, resfP);     // resh|resl, resf -> affU
    { GArgs a = GA();
      a.Ah[0] = in12l; a.Al[0] = bufC;
      a.Bh[0] = f1Th; a.Bl[0] = f1Tl;
      a.C0[0] = bufA; a.C1[0] = bufB;            // hidh|hidl
      a.bias[0] = f1B; a.Nn = 512; a.K = 512;
      gemm_k<2,2,EPI_SPLIT_BIAS,1><<<dim3(64*MB,4,1),256,0,stream>>>(a); }
    { GArgs a = GA();
      a.Ah[0] = bufA; a.Al[0] = bufB;
      a.Bh[0] = f2Th; a.Bl[0] = f2Tl;
      a.C0[0] = accR; a.bias[0] = f2B; a.Rv = resfP;
      a.Nn = 512; a.K = 512;
      gemm_k<2,2,EPI_LEAKY_R,1><<<dim3(64*MB,4,1),256,0,stream>>>(a); }
    normalize(accR, NZ, bufA, bufB, outf);       // bf16 outs are scratch
  };

  // agi1 on feed1+feed2 as one batch-16 chain (shared AGI_1 weights)
  agi(16, in12h, feedfR,
      a1_thT, F32P(17), a1_phT, F32P(19), a1_rhT, F32P(21),
      a1_intT_h, a1_intT_l, F32P(23), a1_f1T_h, a1_f1T_l, F32P(25),
      a1_f2T_h, a1_f2T_l, F32P(27), feedfR);     // self12f -> feedfR

  add_both<<<GE, 256, 0, stream>>>(feedfR, feedfR + SBel, in12h, feedfR);

  agi(8, in12h, feedfR,
      a2_thT, F32P(29), a2_phT, F32P(31), a2_rhT, F32P(33),
      a2_intT_h, a2_intT_l, F32P(35), a2_f1T_h, a2_f1T_l, F32P(37),
      a2_f2T_h, a2_f2T_l, F32P(39), (float*)d_out);
}

// Round 14
// 1700.374 us; speedup vs baseline: 1.6298x; 1.0135x over previous
//
#include <hip/hip_runtime.h>

// ACGI_32195074850822 — round 13: epilogue barrier reduction + PROJ4 DB=1.
//  * LDSOUT epilogue: full 128x128(xCC) tile staged in ONE barrier when the
//    staging LDS is big enough (all LDSOUT EPIs except ACC*_SPLIT) — was
//    4 strips x 2 barriers.
//  * PROJ4 -> DB=1 (counted-vmcnt loop + fast epilogue; 64KB LDS).
// Numerics bit-identical (canary absmax 3.90625e-3).

#define B_ 8
#define N_ 1024
#define D_ 512
#define L_ 4

typedef short s8v __attribute__((ext_vector_type(8)));
typedef short s4v __attribute__((ext_vector_type(4)));
typedef float f4v __attribute__((ext_vector_type(4)));

__device__ __forceinline__ unsigned short f2b(float f) {
  unsigned u = __builtin_bit_cast(unsigned, f);
  u += 0x7FFFu + ((u >> 16) & 1u);          // round-to-nearest-even
  return (unsigned short)(u >> 16);
}
__device__ __forceinline__ float b2f(short s) {
  unsigned u = ((unsigned)(unsigned short)s) << 16;
  return __builtin_bit_cast(float, u);
}

__device__ __forceinline__ void glds16(const short* g, short* l) {
  __builtin_amdgcn_global_load_lds(
      (const __attribute__((address_space(1))) void*)g,
      (__attribute__((address_space(3))) void*)l, 16, 0, 0);
}

enum {
  EPI_PROJ4 = 0,   // seg even: split(acc+bias)->C0/C1; seg odd: TR(acc+bias)->C0
  EPI_PROJ3,       // seg 0,1: bf16(acc+bias)->C0; seg 2: TR->C0
  EPI_B16_SCALE,   // C0 bf16 = acc*alpha
  EPI_ACC2,        // seg s: C0[s] f32 += acc   (z-batched)
  EPI_ACC2_ST,     // seg s: C0[s] f32 = acc    (layer 0)
  EPI_F32_ACC,     // C0[0] f32 += acc          (z-batched)
  EPI_F32_ST,      // C0[0] f32 = acc           (layer 0)
  EPI_F32_BIAS_R,  // C0 f32 = acc+bias+R; R base by z (Rv / Rv2), local idx
  EPI_SPLIT_BIAS,  // C0 hi, C1 lo of acc+bias
  EPI_BOTH_LEAKY,  // C0 bf16 AND C1 f32 = leaky(acc+bias)
  EPI_LEAKY_R,     // C0 f32 = leaky(acc+bias) + R (flat)
  EPI_ACC2_SPLIT,  // seg s: t=(C0[s]+acc)*alpha; hi->C1[s], lo->C1[2+s]
  EPI_ACC_SPLIT    // t=(C0[0]+acc)*alpha; hi->C1[0], lo->C1[1] (z-batched)
};

struct GArgs {
  const short* Ah[4]; const short* Al[4];
  const short* Bh[4]; const short* Bl[4];
  long sA, sB;
  void* C0[4]; void* C1[4];
  long sC;
  const float* bias[4];
  const void* Rv; const void* Rv2;
  float alpha;
  int Nn, K;
};

// C = (ΣA_c)(ΣB_c)^T, bf16 comps, f32 accum; <2,2> drops Al*Bl.
// 128x128 tile, 4 waves, global_load_lds(16B) + both-sides XOR swizzle.
// DB=1: double-buffered staging, counted vmcnt. Block mapping: XCD-chunked,
// y-fastest.
template<int AS, int BS, int EPI, int DB>
__global__ __launch_bounds__(256) void gemm_k(GArgs g) {
  constexpr int TILE = (AS + BS) * 4096;        // shorts per staging buffer
  __shared__ short smem[TILE * (DB ? 2 : 1)];
  constexpr bool SEG = (EPI == EPI_PROJ4 || EPI == EPI_PROJ3 ||
                        EPI == EPI_ACC2 || EPI == EPI_ACC2_ST ||
                        EPI == EPI_ACC2_SPLIT);
  constexpr bool LDSOUT = (EPI == EPI_PROJ4 || EPI == EPI_PROJ3 ||
                           EPI == EPI_B16_SCALE || EPI == EPI_SPLIT_BIAS ||
                           EPI == EPI_BOTH_LEAKY || EPI == EPI_ACC2_SPLIT ||
                           EPI == EPI_ACC_SPLIT);
  constexpr int CC = (EPI == EPI_PROJ4 || EPI == EPI_SPLIT_BIAS ||
                      EPI == EPI_ACC2_SPLIT || EPI == EPI_ACC_SPLIT) ? 2 : 1;
  constexpr bool FITS = (TILE * (DB ? 2 : 1)) >= CC * 16384;  // full-tile epi
  const int z = blockIdx.z;

  // ---- L2-locality swizzle (all grids have nwg % 8 == 0) ----
  const int GX = gridDim.x, GY = gridDim.y;
  const int nwg = GX * GY;
  const int orig = blockIdx.y * GX + blockIdx.x;
  const int wgid = (orig & 7) * (nwg >> 3) + (orig >> 3);
  const int bx = wgid / GY;
  const int by = wgid - bx * GY;
  const int tm = bx * 128;
  const int tn = by * 128;

  const int tid = threadIdx.x;
  const int lane = tid & 63;
  const int w = tid >> 6;
  const int wr = (w >> 1) * 64, wc = (w & 1) * 64;
  const int r16 = lane & 15, kg = lane >> 4;
  const int K = g.K;

  int seg = 0, tnl = tn;
  if constexpr (SEG) { seg = tn >> 9; tnl = tn & 511; }
  const short* Ah = g.Ah[seg];
  const short* Al = (AS == 2) ? g.Al[seg] : nullptr;
  const short* Bh = g.Bh[seg];
  const short* Bl = (BS == 2) ? g.Bl[seg] : nullptr;

  const int srow = lane >> 2;
  const int scol = ((lane & 3) ^ ((lane >> 3) & 3)) * 8;
  const short* gA[2]; const short* gB[2];
  gA[0] = Ah + (size_t)z * g.sA + (size_t)(tm + w * 16 + srow) * K + scol;
  if constexpr (AS == 2)
    gA[1] = Al + (size_t)z * g.sA + (size_t)(tm + w * 16 + srow) * K + scol;
  gB[0] = Bh + (size_t)z * g.sB + (size_t)(tnl + w * 16 + srow) * K + scol;
  if constexpr (BS == 2)
    gB[1] = Bl + (size_t)z * g.sB + (size_t)(tnl + w * 16 + srow) * K + scol;
  const size_t hoff = (size_t)64 * K;

  auto stage = [&](int k0, int buf) {
    short* base = smem + buf * TILE;
    #pragma unroll
    for (int c = 0; c < AS; c++) {
      glds16(gA[c] + k0, base + c * 4096 + (w * 16) * 32);
      glds16(gA[c] + hoff + k0, base + c * 4096 + (64 + w * 16) * 32);
    }
    #pragma unroll
    for (int c = 0; c < BS; c++) {
      glds16(gB[c] + k0, base + (AS + c) * 4096 + (w * 16) * 32);
      glds16(gB[c] + hoff + k0, base + (AS + c) * 4096 + (64 + w * 16) * 32);
    }
  };

  f4v acc[4][4];
  #pragma unroll
  for (int i = 0; i < 4; i++)
    #pragma unroll
    for (int j = 0; j < 4; j++) acc[i][j] = (f4v)0.f;

  const int rc = (kg ^ ((r16 >> 1) & 3)) * 8;

  auto compute = [&](int buf) {
    const short* base = smem + buf * TILE;
    s8v va[2][4], vb[2][4];
    #pragma unroll
    for (int c = 0; c < AS; c++)
      #pragma unroll
      for (int i = 0; i < 4; i++)
        va[c][i] = *(const s8v*)&base[c * 4096 + (wr + i * 16 + r16) * 32 + rc];
    #pragma unroll
    for (int c = 0; c < BS; c++)
      #pragma unroll
      for (int i = 0; i < 4; i++)
        vb[c][i] = *(const s8v*)&base[(AS + c) * 4096 + (wc + i * 16 + r16) * 32 + rc];
    #pragma unroll
    for (int ca = 0; ca < AS; ca++)
      #pragma unroll
      for (int cb = 0; cb < BS; cb++) {
        if (ca == 1 && cb == 1) continue;   // drop lo*lo
        #pragma unroll
        for (int mi = 0; mi < 4; mi++)
          #pragma unroll
          for (int ni = 0; ni < 4; ni++)
            acc[mi][ni] = __builtin_amdgcn_mfma_f32_16x16x32_bf16(
                va[ca][mi], vb[cb][ni], acc[mi][ni], 0, 0, 0);
      }
  };

  const int nt = K >> 5;
  if constexpr (DB) {
    constexpr int NLD = (AS + BS) * 2;        // vmcnt events per stage
    stage(0, 0);
    int buf = 0;
    for (int t = 0; t < nt; t++) {
      if (t + 1 < nt) {
        stage((t + 1) * 32, buf ^ 1);
        if constexpr (NLD == 8)      asm volatile("s_waitcnt vmcnt(8)" ::: "memory");
        else if constexpr (NLD == 6) asm volatile("s_waitcnt vmcnt(6)" ::: "memory");
        else                         asm volatile("s_waitcnt vmcnt(4)" ::: "memory");
      } else {
        asm volatile("s_waitcnt vmcnt(0)" ::: "memory");
      }
      __builtin_amdgcn_sched_barrier(0);
      __builtin_amdgcn_s_barrier();
      compute(buf);
      __builtin_amdgcn_s_barrier();
      buf ^= 1;
    }
  } else {
    for (int t = 0; t < nt; t++) {
      stage(t * 32, 0);
      __syncthreads();
      compute(0);
      __syncthreads();
    }
  }

  short* C0s = (short*)g.C0[seg];  float* C0f = (float*)g.C0[seg];
  short* C1s = (short*)g.C1[seg];  float* C1f = (float*)g.C1[seg];
  const float* biasp = g.bias[seg];
  const int NnL = g.Nn;

  if constexpr (LDSOUT) {
    bool tr = false;
    if constexpr (EPI == EPI_PROJ4) tr = (seg & 1);
    if constexpr (EPI == EPI_PROJ3) tr = (seg == 2);
    if (tr) {
      // transposed write (s4v along n, 8B-coalesced)
      #pragma unroll
      for (int mi = 0; mi < 4; mi++) {
        #pragma unroll
        for (int ni = 0; ni < 4; ni++) {
          const int colL = tnl + wc + ni * 16 + r16;
          const int grow0 = tm + wr + mi * 16 + kg * 4;
          const float bv = biasp[colL];
          s4v o;
          #pragma unroll
          for (int r = 0; r < 4; r++) o[r] = (short)f2b(acc[mi][ni][r] + bv);
          const int b = grow0 >> 10, n = grow0 & 1023;
          *(s4v*)&C0s[((size_t)b * 512 + colL) * 1024 + n] = o;
        }
      }
    } else {
      short* D0 = nullptr; short* D1 = nullptr;
      if constexpr (EPI == EPI_PROJ4 || EPI == EPI_PROJ3) {
        D0 = C0s; D1 = C1s;
      } else if constexpr (EPI == EPI_SPLIT_BIAS) {
        D0 = C0s + (size_t)z * g.sC; D1 = C1s + (size_t)z * g.sC;
      } else if constexpr (EPI == EPI_B16_SCALE || EPI == EPI_BOTH_LEAKY) {
        D0 = C0s + (size_t)z * g.sC;
      } else if constexpr (EPI == EPI_ACC2_SPLIT) {
        D0 = (short*)g.C1[seg] + (size_t)z * g.sC;
        D1 = (short*)g.C1[2 + seg] + (size_t)z * g.sC;
      } else { // EPI_ACC_SPLIT
        D0 = (short*)g.C1[0] + (size_t)z * g.sC;
        D1 = (short*)g.C1[1] + (size_t)z * g.sC;
      }
      auto elem = [&](int mi, int ni, int r, float bv) -> float {
        const int grow = tm + wr + mi * 16 + kg * 4 + r;
        const int colL = tnl + wc + ni * 16 + r16;
        const float v = acc[mi][ni][r];
        float t;
        if constexpr (EPI == EPI_B16_SCALE)
          t = v * g.alpha;
        else if constexpr (EPI == EPI_ACC2_SPLIT || EPI == EPI_ACC_SPLIT)
          t = (C0f[(size_t)z * g.sC + (size_t)grow * NnL + colL] + v) * g.alpha;
        else if constexpr (EPI == EPI_BOTH_LEAKY) {
          t = v + bv; t = (t >= 0.f) ? t : 0.01f * t;
          C1f[(size_t)z * g.sC + (size_t)grow * NnL + colL] = t;
        } else
          t = v + bv;
        return t;
      };
      if constexpr (FITS) {
        // ---- full-tile epilogue: ONE barrier ----
        #pragma unroll
        for (int mi = 0; mi < 4; mi++) {
          #pragma unroll
          for (int ni = 0; ni < 4; ni++) {
            const int lcol = wc + ni * 16 + r16;
            float bv = 0.f;
            if constexpr (EPI == EPI_PROJ4 || EPI == EPI_PROJ3 ||
                          EPI == EPI_SPLIT_BIAS || EPI == EPI_BOTH_LEAKY)
              bv = biasp[tnl + lcol];
            #pragma unroll
            for (int r = 0; r < 4; r++) {
              const float t = elem(mi, ni, r, bv);
              const int lrow = wr + mi * 16 + kg * 4 + r;     // 0..127
              const int sw = ((lrow >> 2) & 3) << 4;          // bank swizzle
              const int li = lrow * 128 + (lcol ^ sw);
              const short h = (short)f2b(t);
              smem[li] = h;
              if constexpr (CC == 2) smem[16384 + li] = (short)f2b(t - b2f(h));
            }
          }
        }
        __syncthreads();
        #pragma unroll
        for (int c2 = 0; c2 < CC; c2++) {
          short* D = c2 ? D1 : D0;
          #pragma unroll
          for (int it = 0; it < 8; it++) {
            const int e = (tid + it * 256) * 8;
            const int lrow2 = e >> 7, col = e & 127;
            const int sw2 = ((lrow2 >> 2) & 3) << 4;
            *(s8v*)&D[(size_t)(tm + lrow2) * NnL + tnl + col] =
                *(const s8v*)&smem[c2 * 16384 + (lrow2 << 7) + (col ^ sw2)];
          }
        }
      } else {
        // ---- per-mi strip epilogue (small-LDS CC=2 cases) ----
        for (int mi = 0; mi < 4; mi++) {
          #pragma unroll
          for (int ni = 0; ni < 4; ni++) {
            const int lcol = wc + ni * 16 + r16;
            float bv = 0.f;
            if constexpr (EPI == EPI_PROJ4 || EPI == EPI_PROJ3 ||
                          EPI == EPI_SPLIT_BIAS || EPI == EPI_BOTH_LEAKY)
              bv = biasp[tnl + lcol];
            #pragma unroll
            for (int r = 0; r < 4; r++) {
              const float t = elem(mi, ni, r, bv);
              const int lrow = (w >> 1) * 16 + kg * 4 + r;
              const int sw = ((lrow >> 2) & 3) << 4;
              const int li = lrow * 128 + (lcol ^ sw);
              const short h = (short)f2b(t);
              smem[li] = h;
              if constexpr (CC == 2) smem[4096 + li] = (short)f2b(t - b2f(h));
            }
          }
          __syncthreads();
          #pragma unroll
          for (int c2 = 0; c2 < CC; c2++) {
            short* D = c2 ? D1 : D0;
            #pragma unroll
            for (int half = 0; half < 2; half++) {
              const int e = (tid + half * 256) * 8;
              const int lrow2 = e >> 7, col = e & 127;
              const int sw2 = ((lrow2 >> 2) & 3) << 4;
              const int grow = tm + (lrow2 >> 4) * 64 + mi * 16 + (lrow2 & 15);
              *(s8v*)&D[(size_t)grow * NnL + tnl + col] =
                  *(const s8v*)&smem[c2 * 4096 + (lrow2 << 7) + (col ^ sw2)];
            }
          }
          __syncthreads();
        }
      }
    }
  } else {
    // direct f32 epilogues (coalesced 64B/group)
    #pragma unroll
    for (int mi = 0; mi < 4; mi++) {
      #pragma unroll
      for (int ni = 0; ni < 4; ni++) {
        const int colL = tnl + wc + ni * 16 + r16;
        const int grow0 = tm + wr + mi * 16 + kg * 4;
        float bv = 0.f;
        if constexpr (EPI == EPI_F32_BIAS_R || EPI == EPI_LEAKY_R)
          bv = biasp[colL];
        #pragma unroll
        for (int r = 0; r < 4; r++) {
          const size_t lidx = (size_t)(grow0 + r) * NnL + colL;
          const size_t idx = (size_t)z * g.sC + lidx;
          const float v = acc[mi][ni][r];
          if constexpr (EPI == EPI_ACC2) {
            C0f[(size_t)z * g.sC + (size_t)(grow0 + r) * 512 + colL] += v;
          } else if constexpr (EPI == EPI_ACC2_ST) {
            C0f[(size_t)z * g.sC + (size_t)(grow0 + r) * 512 + colL] = v;
          } else if constexpr (EPI == EPI_F32_ACC) {
            C0f[idx] += v;
          } else if constexpr (EPI == EPI_F32_ST) {
            C0f[idx] = v;
          } else if constexpr (EPI == EPI_F32_BIAS_R) {
            const float* Rf = (const float*)(z == 0 ? g.Rv : g.Rv2);
            C0f[idx] = v + bv + Rf[lidx];
          } else { // EPI_LEAKY_R
            float t = v + bv; t = (t >= 0.f) ? t : 0.01f * t;
            C0f[idx] = t + ((const float*)g.Rv)[idx];
          }
        }
      }
    }
  }
}

// ---- merged weight conversion: z-indexed table of DxD transposes ----
struct WcvtArgs {
  const float* src[32];
  short* hi[32];
  short* lo[32];      // nullptr -> single bf16
  int n;
};
__global__ __launch_bounds__(256) void wt_cvt_all(WcvtArgs a) {
  __shared__ float t[32][33];
  const int zi = blockIdx.z;
  const int bx = blockIdx.x * 32, by = blockIdx.y * 32;
  const int tx = threadIdx.x, ty = threadIdx.y;
  const float* src = a.src[zi];
  #pragma unroll
  for (int k = 0; k < 4; k++)
    t[ty + 8 * k][tx] = src[(size_t)(by + ty + 8 * k) * D_ + bx + tx];
  __syncthreads();
  short* hi = a.hi[zi];
  short* lo = a.lo[zi];
  if (lo) {
    #pragma unroll
    for (int k = 0; k < 4; k++) {
      const size_t o = (size_t)(bx + ty + 8 * k) * D_ + by + tx;
      float v = t[tx][ty + 8 * k];
      short h = (short)f2b(v);
      hi[o] = h;
      lo[o] = (short)f2b(v - b2f(h));
    }
  } else {
    #pragma unroll
    for (int k = 0; k < 4; k++)
      hi[(size_t)(bx + ty + 8 * k) * D_ + by + tx] =
          (short)f2b(t[tx][ty + 8 * k]);
  }
}

// f32 * scale -> hi bf16 + lo bf16
__global__ __launch_bounds__(256) void split_f32(const float* __restrict__ src,
                                                 short* __restrict__ hi,
                                                 short* __restrict__ lo, float scale) {
  const size_t i = ((size_t)blockIdx.x * 256 + threadIdx.x) * 4;
  f4v v = *(const f4v*)(src + i);
  s4v h, l;
  #pragma unroll
  for (int j = 0; j < 4; j++) {
    float t = v[j] * scale;
    h[j] = (short)f2b(t);
    l[j] = (short)f2b(t - b2f(h[j]));
  }
  *(s4v*)(hi + i) = h;
  *(s4v*)(lo + i) = l;
}

// sum = a + b (f32) elementwise; write bf16 + f32 (outf may alias a)
__global__ __launch_bounds__(256) void add_both(const float* __restrict__ a,
                                                const float* __restrict__ b,
                                                short* __restrict__ outb,
                                                float* outf) {
  const size_t i = ((size_t)blockIdx.x * 256 + threadIdx.x) * 4;
  f4v av = *(const f4v*)(a + i);
  f4v bv = *(const f4v*)(b + i);
  f4v s; s4v o;
  #pragma unroll
  for (int j = 0; j < 4; j++) { s[j] = av[j] + bv[j]; o[j] = (short)f2b(s[j]); }
  *(f4v*)(outf + i) = s;
  *(s4v*)(outb + i) = o;
}

// in-place softmax over bf16 rows of 1024; one wave per row, shuffle reduce
__global__ __launch_bounds__(256) void softmax_rows_b16(short* __restrict__ p) {
  const int row = blockIdx.x * 4 + (threadIdx.x >> 6);
  const int lane = threadIdx.x & 63;
  short* rp = p + (size_t)row * 1024 + lane * 16;
  s8v v0 = *(s8v*)rp, v1 = *(s8v*)(rp + 8);
  float f[16];
  #pragma unroll
  for (int j = 0; j < 8; j++) { f[j] = b2f(v0[j]); f[8 + j] = b2f(v1[j]); }
  float m = f[0];
  #pragma unroll
  for (int j = 1; j < 16; j++) m = fmaxf(m, f[j]);
  #pragma unroll
  for (int s = 32; s; s >>= 1) m = fmaxf(m, __shfl_xor(m, s, 64));
  float sum = 0.f;
  #pragma unroll
  for (int j = 0; j < 16; j++) { f[j] = __expf(f[j] - m); sum += f[j]; }
  #pragma unroll
  for (int s = 32; s; s >>= 1) sum += __shfl_xor(sum, s, 64);
  const float inv = 1.f / sum;
  #pragma unroll
  for (int j = 0; j < 8; j++) {
    v0[j] = (short)f2b(f[j] * inv);
    v1[j] = (short)f2b(f[8 + j] * inv);
  }
  *(s8v*)rp = v0; *(s8v*)(rp + 8) = v1;
}

// L2-normalize over axis=1 (N) of (NB,N,D) f32; deterministic 3-phase.
#define NCHUNK 16
__global__ __launch_bounds__(256) void norm_part(const float* __restrict__ t,
                                                 float* __restrict__ part, int NB) {
  const int d = blockIdx.x * 256 + threadIdx.x;
  const int b = blockIdx.y;
  const int c = blockIdx.z;
  const int n0 = c * (N_ / NCHUNK);
  const float* p = t + ((size_t)b * N_ + n0) * D_ + d;
  float ss = 0.f;
  for (int n = 0; n < N_ / NCHUNK; n++) { float v = p[(size_t)n * D_]; ss += v * v; }
  part[((size_t)c * NB + b) * D_ + d] = ss;
}
__global__ __launch_bounds__(256) void norm_inv(const float* __restrict__ part,
                                                float* __restrict__ inv, int NB) {
  const int i = blockIdx.x * 256 + threadIdx.x;   // b*D + d
  float ss = 0.f;
  for (int c = 0; c < NCHUNK; c++) ss += part[(size_t)c * (NB * D_) + i];
  inv[i] = 1.f / fmaxf(sqrtf(ss), 1e-12f);
}
__global__ __launch_bounds__(256) void norm_scale(const float* __restrict__ t,
                                                  const float* __restrict__ inv,
                                                  short* __restrict__ outh,
                                                  short* __restrict__ outl,
                                                  float* __restrict__ outf) {
  const size_t i = ((size_t)blockIdx.x * 256 + threadIdx.x) * 4;
  const int b = (int)(i >> 19);        // N_*D_ = 2^19
  const int d = (int)(i & (D_ - 1));
  f4v v = *(const f4v*)(t + i);
  f4v w = *(const f4v*)(inv + (size_t)b * D_ + d);
  f4v o; s4v oh, ol;
  #pragma unroll
  for (int j = 0; j < 4; j++) {
    o[j] = v[j] * w[j];
    oh[j] = (short)f2b(o[j]);
    ol[j] = (short)f2b(o[j] - b2f(oh[j]));
  }
  *(f4v*)(outf + i) = o;
  *(s4v*)(outh + i) = oh;
  *(s4v*)(outl + i) = ol;
}

extern "C" void kernel_launch(void* const* d_in, const int* in_sizes, int n_in,
                              void* d_out, int out_size, void* d_ws, size_t ws_size,
                              hipStream_t stream) {
  (void)in_sizes; (void)n_in; (void)out_size; (void)ws_size;
  const float* in1f = (const float*)d_in[0];
  const float* in2f = (const float*)d_in[1];

  const size_t SB = (size_t)B_ * N_ * D_ * 2;      // 8 MB
  const size_t SF = (size_t)B_ * N_ * D_ * 4;      // 16 MB
  const size_t WL = (size_t)L_ * D_ * D_ * 2;
  const size_t W1 = (size_t)D_ * D_ * 2;
  const size_t WD = (size_t)D_ * D_;               // elems per DxD slice
  const long SBel = (long)B_ * N_ * D_;            // 4194304 elems
  const long sAct = (long)N_ * D_;
  const long sAff = (long)N_ * N_;

  char* ws = (char*)d_ws;
  size_t off = 0;
  auto alloc = [&](size_t bytes) -> char* {
    char* p = ws + off;
    off += (bytes + 255) & ~(size_t)255;
    return p;
  };

  // ---- weight region (19 MB); a1/a2 overlay after stage 1 ----
  char* wreg = alloc(8 * WL + 6 * W1);
  short* c_thT_h = (short*)(wreg);
  short* c_thT_l = (short*)(wreg + WL);
  short* c_phT_h = (short*)(wreg + 2 * WL);
  short* c_phT_l = (short*)(wreg + 3 * WL);
  short* c_rhT_h = (short*)(wreg + 4 * WL);
  short* c_rhT_l = (short*)(wreg + 5 * WL);
  short* c_psT_h = (short*)(wreg + 6 * WL);
  short* c_psT_l = (short*)(wreg + 7 * WL);
  short* c_intT_h = (short*)(wreg + 8 * WL);
  short* c_intT_l = (short*)(wreg + 8 * WL + W1);
  short* c_f1T_h  = (short*)(wreg + 8 * WL + 2 * W1);
  short* c_f1T_l  = (short*)(wreg + 8 * WL + 3 * W1);
  short* c_f2T_h  = (short*)(wreg + 8 * WL + 4 * W1);
  short* c_f2T_l  = (short*)(wreg + 8 * WL + 5 * W1);
  short* a1_thT = (short*)(wreg);
  short* a1_phT = (short*)(wreg + WL);
  short* a1_rhT = (short*)(wreg + 2 * WL);
  short* a2_thT = (short*)(wreg + 3 * WL);
  short* a2_phT = (short*)(wreg + 4 * WL);
  short* a2_rhT = (short*)(wreg + 5 * WL);
  char*  aw = wreg + 6 * WL;
  short* a1_intT_h = (short*)(aw);
  short* a1_intT_l = (short*)(aw + W1);
  short* a1_f1T_h  = (short*)(aw + 2 * W1);
  short* a1_f1T_l  = (short*)(aw + 3 * W1);
  short* a1_f2T_h  = (short*)(aw + 4 * W1);
  short* a1_f2T_l  = (short*)(aw + 5 * W1);
  short* a2_intT_h = (short*)(aw + 6 * W1);
  short* a2_intT_l = (short*)(aw + 7 * W1);
  short* a2_f1T_h  = (short*)(aw + 8 * W1);
  short* a2_f1T_l  = (short*)(aw + 9 * W1);
  short* a2_f2T_h  = (short*)(aw + 10 * W1);
  short* a2_f2T_l  = (short*)(aw + 11 * W1);

  // ---- pair-contiguous activation regions (2*SB each = 16 MB) ----
  short* in12h = (short*)alloc(2 * SB);   // in1h|in2h -> feed12b -> sumb
  short* in12l = (short*)alloc(2 * SB);   // in1l|in2l -> resh
  short* bufA  = (short*)alloc(2 * SB);   // thh|thl -> inth -> hidh
  short* bufB  = (short*)alloc(2 * SB);   // phh|phl -> intl -> hidl
  short* bufC  = (short*)alloc(2 * SB);   // rhT|psT -> resl
  char*  affU  = alloc((size_t)32 * 1024 * 1024);
  float* accR  = (float*)alloc(2 * SF);   // acc1|acc2 / acc16 / tmpf
  float* feedfR = (float*)alloc(2 * SF);  // feed12f -> self12f -> sumf
  float* npart = (float*)alloc((size_t)NCHUNK * 16 * D_ * 4);
  float* ninv  = (float*)alloc((size_t)16 * D_ * 4);
  // total ≈ 196 MB (< proven 217)

  short* in1h = in12h;        short* in2h = in12h + SBel;
  short* in1l = in12l;        short* in2l = in12l + SBel;
  short* thh = bufA;          short* thl = bufA + SBel;
  short* phh = bufB;          short* phl = bufB + SBel;
  short* rhT = bufC;          short* psT = bufC + SBel;
  short* affh = (short*)affU;                   // [0,16 MB)
  short* aff16 = (short*)affU;                  // 32 MB bf16 batch-16 logits
  float* resfP = (float*)affU;                  // 32 MB f32 res (affs dead)
  float* acc1 = accR;         float* acc2 = accR + SBel;

  const float scl = 0.04419417382415922f;   // 512^-0.5
  dim3 tb(32, 8);
  const int GE = (B_ * N_ * D_) / (4 * 256);     // 4096
  #define F32P(i) ((const float*)d_in[i])

  auto GA = [&]() { GArgs a; __builtin_memset(&a, 0, sizeof(a)); return a; };
  auto normalize = [&](const float* src, int NB, short* outh, short* outl, float* outf) {
    norm_part<<<dim3(D_/256, NB, NCHUNK), 256, 0, stream>>>(src, npart, NB);
    norm_inv<<<(NB * D_) / 256, 256, 0, stream>>>(npart, ninv, NB);
    norm_scale<<<NB * 512, 256, 0, stream>>>(src, ninv, outh, outl, outf);
  };

  // ---- stage-1 weights: ONE merged dispatch (19 split slices) ----
  {
    WcvtArgs wa; __builtin_memset(&wa, 0, sizeof(wa));
    int n = 0;
    auto addL = [&](const float* s, short* h, short* l, int nl) {
      for (int i = 0; i < nl; i++) {
        wa.src[n] = s + i * WD; wa.hi[n] = h + i * WD; wa.lo[n] = l + i * WD; n++;
      }
    };
    addL(F32P(2),  c_thT_h, c_thT_l, L_);
    addL(F32P(4),  c_phT_h, c_phT_l, L_);
    addL(F32P(6),  c_rhT_h, c_rhT_l, L_);
    addL(F32P(8),  c_psT_h, c_psT_l, L_);
    addL(F32P(10), c_intT_h, c_intT_l, 1);
    addL(F32P(12), c_f1T_h, c_f1T_l, 1);
    addL(F32P(14), c_f2T_h, c_f2T_l, 1);
    wa.n = n;
    wt_cvt_all<<<dim3(16, 16, n), tb, 0, stream>>>(wa);
  }
  split_f32<<<GE, 256, 0, stream>>>(in1f, in1h, in1l, 1.0f);
  split_f32<<<GE, 256, 0, stream>>>(in2f, in2h, in2l, 1.0f);

  // ---- stage 1: 4-seg proj -> bf16 P -> (1,1) applies ----
  for (int i = 0; i < L_; i++) {
    const size_t wo = (size_t)i * D_ * D_;
    const size_t bo = (size_t)i * D_;
    { GArgs a = GA();
      a.Ah[0] = in1h; a.Ah[1] = in1h; a.Ah[2] = in2h; a.Ah[3] = in2h;
      a.Al[0] = in1l; a.Al[1] = in1l; a.Al[2] = in2l; a.Al[3] = in2l;
      a.Bh[0] = c_thT_h + wo; a.Bh[1] = c_rhT_h + wo;
      a.Bh[2] = c_phT_h + wo; a.Bh[3] = c_psT_h + wo;
      a.Bl[0] = c_thT_l + wo; a.Bl[1] = c_rhT_l + wo;
      a.Bl[2] = c_phT_l + wo; a.Bl[3] = c_psT_l + wo;
      a.C0[0] = thh; a.C0[1] = rhT; a.C0[2] = phh; a.C0[3] = psT;
      a.C1[0] = thl; a.C1[2] = phl;
      a.bias[0] = F32P(3) + bo; a.bias[1] = F32P(7) + bo;
      a.bias[2] = F32P(5) + bo; a.bias[3] = F32P(9) + bo;
      a.Nn = 512; a.K = 512;
      gemm_k<2,2,EPI_PROJ4,1><<<dim3(64,16,1),256,0,stream>>>(a); }
    { GArgs a = GA();
      a.Ah[0] = thh; a.Al[0] = thl; a.sA = sAct;
      a.Bh[0] = phh; a.Bl[0] = phl; a.sB = sAct;
      a.C0[0] = affh; a.sC = sAff;
      a.alpha = scl; a.Nn = 1024; a.K = 512;
      gemm_k<2,2,EPI_B16_SCALE,1><<<dim3(8,8,B_),256,0,stream>>>(a); }
    { GArgs a = GA();
      a.Ah[0] = affh; a.Ah[1] = affh; a.sA = sAff;
      a.Bh[0] = rhT; a.Bh[1] = psT; a.sB = sAct;
      a.C0[0] = acc1; a.C0[1] = acc2; a.sC = sAct;
      a.Nn = 512; a.K = 1024;
      if (i == 0) {
        gemm_k<1,1,EPI_ACC2_ST,1><<<dim3(8,8,B_),256,0,stream>>>(a);
      } else if (i < L_ - 1) {
        gemm_k<1,1,EPI_ACC2,1><<<dim3(8,8,B_),256,0,stream>>>(a);
      } else {
        a.C1[0] = bufA; a.C1[1] = bufA + SBel;   // inth (stream1|stream2)
        a.C1[2] = bufB; a.C1[3] = bufB + SBel;   // intl
        a.alpha = 0.25f;
        gemm_k<1,1,EPI_ACC2_SPLIT,1><<<dim3(8,8,B_),256,0,stream>>>(a);
      } }
  }

  // ---- stage-1 epilogue, both streams batched (z=2 / M=16384) ----
  { GArgs a = GA();
    a.Ah[0] = bufA; a.Al[0] = bufB; a.sA = SBel;
    a.Bh[0] = c_intT_h; a.Bl[0] = c_intT_l;
    a.C0[0] = accR; a.sC = SBel;
    a.bias[0] = F32P(11); a.Rv = in1f; a.Rv2 = in2f;
    a.Nn = 512; a.K = 512;
    gemm_k<2,2,EPI_F32_BIAS_R,1><<<dim3(64,4,2),256,0,stream>>>(a); }
  normalize(accR, 16, in12l, bufA, resfP);       // resh|resl (resf scratch)
  { GArgs a = GA();
    a.Ah[0] = in12l; a.Al[0] = bufA;
    a.Bh[0] = c_f1T_h; a.Bl[0] = c_f1T_l;
    a.C0[0] = bufB; a.C1[0] = bufC;              // hidh|hidl
    a.bias[0] = F32P(13); a.Nn = 512; a.K = 512;
    gemm_k<2,2,EPI_SPLIT_BIAS,1><<<dim3(128,4,1),256,0,stream>>>(a); }
  { GArgs a = GA();
    a.Ah[0] = bufB; a.Al[0] = bufC;
    a.Bh[0] = c_f2T_h; a.Bl[0] = c_f2T_l;
    a.C0[0] = in12h; a.C1[0] = feedfR;           // feed12b | feed12f
    a.bias[0] = F32P(15); a.Nn = 512; a.K = 512;
    gemm_k<2,2,EPI_BOTH_LEAKY,1><<<dim3(128,4,1),256,0,stream>>>(a); }

  // ---- a1/a2 weights: ONE merged dispatch (24 single + 6 split slices) ----
  {
    WcvtArgs wa; __builtin_memset(&wa, 0, sizeof(wa));
    int n = 0;
    auto addS = [&](const float* s, short* h, int nl) {
      for (int i = 0; i < nl; i++) {
        wa.src[n] = s + i * WD; wa.hi[n] = h + i * WD; wa.lo[n] = nullptr; n++;
      }
    };
    auto add2 = [&](const float* s, short* h, short* l) {
      wa.src[n] = s; wa.hi[n] = h; wa.lo[n] = l; n++;
    };
    addS(F32P(16), a1_thT, L_);
    addS(F32P(18), a1_phT, L_);
    addS(F32P(20), a1_rhT, L_);
    addS(F32P(28), a2_thT, L_);
    addS(F32P(30), a2_phT, L_);
    addS(F32P(32), a2_rhT, L_);
    add2(F32P(22), a1_intT_h, a1_intT_l);
    add2(F32P(24), a1_f1T_h, a1_f1T_l);
    add2(F32P(26), a1_f2T_h, a1_f2T_l);
    add2(F32P(34), a2_intT_h, a2_intT_l);
    add2(F32P(36), a2_f1T_h, a2_f1T_l);
    add2(F32P(38), a2_f2T_h, a2_f2T_l);
    wa.n = n;                                    // 30 slices
    wt_cvt_all<<<dim3(16, 16, n), tb, 0, stream>>>(wa);
  }

  // ---- generic agi chain ----
  auto agi = [&](int NZ, const short* xb, const float* xf,
                 const short* thT, const float* thB,
                 const short* phT, const float* phB,
                 const short* rhT_, const float* rhB,
                 const short* inTh, const short* inTl, const float* inB,
                 const short* f1Th, const short* f1Tl, const float* f1B,
                 const short* f2Th, const short* f2Tl, const float* f2B,
                 float* outf) {
    const int MB = NZ / B_;                  // 2 or 1 (stream multiplier)
    for (int i = 0; i < L_; i++) {
      const size_t wo = (size_t)i * D_ * D_;
      const size_t bo = (size_t)i * D_;
      { GArgs a = GA();
        a.Ah[0] = xb; a.Ah[1] = xb; a.Ah[2] = xb;
        a.Bh[0] = thT + wo; a.Bh[1] = phT + wo; a.Bh[2] = rhT_ + wo;
        a.C0[0] = bufA; a.C0[1] = bufB; a.C0[2] = bufC;
        a.bias[0] = thB + bo; a.bias[1] = phB + bo; a.bias[2] = rhB + bo;
        a.Nn = 512; a.K = 512;
        gemm_k<1,1,EPI_PROJ3,1><<<dim3(64*MB,12,1),256,0,stream>>>(a); }
      { GArgs a = GA();
        a.Ah[0] = bufA; a.sA = sAct; a.Bh[0] = bufB; a.sB = sAct;
        a.C0[0] = aff16; a.sC = sAff; a.alpha = scl; a.Nn = 1024; a.K = 512;
        gemm_k<1,1,EPI_B16_SCALE,1><<<dim3(8,8,NZ),256,0,stream>>>(a); }
      softmax_rows_b16<<<NZ * 256, 256, 0, stream>>>(aff16);
      { GArgs a = GA();
        a.Ah[0] = aff16; a.sA = sAff; a.Bh[0] = bufC; a.sB = sAct;
        a.C0[0] = accR; a.sC = sAct; a.Nn = 512; a.K = 1024;
        if (i == 0) {
          gemm_k<1,1,EPI_F32_ST,1><<<dim3(8,4,NZ),256,0,stream>>>(a);
        } else if (i < L_ - 1) {
          gemm_k<1,1,EPI_F32_ACC,1><<<dim3(8,4,NZ),256,0,stream>>>(a);
        } else {
          a.C1[0] = bufA; a.C1[1] = bufB; a.alpha = 0.25f;
          gemm_k<1,1,EPI_ACC_SPLIT,1><<<dim3(8,4,NZ),256,0,stream>>>(a);
        } }
    }
    { GArgs a = GA();
      a.Ah[0] = bufA; a.Al[0] = bufB;
      a.Bh[0] = inTh; a.Bl[0] = inTl;
      a.C0[0] = accR; a.bias[0] = inB; a.Rv = xf; a.Rv2 = xf;
      a.Nn = 512; a.K = 512;
      gemm_k<2,2,EPI_F32_BIAS_R,1><<<dim3(64*MB,4,1),256,0,stream>>>(a); }
    normalize(accR, NZ, in12l, bufC, resfP);     // resh|resl, resf -> affU
    { GArgs a = GA();
      a.Ah[0] = in12l; a.Al[0] = bufC;
      a.Bh[0] = f1Th; a.Bl[0] = f1Tl;
      a.C0[0] = bufA; a.C1[0] = bufB;            // hidh|hidl
      a.bias[0] = f1B; a.Nn = 512; a.K = 512;
      gemm_k<2,2,EPI_SPLIT_BIAS,1><<<dim3(64*MB,4,1),256,0,stream>>>(a); }
    { GArgs a = GA();
      a.Ah[0] = bufA; a.Al[0] = bufB;
      a.Bh[0] = f2Th; a.Bl[0] = f2Tl;
      a.C0[0] = accR; a.bias[0] = f2B; a.Rv = resfP;
      a.Nn = 512; a.K = 512;
      gemm_k<2,2,EPI_LEAKY_R,1><<<dim3(64*MB,4,1),256,0,stream>>>(a); }
    normalize(accR, NZ, bufA, bufB, outf);       // bf16 outs are scratch
  };

  // agi1 on feed1+feed2 as one batch-16 chain (shared AGI_1 weights)
  agi(16, in12h, feedfR,
      a1_thT, F32P(17), a1_phT, F32P(19), a1_rhT, F32P(21),
      a1_intT_h, a1_intT_l, F32P(23), a1_f1T_h, a1_f1T_l, F32P(25),
      a1_f2T_h, a1_f2T_l, F32P(27), feedfR);     // self12f -> feedfR

  add_both<<<GE, 256, 0, stream>>>(feedfR, feedfR + SBel, in12h, feedfR);

  agi(8, in12h, feedfR,
      a2_thT, F32P(29), a2_phT, F32P(31), a2_rhT, F32P(33),
      a2_intT_h, a2_intT_l, F32P(35), a2_f1T_h, a2_f1T_l, F32P(37),
      a2_f2T_h, a2_f2T_l, F32P(39), (float*)d_out);
}

// Round 15
// 1662.333 us; speedup vs baseline: 1.6671x; 1.0229x over previous
//
#include <hip/hip_runtime.h>

// ACGI_32195074850822 — round 14: stage-1 proj weights single-bf16.
//  PROJ4 (2,2)->(2,1): drops the W_lo MFMA pass (-33% on the biggest GEMM
//  class) + 1 fewer staged tensor. Error calibrated off the P-trim (+1.46e-3
//  measured for the same-path 0.4% perturbation): expect absmax ~5.2-6.2e-3
//  vs threshold 8.75e-3. Everything else identical to round 13 (1700us).

#define B_ 8
#define N_ 1024
#define D_ 512
#define L_ 4

typedef short s8v __attribute__((ext_vector_type(8)));
typedef short s4v __attribute__((ext_vector_type(4)));
typedef float f4v __attribute__((ext_vector_type(4)));

__device__ __forceinline__ unsigned short f2b(float f) {
  unsigned u = __builtin_bit_cast(unsigned, f);
  u += 0x7FFFu + ((u >> 16) & 1u);          // round-to-nearest-even
  return (unsigned short)(u >> 16);
}
__device__ __forceinline__ float b2f(short s) {
  unsigned u = ((unsigned)(unsigned short)s) << 16;
  return __builtin_bit_cast(float, u);
}

__device__ __forceinline__ void glds16(const short* g, short* l) {
  __builtin_amdgcn_global_load_lds(
      (const __attribute__((address_space(1))) void*)g,
      (__attribute__((address_space(3))) void*)l, 16, 0, 0);
}

enum {
  EPI_PROJ4 = 0,   // seg even: split(acc+bias)->C0/C1; seg odd: TR(acc+bias)->C0
  EPI_PROJ3,       // seg 0,1: bf16(acc+bias)->C0; seg 2: TR->C0
  EPI_B16_SCALE,   // C0 bf16 = acc*alpha
  EPI_ACC2,        // seg s: C0[s] f32 += acc   (z-batched)
  EPI_ACC2_ST,     // seg s: C0[s] f32 = acc    (layer 0)
  EPI_F32_ACC,     // C0[0] f32 += acc          (z-batched)
  EPI_F32_ST,      // C0[0] f32 = acc           (layer 0)
  EPI_F32_BIAS_R,  // C0 f32 = acc+bias+R; R base by z (Rv / Rv2), local idx
  EPI_SPLIT_BIAS,  // C0 hi, C1 lo of acc+bias
  EPI_BOTH_LEAKY,  // C0 bf16 AND C1 f32 = leaky(acc+bias)
  EPI_LEAKY_R,     // C0 f32 = leaky(acc+bias) + R (flat)
  EPI_ACC2_SPLIT,  // seg s: t=(C0[s]+acc)*alpha; hi->C1[s], lo->C1[2+s]
  EPI_ACC_SPLIT    // t=(C0[0]+acc)*alpha; hi->C1[0], lo->C1[1] (z-batched)
};

struct GArgs {
  const short* Ah[4]; const short* Al[4];
  const short* Bh[4]; const short* Bl[4];
  long sA, sB;
  void* C0[4]; void* C1[4];
  long sC;
  const float* bias[4];
  const void* Rv; const void* Rv2;
  float alpha;
  int Nn, K;
};

// C = (ΣA_c)(ΣB_c)^T, bf16 comps, f32 accum; <2,2> drops Al*Bl.
// 128x128 tile, 4 waves, global_load_lds(16B) + both-sides XOR swizzle.
// DB=1: double-buffered staging, counted vmcnt. Block mapping: XCD-chunked,
// y-fastest.
template<int AS, int BS, int EPI, int DB>
__global__ __launch_bounds__(256) void gemm_k(GArgs g) {
  constexpr int TILE = (AS + BS) * 4096;        // shorts per staging buffer
  __shared__ short smem[TILE * (DB ? 2 : 1)];
  constexpr bool SEG = (EPI == EPI_PROJ4 || EPI == EPI_PROJ3 ||
                        EPI == EPI_ACC2 || EPI == EPI_ACC2_ST ||
                        EPI == EPI_ACC2_SPLIT);
  constexpr bool LDSOUT = (EPI == EPI_PROJ4 || EPI == EPI_PROJ3 ||
                           EPI == EPI_B16_SCALE || EPI == EPI_SPLIT_BIAS ||
                           EPI == EPI_BOTH_LEAKY || EPI == EPI_ACC2_SPLIT ||
                           EPI == EPI_ACC_SPLIT);
  constexpr int CC = (EPI == EPI_PROJ4 || EPI == EPI_SPLIT_BIAS ||
                      EPI == EPI_ACC2_SPLIT || EPI == EPI_ACC_SPLIT) ? 2 : 1;
  constexpr bool FITS = (TILE * (DB ? 2 : 1)) >= CC * 16384;  // full-tile epi
  const int z = blockIdx.z;

  // ---- L2-locality swizzle (all grids have nwg % 8 == 0) ----
  const int GX = gridDim.x, GY = gridDim.y;
  const int nwg = GX * GY;
  const int orig = blockIdx.y * GX + blockIdx.x;
  const int wgid = (orig & 7) * (nwg >> 3) + (orig >> 3);
  const int bx = wgid / GY;
  const int by = wgid - bx * GY;
  const int tm = bx * 128;
  const int tn = by * 128;

  const int tid = threadIdx.x;
  const int lane = tid & 63;
  const int w = tid >> 6;
  const int wr = (w >> 1) * 64, wc = (w & 1) * 64;
  const int r16 = lane & 15, kg = lane >> 4;
  const int K = g.K;

  int seg = 0, tnl = tn;
  if constexpr (SEG) { seg = tn >> 9; tnl = tn & 511; }
  const short* Ah = g.Ah[seg];
  const short* Al = (AS == 2) ? g.Al[seg] : nullptr;
  const short* Bh = g.Bh[seg];
  const short* Bl = (BS == 2) ? g.Bl[seg] : nullptr;

  const int srow = lane >> 2;
  const int scol = ((lane & 3) ^ ((lane >> 3) & 3)) * 8;
  const short* gA[2]; const short* gB[2];
  gA[0] = Ah + (size_t)z * g.sA + (size_t)(tm + w * 16 + srow) * K + scol;
  if constexpr (AS == 2)
    gA[1] = Al + (size_t)z * g.sA + (size_t)(tm + w * 16 + srow) * K + scol;
  gB[0] = Bh + (size_t)z * g.sB + (size_t)(tnl + w * 16 + srow) * K + scol;
  if constexpr (BS == 2)
    gB[1] = Bl + (size_t)z * g.sB + (size_t)(tnl + w * 16 + srow) * K + scol;
  const size_t hoff = (size_t)64 * K;

  auto stage = [&](int k0, int buf) {
    short* base = smem + buf * TILE;
    #pragma unroll
    for (int c = 0; c < AS; c++) {
      glds16(gA[c] + k0, base + c * 4096 + (w * 16) * 32);
      glds16(gA[c] + hoff + k0, base + c * 4096 + (64 + w * 16) * 32);
    }
    #pragma unroll
    for (int c = 0; c < BS; c++) {
      glds16(gB[c] + k0, base + (AS + c) * 4096 + (w * 16) * 32);
      glds16(gB[c] + hoff + k0, base + (AS + c) * 4096 + (64 + w * 16) * 32);
    }
  };

  f4v acc[4][4];
  #pragma unroll
  for (int i = 0; i < 4; i++)
    #pragma unroll
    for (int j = 0; j < 4; j++) acc[i][j] = (f4v)0.f;

  const int rc = (kg ^ ((r16 >> 1) & 3)) * 8;

  auto compute = [&](int buf) {
    const short* base = smem + buf * TILE;
    s8v va[2][4], vb[2][4];
    #pragma unroll
    for (int c = 0; c < AS; c++)
      #pragma unroll
      for (int i = 0; i < 4; i++)
        va[c][i] = *(const s8v*)&base[c * 4096 + (wr + i * 16 + r16) * 32 + rc];
    #pragma unroll
    for (int c = 0; c < BS; c++)
      #pragma unroll
      for (int i = 0; i < 4; i++)
        vb[c][i] = *(const s8v*)&base[(AS + c) * 4096 + (wc + i * 16 + r16) * 32 + rc];
    #pragma unroll
    for (int ca = 0; ca < AS; ca++)
      #pragma unroll
      for (int cb = 0; cb < BS; cb++) {
        if (ca == 1 && cb == 1) continue;   // drop lo*lo
        #pragma unroll
        for (int mi = 0; mi < 4; mi++)
          #pragma unroll
          for (int ni = 0; ni < 4; ni++)
            acc[mi][ni] = __builtin_amdgcn_mfma_f32_16x16x32_bf16(
                va[ca][mi], vb[cb][ni], acc[mi][ni], 0, 0, 0);
      }
  };

  const int nt = K >> 5;
  if constexpr (DB) {
    constexpr int NLD = (AS + BS) * 2;        // vmcnt events per stage
    stage(0, 0);
    int buf = 0;
    for (int t = 0; t < nt; t++) {
      if (t + 1 < nt) {
        stage((t + 1) * 32, buf ^ 1);
        if constexpr (NLD == 8)      asm volatile("s_waitcnt vmcnt(8)" ::: "memory");
        else if constexpr (NLD == 6) asm volatile("s_waitcnt vmcnt(6)" ::: "memory");
        else                         asm volatile("s_waitcnt vmcnt(4)" ::: "memory");
      } else {
        asm volatile("s_waitcnt vmcnt(0)" ::: "memory");
      }
      __builtin_amdgcn_sched_barrier(0);
      __builtin_amdgcn_s_barrier();
      compute(buf);
      __builtin_amdgcn_s_barrier();
      buf ^= 1;
    }
  } else {
    for (int t = 0; t < nt; t++) {
      stage(t * 32, 0);
      __syncthreads();
      compute(0);
      __syncthreads();
    }
  }

  short* C0s = (short*)g.C0[seg];  float* C0f = (float*)g.C0[seg];
  short* C1s = (short*)g.C1[seg];  float* C1f = (float*)g.C1[seg];
  const float* biasp = g.bias[seg];
  const int NnL = g.Nn;

  if constexpr (LDSOUT) {
    bool tr = false;
    if constexpr (EPI == EPI_PROJ4) tr = (seg & 1);
    if constexpr (EPI == EPI_PROJ3) tr = (seg == 2);
    if (tr) {
      // transposed write (s4v along n, 8B-coalesced)
      #pragma unroll
      for (int mi = 0; mi < 4; mi++) {
        #pragma unroll
        for (int ni = 0; ni < 4; ni++) {
          const int colL = tnl + wc + ni * 16 + r16;
          const int grow0 = tm + wr + mi * 16 + kg * 4;
          const float bv = biasp[colL];
          s4v o;
          #pragma unroll
          for (int r = 0; r < 4; r++) o[r] = (short)f2b(acc[mi][ni][r] + bv);
          const int b = grow0 >> 10, n = grow0 & 1023;
          *(s4v*)&C0s[((size_t)b * 512 + colL) * 1024 + n] = o;
        }
      }
    } else {
      short* D0 = nullptr; short* D1 = nullptr;
      if constexpr (EPI == EPI_PROJ4 || EPI == EPI_PROJ3) {
        D0 = C0s; D1 = C1s;
      } else if constexpr (EPI == EPI_SPLIT_BIAS) {
        D0 = C0s + (size_t)z * g.sC; D1 = C1s + (size_t)z * g.sC;
      } else if constexpr (EPI == EPI_B16_SCALE || EPI == EPI_BOTH_LEAKY) {
        D0 = C0s + (size_t)z * g.sC;
      } else if constexpr (EPI == EPI_ACC2_SPLIT) {
        D0 = (short*)g.C1[seg] + (size_t)z * g.sC;
        D1 = (short*)g.C1[2 + seg] + (size_t)z * g.sC;
      } else { // EPI_ACC_SPLIT
        D0 = (short*)g.C1[0] + (size_t)z * g.sC;
        D1 = (short*)g.C1[1] + (size_t)z * g.sC;
      }
      auto elem = [&](int mi, int ni, int r, float bv) -> float {
        const int grow = tm + wr + mi * 16 + kg * 4 + r;
        const int colL = tnl + wc + ni * 16 + r16;
        const float v = acc[mi][ni][r];
        float t;
        if constexpr (EPI == EPI_B16_SCALE)
          t = v * g.alpha;
        else if constexpr (EPI == EPI_ACC2_SPLIT || EPI == EPI_ACC_SPLIT)
          t = (C0f[(size_t)z * g.sC + (size_t)grow * NnL + colL] + v) * g.alpha;
        else if constexpr (EPI == EPI_BOTH_LEAKY) {
          t = v + bv; t = (t >= 0.f) ? t : 0.01f * t;
          C1f[(size_t)z * g.sC + (size_t)grow * NnL + colL] = t;
        } else
          t = v + bv;
        return t;
      };
      if constexpr (FITS) {
        // ---- full-tile epilogue: ONE barrier ----
        #pragma unroll
        for (int mi = 0; mi < 4; mi++) {
          #pragma unroll
          for (int ni = 0; ni < 4; ni++) {
            const int lcol = wc + ni * 16 + r16;
            float bv = 0.f;
            if constexpr (EPI == EPI_PROJ4 || EPI == EPI_PROJ3 ||
                          EPI == EPI_SPLIT_BIAS || EPI == EPI_BOTH_LEAKY)
              bv = biasp[tnl + lcol];
            #pragma unroll
            for (int r = 0; r < 4; r++) {
              const float t = elem(mi, ni, r, bv);
              const int lrow = wr + mi * 16 + kg * 4 + r;     // 0..127
              const int sw = ((lrow >> 2) & 3) << 4;          // bank swizzle
              const int li = lrow * 128 + (lcol ^ sw);
              const short h = (short)f2b(t);
              smem[li] = h;
              if constexpr (CC == 2) smem[16384 + li] = (short)f2b(t - b2f(h));
            }
          }
        }
        __syncthreads();
        #pragma unroll
        for (int c2 = 0; c2 < CC; c2++) {
          short* D = c2 ? D1 : D0;
          #pragma unroll
          for (int it = 0; it < 8; it++) {
            const int e = (tid + it * 256) * 8;
            const int lrow2 = e >> 7, col = e & 127;
            const int sw2 = ((lrow2 >> 2) & 3) << 4;
            *(s8v*)&D[(size_t)(tm + lrow2) * NnL + tnl + col] =
                *(const s8v*)&smem[c2 * 16384 + (lrow2 << 7) + (col ^ sw2)];
          }
        }
      } else {
        // ---- per-mi strip epilogue (small-LDS CC=2 cases) ----
        for (int mi = 0; mi < 4; mi++) {
          #pragma unroll
          for (int ni = 0; ni < 4; ni++) {
            const int lcol = wc + ni * 16 + r16;
            float bv = 0.f;
            if constexpr (EPI == EPI_PROJ4 || EPI == EPI_PROJ3 ||
                          EPI == EPI_SPLIT_BIAS || EPI == EPI_BOTH_LEAKY)
              bv = biasp[tnl + lcol];
            #pragma unroll
            for (int r = 0; r < 4; r++) {
              const float t = elem(mi, ni, r, bv);
              const int lrow = (w >> 1) * 16 + kg * 4 + r;
              const int sw = ((lrow >> 2) & 3) << 4;
              const int li = lrow * 128 + (lcol ^ sw);
              const short h = (short)f2b(t);
              smem[li] = h;
              if constexpr (CC == 2) smem[4096 + li] = (short)f2b(t - b2f(h));
            }
          }
          __syncthreads();
          #pragma unroll
          for (int c2 = 0; c2 < CC; c2++) {
            short* D = c2 ? D1 : D0;
            #pragma unroll
            for (int half = 0; half < 2; half++) {
              const int e = (tid + half * 256) * 8;
              const int lrow2 = e >> 7, col = e & 127;
              const int sw2 = ((lrow2 >> 2) & 3) << 4;
              const int grow = tm + (lrow2 >> 4) * 64 + mi * 16 + (lrow2 & 15);
              *(s8v*)&D[(size_t)grow * NnL + tnl + col] =
                  *(const s8v*)&smem[c2 * 4096 + (lrow2 << 7) + (col ^ sw2)];
            }
          }
          __syncthreads();
        }
      }
    }
  } else {
    // direct f32 epilogues (coalesced 64B/group)
    #pragma unroll
    for (int mi = 0; mi < 4; mi++) {
      #pragma unroll
      for (int ni = 0; ni < 4; ni++) {
        const int colL = tnl + wc + ni * 16 + r16;
        const int grow0 = tm + wr + mi * 16 + kg * 4;
        float bv = 0.f;
        if constexpr (EPI == EPI_F32_BIAS_R || EPI == EPI_LEAKY_R)
          bv = biasp[colL];
        #pragma unroll
        for (int r = 0; r < 4; r++) {
          const size_t lidx = (size_t)(grow0 + r) * NnL + colL;
          const size_t idx = (size_t)z * g.sC + lidx;
          const float v = acc[mi][ni][r];
          if constexpr (EPI == EPI_ACC2) {
            C0f[(size_t)z * g.sC + (size_t)(grow0 + r) * 512 + colL] += v;
          } else if constexpr (EPI == EPI_ACC2_ST) {
            C0f[(size_t)z * g.sC + (size_t)(grow0 + r) * 512 + colL] = v;
          } else if constexpr (EPI == EPI_F32_ACC) {
            C0f[idx] += v;
          } else if constexpr (EPI == EPI_F32_ST) {
            C0f[idx] = v;
          } else if constexpr (EPI == EPI_F32_BIAS_R) {
            const float* Rf = (const float*)(z == 0 ? g.Rv : g.Rv2);
            C0f[idx] = v + bv + Rf[lidx];
          } else { // EPI_LEAKY_R
            float t = v + bv; t = (t >= 0.f) ? t : 0.01f * t;
            C0f[idx] = t + ((const float*)g.Rv)[idx];
          }
        }
      }
    }
  }
}

// ---- merged weight conversion: z-indexed table of DxD transposes ----
struct WcvtArgs {
  const float* src[32];
  short* hi[32];
  short* lo[32];      // nullptr -> single bf16
  int n;
};
__global__ __launch_bounds__(256) void wt_cvt_all(WcvtArgs a) {
  __shared__ float t[32][33];
  const int zi = blockIdx.z;
  const int bx = blockIdx.x * 32, by = blockIdx.y * 32;
  const int tx = threadIdx.x, ty = threadIdx.y;
  const float* src = a.src[zi];
  #pragma unroll
  for (int k = 0; k < 4; k++)
    t[ty + 8 * k][tx] = src[(size_t)(by + ty + 8 * k) * D_ + bx + tx];
  __syncthreads();
  short* hi = a.hi[zi];
  short* lo = a.lo[zi];
  if (lo) {
    #pragma unroll
    for (int k = 0; k < 4; k++) {
      const size_t o = (size_t)(bx + ty + 8 * k) * D_ + by + tx;
      float v = t[tx][ty + 8 * k];
      short h = (short)f2b(v);
      hi[o] = h;
      lo[o] = (short)f2b(v - b2f(h));
    }
  } else {
    #pragma unroll
    for (int k = 0; k < 4; k++)
      hi[(size_t)(bx + ty + 8 * k) * D_ + by + tx] =
          (short)f2b(t[tx][ty + 8 * k]);
  }
}

// f32 * scale -> hi bf16 + lo bf16
__global__ __launch_bounds__(256) void split_f32(const float* __restrict__ src,
                                                 short* __restrict__ hi,
                                                 short* __restrict__ lo, float scale) {
  const size_t i = ((size_t)blockIdx.x * 256 + threadIdx.x) * 4;
  f4v v = *(const f4v*)(src + i);
  s4v h, l;
  #pragma unroll
  for (int j = 0; j < 4; j++) {
    float t = v[j] * scale;
    h[j] = (short)f2b(t);
    l[j] = (short)f2b(t - b2f(h[j]));
  }
  *(s4v*)(hi + i) = h;
  *(s4v*)(lo + i) = l;
}

// sum = a + b (f32) elementwise; write bf16 + f32 (outf may alias a)
__global__ __launch_bounds__(256) void add_both(const float* __restrict__ a,
                                                const float* __restrict__ b,
                                                short* __restrict__ outb,
                                                float* outf) {
  const size_t i = ((size_t)blockIdx.x * 256 + threadIdx.x) * 4;
  f4v av = *(const f4v*)(a + i);
  f4v bv = *(const f4v*)(b + i);
  f4v s; s4v o;
  #pragma unroll
  for (int j = 0; j < 4; j++) { s[j] = av[j] + bv[j]; o[j] = (short)f2b(s[j]); }
  *(f4v*)(outf + i) = s;
  *(s4v*)(outb + i) = o;
}

// in-place softmax over bf16 rows of 1024; one wave per row, shuffle reduce
__global__ __launch_bounds__(256) void softmax_rows_b16(short* __restrict__ p) {
  const int row = blockIdx.x * 4 + (threadIdx.x >> 6);
  const int lane = threadIdx.x & 63;
  short* rp = p + (size_t)row * 1024 + lane * 16;
  s8v v0 = *(s8v*)rp, v1 = *(s8v*)(rp + 8);
  float f[16];
  #pragma unroll
  for (int j = 0; j < 8; j++) { f[j] = b2f(v0[j]); f[8 + j] = b2f(v1[j]); }
  float m = f[0];
  #pragma unroll
  for (int j = 1; j < 16; j++) m = fmaxf(m, f[j]);
  #pragma unroll
  for (int s = 32; s; s >>= 1) m = fmaxf(m, __shfl_xor(m, s, 64));
  float sum = 0.f;
  #pragma unroll
  for (int j = 0; j < 16; j++) { f[j] = __expf(f[j] - m); sum += f[j]; }
  #pragma unroll
  for (int s = 32; s; s >>= 1) sum += __shfl_xor(sum, s, 64);
  const float inv = 1.f / sum;
  #pragma unroll
  for (int j = 0; j < 8; j++) {
    v0[j] = (short)f2b(f[j] * inv);
    v1[j] = (short)f2b(f[8 + j] * inv);
  }
  *(s8v*)rp = v0; *(s8v*)(rp + 8) = v1;
}

// L2-normalize over axis=1 (N) of (NB,N,D) f32; deterministic 3-phase.
#define NCHUNK 16
__global__ __launch_bounds__(256) void norm_part(const float* __restrict__ t,
                                                 float* __restrict__ part, int NB) {
  const int d = blockIdx.x * 256 + threadIdx.x;
  const int b = blockIdx.y;
  const int c = blockIdx.z;
  const int n0 = c * (N_ / NCHUNK);
  const float* p = t + ((size_t)b * N_ + n0) * D_ + d;
  float ss = 0.f;
  for (int n = 0; n < N_ / NCHUNK; n++) { float v = p[(size_t)n * D_]; ss += v * v; }
  part[((size_t)c * NB + b) * D_ + d] = ss;
}
__global__ __launch_bounds__(256) void norm_inv(const float* __restrict__ part,
                                                float* __restrict__ inv, int NB) {
  const int i = blockIdx.x * 256 + threadIdx.x;   // b*D + d
  float ss = 0.f;
  for (int c = 0; c < NCHUNK; c++) ss += part[(size_t)c * (NB * D_) + i];
  inv[i] = 1.f / fmaxf(sqrtf(ss), 1e-12f);
}
__global__ __launch_bounds__(256) void norm_scale(const float* __restrict__ t,
                                                  const float* __restrict__ inv,
                                                  short* __restrict__ outh,
                                                  short* __restrict__ outl,
                                                  float* __restrict__ outf) {
  const size_t i = ((size_t)blockIdx.x * 256 + threadIdx.x) * 4;
  const int b = (int)(i >> 19);        // N_*D_ = 2^19
  const int d = (int)(i & (D_ - 1));
  f4v v = *(const f4v*)(t + i);
  f4v w = *(const f4v*)(inv + (size_t)b * D_ + d);
  f4v o; s4v oh, ol;
  #pragma unroll
  for (int j = 0; j < 4; j++) {
    o[j] = v[j] * w[j];
    oh[j] = (short)f2b(o[j]);
    ol[j] = (short)f2b(o[j] - b2f(oh[j]));
  }
  *(f4v*)(outf + i) = o;
  *(s4v*)(outh + i) = oh;
  *(s4v*)(outl + i) = ol;
}

extern "C" void kernel_launch(void* const* d_in, const int* in_sizes, int n_in,
                              void* d_out, int out_size, void* d_ws, size_t ws_size,
                              hipStream_t stream) {
  (void)in_sizes; (void)n_in; (void)out_size; (void)ws_size;
  const float* in1f = (const float*)d_in[0];
  const float* in2f = (const float*)d_in[1];

  const size_t SB = (size_t)B_ * N_ * D_ * 2;      // 8 MB
  const size_t SF = (size_t)B_ * N_ * D_ * 4;      // 16 MB
  const size_t WL = (size_t)L_ * D_ * D_ * 2;
  const size_t W1 = (size_t)D_ * D_ * 2;
  const size_t WD = (size_t)D_ * D_;               // elems per DxD slice
  const long SBel = (long)B_ * N_ * D_;            // 4194304 elems
  const long sAct = (long)N_ * D_;
  const long sAff = (long)N_ * N_;

  char* ws = (char*)d_ws;
  size_t off = 0;
  auto alloc = [&](size_t bytes) -> char* {
    char* p = ws + off;
    off += (bytes + 255) & ~(size_t)255;
    return p;
  };

  // ---- weight region; stage-1 proj weights now SINGLE bf16 ----
  char* wreg = alloc(8 * WL + 6 * W1);
  short* c_thT_h = (short*)(wreg);
  short* c_phT_h = (short*)(wreg + WL);
  short* c_rhT_h = (short*)(wreg + 2 * WL);
  short* c_psT_h = (short*)(wreg + 3 * WL);
  short* c_intT_h = (short*)(wreg + 8 * WL);
  short* c_intT_l = (short*)(wreg + 8 * WL + W1);
  short* c_f1T_h  = (short*)(wreg + 8 * WL + 2 * W1);
  short* c_f1T_l  = (short*)(wreg + 8 * WL + 3 * W1);
  short* c_f2T_h  = (short*)(wreg + 8 * WL + 4 * W1);
  short* c_f2T_l  = (short*)(wreg + 8 * WL + 5 * W1);
  short* a1_thT = (short*)(wreg);
  short* a1_phT = (short*)(wreg + WL);
  short* a1_rhT = (short*)(wreg + 2 * WL);
  short* a2_thT = (short*)(wreg + 3 * WL);
  short* a2_phT = (short*)(wreg + 4 * WL);
  short* a2_rhT = (short*)(wreg + 5 * WL);
  char*  aw = wreg + 6 * WL;
  short* a1_intT_h = (short*)(aw);
  short* a1_intT_l = (short*)(aw + W1);
  short* a1_f1T_h  = (short*)(aw + 2 * W1);
  short* a1_f1T_l  = (short*)(aw + 3 * W1);
  short* a1_f2T_h  = (short*)(aw + 4 * W1);
  short* a1_f2T_l  = (short*)(aw + 5 * W1);
  short* a2_intT_h = (short*)(aw + 6 * W1);
  short* a2_intT_l = (short*)(aw + 7 * W1);
  short* a2_f1T_h  = (short*)(aw + 8 * W1);
  short* a2_f1T_l  = (short*)(aw + 9 * W1);
  short* a2_f2T_h  = (short*)(aw + 10 * W1);
  short* a2_f2T_l  = (short*)(aw + 11 * W1);

  // ---- pair-contiguous activation regions (2*SB each = 16 MB) ----
  short* in12h = (short*)alloc(2 * SB);   // in1h|in2h -> feed12b -> sumb
  short* in12l = (short*)alloc(2 * SB);   // in1l|in2l -> resh
  short* bufA  = (short*)alloc(2 * SB);   // thh|thl -> inth -> hidh
  short* bufB  = (short*)alloc(2 * SB);   // phh|phl -> intl -> hidl
  short* bufC  = (short*)alloc(2 * SB);   // rhT|psT -> resl
  char*  affU  = alloc((size_t)32 * 1024 * 1024);
  float* accR  = (float*)alloc(2 * SF);   // acc1|acc2 / acc16 / tmpf
  float* feedfR = (float*)alloc(2 * SF);  // feed12f -> self12f -> sumf
  float* npart = (float*)alloc((size_t)NCHUNK * 16 * D_ * 4);
  float* ninv  = (float*)alloc((size_t)16 * D_ * 4);
  // total ≈ 196 MB (< proven 217)

  short* in1h = in12h;        short* in2h = in12h + SBel;
  short* in1l = in12l;        short* in2l = in12l + SBel;
  short* thh = bufA;          short* thl = bufA + SBel;
  short* phh = bufB;          short* phl = bufB + SBel;
  short* rhT = bufC;          short* psT = bufC + SBel;
  short* affh = (short*)affU;                   // [0,16 MB)
  short* aff16 = (short*)affU;                  // 32 MB bf16 batch-16 logits
  float* resfP = (float*)affU;                  // 32 MB f32 res (affs dead)
  float* acc1 = accR;         float* acc2 = accR + SBel;

  const float scl = 0.04419417382415922f;   // 512^-0.5
  dim3 tb(32, 8);
  const int GE = (B_ * N_ * D_) / (4 * 256);     // 4096
  #define F32P(i) ((const float*)d_in[i])

  auto GA = [&]() { GArgs a; __builtin_memset(&a, 0, sizeof(a)); return a; };
  auto normalize = [&](const float* src, int NB, short* outh, short* outl, float* outf) {
    norm_part<<<dim3(D_/256, NB, NCHUNK), 256, 0, stream>>>(src, npart, NB);
    norm_inv<<<(NB * D_) / 256, 256, 0, stream>>>(npart, ninv, NB);
    norm_scale<<<NB * 512, 256, 0, stream>>>(src, ninv, outh, outl, outf);
  };

  // ---- stage-1 weights: proj single bf16 + int/f1/f2 split ----
  {
    WcvtArgs wa; __builtin_memset(&wa, 0, sizeof(wa));
    int n = 0;
    auto addS = [&](const float* s, short* h, int nl) {
      for (int i = 0; i < nl; i++) {
        wa.src[n] = s + i * WD; wa.hi[n] = h + i * WD; wa.lo[n] = nullptr; n++;
      }
    };
    auto add2 = [&](const float* s, short* h, short* l) {
      wa.src[n] = s; wa.hi[n] = h; wa.lo[n] = l; n++;
    };
    addS(F32P(2),  c_thT_h, L_);
    addS(F32P(4),  c_phT_h, L_);
    addS(F32P(6),  c_rhT_h, L_);
    addS(F32P(8),  c_psT_h, L_);
    add2(F32P(10), c_intT_h, c_intT_l);
    add2(F32P(12), c_f1T_h, c_f1T_l);
    add2(F32P(14), c_f2T_h, c_f2T_l);
    wa.n = n;                                    // 19 slices
    wt_cvt_all<<<dim3(16, 16, n), tb, 0, stream>>>(wa);
  }
  split_f32<<<GE, 256, 0, stream>>>(in1f, in1h, in1l, 1.0f);
  split_f32<<<GE, 256, 0, stream>>>(in2f, in2h, in2l, 1.0f);

  // ---- stage 1: (2,1) proj -> bf16 P -> (1,1) applies ----
  for (int i = 0; i < L_; i++) {
    const size_t wo = (size_t)i * D_ * D_;
    const size_t bo = (size_t)i * D_;
    { GArgs a = GA();
      a.Ah[0] = in1h; a.Ah[1] = in1h; a.Ah[2] = in2h; a.Ah[3] = in2h;
      a.Al[0] = in1l; a.Al[1] = in1l; a.Al[2] = in2l; a.Al[3] = in2l;
      a.Bh[0] = c_thT_h + wo; a.Bh[1] = c_rhT_h + wo;
      a.Bh[2] = c_phT_h + wo; a.Bh[3] = c_psT_h + wo;
      a.C0[0] = thh; a.C0[1] = rhT; a.C0[2] = phh; a.C0[3] = psT;
      a.C1[0] = thl; a.C1[2] = phl;
      a.bias[0] = F32P(3) + bo; a.bias[1] = F32P(7) + bo;
      a.bias[2] = F32P(5) + bo; a.bias[3] = F32P(9) + bo;
      a.Nn = 512; a.K = 512;
      gemm_k<2,1,EPI_PROJ4,1><<<dim3(64,16,1),256,0,stream>>>(a); }
    { GArgs a = GA();
      a.Ah[0] = thh; a.Al[0] = thl; a.sA = sAct;
      a.Bh[0] = phh; a.Bl[0] = phl; a.sB = sAct;
      a.C0[0] = affh; a.sC = sAff;
      a.alpha = scl; a.Nn = 1024; a.K = 512;
      gemm_k<2,2,EPI_B16_SCALE,1><<<dim3(8,8,B_),256,0,stream>>>(a); }
    { GArgs a = GA();
      a.Ah[0] = affh; a.Ah[1] = affh; a.sA = sAff;
      a.Bh[0] = rhT; a.Bh[1] = psT; a.sB = sAct;
      a.C0[0] = acc1; a.C0[1] = acc2; a.sC = sAct;
      a.Nn = 512; a.K = 1024;
      if (i == 0) {
        gemm_k<1,1,EPI_ACC2_ST,1><<<dim3(8,8,B_),256,0,stream>>>(a);
      } else if (i < L_ - 1) {
        gemm_k<1,1,EPI_ACC2,1><<<dim3(8,8,B_),256,0,stream>>>(a);
      } else {
        a.C1[0] = bufA; a.C1[1] = bufA + SBel;   // inth (stream1|stream2)
        a.C1[2] = bufB; a.C1[3] = bufB + SBel;   // intl
        a.alpha = 0.25f;
        gemm_k<1,1,EPI_ACC2_SPLIT,1><<<dim3(8,8,B_),256,0,stream>>>(a);
      } }
  }

  // ---- stage-1 epilogue, both streams batched (z=2 / M=16384) ----
  { GArgs a = GA();
    a.Ah[0] = bufA; a.Al[0] = bufB; a.sA = SBel;
    a.Bh[0] = c_intT_h; a.Bl[0] = c_intT_l;
    a.C0[0] = accR; a.sC = SBel;
    a.bias[0] = F32P(11); a.Rv = in1f; a.Rv2 = in2f;
    a.Nn = 512; a.K = 512;
    gemm_k<2,2,EPI_F32_BIAS_R,1><<<dim3(64,4,2),256,0,stream>>>(a); }
  normalize(accR, 16, in12l, bufA, resfP);       // resh|resl (resf scratch)
  { GArgs a = GA();
    a.Ah[0] = in12l; a.Al[0] = bufA;
    a.Bh[0] = c_f1T_h; a.Bl[0] = c_f1T_l;
    a.C0[0] = bufB; a.C1[0] = bufC;              // hidh|hidl
    a.bias[0] = F32P(13); a.Nn = 512; a.K = 512;
    gemm_k<2,2,EPI_SPLIT_BIAS,1><<<dim3(128,4,1),256,0,stream>>>(a); }
  { GArgs a = GA();
    a.Ah[0] = bufB; a.Al[0] = bufC;
    a.Bh[0] = c_f2T_h; a.Bl[0] = c_f2T_l;
    a.C0[0] = in12h; a.C1[0] = feedfR;           // feed12b | feed12f
    a.bias[0] = F32P(15); a.Nn = 512; a.K = 512;
    gemm_k<2,2,EPI_BOTH_LEAKY,1><<<dim3(128,4,1),256,0,stream>>>(a); }

  // ---- a1/a2 weights: ONE merged dispatch (24 single + 6 split slices) ----
  {
    WcvtArgs wa; __builtin_memset(&wa, 0, sizeof(wa));
    int n = 0;
    auto addS = [&](const float* s, short* h, int nl) {
      for (int i = 0; i < nl; i++) {
        wa.src[n] = s + i * WD; wa.hi[n] = h + i * WD; wa.lo[n] = nullptr; n++;
      }
    };
    auto add2 = [&](const float* s, short* h, short* l) {
      wa.src[n] = s; wa.hi[n] = h; wa.lo[n] = l; n++;
    };
    addS(F32P(16), a1_thT, L_);
    addS(F32P(18), a1_phT, L_);
    addS(F32P(20), a1_rhT, L_);
    addS(F32P(28), a2_thT, L_);
    addS(F32P(30), a2_phT, L_);
    addS(F32P(32), a2_rhT, L_);
    add2(F32P(22), a1_intT_h, a1_intT_l);
    add2(F32P(24), a1_f1T_h, a1_f1T_l);
    add2(F32P(26), a1_f2T_h, a1_f2T_l);
    add2(F32P(34), a2_intT_h, a2_intT_l);
    add2(F32P(36), a2_f1T_h, a2_f1T_l);
    add2(F32P(38), a2_f2T_h, a2_f2T_l);
    wa.n = n;                                    // 30 slices
    wt_cvt_all<<<dim3(16, 16, n), tb, 0, stream>>>(wa);
  }

  // ---- generic agi chain ----
  auto agi = [&](int NZ, const short* xb, const float* xf,
                 const short* thT, const float* thB,
                 const short* phT, const float* phB,
                 const short* rhT_, const float* rhB,
                 const short* inTh, const short* inTl, const float* inB,
                 const short* f1Th, const short* f1Tl, const float* f1B,
                 const short* f2Th, const short* f2Tl, const float* f2B,
                 float* outf) {
    const int MB = NZ / B_;                  // 2 or 1 (stream multiplier)
    for (int i = 0; i < L_; i++) {
      const size_t wo = (size_t)i * D_ * D_;
      const size_t bo = (size_t)i * D_;
      { GArgs a = GA();
        a.Ah[0] = xb; a.Ah[1] = xb; a.Ah[2] = xb;
        a.Bh[0] = thT + wo; a.Bh[1] = phT + wo; a.Bh[2] = rhT_ + wo;
        a.C0[0] = bufA; a.C0[1] = bufB; a.C0[2] = bufC;
        a.bias[0] = thB + bo; a.bias[1] = phB + bo; a.bias[2] = rhB + bo;
        a.Nn = 512; a.K = 512;
        gemm_k<1,1,EPI_PROJ3,1><<<dim3(64*MB,12,1),256,0,stream>>>(a); }
      { GArgs a = GA();
        a.Ah[0] = bufA; a.sA = sAct; a.Bh[0] = bufB; a.sB = sAct;
        a.C0[0] = aff16; a.sC = sAff; a.alpha = scl; a.Nn = 1024; a.K = 512;
        gemm_k<1,1,EPI_B16_SCALE,1><<<dim3(8,8,NZ),256,0,stream>>>(a); }
      softmax_rows_b16<<<NZ * 256, 256, 0, stream>>>(aff16);
      { GArgs a = GA();
        a.Ah[0] = aff16; a.sA = sAff; a.Bh[0] = bufC; a.sB = sAct;
        a.C0[0] = accR; a.sC = sAct; a.Nn = 512; a.K = 1024;
        if (i == 0) {
          gemm_k<1,1,EPI_F32_ST,1><<<dim3(8,4,NZ),256,0,stream>>>(a);
        } else if (i < L_ - 1) {
          gemm_k<1,1,EPI_F32_ACC,1><<<dim3(8,4,NZ),256,0,stream>>>(a);
        } else {
          a.C1[0] = bufA; a.C1[1] = bufB; a.alpha = 0.25f;
          gemm_k<1,1,EPI_ACC_SPLIT,1><<<dim3(8,4,NZ),256,0,stream>>>(a);
        } }
    }
    { GArgs a = GA();
      a.Ah[0] = bufA; a.Al[0] = bufB;
      a.Bh[0] = inTh; a.Bl[0] = inTl;
      a.C0[0] = accR; a.bias[0] = inB; a.Rv = xf; a.Rv2 = xf;
      a.Nn = 512; a.K = 512;
      gemm_k<2,2,EPI_F32_BIAS_R,1><<<dim3(64*MB,4,1),256,0,stream>>>(a); }
    normalize(accR, NZ, in12l, bufC, resfP);     // resh|resl, resf -> affU
    { GArgs a = GA();
      a.Ah[0] = in12l; a.Al[0] = bufC;
      a.Bh[0] = f1Th; a.Bl[0] = f1Tl;
      a.C0[0] = bufA; a.C1[0] = bufB;            // hidh|hidl
      a.bias[0] = f1B; a.Nn = 512; a.K = 512;
      gemm_k<2,2,EPI_SPLIT_BIAS,1><<<dim3(64*MB,4,1),256,0,stream>>>(a); }
    { GArgs a = GA();
      a.Ah[0] = bufA; a.Al[0] = bufB;
      a.Bh[0] = f2Th; a.Bl[0] = f2Tl;
      a.C0[0] = accR; a.bias[0] = f2B; a.Rv = resfP;
      a.Nn = 512; a.K = 512;
      gemm_k<2,2,EPI_LEAKY_R,1><<<dim3(64*MB,4,1),256,0,stream>>>(a); }
    normalize(accR, NZ, bufA, bufB, outf);       // bf16 outs are scratch
  };

  // agi1 on feed1+feed2 as one batch-16 chain (shared AGI_1 weights)
  agi(16, in12h, feedfR,
      a1_thT, F32P(17), a1_phT, F32P(19), a1_rhT, F32P(21),
      a1_intT_h, a1_intT_l, F32P(23), a1_f1T_h, a1_f1T_l, F32P(25),
      a1_f2T_h, a1_f2T_l, F32P(27), feedfR);     // self12f -> feedfR

  add_both<<<GE, 256, 0, stream>>>(feedfR, feedfR + SBel, in12h, feedfR);

  agi(8, in12h, feedfR,
      a2_thT, F32P(29), a2_phT, F32P(31), a2_rhT, F32P(33),
      a2_intT_h, a2_intT_l, F32P(35), a2_f1T_h, a2_f1T_l, F32P(37),
      a2_f2T_h, a2_f2T_l, F32P(39), (float*)d_out);
}

// Round 16
// 1632.123 us; speedup vs baseline: 1.6980x; 1.0185x over previous
//
#include <hip/hip_runtime.h>

// ACGI_32195074850822 — round 15: fuse L2-norm partial sums into the
// producing GEMM epilogues (F32_BIAS_R / LEAKY_R). Removes all 5 norm_part
// dispatches (~128 MB of f32 trunk re-reads). Reduction is per-block
// write-once (deterministic); only summation ORDER changes (~1e-7 rel).
// Expected absmax unchanged (3.90625e-3 canary, threshold 8.75e-3).

#define B_ 8
#define N_ 1024
#define D_ 512
#define L_ 4

typedef short s8v __attribute__((ext_vector_type(8)));
typedef short s4v __attribute__((ext_vector_type(4)));
typedef float f4v __attribute__((ext_vector_type(4)));

__device__ __forceinline__ unsigned short f2b(float f) {
  unsigned u = __builtin_bit_cast(unsigned, f);
  u += 0x7FFFu + ((u >> 16) & 1u);          // round-to-nearest-even
  return (unsigned short)(u >> 16);
}
__device__ __forceinline__ float b2f(short s) {
  unsigned u = ((unsigned)(unsigned short)s) << 16;
  return __builtin_bit_cast(float, u);
}

__device__ __forceinline__ void glds16(const short* g, short* l) {
  __builtin_amdgcn_global_load_lds(
      (const __attribute__((address_space(1))) void*)g,
      (__attribute__((address_space(3))) void*)l, 16, 0, 0);
}

enum {
  EPI_PROJ4 = 0,   // seg even: split(acc+bias)->C0/C1; seg odd: TR(acc+bias)->C0
  EPI_PROJ3,       // seg 0,1: bf16(acc+bias)->C0; seg 2: TR->C0
  EPI_B16_SCALE,   // C0 bf16 = acc*alpha
  EPI_ACC2,        // seg s: C0[s] f32 += acc   (z-batched)
  EPI_ACC2_ST,     // seg s: C0[s] f32 = acc    (layer 0)
  EPI_F32_ACC,     // C0[0] f32 += acc          (z-batched)
  EPI_F32_ST,      // C0[0] f32 = acc           (layer 0)
  EPI_F32_BIAS_R,  // C0 f32 = acc+bias+R (+ fused norm partials -> NP)
  EPI_SPLIT_BIAS,  // C0 hi, C1 lo of acc+bias
  EPI_BOTH_LEAKY,  // C0 bf16 AND C1 f32 = leaky(acc+bias)
  EPI_LEAKY_R,     // C0 f32 = leaky(acc+bias)+R (+ fused norm partials -> NP)
  EPI_ACC2_SPLIT,  // seg s: t=(C0[s]+acc)*alpha; hi->C1[s], lo->C1[2+s]
  EPI_ACC_SPLIT    // t=(C0[0]+acc)*alpha; hi->C1[0], lo->C1[1] (z-batched)
};

struct GArgs {
  const short* Ah[4]; const short* Al[4];
  const short* Bh[4]; const short* Bl[4];
  long sA, sB;
  void* C0[4]; void* C1[4];
  long sC;
  const float* bias[4];
  const void* Rv; const void* Rv2;
  float* NP;                      // fused norm partials (F32_BIAS_R/LEAKY_R)
  float alpha;
  int Nn, K;
};

// C = (ΣA_c)(ΣB_c)^T, bf16 comps, f32 accum; <2,2> drops Al*Bl.
// 128x128 tile, 4 waves, global_load_lds(16B) + both-sides XOR swizzle.
// DB=1: double-buffered staging, counted vmcnt. XCD-chunked y-fastest blocks.
template<int AS, int BS, int EPI, int DB>
__global__ __launch_bounds__(256) void gemm_k(GArgs g) {
  constexpr int TILE = (AS + BS) * 4096;        // shorts per staging buffer
  __shared__ short smem[TILE * (DB ? 2 : 1)];
  constexpr bool SEG = (EPI == EPI_PROJ4 || EPI == EPI_PROJ3 ||
                        EPI == EPI_ACC2 || EPI == EPI_ACC2_ST ||
                        EPI == EPI_ACC2_SPLIT);
  constexpr bool LDSOUT = (EPI == EPI_PROJ4 || EPI == EPI_PROJ3 ||
                           EPI == EPI_B16_SCALE || EPI == EPI_SPLIT_BIAS ||
                           EPI == EPI_BOTH_LEAKY || EPI == EPI_ACC2_SPLIT ||
                           EPI == EPI_ACC_SPLIT);
  constexpr int CC = (EPI == EPI_PROJ4 || EPI == EPI_SPLIT_BIAS ||
                      EPI == EPI_ACC2_SPLIT || EPI == EPI_ACC_SPLIT) ? 2 : 1;
  constexpr bool FITS = (TILE * (DB ? 2 : 1)) >= CC * 16384;  // full-tile epi
  constexpr bool NPART = (EPI == EPI_F32_BIAS_R || EPI == EPI_LEAKY_R);
  const int z = blockIdx.z;

  // ---- L2-locality swizzle (all grids have nwg % 8 == 0) ----
  const int GX = gridDim.x, GY = gridDim.y;
  const int nwg = GX * GY;
  const int orig = blockIdx.y * GX + blockIdx.x;
  const int wgid = (orig & 7) * (nwg >> 3) + (orig >> 3);
  const int bx = wgid / GY;
  const int by = wgid - bx * GY;
  const int tm = bx * 128;
  const int tn = by * 128;

  const int tid = threadIdx.x;
  const int lane = tid & 63;
  const int w = tid >> 6;
  const int wr = (w >> 1) * 64, wc = (w & 1) * 64;
  const int r16 = lane & 15, kg = lane >> 4;
  const int K = g.K;

  int seg = 0, tnl = tn;
  if constexpr (SEG) { seg = tn >> 9; tnl = tn & 511; }
  const short* Ah = g.Ah[seg];
  const short* Al = (AS == 2) ? g.Al[seg] : nullptr;
  const short* Bh = g.Bh[seg];
  const short* Bl = (BS == 2) ? g.Bl[seg] : nullptr;

  const int srow = lane >> 2;
  const int scol = ((lane & 3) ^ ((lane >> 3) & 3)) * 8;
  const short* gA[2]; const short* gB[2];
  gA[0] = Ah + (size_t)z * g.sA + (size_t)(tm + w * 16 + srow) * K + scol;
  if constexpr (AS == 2)
    gA[1] = Al + (size_t)z * g.sA + (size_t)(tm + w * 16 + srow) * K + scol;
  gB[0] = Bh + (size_t)z * g.sB + (size_t)(tnl + w * 16 + srow) * K + scol;
  if constexpr (BS == 2)
    gB[1] = Bl + (size_t)z * g.sB + (size_t)(tnl + w * 16 + srow) * K + scol;
  const size_t hoff = (size_t)64 * K;

  auto stage = [&](int k0, int buf) {
    short* base = smem + buf * TILE;
    #pragma unroll
    for (int c = 0; c < AS; c++) {
      glds16(gA[c] + k0, base + c * 4096 + (w * 16) * 32);
      glds16(gA[c] + hoff + k0, base + c * 4096 + (64 + w * 16) * 32);
    }
    #pragma unroll
    for (int c = 0; c < BS; c++) {
      glds16(gB[c] + k0, base + (AS + c) * 4096 + (w * 16) * 32);
      glds16(gB[c] + hoff + k0, base + (AS + c) * 4096 + (64 + w * 16) * 32);
    }
  };

  f4v acc[4][4];
  #pragma unroll
  for (int i = 0; i < 4; i++)
    #pragma unroll
    for (int j = 0; j < 4; j++) acc[i][j] = (f4v)0.f;

  const int rc = (kg ^ ((r16 >> 1) & 3)) * 8;

  auto compute = [&](int buf) {
    const short* base = smem + buf * TILE;
    s8v va[2][4], vb[2][4];
    #pragma unroll
    for (int c = 0; c < AS; c++)
      #pragma unroll
      for (int i = 0; i < 4; i++)
        va[c][i] = *(const s8v*)&base[c * 4096 + (wr + i * 16 + r16) * 32 + rc];
    #pragma unroll
    for (int c = 0; c < BS; c++)
      #pragma unroll
      for (int i = 0; i < 4; i++)
        vb[c][i] = *(const s8v*)&base[(AS + c) * 4096 + (wc + i * 16 + r16) * 32 + rc];
    #pragma unroll
    for (int ca = 0; ca < AS; ca++)
      #pragma unroll
      for (int cb = 0; cb < BS; cb++) {
        if (ca == 1 && cb == 1) continue;   // drop lo*lo
        #pragma unroll
        for (int mi = 0; mi < 4; mi++)
          #pragma unroll
          for (int ni = 0; ni < 4; ni++)
            acc[mi][ni] = __builtin_amdgcn_mfma_f32_16x16x32_bf16(
                va[ca][mi], vb[cb][ni], acc[mi][ni], 0, 0, 0);
      }
  };

  const int nt = K >> 5;
  if constexpr (DB) {
    constexpr int NLD = (AS + BS) * 2;        // vmcnt events per stage
    stage(0, 0);
    int buf = 0;
    for (int t = 0; t < nt; t++) {
      if (t + 1 < nt) {
        stage((t + 1) * 32, buf ^ 1);
        if constexpr (NLD == 8)      asm volatile("s_waitcnt vmcnt(8)" ::: "memory");
        else if constexpr (NLD == 6) asm volatile("s_waitcnt vmcnt(6)" ::: "memory");
        else                         asm volatile("s_waitcnt vmcnt(4)" ::: "memory");
      } else {
        asm volatile("s_waitcnt vmcnt(0)" ::: "memory");
      }
      __builtin_amdgcn_sched_barrier(0);
      __builtin_amdgcn_s_barrier();
      compute(buf);
      __builtin_amdgcn_s_barrier();
      buf ^= 1;
    }
  } else {
    for (int t = 0; t < nt; t++) {
      stage(t * 32, 0);
      __syncthreads();
      compute(0);
      __syncthreads();
    }
  }

  short* C0s = (short*)g.C0[seg];  float* C0f = (float*)g.C0[seg];
  short* C1s = (short*)g.C1[seg];  float* C1f = (float*)g.C1[seg];
  const float* biasp = g.bias[seg];
  const int NnL = g.Nn;

  if constexpr (LDSOUT) {
    bool tr = false;
    if constexpr (EPI == EPI_PROJ4) tr = (seg & 1);
    if constexpr (EPI == EPI_PROJ3) tr = (seg == 2);
    if (tr) {
      // transposed write (s4v along n, 8B-coalesced)
      #pragma unroll
      for (int mi = 0; mi < 4; mi++) {
        #pragma unroll
        for (int ni = 0; ni < 4; ni++) {
          const int colL = tnl + wc + ni * 16 + r16;
          const int grow0 = tm + wr + mi * 16 + kg * 4;
          const float bv = biasp[colL];
          s4v o;
          #pragma unroll
          for (int r = 0; r < 4; r++) o[r] = (short)f2b(acc[mi][ni][r] + bv);
          const int b = grow0 >> 10, n = grow0 & 1023;
          *(s4v*)&C0s[((size_t)b * 512 + colL) * 1024 + n] = o;
        }
      }
    } else {
      short* D0 = nullptr; short* D1 = nullptr;
      if constexpr (EPI == EPI_PROJ4 || EPI == EPI_PROJ3) {
        D0 = C0s; D1 = C1s;
      } else if constexpr (EPI == EPI_SPLIT_BIAS) {
        D0 = C0s + (size_t)z * g.sC; D1 = C1s + (size_t)z * g.sC;
      } else if constexpr (EPI == EPI_B16_SCALE || EPI == EPI_BOTH_LEAKY) {
        D0 = C0s + (size_t)z * g.sC;
      } else if constexpr (EPI == EPI_ACC2_SPLIT) {
        D0 = (short*)g.C1[seg] + (size_t)z * g.sC;
        D1 = (short*)g.C1[2 + seg] + (size_t)z * g.sC;
      } else { // EPI_ACC_SPLIT
        D0 = (short*)g.C1[0] + (size_t)z * g.sC;
        D1 = (short*)g.C1[1] + (size_t)z * g.sC;
      }
      auto elem = [&](int mi, int ni, int r, float bv) -> float {
        const int grow = tm + wr + mi * 16 + kg * 4 + r;
        const int colL = tnl + wc + ni * 16 + r16;
        const float v = acc[mi][ni][r];
        float t;
        if constexpr (EPI == EPI_B16_SCALE)
          t = v * g.alpha;
        else if constexpr (EPI == EPI_ACC2_SPLIT || EPI == EPI_ACC_SPLIT)
          t = (C0f[(size_t)z * g.sC + (size_t)grow * NnL + colL] + v) * g.alpha;
        else if constexpr (EPI == EPI_BOTH_LEAKY) {
          t = v + bv; t = (t >= 0.f) ? t : 0.01f * t;
          C1f[(size_t)z * g.sC + (size_t)grow * NnL + colL] = t;
        } else
          t = v + bv;
        return t;
      };
      if constexpr (FITS) {
        // ---- full-tile epilogue: ONE barrier ----
        #pragma unroll
        for (int mi = 0; mi < 4; mi++) {
          #pragma unroll
          for (int ni = 0; ni < 4; ni++) {
            const int lcol = wc + ni * 16 + r16;
            float bv = 0.f;
            if constexpr (EPI == EPI_PROJ4 || EPI == EPI_PROJ3 ||
                          EPI == EPI_SPLIT_BIAS || EPI == EPI_BOTH_LEAKY)
              bv = biasp[tnl + lcol];
            #pragma unroll
            for (int r = 0; r < 4; r++) {
              const float t = elem(mi, ni, r, bv);
              const int lrow = wr + mi * 16 + kg * 4 + r;     // 0..127
              const int sw = ((lrow >> 2) & 3) << 4;          // bank swizzle
              const int li = lrow * 128 + (lcol ^ sw);
              const short h = (short)f2b(t);
              smem[li] = h;
              if constexpr (CC == 2) smem[16384 + li] = (short)f2b(t - b2f(h));
            }
          }
        }
        __syncthreads();
        #pragma unroll
        for (int c2 = 0; c2 < CC; c2++) {
          short* D = c2 ? D1 : D0;
          #pragma unroll
          for (int it = 0; it < 8; it++) {
            const int e = (tid + it * 256) * 8;
            const int lrow2 = e >> 7, col = e & 127;
            const int sw2 = ((lrow2 >> 2) & 3) << 4;
            *(s8v*)&D[(size_t)(tm + lrow2) * NnL + tnl + col] =
                *(const s8v*)&smem[c2 * 16384 + (lrow2 << 7) + (col ^ sw2)];
          }
        }
      } else {
        // ---- per-mi strip epilogue (small-LDS CC=2 cases) ----
        for (int mi = 0; mi < 4; mi++) {
          #pragma unroll
          for (int ni = 0; ni < 4; ni++) {
            const int lcol = wc + ni * 16 + r16;
            float bv = 0.f;
            if constexpr (EPI == EPI_PROJ4 || EPI == EPI_PROJ3 ||
                          EPI == EPI_SPLIT_BIAS || EPI == EPI_BOTH_LEAKY)
              bv = biasp[tnl + lcol];
            #pragma unroll
            for (int r = 0; r < 4; r++) {
              const float t = elem(mi, ni, r, bv);
              const int lrow = (w >> 1) * 16 + kg * 4 + r;
              const int sw = ((lrow >> 2) & 3) << 4;
              const int li = lrow * 128 + (lcol ^ sw);
              const short h = (short)f2b(t);
              smem[li] = h;
              if constexpr (CC == 2) smem[4096 + li] = (short)f2b(t - b2f(h));
            }
          }
          __syncthreads();
          #pragma unroll
          for (int c2 = 0; c2 < CC; c2++) {
            short* D = c2 ? D1 : D0;
            #pragma unroll
            for (int half = 0; half < 2; half++) {
              const int e = (tid + half * 256) * 8;
              const int lrow2 = e >> 7, col = e & 127;
              const int sw2 = ((lrow2 >> 2) & 3) << 4;
              const int grow = tm + (lrow2 >> 4) * 64 + mi * 16 + (lrow2 & 15);
              *(s8v*)&D[(size_t)grow * NnL + tnl + col] =
                  *(const s8v*)&smem[c2 * 4096 + (lrow2 << 7) + (col ^ sw2)];
            }
          }
          __syncthreads();
        }
      }
    }
  } else {
    // direct f32 epilogues (coalesced 64B/group); NPART fuses norm partials
    float ss[4] = {0.f, 0.f, 0.f, 0.f};
    #pragma unroll
    for (int mi = 0; mi < 4; mi++) {
      #pragma unroll
      for (int ni = 0; ni < 4; ni++) {
        const int colL = tnl + wc + ni * 16 + r16;
        const int grow0 = tm + wr + mi * 16 + kg * 4;
        float bv = 0.f;
        if constexpr (EPI == EPI_F32_BIAS_R || EPI == EPI_LEAKY_R)
          bv = biasp[colL];
        #pragma unroll
        for (int r = 0; r < 4; r++) {
          const size_t lidx = (size_t)(grow0 + r) * NnL + colL;
          const size_t idx = (size_t)z * g.sC + lidx;
          const float v = acc[mi][ni][r];
          if constexpr (EPI == EPI_ACC2) {
            C0f[(size_t)z * g.sC + (size_t)(grow0 + r) * 512 + colL] += v;
          } else if constexpr (EPI == EPI_ACC2_ST) {
            C0f[(size_t)z * g.sC + (size_t)(grow0 + r) * 512 + colL] = v;
          } else if constexpr (EPI == EPI_F32_ACC) {
            C0f[idx] += v;
          } else if constexpr (EPI == EPI_F32_ST) {
            C0f[idx] = v;
          } else if constexpr (EPI == EPI_F32_BIAS_R) {
            const float* Rf = (const float*)(z == 0 ? g.Rv : g.Rv2);
            const float t = v + bv + Rf[lidx];
            C0f[idx] = t;
            ss[ni] += t * t;
          } else { // EPI_LEAKY_R
            float t = v + bv; t = (t >= 0.f) ? t : 0.01f * t;
            t += ((const float*)g.Rv)[idx];
            C0f[idx] = t;
            ss[ni] += t * t;
          }
        }
      }
    }
    if constexpr (NPART) {
      // reduce 8 contributors per column via LDS; one write per (tile,col)
      float* sred = (float*)smem;                  // 128 cols x 8 slots
      const int slot = (w >> 1) * 4 + kg;          // 0..7
      __syncthreads();                             // smem free after K-loop
      #pragma unroll
      for (int ni = 0; ni < 4; ni++)
        sred[(wc + ni * 16 + r16) * 8 + slot] = ss[ni];
      __syncthreads();
      if (tid < 128) {
        float s = 0.f;
        #pragma unroll
        for (int j = 0; j < 8; j++) s += sred[tid * 8 + j];
        g.NP[(size_t)(z * GX + bx) * 512 + tnl + tid] = s;
      }
    }
  }
}

// ---- merged weight conversion: z-indexed table of DxD transposes ----
struct WcvtArgs {
  const float* src[32];
  short* hi[32];
  short* lo[32];      // nullptr -> single bf16
  int n;
};
__global__ __launch_bounds__(256) void wt_cvt_all(WcvtArgs a) {
  __shared__ float t[32][33];
  const int zi = blockIdx.z;
  const int bx = blockIdx.x * 32, by = blockIdx.y * 32;
  const int tx = threadIdx.x, ty = threadIdx.y;
  const float* src = a.src[zi];
  #pragma unroll
  for (int k = 0; k < 4; k++)
    t[ty + 8 * k][tx] = src[(size_t)(by + ty + 8 * k) * D_ + bx + tx];
  __syncthreads();
  short* hi = a.hi[zi];
  short* lo = a.lo[zi];
  if (lo) {
    #pragma unroll
    for (int k = 0; k < 4; k++) {
      const size_t o = (size_t)(bx + ty + 8 * k) * D_ + by + tx;
      float v = t[tx][ty + 8 * k];
      short h = (short)f2b(v);
      hi[o] = h;
      lo[o] = (short)f2b(v - b2f(h));
    }
  } else {
    #pragma unroll
    for (int k = 0; k < 4; k++)
      hi[(size_t)(bx + ty + 8 * k) * D_ + by + tx] =
          (short)f2b(t[tx][ty + 8 * k]);
  }
}

// f32 * scale -> hi bf16 + lo bf16
__global__ __launch_bounds__(256) void split_f32(const float* __restrict__ src,
                                                 short* __restrict__ hi,
                                                 short* __restrict__ lo, float scale) {
  const size_t i = ((size_t)blockIdx.x * 256 + threadIdx.x) * 4;
  f4v v = *(const f4v*)(src + i);
  s4v h, l;
  #pragma unroll
  for (int j = 0; j < 4; j++) {
    float t = v[j] * scale;
    h[j] = (short)f2b(t);
    l[j] = (short)f2b(t - b2f(h[j]));
  }
  *(s4v*)(hi + i) = h;
  *(s4v*)(lo + i) = l;
}

// sum = a + b (f32) elementwise; write bf16 + f32 (outf may alias a)
__global__ __launch_bounds__(256) void add_both(const float* __restrict__ a,
                                                const float* __restrict__ b,
                                                short* __restrict__ outb,
                                                float* outf) {
  const size_t i = ((size_t)blockIdx.x * 256 + threadIdx.x) * 4;
  f4v av = *(const f4v*)(a + i);
  f4v bv = *(const f4v*)(b + i);
  f4v s; s4v o;
  #pragma unroll
  for (int j = 0; j < 4; j++) { s[j] = av[j] + bv[j]; o[j] = (short)f2b(s[j]); }
  *(f4v*)(outf + i) = s;
  *(s4v*)(outb + i) = o;
}

// in-place softmax over bf16 rows of 1024; one wave per row, shuffle reduce
__global__ __launch_bounds__(256) void softmax_rows_b16(short* __restrict__ p) {
  const int row = blockIdx.x * 4 + (threadIdx.x >> 6);
  const int lane = threadIdx.x & 63;
  short* rp = p + (size_t)row * 1024 + lane * 16;
  s8v v0 = *(s8v*)rp, v1 = *(s8v*)(rp + 8);
  float f[16];
  #pragma unroll
  for (int j = 0; j < 8; j++) { f[j] = b2f(v0[j]); f[8 + j] = b2f(v1[j]); }
  float m = f[0];
  #pragma unroll
  for (int j = 1; j < 16; j++) m = fmaxf(m, f[j]);
  #pragma unroll
  for (int s = 32; s; s >>= 1) m = fmaxf(m, __shfl_xor(m, s, 64));
  float sum = 0.f;
  #pragma unroll
  for (int j = 0; j < 16; j++) { f[j] = __expf(f[j] - m); sum += f[j]; }
  #pragma unroll
  for (int s = 32; s; s >>= 1) sum += __shfl_xor(sum, s, 64);
  const float inv = 1.f / sum;
  #pragma unroll
  for (int j = 0; j < 8; j++) {
    v0[j] = (short)f2b(f[j] * inv);
    v1[j] = (short)f2b(f[8 + j] * inv);
  }
  *(s8v*)rp = v0; *(s8v*)(rp + 8) = v1;
}

// norm_inv from fused tile partials: part[tile][512], 8 tiles per batch row
__global__ __launch_bounds__(256) void norm_inv(const float* __restrict__ part,
                                                float* __restrict__ inv, int NB) {
  const int i = blockIdx.x * 256 + threadIdx.x;   // b*512 + d
  const int b = i >> 9, d = i & 511;
  float ss = 0.f;
  #pragma unroll
  for (int t = 0; t < 8; t++)
    ss += part[(size_t)(b * 8 + t) * 512 + d];
  inv[i] = 1.f / fmaxf(sqrtf(ss), 1e-12f);
}
__global__ __launch_bounds__(256) void norm_scale(const float* __restrict__ t,
                                                  const float* __restrict__ inv,
                                                  short* __restrict__ outh,
                                                  short* __restrict__ outl,
                                                  float* __restrict__ outf) {
  const size_t i = ((size_t)blockIdx.x * 256 + threadIdx.x) * 4;
  const int b = (int)(i >> 19);        // N_*D_ = 2^19
  const int d = (int)(i & (D_ - 1));
  f4v v = *(const f4v*)(t + i);
  f4v w = *(const f4v*)(inv + (size_t)b * D_ + d);
  f4v o; s4v oh, ol;
  #pragma unroll
  for (int j = 0; j < 4; j++) {
    o[j] = v[j] * w[j];
    oh[j] = (short)f2b(o[j]);
    ol[j] = (short)f2b(o[j] - b2f(oh[j]));
  }
  *(f4v*)(outf + i) = o;
  *(s4v*)(outh + i) = oh;
  *(s4v*)(outl + i) = ol;
}

extern "C" void kernel_launch(void* const* d_in, const int* in_sizes, int n_in,
                              void* d_out, int out_size, void* d_ws, size_t ws_size,
                              hipStream_t stream) {
  (void)in_sizes; (void)n_in; (void)out_size; (void)ws_size;
  const float* in1f = (const float*)d_in[0];
  const float* in2f = (const float*)d_in[1];

  const size_t SB = (size_t)B_ * N_ * D_ * 2;      // 8 MB
  const size_t SF = (size_t)B_ * N_ * D_ * 4;      // 16 MB
  const size_t WL = (size_t)L_ * D_ * D_ * 2;
  const size_t W1 = (size_t)D_ * D_ * 2;
  const size_t WD = (size_t)D_ * D_;               // elems per DxD slice
  const long SBel = (long)B_ * N_ * D_;            // 4194304 elems
  const long sAct = (long)N_ * D_;
  const long sAff = (long)N_ * N_;

  char* ws = (char*)d_ws;
  size_t off = 0;
  auto alloc = [&](size_t bytes) -> char* {
    char* p = ws + off;
    off += (bytes + 255) & ~(size_t)255;
    return p;
  };

  // ---- weight region; stage-1 proj weights SINGLE bf16 ----
  char* wreg = alloc(8 * WL + 6 * W1);
  short* c_thT_h = (short*)(wreg);
  short* c_phT_h = (short*)(wreg + WL);
  short* c_rhT_h = (short*)(wreg + 2 * WL);
  short* c_psT_h = (short*)(wreg + 3 * WL);
  short* c_intT_h = (short*)(wreg + 8 * WL);
  short* c_intT_l = (short*)(wreg + 8 * WL + W1);
  short* c_f1T_h  = (short*)(wreg + 8 * WL + 2 * W1);
  short* c_f1T_l  = (short*)(wreg + 8 * WL + 3 * W1);
  short* c_f2T_h  = (short*)(wreg + 8 * WL + 4 * W1);
  short* c_f2T_l  = (short*)(wreg + 8 * WL + 5 * W1);
  short* a1_thT = (short*)(wreg);
  short* a1_phT = (short*)(wreg + WL);
  short* a1_rhT = (short*)(wreg + 2 * WL);
  short* a2_thT = (short*)(wreg + 3 * WL);
  short* a2_phT = (short*)(wreg + 4 * WL);
  short* a2_rhT = (short*)(wreg + 5 * WL);
  char*  aw = wreg + 6 * WL;
  short* a1_intT_h = (short*)(aw);
  short* a1_intT_l = (short*)(aw + W1);
  short* a1_f1T_h  = (short*)(aw + 2 * W1);
  short* a1_f1T_l  = (short*)(aw + 3 * W1);
  short* a1_f2T_h  = (short*)(aw + 4 * W1);
  short* a1_f2T_l  = (short*)(aw + 5 * W1);
  short* a2_intT_h = (short*)(aw + 6 * W1);
  short* a2_intT_l = (short*)(aw + 7 * W1);
  short* a2_f1T_h  = (short*)(aw + 8 * W1);
  short* a2_f1T_l  = (short*)(aw + 9 * W1);
  short* a2_f2T_h  = (short*)(aw + 10 * W1);
  short* a2_f2T_l  = (short*)(aw + 11 * W1);

  // ---- pair-contiguous activation regions (2*SB each = 16 MB) ----
  short* in12h = (short*)alloc(2 * SB);   // in1h|in2h -> feed12b -> sumb
  short* in12l = (short*)alloc(2 * SB);   // in1l|in2l -> resh
  short* bufA  = (short*)alloc(2 * SB);   // thh|thl -> inth -> hidh
  short* bufB  = (short*)alloc(2 * SB);   // phh|phl -> intl -> hidl
  short* bufC  = (short*)alloc(2 * SB);   // rhT|psT -> resl
  char*  affU  = alloc((size_t)32 * 1024 * 1024);
  float* accR  = (float*)alloc(2 * SF);   // acc1|acc2 / acc16 / tmpf
  float* feedfR = (float*)alloc(2 * SF);  // feed12f -> self12f -> sumf
  float* npart = (float*)alloc((size_t)128 * 512 * 4);   // tile partials
  float* ninv  = (float*)alloc((size_t)16 * D_ * 4);
  // total ≈ 196 MB (< proven 217)

  short* in1h = in12h;        short* in2h = in12h + SBel;
  short* in1l = in12l;        short* in2l = in12l + SBel;
  short* thh = bufA;          short* thl = bufA + SBel;
  short* phh = bufB;          short* phl = bufB + SBel;
  short* rhT = bufC;          short* psT = bufC + SBel;
  short* affh = (short*)affU;                   // [0,16 MB)
  short* aff16 = (short*)affU;                  // 32 MB bf16 batch-16 logits
  float* resfP = (float*)affU;                  // 32 MB f32 res (affs dead)
  float* acc1 = accR;         float* acc2 = accR + SBel;

  const float scl = 0.04419417382415922f;   // 512^-0.5
  dim3 tb(32, 8);
  const int GE = (B_ * N_ * D_) / (4 * 256);     // 4096
  #define F32P(i) ((const float*)d_in[i])

  auto GA = [&]() { GArgs a; __builtin_memset(&a, 0, sizeof(a)); return a; };
  auto normalize = [&](const float* src, int NB, short* outh, short* outl, float* outf) {
    norm_inv<<<(NB * D_) / 256, 256, 0, stream>>>(npart, ninv, NB);
    norm_scale<<<NB * 512, 256, 0, stream>>>(src, ninv, outh, outl, outf);
  };

  // ---- stage-1 weights: proj single bf16 + int/f1/f2 split ----
  {
    WcvtArgs wa; __builtin_memset(&wa, 0, sizeof(wa));
    int n = 0;
    auto addS = [&](const float* s, short* h, int nl) {
      for (int i = 0; i < nl; i++) {
        wa.src[n] = s + i * WD; wa.hi[n] = h + i * WD; wa.lo[n] = nullptr; n++;
      }
    };
    auto add2 = [&](const float* s, short* h, short* l) {
      wa.src[n] = s; wa.hi[n] = h; wa.lo[n] = l; n++;
    };
    addS(F32P(2),  c_thT_h, L_);
    addS(F32P(4),  c_phT_h, L_);
    addS(F32P(6),  c_rhT_h, L_);
    addS(F32P(8),  c_psT_h, L_);
    add2(F32P(10), c_intT_h, c_intT_l);
    add2(F32P(12), c_f1T_h, c_f1T_l);
    add2(F32P(14), c_f2T_h, c_f2T_l);
    wa.n = n;
    wt_cvt_all<<<dim3(16, 16, n), tb, 0, stream>>>(wa);
  }
  split_f32<<<GE, 256, 0, stream>>>(in1f, in1h, in1l, 1.0f);
  split_f32<<<GE, 256, 0, stream>>>(in2f, in2h, in2l, 1.0f);

  // ---- stage 1: (2,1) proj -> bf16 P -> (1,1) applies ----
  for (int i = 0; i < L_; i++) {
    const size_t wo = (size_t)i * D_ * D_;
    const size_t bo = (size_t)i * D_;
    { GArgs a = GA();
      a.Ah[0] = in1h; a.Ah[1] = in1h; a.Ah[2] = in2h; a.Ah[3] = in2h;
      a.Al[0] = in1l; a.Al[1] = in1l; a.Al[2] = in2l; a.Al[3] = in2l;
      a.Bh[0] = c_thT_h + wo; a.Bh[1] = c_rhT_h + wo;
      a.Bh[2] = c_phT_h + wo; a.Bh[3] = c_psT_h + wo;
      a.C0[0] = thh; a.C0[1] = rhT; a.C0[2] = phh; a.C0[3] = psT;
      a.C1[0] = thl; a.C1[2] = phl;
      a.bias[0] = F32P(3) + bo; a.bias[1] = F32P(7) + bo;
      a.bias[2] = F32P(5) + bo; a.bias[3] = F32P(9) + bo;
      a.Nn = 512; a.K = 512;
      gemm_k<2,1,EPI_PROJ4,1><<<dim3(64,16,1),256,0,stream>>>(a); }
    { GArgs a = GA();
      a.Ah[0] = thh; a.Al[0] = thl; a.sA = sAct;
      a.Bh[0] = phh; a.Bl[0] = phl; a.sB = sAct;
      a.C0[0] = affh; a.sC = sAff;
      a.alpha = scl; a.Nn = 1024; a.K = 512;
      gemm_k<2,2,EPI_B16_SCALE,1><<<dim3(8,8,B_),256,0,stream>>>(a); }
    { GArgs a = GA();
      a.Ah[0] = affh; a.Ah[1] = affh; a.sA = sAff;
      a.Bh[0] = rhT; a.Bh[1] = psT; a.sB = sAct;
      a.C0[0] = acc1; a.C0[1] = acc2; a.sC = sAct;
      a.Nn = 512; a.K = 1024;
      if (i == 0) {
        gemm_k<1,1,EPI_ACC2_ST,1><<<dim3(8,8,B_),256,0,stream>>>(a);
      } else if (i < L_ - 1) {
        gemm_k<1,1,EPI_ACC2,1><<<dim3(8,8,B_),256,0,stream>>>(a);
      } else {
        a.C1[0] = bufA; a.C1[1] = bufA + SBel;   // inth (stream1|stream2)
        a.C1[2] = bufB; a.C1[3] = bufB + SBel;   // intl
        a.alpha = 0.25f;
        gemm_k<1,1,EPI_ACC2_SPLIT,1><<<dim3(8,8,B_),256,0,stream>>>(a);
      } }
  }

  // ---- stage-1 epilogue, both streams batched (z=2 / M=16384) ----
  { GArgs a = GA();
    a.Ah[0] = bufA; a.Al[0] = bufB; a.sA = SBel;
    a.Bh[0] = c_intT_h; a.Bl[0] = c_intT_l;
    a.C0[0] = accR; a.sC = SBel;
    a.bias[0] = F32P(11); a.Rv = in1f; a.Rv2 = in2f; a.NP = npart;
    a.Nn = 512; a.K = 512;
    gemm_k<2,2,EPI_F32_BIAS_R,1><<<dim3(64,4,2),256,0,stream>>>(a); }
  normalize(accR, 16, in12l, bufA, resfP);       // resh|resl (resf scratch)
  { GArgs a = GA();
    a.Ah[0] = in12l; a.Al[0] = bufA;
    a.Bh[0] = c_f1T_h; a.Bl[0] = c_f1T_l;
    a.C0[0] = bufB; a.C1[0] = bufC;              // hidh|hidl
    a.bias[0] = F32P(13); a.Nn = 512; a.K = 512;
    gemm_k<2,2,EPI_SPLIT_BIAS,1><<<dim3(128,4,1),256,0,stream>>>(a); }
  { GArgs a = GA();
    a.Ah[0] = bufB; a.Al[0] = bufC;
    a.Bh[0] = c_f2T_h; a.Bl[0] = c_f2T_l;
    a.C0[0] = in12h; a.C1[0] = feedfR;           // feed12b | feed12f
    a.bias[0] = F32P(15); a.Nn = 512; a.K = 512;
    gemm_k<2,2,EPI_BOTH_LEAKY,1><<<dim3(128,4,1),256,0,stream>>>(a); }

  // ---- a1/a2 weights: ONE merged dispatch ----
  {
    WcvtArgs wa; __builtin_memset(&wa, 0, sizeof(wa));
    int n = 0;
    auto addS = [&](const float* s, short* h, int nl) {
      for (int i = 0; i < nl; i++) {
        wa.src[n] = s + i * WD; wa.hi[n] = h + i * WD; wa.lo[n] = nullptr; n++;
      }
    };
    auto add2 = [&](const float* s, short* h, short* l) {
      wa.src[n] = s; wa.hi[n] = h; wa.lo[n] = l; n++;
    };
    addS(F32P(16), a1_thT, L_);
    addS(F32P(18), a1_phT, L_);
    addS(F32P(20), a1_rhT, L_);
    addS(F32P(28), a2_thT, L_);
    addS(F32P(30), a2_phT, L_);
    addS(F32P(32), a2_rhT, L_);
    add2(F32P(22), a1_intT_h, a1_intT_l);
    add2(F32P(24), a1_f1T_h, a1_f1T_l);
    add2(F32P(26), a1_f2T_h, a1_f2T_l);
    add2(F32P(34), a2_intT_h, a2_intT_l);
    add2(F32P(36), a2_f1T_h, a2_f1T_l);
    add2(F32P(38), a2_f2T_h, a2_f2T_l);
    wa.n = n;                                    // 30 slices
    wt_cvt_all<<<dim3(16, 16, n), tb, 0, stream>>>(wa);
  }

  // ---- generic agi chain ----
  auto agi = [&](int NZ, const short* xb, const float* xf,
                 const short* thT, const float* thB,
                 const short* phT, const float* phB,
                 const short* rhT_, const float* rhB,
                 const short* inTh, const short* inTl, const float* inB,
                 const short* f1Th, const short* f1Tl, const float* f1B,
                 const short* f2Th, const short* f2Tl, const float* f2B,
                 float* outf) {
    const int MB = NZ / B_;                  // 2 or 1 (stream multiplier)
    for (int i = 0; i < L_; i++) {
      const size_t wo = (size_t)i * D_ * D_;
      const size_t bo = (size_t)i * D_;
      { GArgs a = GA();
        a.Ah[0] = xb; a.Ah[1] = xb; a.Ah[2] = xb;
        a.Bh[0] = thT + wo; a.Bh[1] = phT + wo; a.Bh[2] = rhT_ + wo;
        a.C0[0] = bufA; a.C0[1] = bufB; a.C0[2] = bufC;
        a.bias[0] = thB + bo; a.bias[1] = phB + bo; a.bias[2] = rhB + bo;
        a.Nn = 512; a.K = 512;
        gemm_k<1,1,EPI_PROJ3,1><<<dim3(64*MB,12,1),256,0,stream>>>(a); }
      { GArgs a = GA();
        a.Ah[0] = bufA; a.sA = sAct; a.Bh[0] = bufB; a.sB = sAct;
        a.C0[0] = aff16; a.sC = sAff; a.alpha = scl; a.Nn = 1024; a.K = 512;
        gemm_k<1,1,EPI_B16_SCALE,1><<<dim3(8,8,NZ),256,0,stream>>>(a); }
      softmax_rows_b16<<<NZ * 256, 256, 0, stream>>>(aff16);
      { GArgs a = GA();
        a.Ah[0] = aff16; a.sA = sAff; a.Bh[0] = bufC; a.sB = sAct;
        a.C0[0] = accR; a.sC = sAct; a.Nn = 512; a.K = 1024;
        if (i == 0) {
          gemm_k<1,1,EPI_F32_ST,1><<<dim3(8,4,NZ),256,0,stream>>>(a);
        } else if (i < L_ - 1) {
          gemm_k<1,1,EPI_F32_ACC,1><<<dim3(8,4,NZ),256,0,stream>>>(a);
        } else {
          a.C1[0] = bufA; a.C1[1] = bufB; a.alpha = 0.25f;
          gemm_k<1,1,EPI_ACC_SPLIT,1><<<dim3(8,4,NZ),256,0,stream>>>(a);
        } }
    }
    { GArgs a = GA();
      a.Ah[0] = bufA; a.Al[0] = bufB;
      a.Bh[0] = inTh; a.Bl[0] = inTl;
      a.C0[0] = accR; a.bias[0] = inB; a.Rv = xf; a.Rv2 = xf; a.NP = npart;
      a.Nn = 512; a.K = 512;
      gemm_k<2,2,EPI_F32_BIAS_R,1><<<dim3(64*MB,4,1),256,0,stream>>>(a); }
    normalize(accR, NZ, in12l, bufC, resfP);     // resh|resl, resf -> affU
    { GArgs a = GA();
      a.Ah[0] = in12l; a.Al[0] = bufC;
      a.Bh[0] = f1Th; a.Bl[0] = f1Tl;
      a.C0[0] = bufA; a.C1[0] = bufB;            // hidh|hidl
      a.bias[0] = f1B; a.Nn = 512; a.K = 512;
      gemm_k<2,2,EPI_SPLIT_BIAS,1><<<dim3(64*MB,4,1),256,0,stream>>>(a); }
    { GArgs a = GA();
      a.Ah[0] = bufA; a.Al[0] = bufB;
      a.Bh[0] = f2Th; a.Bl[0] = f2Tl;
      a.C0[0] = accR; a.bias[0] = f2B; a.Rv = resfP; a.NP = npart;
      a.Nn = 512; a.K = 512;
      gemm_k<2,2,EPI_LEAKY_R,1><<<dim3(64*MB,4,1),256,0,stream>>>(a); }
    normalize(accR, NZ, bufA, bufB, outf);       // bf16 outs are scratch
  };

  // agi1 on feed1+feed2 as one batch-16 chain (shared AGI_1 weights)
  agi(16, in12h, feedfR,
      a1_thT, F32P(17), a1_phT, F32P(19), a1_rhT, F32P(21),
      a1_intT_h, a1_intT_l, F32P(23), a1_f1T_h, a1_f1T_l, F32P(25),
      a1_f2T_h, a1_f2T_l, F32P(27), feedfR);     // self12f -> feedfR

  add_both<<<GE, 256, 0, stream>>>(feedfR, feedfR + SBel, in12h, feedfR);

  agi(8, in12h, feedfR,
      a2_thT, F32P(29), a2_phT, F32P(31), a2_rhT, F32P(33),
      a2_intT_h, a2_intT_l, F32P(35), a2_f1T_h, a2_f1T_l, F32P(37),
      a2_f2T_h, a2_f2T_l, F32P(39), (float*)d_out);
}